// Round 1
// 659.663 us; speedup vs baseline: 1.1006x; 1.1006x over previous
//
#include <hip/hip_runtime.h>

// ---------------- constants ----------------
#define Bn 8
#define Sn 768
#define Hn 768
#define NHn 12
#define HDn 64
#define NLn 5

typedef unsigned short u16;
typedef __bf16 bf16x8 __attribute__((ext_vector_type(8)));
typedef short s16x8 __attribute__((ext_vector_type(8)));
typedef float f32x4 __attribute__((ext_vector_type(4)));
typedef unsigned short u16x4 __attribute__((ext_vector_type(4)));

static __device__ __forceinline__ float bf2f(u16 v) {
    return __uint_as_float(((unsigned)v) << 16);
}
static __device__ __forceinline__ u16 f2bf(float f) {
    unsigned u = __float_as_uint(f);
    unsigned r = u + 0x7fffu + ((u >> 16) & 1u);
    return (u16)(r >> 16);
}
static __device__ __forceinline__ bf16x8 ld8(const u16* p) {
    return *reinterpret_cast<const bf16x8*>(p);
}
static __device__ __forceinline__ void glds16(const u16* g, u16* l) {
    __builtin_amdgcn_global_load_lds(
        (const __attribute__((address_space(1))) void*)g,
        (__attribute__((address_space(3))) void*)l, 16, 0, 0);
}

// ---------------- merged f32 -> bf16 conversion (4 tensors) ----------------
__global__ __launch_bounds__(256) void k_f2b4(
    const float* __restrict__ s0, u16* __restrict__ d0, int n0,
    const float* __restrict__ s1, u16* __restrict__ d1, int n1,
    const float* __restrict__ s2, u16* __restrict__ d2, int n2,
    const float* __restrict__ s3, u16* __restrict__ d3, int n3)
{
    int i = blockIdx.x * 256 + threadIdx.x;
    const float* s; u16* d; int off;
    if (i < n0)                     { s = s0; d = d0; off = i; }
    else if (i < n0 + n1)           { s = s1; d = d1; off = i - n0; }
    else if (i < n0 + n1 + n2)      { s = s2; d = d2; off = i - n0 - n1; }
    else if (i < n0 + n1 + n2 + n3) { s = s3; d = d3; off = i - n0 - n1 - n2; }
    else return;
    float4 v = reinterpret_cast<const float4*>(s)[off];
    u16x4 o;
    o[0] = f2bf(v.x); o[1] = f2bf(v.y); o[2] = f2bf(v.z); o[3] = f2bf(v.w);
    reinterpret_cast<u16x4*>(d)[off] = o;
}

// transpose f32 HxH -> bf16 HxH (out[i,o] = in[o,i]).  grid (12,12,count)
__global__ __launch_bounds__(256) void k_transpose(
    const float* __restrict__ in, u16* __restrict__ out)
{
    __shared__ float T[64][65];
    const float* src = in + (size_t)blockIdx.z * Hn * Hn;
    u16* dst = out + (size_t)blockIdx.z * Hn * Hn;
    int i0 = blockIdx.x * 64, o0 = blockIdx.y * 64;
    int x = threadIdx.x & 63, ys = threadIdx.x >> 6;
    for (int r = ys; r < 64; r += 4)
        T[r][x] = src[(size_t)(o0 + r) * Hn + i0 + x];
    __syncthreads();
    for (int r = ys; r < 64; r += 4)
        dst[(size_t)(i0 + r) * Hn + o0 + x] = f2bf(T[x][r]);
}

// ------- 128x128 double-buffered NT GEMM core (256 thr, 4 waves) ---------
// C[m,n] = sum_k A[m,k]*B[n,k]; out bf16 / f32(+addres) / VT-layout.
__device__ __forceinline__ void gemm128(
    const u16* __restrict__ A, int lda,
    const u16* __restrict__ Bw, int ldb,
    const float* __restrict__ bias,
    const float* __restrict__ addres,
    u16* __restrict__ outH, float* __restrict__ outF,
    u16* __restrict__ outVT, int ldc,
    int K, int m0, int n0, float scale)
{
    __shared__ u16 As[2][128 * 32];
    __shared__ u16 Bs[2][128 * 32];
    const int tid = threadIdx.x;
    const int lane = tid & 63, wave = tid >> 6;
    const int lrow = lane & 15, lquad = lane >> 4;
    const int wm = (wave >> 1) * 64, wn = (wave & 1) * 64;

    const int s0 = tid, s1 = tid + 256;
    const u16* gA0 = A + (size_t)(m0 + (s0 >> 2)) * lda + (s0 & 3) * 8;
    const u16* gA1 = A + (size_t)(m0 + (s1 >> 2)) * lda + (s1 & 3) * 8;
    const u16* gB0 = Bw + (size_t)(n0 + (s0 >> 2)) * ldb + (s0 & 3) * 8;
    const u16* gB1 = Bw + (size_t)(n0 + (s1 >> 2)) * ldb + (s1 & 3) * 8;

    f32x4 z = {0.f, 0.f, 0.f, 0.f};
    f32x4 acc[4][4];
    #pragma unroll
    for (int i = 0; i < 4; ++i)
        #pragma unroll
        for (int j = 0; j < 4; ++j) acc[i][j] = z;

    const int NT = K >> 5;
    auto stage = [&](int buf, int k0) {
        glds16(gA0 + k0, &As[buf][s0 * 8]);
        glds16(gA1 + k0, &As[buf][s1 * 8]);
        glds16(gB0 + k0, &Bs[buf][s0 * 8]);
        glds16(gB1 + k0, &Bs[buf][s1 * 8]);
    };
    auto compute = [&](int buf) {
        bf16x8 af[4], bf_[4];
        #pragma unroll
        for (int i = 0; i < 4; ++i)
            af[i] = ld8(&As[buf][(wm + i * 16 + lrow) * 32 + lquad * 8]);
        #pragma unroll
        for (int j = 0; j < 4; ++j)
            bf_[j] = ld8(&Bs[buf][(wn + j * 16 + lrow) * 32 + lquad * 8]);
        #pragma unroll
        for (int i = 0; i < 4; ++i)
            #pragma unroll
            for (int j = 0; j < 4; ++j)
                acc[i][j] = __builtin_amdgcn_mfma_f32_16x16x32_bf16(af[i], bf_[j], acc[i][j], 0, 0, 0);
    };

    stage(0, 0);
    __syncthreads();
    for (int kt = 1; kt < NT; ++kt) {
        stage(kt & 1, kt * 32);
        compute((kt - 1) & 1);
        __syncthreads();
    }
    compute((NT - 1) & 1);

    #pragma unroll
    for (int i = 0; i < 4; ++i) {
        #pragma unroll
        for (int j = 0; j < 4; ++j) {
            int col = n0 + wn + j * 16 + lrow;
            float bv = bias ? bias[col] : 0.f;
            if (outVT) {
                // V^T layout: [b][h][d][s], 4 consecutive s per lane
                int row0 = m0 + wm + i * 16 + lquad * 4;
                int bb = row0 / Sn, s = row0 % Sn;
                int hh = col >> 6, dd = col & 63;
                u16x4 o;
                #pragma unroll
                for (int r = 0; r < 4; ++r) o[r] = f2bf((acc[i][j][r] + bv) * scale);
                *reinterpret_cast<u16x4*>(
                    outVT + (((size_t)bb * NHn + hh) * 64 + dd) * Sn + s) = o;
            } else {
                #pragma unroll
                for (int r = 0; r < 4; ++r) {
                    int row = m0 + wm + i * 16 + lquad * 4 + r;
                    float v = (acc[i][j][r] + bv) * scale;
                    if (addres) v += addres[(size_t)row * ldc + col];
                    if (outF) outF[(size_t)row * ldc + col] = v;
                    else      outH[(size_t)row * ldc + col] = f2bf(v);
                }
            }
        }
    }
}

// ---------------- GEMM wrapper kernels ----------------

// activation GEMM, M = 8*768.  grid (48, 6).
__global__ __launch_bounds__(256) void k_gemm_act(
    const u16* __restrict__ A, const u16* __restrict__ W5,
    const float* __restrict__ bias5, const int* __restrict__ lang,
    u16* __restrict__ out, float scale)
{
    int b = blockIdx.x / 6;
    int l = lang ? lang[b] : 0;
    gemm128(A, Hn, W5 + (size_t)l * Hn * Hn, Hn,
            bias5 + (size_t)l * Hn, nullptr, out, nullptr, nullptr, Hn, Hn,
            blockIdx.x * 128, blockIdx.y * 128, scale);
}

// V projection writing V^T layout.  grid (48, 6).
__global__ __launch_bounds__(256) void k_gemm_vt(
    const u16* __restrict__ A, const u16* __restrict__ W,
    const float* __restrict__ bias, u16* __restrict__ outVT)
{
    gemm128(A, Hn, W, Hn, bias, nullptr, nullptr, nullptr, outVT, Hn, Hn,
            blockIdx.x * 128, blockIdx.y * 128, 1.f);
}

// weight combine: out_z = NT(Afix, B + z*HH).  grid (6,6,5)
__global__ __launch_bounds__(256) void k_comb(
    const u16* __restrict__ Afix, const u16* __restrict__ B5,
    u16* __restrict__ out5)
{
    size_t off = (size_t)blockIdx.z * Hn * Hn;
    gemm128(Afix, Hn, B5 + off, Hn, nullptr, nullptr,
            out5 + off, nullptr, nullptr, Hn, Hn,
            blockIdx.x * 128, blockIdx.y * 128, 1.f);
}

// Y build: Y_z = NT(MT + z*HH, opwT).  grid (6,6,5)
__global__ __launch_bounds__(256) void k_ybuild(
    const u16* __restrict__ MT5, const u16* __restrict__ Bfix,
    u16* __restrict__ out5)
{
    size_t off = (size_t)blockIdx.z * Hn * Hn;
    gemm128(MT5 + off, Hn, Bfix, Hn, nullptr, nullptr,
            out5 + off, nullptr, nullptr, Hn, Hn,
            blockIdx.x * 128, blockIdx.y * 128, 1.f);
}

// final: x = NT(z, pjw) + projb + hidden(f32) -> f32 d_out.  grid (48,6)
__global__ __launch_bounds__(256) void k_xgemm(
    const u16* __restrict__ A, const u16* __restrict__ W,
    const float* __restrict__ bias, const float* __restrict__ hidden,
    float* __restrict__ x)
{
    gemm128(A, Hn, W, Hn, bias, hidden, nullptr, x, nullptr, Hn, Hn,
            blockIdx.x * 128, blockIdx.y * 128, 1.f);
}

// chain step: Pout_l = Pin_l @ F_j^T (F pre-converted bf16).  grid (6,6,5)
__global__ __launch_bounds__(256) void k_chain(
    const u16* __restrict__ Pin, u16* __restrict__ Pout,
    const u16* __restrict__ alignb, const int* __restrict__ lang, int j)
{
    int l = blockIdx.z;
    int lj = lang[j];
    const u16* Pl = Pin + (size_t)l * Hn * Hn;
    u16* Po = Pout + (size_t)l * Hn * Hn;
    int m0 = blockIdx.x * 128, n0 = blockIdx.y * 128;
    if (lj == l) {
        int tid = threadIdx.x;
        #pragma unroll
        for (int it = 0; it < 8; ++it) {
            int s = tid + 256 * it;            // 2048 segs of 8 elems
            int row = s >> 4, seg = s & 15;
            *reinterpret_cast<s16x8*>(Po + (size_t)(m0 + row) * Hn + n0 + seg * 8) =
                *reinterpret_cast<const s16x8*>(Pl + (size_t)(m0 + row) * Hn + n0 + seg * 8);
        }
    } else {
        const u16* F = alignb + ((size_t)l * NLn + lj) * Hn * Hn;
        gemm128(Pl, Hn, F, Hn, nullptr, nullptr,
                Po, nullptr, nullptr, Hn, Hn, m0, n0, 1.f);
    }
}

// identity init of MT (5 copies of I).  grid 11520, block 256
__global__ __launch_bounds__(256) void k_init_identity(u16* __restrict__ MT)
{
    size_t idx = (size_t)blockIdx.x * 256 + threadIdx.x;
    int row = (int)((idx / Hn) % Hn);
    int col = (int)(idx % Hn);
    MT[idx] = (row == col) ? (u16)0x3F80 : (u16)0;
}

// combined QK biases.  grid (3, 10), block 256
__global__ __launch_bounds__(256) void k_biasqk(
    const float* __restrict__ ipw, const float* __restrict__ ipb,
    const float* __restrict__ bq_lang, const float* __restrict__ bk_lang,
    float* __restrict__ beff)
{
    int o = blockIdx.x * 256 + threadIdx.x;
    int which = blockIdx.y / 5, l = blockIdx.y % 5;
    const float4* w = reinterpret_cast<const float4*>(ipw + (size_t)which * Hn * Hn + (size_t)o * Hn);
    const float4* bv = reinterpret_cast<const float4*>(((which ? bk_lang : bq_lang) + (size_t)l * Hn));
    float s = 0.f;
    for (int j = 0; j < Hn / 4; ++j) {
        float4 a = w[j], b = bv[j];
        s += a.x * b.x + a.y * b.y + a.z * b.z + a.w * b.w;
    }
    s += ipb[which * Hn + o];
    beff[(size_t)(which * 5 + l) * Hn + o] = s;
}

// opb_eff[l*H + n] = sum_k opb[k] * MT_l[n,k].  grid (3,5), block 256
__global__ __launch_bounds__(256) void k_opbeff(
    const float* __restrict__ opb, const u16* __restrict__ MT5,
    float* __restrict__ out)
{
    int n = blockIdx.x * 256 + threadIdx.x;
    int l = blockIdx.y;
    const u16* mt = MT5 + ((size_t)l * Hn + n) * Hn;
    float s = 0.f;
    for (int k = 0; k < Hn; k += 8) {
        s16x8 v = *reinterpret_cast<const s16x8*>(mt + k);
        #pragma unroll
        for (int j = 0; j < 8; ++j) s += opb[k + j] * bf2f((u16)v[j]);
    }
    out[(size_t)l * Hn + n] = s;
}

// ---------------- flash attention (V^T input) ----------------
// one block per (b, h, 64-query tile); online softmax.
// K double-buffered via glds16; V single LDS buffer, reg-staged (T14) so
// LDS = 33 KB -> 4 blocks/CU.  Q pre-scaled by 1/8 at projection time.
// grid (12, NH, B), block 256.
__global__ __launch_bounds__(256) void k_attn(
    const u16* __restrict__ Q, const u16* __restrict__ K,
    const u16* __restrict__ VT, u16* __restrict__ ctx)
{
    __shared__ u16 Ks[2][64 * 64];       // [key][d], seg-xor-swizzled
    __shared__ u16 Vs[64 * 64];          // [d][key], seg-xor-swizzled
    __shared__ u16 Pw[4][16 * 72];       // per-wave P, 16B-aligned stride

    const int bz = blockIdx.z, h = blockIdx.y, q0 = blockIdx.x * 64;
    const int tid = threadIdx.x;
    const int wave = tid >> 6, lane = tid & 63;
    const int lrow = lane & 15, lquad = lane >> 4;
    const int sw = lrow & 7;

    const u16* Qp = Q + ((size_t)(bz * Sn + q0 + wave * 16 + lrow)) * Hn + h * HDn;
    const u16* Kb = K + (size_t)bz * Sn * Hn + h * HDn;
    const u16* Vb = VT + ((size_t)(bz * NHn + h) * 64) * Sn;   // row d, stride Sn

    bf16x8 qa0 = ld8(Qp + lquad * 8);
    bf16x8 qa1 = ld8(Qp + 32 + lquad * 8);

    f32x4 z4 = {0.f, 0.f, 0.f, 0.f};
    float m_r[4], l_l[4];                // l_l: per-LANE partial denominators
    f32x4 oacc[4];
    #pragma unroll
    for (int r = 0; r < 4; ++r) { m_r[r] = -1e30f; l_l[r] = 0.f; }
    #pragma unroll
    for (int jd = 0; jd < 4; ++jd) oacc[jd] = z4;

    // V reg-staging addresses (same swizzled mapping as the old glds stage)
    const int vd0 = tid >> 3,        vp0 = (tid & 7) ^ (vd0 & 7);
    const int vd1 = (tid + 256) >> 3, vp1 = ((tid + 256) & 7) ^ (vd1 & 7);
    const u16* vg0 = Vb + (size_t)vd0 * Sn + vp0 * 8;
    const u16* vg1 = Vb + (size_t)vd1 * Sn + vp1 * 8;
    s16x8 vr0, vr1;

    auto vload = [&](int t0) {
        vr0 = *reinterpret_cast<const s16x8*>(vg0 + t0);
        vr1 = *reinterpret_cast<const s16x8*>(vg1 + t0);
    };
    auto vstore = [&]() {
        *reinterpret_cast<s16x8*>(&Vs[tid * 8]) = vr0;
        *reinterpret_cast<s16x8*>(&Vs[(tid + 256) * 8]) = vr1;
    };
    auto stageK = [&](int t0, int buf) {
        #pragma unroll
        for (int it = 0; it < 2; ++it) {
            int idx = tid + 256 * it;          // 512 16B segs
            int row = idx >> 3, p = idx & 7;
            glds16(Kb + (size_t)(t0 + row) * Hn + (p ^ (row & 7)) * 8,
                   &Ks[buf][idx * 8]);
        }
    };

    auto compute = [&](int buf) {
        // QK^T: this wave's 16 q-rows x 64 keys (Q already carries 1/8)
        f32x4 sc[4];
        __builtin_amdgcn_s_setprio(1);
        #pragma unroll
        for (int j = 0; j < 4; ++j) {
            int base = (j * 16 + lrow) * 64 + ((lquad ^ sw) * 8);
            f32x4 s = __builtin_amdgcn_mfma_f32_16x16x32_bf16(qa0, ld8(&Ks[buf][base]), z4, 0, 0, 0);
            sc[j] = __builtin_amdgcn_mfma_f32_16x16x32_bf16(qa1, ld8(&Ks[buf][base ^ 32]), s, 0, 0, 0);
        }
        __builtin_amdgcn_s_setprio(0);
        float tmax[4];
        #pragma unroll
        for (int r = 0; r < 4; ++r)
            tmax[r] = fmaxf(fmaxf(sc[0][r], sc[1][r]), fmaxf(sc[2][r], sc[3][r]));
        #pragma unroll
        for (int off = 1; off < 16; off <<= 1)
            #pragma unroll
            for (int r = 0; r < 4; ++r)
                tmax[r] = fmaxf(tmax[r], __shfl_xor(tmax[r], off));
        // defer-max: rescale only when the running max actually grows (exact)
        bool grow = (tmax[0] > m_r[0]) | (tmax[1] > m_r[1]) |
                    (tmax[2] > m_r[2]) | (tmax[3] > m_r[3]);
        if (grow) {
            #pragma unroll
            for (int r = 0; r < 4; ++r) {
                float mn = fmaxf(m_r[r], tmax[r]);
                float a = __expf(m_r[r] - mn);
                m_r[r] = mn;
                l_l[r] *= a;
                #pragma unroll
                for (int jd = 0; jd < 4; ++jd) oacc[jd][r] *= a;
            }
        }
        float ps[4] = {0.f, 0.f, 0.f, 0.f};
        #pragma unroll
        for (int j = 0; j < 4; ++j)
            #pragma unroll
            for (int r = 0; r < 4; ++r) {
                float p = __expf(sc[j][r] - m_r[r]);
                ps[r] += p;
                Pw[wave][(lquad * 4 + r) * 72 + j * 16 + lrow] = f2bf(p);
            }
        #pragma unroll
        for (int r = 0; r < 4; ++r) l_l[r] += ps[r];   // per-lane; reduce at end
        // PV: A = P[q][key], B = V^T[d][key]
        bf16x8 pa0 = ld8(&Pw[wave][lrow * 72 + lquad * 8]);
        bf16x8 pa1 = ld8(&Pw[wave][lrow * 72 + 32 + lquad * 8]);
        __builtin_amdgcn_s_setprio(1);
        #pragma unroll
        for (int jd = 0; jd < 4; ++jd) {
            int vbase = (jd * 16 + lrow) * 64 + ((lquad ^ sw) * 8);
            oacc[jd] = __builtin_amdgcn_mfma_f32_16x16x32_bf16(pa0, ld8(&Vs[vbase]), oacc[jd], 0, 0, 0);
            oacc[jd] = __builtin_amdgcn_mfma_f32_16x16x32_bf16(pa1, ld8(&Vs[vbase ^ 32]), oacc[jd], 0, 0, 0);
        }
        __builtin_amdgcn_s_setprio(0);
    };

    // prologue: K(0) -> Ks[0], V(0) -> regs -> Vs
    stageK(0, 0);
    vload(0);
    vstore();
    __syncthreads();
    for (int kt = 0; kt < 12; ++kt) {
        if (kt < 11) {
            vload((kt + 1) * 64);              // latency hidden under compute
            stageK((kt + 1) * 64, (kt + 1) & 1);
        }
        compute(kt & 1);
        if (kt < 11) {
            __syncthreads();                   // all waves done with Vs & K ready
            vstore();                          // Vs <- V(kt+1)
            __syncthreads();
        }
    }

    // final 16-lane reduction of the denominators (once, not per tile)
    #pragma unroll
    for (int off = 1; off < 16; off <<= 1)
        #pragma unroll
        for (int r = 0; r < 4; ++r)
            l_l[r] += __shfl_xor(l_l[r], off);

    float rl[4];
    #pragma unroll
    for (int r = 0; r < 4; ++r) rl[r] = 1.f / l_l[r];
    #pragma unroll
    for (int jd = 0; jd < 4; ++jd)
        #pragma unroll
        for (int r = 0; r < 4; ++r) {
            size_t row = (size_t)bz * Sn + q0 + wave * 16 + lquad * 4 + r;
            ctx[row * Hn + h * HDn + jd * 16 + lrow] = f2bf(oacc[jd][r] * rl[r]);
        }
}

// layernorm in-place on f32 d_out.  grid B*S, block 64
__global__ __launch_bounds__(64) void k_ln(
    float* x, const float* __restrict__ g, const float* __restrict__ beta)
{
    size_t row = blockIdx.x;
    float* xr = x + row * Hn;
    int lane = threadIdx.x;
    float v[12];
    float s = 0.f, ss = 0.f;
    #pragma unroll
    for (int i = 0; i < 12; ++i) {
        v[i] = xr[lane + i * 64];
        s += v[i];
        ss += v[i] * v[i];
    }
    #pragma unroll
    for (int off = 1; off < 64; off <<= 1) {
        s  += __shfl_xor(s, off);
        ss += __shfl_xor(ss, off);
    }
    float mu = s * (1.f / Hn);
    float var = ss * (1.f / Hn) - mu * mu;
    float inv = rsqrtf(var + 1e-5f);
    #pragma unroll
    for (int i = 0; i < 12; ++i) {
        int c = lane + i * 64;
        xr[c] = (v[i] - mu) * inv * g[c] + beta[c];
    }
}

// ---------------- launch ----------------
extern "C" void kernel_launch(void* const* d_in, const int* in_sizes, int n_in,
                              void* d_out, int out_size, void* d_ws, size_t ws_size,
                              hipStream_t stream)
{
    (void)in_sizes; (void)n_in; (void)out_size; (void)ws_size;

    const float* hidden  = (const float*)d_in[0];
    const int*   lang    = (const int*)d_in[1];
    const float* Wq_lang = (const float*)d_in[3];
    const float* bq_lang = (const float*)d_in[4];
    const float* Wk_lang = (const float*)d_in[5];
    const float* bk_lang = (const float*)d_in[6];
    const float* ipw     = (const float*)d_in[7];
    const float* ipb     = (const float*)d_in[8];
    const float* opw     = (const float*)d_in[9];
    const float* opb     = (const float*)d_in[10];
    const float* align   = (const float*)d_in[11];
    const float* projw   = (const float*)d_in[12];
    const float* projb   = (const float*)d_in[13];
    const float* ln_g    = (const float*)d_in[14];
    const float* ln_b    = (const float*)d_in[15];
    float* out = (float*)d_out;

    const size_t HH  = (size_t)Hn * Hn;          // 589824
    const size_t BSH = (size_t)Bn * Sn * Hn;     // 4718592
    const size_t LHH = (size_t)NLn * HH;         // 2949120
    const size_t AHH = (size_t)NLn * NLn * HH;   // 14745600

    u16* rA = (u16*)d_ws;        // hb -> ctx
    u16* rB = rA + BSH;          // Q -> z
    u16* rC = rB + BSH;          // WqT/WkT -> K -> MT ping
    u16* rD = rC + BSH;          // Weffq/Weffk -> V^T -> MT pong -> Y
    u16* ipwb = rD + BSH;        // wq|wk|wv bf16 (3*HH)
    u16* pjwb = ipwb + 3 * HH;   // HH
    u16* opwT = pjwb + HH;       // HH
    u16* alignb = opwT + HH;     // 25*HH bf16
    float* beff   = (float*)(alignb + AHH);   // 2*5*768 f32
    float* opbeff = beff + 10 * Hn;           // 5*768 f32

    dim3 gw(6, 6, 5), ga(48, 6);

    // conversions (merged: hidden, in_proj, proj_w, align) + transposes + bias folds
    {
        int n0 = (int)(BSH / 4), n1 = (int)(3 * HH / 4), n2 = (int)(HH / 4);
        int n3 = (int)(AHH / 4);
        k_f2b4<<<(unsigned)((n0 + n1 + n2 + n3 + 255) / 256), 256, 0, stream>>>(
            hidden, rA, n0, ipw, ipwb, n1, projw, pjwb, n2, align, alignb, n3);
    }
    k_transpose<<<dim3(12, 12, 1), 256, 0, stream>>>(opw, opwT);
    k_biasqk<<<dim3(3, 10), 256, 0, stream>>>(ipw, ipb, bq_lang, bk_lang, beff);

    // Weffq = wq @ Wq[l]  (WqT staged in rC, result in rD)
    k_transpose<<<dim3(12, 12, NLn), 256, 0, stream>>>(Wq_lang, rC);
    k_comb<<<gw, 256, 0, stream>>>(ipwb, rC, rD);
    // Q = (hb @ Weffq^T + beffq) * 1/8  -> rB   (fold attention scale into Q)
    k_gemm_act<<<ga, 256, 0, stream>>>(rA, rD, beff, lang, rB, 0.125f);
    // WkT into rC, Weffk -> rD
    k_transpose<<<dim3(12, 12, NLn), 256, 0, stream>>>(Wk_lang, rC);
    k_comb<<<gw, 256, 0, stream>>>(ipwb + HH, rC, rD);
    // K -> rC
    k_gemm_act<<<ga, 256, 0, stream>>>(rA, rD, beff + 5 * Hn, lang, rC, 1.f);
    // V^T -> rD
    k_gemm_vt<<<ga, 256, 0, stream>>>(rA, ipwb + 2 * HH, ipb + 2 * Hn, rD);

    // attention: ctx -> rA (hb dead)
    k_attn<<<dim3(12, NHn, Bn), 256, 0, stream>>>(rB, rC, rD, rA);

    // language chain in rC/rD (K, V^T dead), bf16 align operand, dbuf GEMM
    k_init_identity<<<(unsigned)(LHH / 256), 256, 0, stream>>>(rC);
    u16* Pin = rC;
    u16* Pout = rD;
    for (int j = Bn - 1; j >= 0; --j) {
        k_chain<<<gw, 256, 0, stream>>>(Pin, Pout, alignb, lang, j);
        u16* t = Pin; Pin = Pout; Pout = t;
    }
    // 8 steps -> MT final back in rC

    k_opbeff<<<dim3(3, NLn), 256, 0, stream>>>(opb, Pin, opbeff);
    // Y_l = MT_l @ opw -> rD
    k_ybuild<<<gw, 256, 0, stream>>>(Pin, opwT, rD);

    // z = ctx @ Y[lang]^T + opb_eff -> rB
    k_gemm_act<<<ga, 256, 0, stream>>>(rA, rD, opbeff, lang, rB, 1.f);
    // x = z @ projw^T + projb + hidden -> d_out (f32)
    k_xgemm<<<ga, 256, 0, stream>>>(rB, pjwb, projb, hidden, out);
    // layernorm in place
    k_ln<<<(unsigned)(Bn * Sn), 64, 0, stream>>>(out, ln_g, ln_b);
}

// Round 2
// 543.780 us; speedup vs baseline: 1.3351x; 1.2131x over previous
//
#include <hip/hip_runtime.h>

// ---------------- constants ----------------
#define Bn 8
#define Sn 768
#define Hn 768
#define NHn 12
#define HDn 64
#define NLn 5

typedef unsigned short u16;
typedef __bf16 bf16x8 __attribute__((ext_vector_type(8)));
typedef short s16x8 __attribute__((ext_vector_type(8)));
typedef float f32x4 __attribute__((ext_vector_type(4)));
typedef unsigned short u16x4 __attribute__((ext_vector_type(4)));

static __device__ __forceinline__ float bf2f(u16 v) {
    return __uint_as_float(((unsigned)v) << 16);
}
static __device__ __forceinline__ u16 f2bf(float f) {
    unsigned u = __float_as_uint(f);
    unsigned r = u + 0x7fffu + ((u >> 16) & 1u);
    return (u16)(r >> 16);
}
static __device__ __forceinline__ bf16x8 ld8(const u16* p) {
    return *reinterpret_cast<const bf16x8*>(p);
}
static __device__ __forceinline__ void glds16(const u16* g, u16* l) {
    __builtin_amdgcn_global_load_lds(
        (const __attribute__((address_space(1))) void*)g,
        (__attribute__((address_space(3))) void*)l, 16, 0, 0);
}

// ---------------- merged f32 -> bf16 conversion (3 tensors) ----------------
__global__ __launch_bounds__(256) void k_f2b3(
    const float* __restrict__ s0, u16* __restrict__ d0, int n0,
    const float* __restrict__ s1, u16* __restrict__ d1, int n1,
    const float* __restrict__ s2, u16* __restrict__ d2, int n2)
{
    int i = blockIdx.x * 256 + threadIdx.x;
    const float* s; u16* d; int off;
    if (i < n0)                { s = s0; d = d0; off = i; }
    else if (i < n0 + n1)      { s = s1; d = d1; off = i - n0; }
    else if (i < n0 + n1 + n2) { s = s2; d = d2; off = i - n0 - n1; }
    else return;
    float4 v = reinterpret_cast<const float4*>(s)[off];
    u16x4 o;
    o[0] = f2bf(v.x); o[1] = f2bf(v.y); o[2] = f2bf(v.z); o[3] = f2bf(v.w);
    reinterpret_cast<u16x4*>(d)[off] = o;
}

// single-tensor f32 -> bf16 (align matrices; runs after QKV frees scratch)
__global__ __launch_bounds__(256) void k_f2b1(
    const float* __restrict__ s, u16* __restrict__ d, int n)
{
    int i = blockIdx.x * 256 + threadIdx.x;
    if (i >= n) return;
    float4 v = reinterpret_cast<const float4*>(s)[i];
    u16x4 o;
    o[0] = f2bf(v.x); o[1] = f2bf(v.y); o[2] = f2bf(v.z); o[3] = f2bf(v.w);
    reinterpret_cast<u16x4*>(d)[i] = o;
}

// fused transpose f32 HxH -> bf16 HxH (out[i,o] = in[o,i]).
// grid (12,12,11): z<5 Wq -> S[z], z in 5..9 Wk -> S[z], z==10 opw -> opwT.
__global__ __launch_bounds__(256) void k_transpose11(
    const float* __restrict__ Wq, const float* __restrict__ Wk,
    const float* __restrict__ opw, u16* __restrict__ S, u16* __restrict__ opwT)
{
    __shared__ float T[64][65];
    const size_t HH = (size_t)Hn * Hn;
    int z = blockIdx.z;
    const float* src;
    u16* dst;
    if (z < 5)       { src = Wq + (size_t)z * HH;       dst = S + (size_t)z * HH; }
    else if (z < 10) { src = Wk + (size_t)(z - 5) * HH; dst = S + (size_t)z * HH; }
    else             { src = opw;                        dst = opwT; }
    int i0 = blockIdx.x * 64, o0 = blockIdx.y * 64;
    int x = threadIdx.x & 63, ys = threadIdx.x >> 6;
    for (int r = ys; r < 64; r += 4)
        T[r][x] = src[(size_t)(o0 + r) * Hn + i0 + x];
    __syncthreads();
    for (int r = ys; r < 64; r += 4)
        dst[(size_t)(i0 + r) * Hn + o0 + x] = f2bf(T[x][r]);
}

// ------- 128x128 double-buffered NT GEMM core (256 thr, 4 waves) ---------
// C[m,n] = sum_k A[m,k]*B[n,k]; out bf16 / f32(+addres) / VT-layout.
__device__ __forceinline__ void gemm128(
    const u16* __restrict__ A, int lda,
    const u16* __restrict__ Bw, int ldb,
    const float* __restrict__ bias,
    const float* __restrict__ addres,
    u16* __restrict__ outH, float* __restrict__ outF,
    u16* __restrict__ outVT, int ldc,
    int K, int m0, int n0, float scale)
{
    __shared__ u16 As[2][128 * 32];
    __shared__ u16 Bs[2][128 * 32];
    const int tid = threadIdx.x;
    const int lane = tid & 63, wave = tid >> 6;
    const int lrow = lane & 15, lquad = lane >> 4;
    const int wm = (wave >> 1) * 64, wn = (wave & 1) * 64;

    const int s0 = tid, s1 = tid + 256;
    const u16* gA0 = A + (size_t)(m0 + (s0 >> 2)) * lda + (s0 & 3) * 8;
    const u16* gA1 = A + (size_t)(m0 + (s1 >> 2)) * lda + (s1 & 3) * 8;
    const u16* gB0 = Bw + (size_t)(n0 + (s0 >> 2)) * ldb + (s0 & 3) * 8;
    const u16* gB1 = Bw + (size_t)(n0 + (s1 >> 2)) * ldb + (s1 & 3) * 8;

    f32x4 z = {0.f, 0.f, 0.f, 0.f};
    f32x4 acc[4][4];
    #pragma unroll
    for (int i = 0; i < 4; ++i)
        #pragma unroll
        for (int j = 0; j < 4; ++j) acc[i][j] = z;

    const int NT = K >> 5;
    auto stage = [&](int buf, int k0) {
        glds16(gA0 + k0, &As[buf][s0 * 8]);
        glds16(gA1 + k0, &As[buf][s1 * 8]);
        glds16(gB0 + k0, &Bs[buf][s0 * 8]);
        glds16(gB1 + k0, &Bs[buf][s1 * 8]);
    };
    auto compute = [&](int buf) {
        bf16x8 af[4], bf_[4];
        #pragma unroll
        for (int i = 0; i < 4; ++i)
            af[i] = ld8(&As[buf][(wm + i * 16 + lrow) * 32 + lquad * 8]);
        #pragma unroll
        for (int j = 0; j < 4; ++j)
            bf_[j] = ld8(&Bs[buf][(wn + j * 16 + lrow) * 32 + lquad * 8]);
        #pragma unroll
        for (int i = 0; i < 4; ++i)
            #pragma unroll
            for (int j = 0; j < 4; ++j)
                acc[i][j] = __builtin_amdgcn_mfma_f32_16x16x32_bf16(af[i], bf_[j], acc[i][j], 0, 0, 0);
    };

    stage(0, 0);
    __syncthreads();
    for (int kt = 1; kt < NT; ++kt) {
        stage(kt & 1, kt * 32);
        compute((kt - 1) & 1);
        __syncthreads();
    }
    compute((NT - 1) & 1);

    #pragma unroll
    for (int i = 0; i < 4; ++i) {
        #pragma unroll
        for (int j = 0; j < 4; ++j) {
            int col = n0 + wn + j * 16 + lrow;
            float bv = bias ? bias[col] : 0.f;
            if (outVT) {
                // V^T layout: [b][h][d][s], 4 consecutive s per lane
                int row0 = m0 + wm + i * 16 + lquad * 4;
                int bb = row0 / Sn, s = row0 % Sn;
                int hh = col >> 6, dd = col & 63;
                u16x4 o;
                #pragma unroll
                for (int r = 0; r < 4; ++r) o[r] = f2bf((acc[i][j][r] + bv) * scale);
                *reinterpret_cast<u16x4*>(
                    outVT + (((size_t)bb * NHn + hh) * 64 + dd) * Sn + s) = o;
            } else {
                #pragma unroll
                for (int r = 0; r < 4; ++r) {
                    int row = m0 + wm + i * 16 + lquad * 4 + r;
                    float v = (acc[i][j][r] + bv) * scale;
                    if (addres) v += addres[(size_t)row * ldc + col];
                    if (outF) outF[(size_t)row * ldc + col] = v;
                    else      outH[(size_t)row * ldc + col] = f2bf(v);
                }
            }
        }
    }
}

// ------- 64x64 double-buffered NT GEMM core (256 thr, 4 waves) ---------
// More blocks per grid -> better latency hiding for small weight GEMMs.
__device__ __forceinline__ void gemm64(
    const u16* __restrict__ A, const u16* __restrict__ Bw,
    u16* __restrict__ outH, int K, int m0, int n0)
{
    __shared__ u16 As[2][64 * 32];
    __shared__ u16 Bs[2][64 * 32];
    const int tid = threadIdx.x;
    const int lane = tid & 63, wave = tid >> 6;
    const int lrow = lane & 15, lquad = lane >> 4;
    const int wm = (wave >> 1) * 32, wn = (wave & 1) * 32;

    const int row = tid >> 2, seg = tid & 3;
    const u16* gA = A + (size_t)(m0 + row) * Hn + seg * 8;
    const u16* gB = Bw + (size_t)(n0 + row) * Hn + seg * 8;

    f32x4 z = {0.f, 0.f, 0.f, 0.f};
    f32x4 acc[2][2];
    #pragma unroll
    for (int i = 0; i < 2; ++i)
        #pragma unroll
        for (int j = 0; j < 2; ++j) acc[i][j] = z;

    const int NT = K >> 5;
    auto stage = [&](int buf, int k0) {
        glds16(gA + k0, &As[buf][tid * 8]);
        glds16(gB + k0, &Bs[buf][tid * 8]);
    };
    auto compute = [&](int buf) {
        bf16x8 af[2], bf_[2];
        #pragma unroll
        for (int i = 0; i < 2; ++i)
            af[i] = ld8(&As[buf][(wm + i * 16 + lrow) * 32 + lquad * 8]);
        #pragma unroll
        for (int j = 0; j < 2; ++j)
            bf_[j] = ld8(&Bs[buf][(wn + j * 16 + lrow) * 32 + lquad * 8]);
        #pragma unroll
        for (int i = 0; i < 2; ++i)
            #pragma unroll
            for (int j = 0; j < 2; ++j)
                acc[i][j] = __builtin_amdgcn_mfma_f32_16x16x32_bf16(af[i], bf_[j], acc[i][j], 0, 0, 0);
    };

    stage(0, 0);
    __syncthreads();
    for (int kt = 1; kt < NT; ++kt) {
        stage(kt & 1, kt * 32);
        compute((kt - 1) & 1);
        __syncthreads();
    }
    compute((NT - 1) & 1);

    #pragma unroll
    for (int i = 0; i < 2; ++i)
        #pragma unroll
        for (int j = 0; j < 2; ++j) {
            int col = n0 + wn + j * 16 + lrow;
            #pragma unroll
            for (int r = 0; r < 4; ++r) {
                int row_ = m0 + wm + i * 16 + lquad * 4 + r;
                outH[(size_t)row_ * Hn + col] = f2bf(acc[i][j][r]);
            }
        }
}

// ---------------- GEMM wrapper kernels ----------------

// fused QKV projection.  grid (48, 6, 3): z=0 Q, z=1 K, z=2 V(T layout).
__global__ __launch_bounds__(256) void k_gemm_qkv(
    const u16* __restrict__ A,
    const u16* __restrict__ Sq, const u16* __restrict__ Sk,
    const u16* __restrict__ Wv,
    const float* __restrict__ beff, const float* __restrict__ ipb,
    const int* __restrict__ lang,
    u16* __restrict__ outQ, u16* __restrict__ outK, u16* __restrict__ outVT)
{
    const size_t HH = (size_t)Hn * Hn;
    int z = blockIdx.z;
    int m0 = blockIdx.x * 128, n0 = blockIdx.y * 128;
    int l = lang[blockIdx.x / 6];
    if (z == 0) {
        gemm128(A, Hn, Sq + (size_t)l * HH, Hn, beff + (size_t)l * Hn,
                nullptr, outQ, nullptr, nullptr, Hn, Hn, m0, n0, 0.125f);
    } else if (z == 1) {
        gemm128(A, Hn, Sk + (size_t)l * HH, Hn, beff + (size_t)(5 + l) * Hn,
                nullptr, outK, nullptr, nullptr, Hn, Hn, m0, n0, 1.f);
    } else {
        gemm128(A, Hn, Wv, Hn, ipb + 2 * Hn,
                nullptr, nullptr, nullptr, outVT, Hn, Hn, m0, n0, 1.f);
    }
}

// activation GEMM (z = ctx @ Y[lang]^T + opb_eff).  grid (48, 6).
__global__ __launch_bounds__(256) void k_gemm_act(
    const u16* __restrict__ A, const u16* __restrict__ W5,
    const float* __restrict__ bias5, const int* __restrict__ lang,
    u16* __restrict__ out, float scale)
{
    int b = blockIdx.x / 6;
    int l = lang ? lang[b] : 0;
    gemm128(A, Hn, W5 + (size_t)l * Hn * Hn, Hn,
            bias5 + (size_t)l * Hn, nullptr, out, nullptr, nullptr, Hn, Hn,
            blockIdx.x * 128, blockIdx.y * 128, scale);
}

// fused weight combine: z<5: Weffq_z = NT(wq, WqT_z); z>=5: Weffk = NT(wk, WkT).
// inputs in S[z], outputs to S[10+z].  grid (6,6,10)
__global__ __launch_bounds__(256) void k_comb10(
    const u16* __restrict__ ipwb, u16* __restrict__ S)
{
    const size_t HH = (size_t)Hn * Hn;
    int z = blockIdx.z;
    const u16* Aop = ipwb + (z < 5 ? 0 : HH);
    gemm128(Aop, Hn, S + (size_t)z * HH, Hn, nullptr, nullptr,
            S + (size_t)(10 + z) * HH, nullptr, nullptr, Hn, Hn,
            blockIdx.x * 128, blockIdx.y * 128, 1.f);
}

// Y build: Y_z = NT(MT + z*HH, opwT).  grid (12,12,5), 64^2 tiles
__global__ __launch_bounds__(256) void k_ybuild64(
    const u16* __restrict__ MT5, const u16* __restrict__ Bfix,
    u16* __restrict__ out5)
{
    size_t off = (size_t)blockIdx.z * Hn * Hn;
    gemm64(MT5 + off, Bfix, out5 + off, Hn,
           blockIdx.x * 64, blockIdx.y * 64);
}

// final: x = NT(z, pjw) + projb + hidden(f32) -> f32 d_out.  grid (48,6)
__global__ __launch_bounds__(256) void k_xgemm(
    const u16* __restrict__ A, const u16* __restrict__ W,
    const float* __restrict__ bias, const float* __restrict__ hidden,
    float* __restrict__ x)
{
    gemm128(A, Hn, W, Hn, bias, hidden, nullptr, x, nullptr, Hn, Hn,
            blockIdx.x * 128, blockIdx.y * 128, 1.f);
}

// chain first step: MT0_l = F7^T (transpose of align bf16, or I).  grid (12,12,5)
__global__ __launch_bounds__(256) void k_chain_first(
    const u16* __restrict__ alignb, const int* __restrict__ lang,
    u16* __restrict__ out5)
{
    const size_t HH = (size_t)Hn * Hn;
    int l = blockIdx.z, lj = lang[Bn - 1];
    u16* dst = out5 + (size_t)l * HH;
    int i0 = blockIdx.x * 64, o0 = blockIdx.y * 64;
    const int tid = threadIdx.x;
    if (lj == l) {
        // identity tile
        #pragma unroll
        for (int it = 0; it < 2; ++it) {
            int s = tid + 256 * it;
            int ri = s >> 3, c8 = s & 7;
            s16x8 v;
            #pragma unroll
            for (int e = 0; e < 8; ++e)
                v[e] = (short)((i0 + ri == o0 + c8 * 8 + e) ? 0x3F80 : 0);
            *reinterpret_cast<s16x8*>(dst + (size_t)(i0 + ri) * Hn + o0 + c8 * 8) = v;
        }
    } else {
        const u16* src = alignb + ((size_t)l * NLn + lj) * HH;
        __shared__ u16 T[64][72];   // T[i][o] = src[o][i]
        #pragma unroll
        for (int it = 0; it < 2; ++it) {
            int s = tid + 256 * it;
            int r = s >> 3, c8 = s & 7;
            s16x8 v = *reinterpret_cast<const s16x8*>(
                src + (size_t)(o0 + r) * Hn + i0 + c8 * 8);
            #pragma unroll
            for (int e = 0; e < 8; ++e) T[c8 * 8 + e][r] = (u16)v[e];
        }
        __syncthreads();
        #pragma unroll
        for (int it = 0; it < 2; ++it) {
            int s = tid + 256 * it;
            int ri = s >> 3, c8 = s & 7;
            s16x8 v = *reinterpret_cast<const s16x8*>(&T[ri][c8 * 8]);
            *reinterpret_cast<s16x8*>(dst + (size_t)(i0 + ri) * Hn + o0 + c8 * 8) = v;
        }
    }
}

// chain step: Pout_l = Pin_l @ F_j^T.  grid (12,12,5), 64^2 tiles
__global__ __launch_bounds__(256) void k_chain64(
    const u16* __restrict__ Pin, u16* __restrict__ Pout,
    const u16* __restrict__ alignb, const int* __restrict__ lang, int j)
{
    const size_t HH = (size_t)Hn * Hn;
    int l = blockIdx.z;
    int lj = lang[j];
    const u16* Pl = Pin + (size_t)l * HH;
    u16* Po = Pout + (size_t)l * HH;
    int m0 = blockIdx.x * 64, n0 = blockIdx.y * 64;
    if (lj == l) {
        int tid = threadIdx.x;
        #pragma unroll
        for (int it = 0; it < 2; ++it) {
            int s = tid + 256 * it;            // 512 segs of 8 elems
            int row = s >> 3, seg = s & 7;
            *reinterpret_cast<s16x8*>(Po + (size_t)(m0 + row) * Hn + n0 + seg * 8) =
                *reinterpret_cast<const s16x8*>(Pl + (size_t)(m0 + row) * Hn + n0 + seg * 8);
        }
    } else {
        const u16* F = alignb + ((size_t)l * NLn + lj) * HH;
        gemm64(Pl, F, Po, Hn, m0, n0);
    }
}

// combined QK biases.  grid (3, 10), block 256
__global__ __launch_bounds__(256) void k_biasqk(
    const float* __restrict__ ipw, const float* __restrict__ ipb,
    const float* __restrict__ bq_lang, const float* __restrict__ bk_lang,
    float* __restrict__ beff)
{
    int o = blockIdx.x * 256 + threadIdx.x;
    int which = blockIdx.y / 5, l = blockIdx.y % 5;
    const float4* w = reinterpret_cast<const float4*>(ipw + (size_t)which * Hn * Hn + (size_t)o * Hn);
    const float4* bv = reinterpret_cast<const float4*>(((which ? bk_lang : bq_lang) + (size_t)l * Hn));
    float s = 0.f;
    for (int j = 0; j < Hn / 4; ++j) {
        float4 a = w[j], b = bv[j];
        s += a.x * b.x + a.y * b.y + a.z * b.z + a.w * b.w;
    }
    s += ipb[which * Hn + o];
    beff[(size_t)(which * 5 + l) * Hn + o] = s;
}

// opb_eff[l*H + n] = sum_k opb[k] * MT_l[n,k].  grid (3,5), block 256
__global__ __launch_bounds__(256) void k_opbeff(
    const float* __restrict__ opb, const u16* __restrict__ MT5,
    float* __restrict__ out)
{
    int n = blockIdx.x * 256 + threadIdx.x;
    int l = blockIdx.y;
    const u16* mt = MT5 + ((size_t)l * Hn + n) * Hn;
    float s = 0.f;
    for (int k = 0; k < Hn; k += 8) {
        s16x8 v = *reinterpret_cast<const s16x8*>(mt + k);
        #pragma unroll
        for (int j = 0; j < 8; ++j) s += opb[k + j] * bf2f((u16)v[j]);
    }
    out[(size_t)l * Hn + n] = s;
}

// ---------------- flash attention (V^T input) ----------------
// one block per (b, h, 64-query tile); online softmax.
// K double-buffered via glds16; V single LDS buffer, reg-staged (T14).
// Q pre-scaled by 1/8 at projection time.  grid (12, NH, B), block 256.
__global__ __launch_bounds__(256) void k_attn(
    const u16* __restrict__ Q, const u16* __restrict__ K,
    const u16* __restrict__ VT, u16* __restrict__ ctx)
{
    __shared__ u16 Ks[2][64 * 64];       // [key][d], seg-xor-swizzled
    __shared__ u16 Vs[64 * 64];          // [d][key], seg-xor-swizzled
    __shared__ u16 Pw[4][16 * 72];       // per-wave P, 16B-aligned stride

    const int bz = blockIdx.z, h = blockIdx.y, q0 = blockIdx.x * 64;
    const int tid = threadIdx.x;
    const int wave = tid >> 6, lane = tid & 63;
    const int lrow = lane & 15, lquad = lane >> 4;
    const int sw = lrow & 7;

    const u16* Qp = Q + ((size_t)(bz * Sn + q0 + wave * 16 + lrow)) * Hn + h * HDn;
    const u16* Kb = K + (size_t)bz * Sn * Hn + h * HDn;
    const u16* Vb = VT + ((size_t)(bz * NHn + h) * 64) * Sn;   // row d, stride Sn

    bf16x8 qa0 = ld8(Qp + lquad * 8);
    bf16x8 qa1 = ld8(Qp + 32 + lquad * 8);

    f32x4 z4 = {0.f, 0.f, 0.f, 0.f};
    float m_r[4], l_l[4];                // l_l: per-LANE partial denominators
    f32x4 oacc[4];
    #pragma unroll
    for (int r = 0; r < 4; ++r) { m_r[r] = -1e30f; l_l[r] = 0.f; }
    #pragma unroll
    for (int jd = 0; jd < 4; ++jd) oacc[jd] = z4;

    // V reg-staging addresses (swizzled mapping)
    const int vd0 = tid >> 3,        vp0 = (tid & 7) ^ (vd0 & 7);
    const int vd1 = (tid + 256) >> 3, vp1 = ((tid + 256) & 7) ^ (vd1 & 7);
    const u16* vg0 = Vb + (size_t)vd0 * Sn + vp0 * 8;
    const u16* vg1 = Vb + (size_t)vd1 * Sn + vp1 * 8;
    s16x8 vr0, vr1;

    auto vload = [&](int t0) {
        vr0 = *reinterpret_cast<const s16x8*>(vg0 + t0);
        vr1 = *reinterpret_cast<const s16x8*>(vg1 + t0);
    };
    auto vstore = [&]() {
        *reinterpret_cast<s16x8*>(&Vs[tid * 8]) = vr0;
        *reinterpret_cast<s16x8*>(&Vs[(tid + 256) * 8]) = vr1;
    };
    auto stageK = [&](int t0, int buf) {
        #pragma unroll
        for (int it = 0; it < 2; ++it) {
            int idx = tid + 256 * it;          // 512 16B segs
            int row = idx >> 3, p = idx & 7;
            glds16(Kb + (size_t)(t0 + row) * Hn + (p ^ (row & 7)) * 8,
                   &Ks[buf][idx * 8]);
        }
    };

    auto compute = [&](int buf) {
        // QK^T: this wave's 16 q-rows x 64 keys (Q already carries 1/8)
        f32x4 sc[4];
        __builtin_amdgcn_s_setprio(1);
        #pragma unroll
        for (int j = 0; j < 4; ++j) {
            int base = (j * 16 + lrow) * 64 + ((lquad ^ sw) * 8);
            f32x4 s = __builtin_amdgcn_mfma_f32_16x16x32_bf16(qa0, ld8(&Ks[buf][base]), z4, 0, 0, 0);
            sc[j] = __builtin_amdgcn_mfma_f32_16x16x32_bf16(qa1, ld8(&Ks[buf][base ^ 32]), s, 0, 0, 0);
        }
        __builtin_amdgcn_s_setprio(0);
        float tmax[4];
        #pragma unroll
        for (int r = 0; r < 4; ++r)
            tmax[r] = fmaxf(fmaxf(sc[0][r], sc[1][r]), fmaxf(sc[2][r], sc[3][r]));
        #pragma unroll
        for (int off = 1; off < 16; off <<= 1)
            #pragma unroll
            for (int r = 0; r < 4; ++r)
                tmax[r] = fmaxf(tmax[r], __shfl_xor(tmax[r], off));
        // defer-max: rescale only when the running max actually grows (exact)
        bool grow = (tmax[0] > m_r[0]) | (tmax[1] > m_r[1]) |
                    (tmax[2] > m_r[2]) | (tmax[3] > m_r[3]);
        if (grow) {
            #pragma unroll
            for (int r = 0; r < 4; ++r) {
                float mn = fmaxf(m_r[r], tmax[r]);
                float a = __expf(m_r[r] - mn);
                m_r[r] = mn;
                l_l[r] *= a;
                #pragma unroll
                for (int jd = 0; jd < 4; ++jd) oacc[jd][r] *= a;
            }
        }
        float ps[4] = {0.f, 0.f, 0.f, 0.f};
        #pragma unroll
        for (int j = 0; j < 4; ++j)
            #pragma unroll
            for (int r = 0; r < 4; ++r) {
                float p = __expf(sc[j][r] - m_r[r]);
                ps[r] += p;
                Pw[wave][(lquad * 4 + r) * 72 + j * 16 + lrow] = f2bf(p);
            }
        #pragma unroll
        for (int r = 0; r < 4; ++r) l_l[r] += ps[r];   // per-lane; reduce at end
        // PV: A = P[q][key], B = V^T[d][key]
        bf16x8 pa0 = ld8(&Pw[wave][lrow * 72 + lquad * 8]);
        bf16x8 pa1 = ld8(&Pw[wave][lrow * 72 + 32 + lquad * 8]);
        __builtin_amdgcn_s_setprio(1);
        #pragma unroll
        for (int jd = 0; jd < 4; ++jd) {
            int vbase = (jd * 16 + lrow) * 64 + ((lquad ^ sw) * 8);
            oacc[jd] = __builtin_amdgcn_mfma_f32_16x16x32_bf16(pa0, ld8(&Vs[vbase]), oacc[jd], 0, 0, 0);
            oacc[jd] = __builtin_amdgcn_mfma_f32_16x16x32_bf16(pa1, ld8(&Vs[vbase ^ 32]), oacc[jd], 0, 0, 0);
        }
        __builtin_amdgcn_s_setprio(0);
    };

    // prologue: K(0) -> Ks[0], V(0) -> regs -> Vs
    stageK(0, 0);
    vload(0);
    vstore();
    __syncthreads();
    for (int kt = 0; kt < 12; ++kt) {
        if (kt < 11) {
            vload((kt + 1) * 64);              // latency hidden under compute
            stageK((kt + 1) * 64, (kt + 1) & 1);
        }
        compute(kt & 1);
        if (kt < 11) {
            __syncthreads();                   // all waves done with Vs & K ready
            vstore();                          // Vs <- V(kt+1)
            __syncthreads();
        }
    }

    // final 16-lane reduction of the denominators (once, not per tile)
    #pragma unroll
    for (int off = 1; off < 16; off <<= 1)
        #pragma unroll
        for (int r = 0; r < 4; ++r)
            l_l[r] += __shfl_xor(l_l[r], off);

    float rl[4];
    #pragma unroll
    for (int r = 0; r < 4; ++r) rl[r] = 1.f / l_l[r];
    #pragma unroll
    for (int jd = 0; jd < 4; ++jd)
        #pragma unroll
        for (int r = 0; r < 4; ++r) {
            size_t row = (size_t)bz * Sn + q0 + wave * 16 + lquad * 4 + r;
            ctx[row * Hn + h * HDn + jd * 16 + lrow] = f2bf(oacc[jd][r] * rl[r]);
        }
}

// layernorm in-place on f32 d_out.  grid B*S, block 64
__global__ __launch_bounds__(64) void k_ln(
    float* x, const float* __restrict__ g, const float* __restrict__ beta)
{
    size_t row = blockIdx.x;
    float* xr = x + row * Hn;
    int lane = threadIdx.x;
    float v[12];
    float s = 0.f, ss = 0.f;
    #pragma unroll
    for (int i = 0; i < 12; ++i) {
        v[i] = xr[lane + i * 64];
        s += v[i];
        ss += v[i] * v[i];
    }
    #pragma unroll
    for (int off = 1; off < 64; off <<= 1) {
        s  += __shfl_xor(s, off);
        ss += __shfl_xor(ss, off);
    }
    float mu = s * (1.f / Hn);
    float var = ss * (1.f / Hn) - mu * mu;
    float inv = rsqrtf(var + 1e-5f);
    #pragma unroll
    for (int i = 0; i < 12; ++i) {
        int c = lane + i * 64;
        xr[c] = (v[i] - mu) * inv * g[c] + beta[c];
    }
}

// ---------------- launch ----------------
extern "C" void kernel_launch(void* const* d_in, const int* in_sizes, int n_in,
                              void* d_out, int out_size, void* d_ws, size_t ws_size,
                              hipStream_t stream)
{
    (void)in_sizes; (void)n_in; (void)out_size; (void)ws_size;

    const float* hidden  = (const float*)d_in[0];
    const int*   lang    = (const int*)d_in[1];
    const float* Wq_lang = (const float*)d_in[3];
    const float* bq_lang = (const float*)d_in[4];
    const float* Wk_lang = (const float*)d_in[5];
    const float* bk_lang = (const float*)d_in[6];
    const float* ipw     = (const float*)d_in[7];
    const float* ipb     = (const float*)d_in[8];
    const float* opw     = (const float*)d_in[9];
    const float* opb     = (const float*)d_in[10];
    const float* align   = (const float*)d_in[11];
    const float* projw   = (const float*)d_in[12];
    const float* projb   = (const float*)d_in[13];
    const float* ln_g    = (const float*)d_in[14];
    const float* ln_b    = (const float*)d_in[15];
    float* out = (float*)d_out;

    const size_t HH  = (size_t)Hn * Hn;          // 589824
    const size_t BSH = (size_t)Bn * Sn * Hn;     // 4718592
    const size_t AHH = (size_t)NLn * NLn * HH;   // 14745600

    u16* rA = (u16*)d_ws;        // hb -> ctx
    u16* rB = rA + BSH;          // Q -> z
    u16* rC = rB + BSH;          // K -> MT ping -> Y
    u16* rD = rC + BSH;          // V^T -> MT pong (final)
    u16* ipwb = rD + BSH;        // wq|wk|wv bf16 (3*HH)
    u16* pjwb = ipwb + 3 * HH;   // HH
    u16* opwT = pjwb + HH;       // HH
    u16* alignb = opwT + HH;     // 25*HH bf16; pre-attn: weight scratch S[0..20)
    float* beff   = (float*)(alignb + AHH);   // 2*5*768 f32
    float* opbeff = beff + 10 * Hn;           // 5*768 f32

    u16* S = alignb;             // scratch: WqT[0..5) WkT[5..10) Weffq[10..15) Weffk[15..20)

    // conversions (hidden, in_proj, proj_w) + fused transposes + bias folds
    {
        int n0 = (int)(BSH / 4), n1 = (int)(3 * HH / 4), n2 = (int)(HH / 4);
        k_f2b3<<<(unsigned)((n0 + n1 + n2 + 255) / 256), 256, 0, stream>>>(
            hidden, rA, n0, ipw, ipwb, n1, projw, pjwb, n2);
    }
    k_transpose11<<<dim3(12, 12, 11), 256, 0, stream>>>(Wq_lang, Wk_lang, opw, S, opwT);
    k_biasqk<<<dim3(3, 10), 256, 0, stream>>>(ipw, ipb, bq_lang, bk_lang, beff);

    // Weffq/Weffk (both in one launch) -> S[10..20)
    k_comb10<<<dim3(6, 6, 10), 256, 0, stream>>>(ipwb, S);

    // fused QKV: Q*(1/8) -> rB, K -> rC, V^T -> rD
    k_gemm_qkv<<<dim3(48, 6, 3), 256, 0, stream>>>(
        rA, S + 10 * HH, S + 15 * HH, ipwb + 2 * HH, beff, ipb, lang, rB, rC, rD);

    // align f32 -> bf16 (scratch S now dead)
    k_f2b1<<<(unsigned)(AHH / 4 / 256), 256, 0, stream>>>(align, alignb, (int)(AHH / 4));

    // attention: ctx -> rA (hb dead)
    k_attn<<<dim3(12, NHn, Bn), 256, 0, stream>>>(rB, rC, rD, rA);

    // language chain: first step is a transposing copy (MT0 = F7^T), then 7 GEMM steps
    k_chain_first<<<dim3(12, 12, NLn), 256, 0, stream>>>(alignb, lang, rC);
    u16* Pin = rC;
    u16* Pout = rD;
    for (int j = Bn - 2; j >= 0; --j) {
        k_chain64<<<dim3(12, 12, NLn), 256, 0, stream>>>(Pin, Pout, alignb, lang, j);
        u16* t = Pin; Pin = Pout; Pout = t;
    }
    // 7 steps -> final MT in rD (Pin == rD)

    k_opbeff<<<dim3(3, NLn), 256, 0, stream>>>(opb, Pin, opbeff);
    // Y_l = MT_l @ opw -> rC
    k_ybuild64<<<dim3(12, 12, NLn), 256, 0, stream>>>(Pin, opwT, Pout);

    // z = ctx @ Y[lang]^T + opb_eff -> rB
    k_gemm_act<<<dim3(48, 6), 256, 0, stream>>>(rA, Pout, opbeff, lang, rB, 1.f);
    // x = z @ projw^T + projb + hidden -> d_out (f32)
    k_xgemm<<<dim3(48, 6), 256, 0, stream>>>(rB, pjwb, projb, hidden, out);
    // layernorm in place
    k_ln<<<(unsigned)(Bn * Sn), 64, 0, stream>>>(out, ln_g, ln_b);
}

// Round 3
// 538.200 us; speedup vs baseline: 1.3490x; 1.0104x over previous
//
#include <hip/hip_runtime.h>

// ---------------- constants ----------------
#define Bn 8
#define Sn 768
#define Hn 768
#define NHn 12
#define HDn 64
#define NLn 5

typedef unsigned short u16;
typedef __bf16 bf16x8 __attribute__((ext_vector_type(8)));
typedef short s16x8 __attribute__((ext_vector_type(8)));
typedef float f32x4 __attribute__((ext_vector_type(4)));
typedef unsigned short u16x4 __attribute__((ext_vector_type(4)));

static __device__ __forceinline__ float bf2f(u16 v) {
    return __uint_as_float(((unsigned)v) << 16);
}
static __device__ __forceinline__ u16 f2bf(float f) {
    unsigned u = __float_as_uint(f);
    unsigned r = u + 0x7fffu + ((u >> 16) & 1u);
    return (u16)(r >> 16);
}
static __device__ __forceinline__ bf16x8 ld8(const u16* p) {
    return *reinterpret_cast<const bf16x8*>(p);
}
static __device__ __forceinline__ void glds16(const u16* g, u16* l) {
    __builtin_amdgcn_global_load_lds(
        (const __attribute__((address_space(1))) void*)g,
        (__attribute__((address_space(3))) void*)l, 16, 0, 0);
}

// ---------------- fused prep: f32->bf16 conversions + transposes + bias folds
// blocks [0, 6912): merged f2b of (hidden, in_proj_w, proj_w)
// blocks [6912, 8496): 11 transposes f32->bf16 (Wq x5 -> S, Wk x5 -> S, opw -> opwT)
// blocks [8496, 8526): combined QK bias GEMVs
#define PREP_NF2B 6912
#define PREP_NTR  1584
__global__ __launch_bounds__(256) void k_prep(
    const float* __restrict__ hidden, u16* __restrict__ hb,
    const float* __restrict__ ipw, u16* __restrict__ ipwb,
    const float* __restrict__ projw, u16* __restrict__ pjwb,
    const float* __restrict__ Wq, const float* __restrict__ Wk,
    const float* __restrict__ opw, u16* __restrict__ S, u16* __restrict__ opwT,
    const float* __restrict__ ipb,
    const float* __restrict__ bq_lang, const float* __restrict__ bk_lang,
    float* __restrict__ beff)
{
    __shared__ float T[64][65];
    const size_t HH = (size_t)Hn * Hn;
    const int bid = blockIdx.x, tid = threadIdx.x;
    if (bid < PREP_NF2B) {
        const int n0 = (int)(Bn * Sn * Hn / 4), n1 = (int)(3 * HH / 4), n2 = (int)(HH / 4);
        int i = bid * 256 + tid;
        const float* s; u16* d; int off;
        if (i < n0)                { s = hidden; d = hb;   off = i; }
        else if (i < n0 + n1)      { s = ipw;    d = ipwb; off = i - n0; }
        else if (i < n0 + n1 + n2) { s = projw;  d = pjwb; off = i - n0 - n1; }
        else return;
        float4 v = reinterpret_cast<const float4*>(s)[off];
        u16x4 o;
        o[0] = f2bf(v.x); o[1] = f2bf(v.y); o[2] = f2bf(v.z); o[3] = f2bf(v.w);
        reinterpret_cast<u16x4*>(d)[off] = o;
    } else if (bid < PREP_NF2B + PREP_NTR) {
        int b2 = bid - PREP_NF2B;
        int z = b2 / 144, r = b2 % 144;
        int bx = r % 12, by = r / 12;
        const float* src;
        u16* dst;
        if (z < 5)       { src = Wq + (size_t)z * HH;       dst = S + (size_t)z * HH; }
        else if (z < 10) { src = Wk + (size_t)(z - 5) * HH; dst = S + (size_t)z * HH; }
        else             { src = opw;                        dst = opwT; }
        int i0 = bx * 64, o0 = by * 64;
        int x = tid & 63, ys = tid >> 6;
        for (int rr = ys; rr < 64; rr += 4)
            T[rr][x] = src[(size_t)(o0 + rr) * Hn + i0 + x];
        __syncthreads();
        for (int rr = ys; rr < 64; rr += 4)
            dst[(size_t)(i0 + rr) * Hn + o0 + x] = f2bf(T[x][rr]);
    } else {
        int b3 = bid - PREP_NF2B - PREP_NTR;       // 0..29
        int ox = b3 % 3, y = b3 / 3;
        int o = ox * 256 + tid;
        int which = y / 5, l = y % 5;
        const float4* w = reinterpret_cast<const float4*>(ipw + (size_t)which * HH + (size_t)o * Hn);
        const float4* bv = reinterpret_cast<const float4*>(((which ? bk_lang : bq_lang) + (size_t)l * Hn));
        float s = 0.f;
        for (int j = 0; j < Hn / 4; ++j) {
            float4 a = w[j], b = bv[j];
            s += a.x * b.x + a.y * b.y + a.z * b.z + a.w * b.w;
        }
        s += ipb[which * Hn + o];
        beff[(size_t)(which * 5 + l) * Hn + o] = s;
    }
}

// single-tensor f32 -> bf16 (align matrices; runs after QKV frees scratch)
__global__ __launch_bounds__(256) void k_f2b1(
    const float* __restrict__ s, u16* __restrict__ d, int n)
{
    int i = blockIdx.x * 256 + threadIdx.x;
    if (i >= n) return;
    float4 v = reinterpret_cast<const float4*>(s)[i];
    u16x4 o;
    o[0] = f2bf(v.x); o[1] = f2bf(v.y); o[2] = f2bf(v.z); o[3] = f2bf(v.w);
    reinterpret_cast<u16x4*>(d)[i] = o;
}

// ------- 128x128 double-buffered NT GEMM core (256 thr, 4 waves) ---------
// C[m,n] = sum_k A[m,k]*B[n,k]; out bf16 / f32(+addres) / VT-layout.
__device__ __forceinline__ void gemm128(
    const u16* __restrict__ A, int lda,
    const u16* __restrict__ Bw, int ldb,
    const float* __restrict__ bias,
    const float* __restrict__ addres,
    u16* __restrict__ outH, float* __restrict__ outF,
    u16* __restrict__ outVT, int ldc,
    int K, int m0, int n0, float scale)
{
    __shared__ u16 As[2][128 * 32];
    __shared__ u16 Bs[2][128 * 32];
    const int tid = threadIdx.x;
    const int lane = tid & 63, wave = tid >> 6;
    const int lrow = lane & 15, lquad = lane >> 4;
    const int wm = (wave >> 1) * 64, wn = (wave & 1) * 64;

    const int s0 = tid, s1 = tid + 256;
    const u16* gA0 = A + (size_t)(m0 + (s0 >> 2)) * lda + (s0 & 3) * 8;
    const u16* gA1 = A + (size_t)(m0 + (s1 >> 2)) * lda + (s1 & 3) * 8;
    const u16* gB0 = Bw + (size_t)(n0 + (s0 >> 2)) * ldb + (s0 & 3) * 8;
    const u16* gB1 = Bw + (size_t)(n0 + (s1 >> 2)) * ldb + (s1 & 3) * 8;

    f32x4 z = {0.f, 0.f, 0.f, 0.f};
    f32x4 acc[4][4];
    #pragma unroll
    for (int i = 0; i < 4; ++i)
        #pragma unroll
        for (int j = 0; j < 4; ++j) acc[i][j] = z;

    const int NT = K >> 5;
    auto stage = [&](int buf, int k0) {
        glds16(gA0 + k0, &As[buf][s0 * 8]);
        glds16(gA1 + k0, &As[buf][s1 * 8]);
        glds16(gB0 + k0, &Bs[buf][s0 * 8]);
        glds16(gB1 + k0, &Bs[buf][s1 * 8]);
    };
    auto compute = [&](int buf) {
        bf16x8 af[4], bf_[4];
        #pragma unroll
        for (int i = 0; i < 4; ++i)
            af[i] = ld8(&As[buf][(wm + i * 16 + lrow) * 32 + lquad * 8]);
        #pragma unroll
        for (int j = 0; j < 4; ++j)
            bf_[j] = ld8(&Bs[buf][(wn + j * 16 + lrow) * 32 + lquad * 8]);
        #pragma unroll
        for (int i = 0; i < 4; ++i)
            #pragma unroll
            for (int j = 0; j < 4; ++j)
                acc[i][j] = __builtin_amdgcn_mfma_f32_16x16x32_bf16(af[i], bf_[j], acc[i][j], 0, 0, 0);
    };

    stage(0, 0);
    __syncthreads();
    for (int kt = 1; kt < NT; ++kt) {
        stage(kt & 1, kt * 32);
        compute((kt - 1) & 1);
        __syncthreads();
    }
    compute((NT - 1) & 1);

    #pragma unroll
    for (int i = 0; i < 4; ++i) {
        #pragma unroll
        for (int j = 0; j < 4; ++j) {
            int col = n0 + wn + j * 16 + lrow;
            float bv = bias ? bias[col] : 0.f;
            if (outVT) {
                // V^T layout: [b][h][d][s], 4 consecutive s per lane
                int row0 = m0 + wm + i * 16 + lquad * 4;
                int bb = row0 / Sn, s = row0 % Sn;
                int hh = col >> 6, dd = col & 63;
                u16x4 o;
                #pragma unroll
                for (int r = 0; r < 4; ++r) o[r] = f2bf((acc[i][j][r] + bv) * scale);
                *reinterpret_cast<u16x4*>(
                    outVT + (((size_t)bb * NHn + hh) * 64 + dd) * Sn + s) = o;
            } else {
                #pragma unroll
                for (int r = 0; r < 4; ++r) {
                    int row = m0 + wm + i * 16 + lquad * 4 + r;
                    float v = (acc[i][j][r] + bv) * scale;
                    if (addres) v += addres[(size_t)row * ldc + col];
                    if (outF) outF[(size_t)row * ldc + col] = v;
                    else      outH[(size_t)row * ldc + col] = f2bf(v);
                }
            }
        }
    }
}

// ------- 64x64 double-buffered NT GEMM core (256 thr, 4 waves) ---------
__device__ __forceinline__ void gemm64(
    const u16* __restrict__ A, const u16* __restrict__ Bw,
    u16* __restrict__ outH, int K, int m0, int n0)
{
    __shared__ u16 As[2][64 * 32];
    __shared__ u16 Bs[2][64 * 32];
    const int tid = threadIdx.x;
    const int lane = tid & 63, wave = tid >> 6;
    const int lrow = lane & 15, lquad = lane >> 4;
    const int wm = (wave >> 1) * 32, wn = (wave & 1) * 32;

    const int row = tid >> 2, seg = tid & 3;
    const u16* gA = A + (size_t)(m0 + row) * Hn + seg * 8;
    const u16* gB = Bw + (size_t)(n0 + row) * Hn + seg * 8;

    f32x4 z = {0.f, 0.f, 0.f, 0.f};
    f32x4 acc[2][2];
    #pragma unroll
    for (int i = 0; i < 2; ++i)
        #pragma unroll
        for (int j = 0; j < 2; ++j) acc[i][j] = z;

    const int NT = K >> 5;
    auto stage = [&](int buf, int k0) {
        glds16(gA + k0, &As[buf][tid * 8]);
        glds16(gB + k0, &Bs[buf][tid * 8]);
    };
    auto compute = [&](int buf) {
        bf16x8 af[2], bf_[2];
        #pragma unroll
        for (int i = 0; i < 2; ++i)
            af[i] = ld8(&As[buf][(wm + i * 16 + lrow) * 32 + lquad * 8]);
        #pragma unroll
        for (int j = 0; j < 2; ++j)
            bf_[j] = ld8(&Bs[buf][(wn + j * 16 + lrow) * 32 + lquad * 8]);
        #pragma unroll
        for (int i = 0; i < 2; ++i)
            #pragma unroll
            for (int j = 0; j < 2; ++j)
                acc[i][j] = __builtin_amdgcn_mfma_f32_16x16x32_bf16(af[i], bf_[j], acc[i][j], 0, 0, 0);
    };

    stage(0, 0);
    __syncthreads();
    for (int kt = 1; kt < NT; ++kt) {
        stage(kt & 1, kt * 32);
        compute((kt - 1) & 1);
        __syncthreads();
    }
    compute((NT - 1) & 1);

    #pragma unroll
    for (int i = 0; i < 2; ++i)
        #pragma unroll
        for (int j = 0; j < 2; ++j) {
            int col = n0 + wn + j * 16 + lrow;
            #pragma unroll
            for (int r = 0; r < 4; ++r) {
                int row_ = m0 + wm + i * 16 + lquad * 4 + r;
                outH[(size_t)row_ * Hn + col] = f2bf(acc[i][j][r]);
            }
        }
}

// ---------------- GEMM wrapper kernels ----------------

// fused QKV projection.  grid (48, 6, 3): z=0 Q, z=1 K, z=2 V(T layout).
__global__ __launch_bounds__(256) void k_gemm_qkv(
    const u16* __restrict__ A,
    const u16* __restrict__ Sq, const u16* __restrict__ Sk,
    const u16* __restrict__ Wv,
    const float* __restrict__ beff, const float* __restrict__ ipb,
    const int* __restrict__ lang,
    u16* __restrict__ outQ, u16* __restrict__ outK, u16* __restrict__ outVT)
{
    const size_t HH = (size_t)Hn * Hn;
    int z = blockIdx.z;
    int m0 = blockIdx.x * 128, n0 = blockIdx.y * 128;
    int l = lang[blockIdx.x / 6];
    if (z == 0) {
        gemm128(A, Hn, Sq + (size_t)l * HH, Hn, beff + (size_t)l * Hn,
                nullptr, outQ, nullptr, nullptr, Hn, Hn, m0, n0, 0.125f);
    } else if (z == 1) {
        gemm128(A, Hn, Sk + (size_t)l * HH, Hn, beff + (size_t)(5 + l) * Hn,
                nullptr, outK, nullptr, nullptr, Hn, Hn, m0, n0, 1.f);
    } else {
        gemm128(A, Hn, Wv, Hn, ipb + 2 * Hn,
                nullptr, nullptr, nullptr, outVT, Hn, Hn, m0, n0, 1.f);
    }
}

// fused weight combine: z<5: Weffq_z = NT(wq, WqT_z); z>=5: Weffk = NT(wk, WkT).
// inputs in S[z], outputs to S[10+z].  grid (6,6,10)
__global__ __launch_bounds__(256) void k_comb10(
    const u16* __restrict__ ipwb, u16* __restrict__ S)
{
    const size_t HH = (size_t)Hn * Hn;
    int z = blockIdx.z;
    const u16* Aop = ipwb + (z < 5 ? 0 : HH);
    gemm128(Aop, Hn, S + (size_t)z * HH, Hn, nullptr, nullptr,
            S + (size_t)(10 + z) * HH, nullptr, nullptr, Hn, Hn,
            blockIdx.x * 128, blockIdx.y * 128, 1.f);
}

// chain first step: MT0_l = F7^T (transpose of align bf16, or I).  grid (12,12,5)
__global__ __launch_bounds__(256) void k_chain_first(
    const u16* __restrict__ alignb, const int* __restrict__ lang,
    u16* __restrict__ out5)
{
    const size_t HH = (size_t)Hn * Hn;
    int l = blockIdx.z, lj = lang[Bn - 1];
    u16* dst = out5 + (size_t)l * HH;
    int i0 = blockIdx.x * 64, o0 = blockIdx.y * 64;
    const int tid = threadIdx.x;
    if (lj == l) {
        #pragma unroll
        for (int it = 0; it < 2; ++it) {
            int s = tid + 256 * it;
            int ri = s >> 3, c8 = s & 7;
            s16x8 v;
            #pragma unroll
            for (int e = 0; e < 8; ++e)
                v[e] = (short)((i0 + ri == o0 + c8 * 8 + e) ? 0x3F80 : 0);
            *reinterpret_cast<s16x8*>(dst + (size_t)(i0 + ri) * Hn + o0 + c8 * 8) = v;
        }
    } else {
        const u16* src = alignb + ((size_t)l * NLn + lj) * HH;
        __shared__ u16 T[64][72];   // T[i][o] = src[o][i]
        #pragma unroll
        for (int it = 0; it < 2; ++it) {
            int s = tid + 256 * it;
            int r = s >> 3, c8 = s & 7;
            s16x8 v = *reinterpret_cast<const s16x8*>(
                src + (size_t)(o0 + r) * Hn + i0 + c8 * 8);
            #pragma unroll
            for (int e = 0; e < 8; ++e) T[c8 * 8 + e][r] = (u16)v[e];
        }
        __syncthreads();
        #pragma unroll
        for (int it = 0; it < 2; ++it) {
            int s = tid + 256 * it;
            int ri = s >> 3, c8 = s & 7;
            s16x8 v = *reinterpret_cast<const s16x8*>(&T[ri][c8 * 8]);
            *reinterpret_cast<s16x8*>(dst + (size_t)(i0 + ri) * Hn + o0 + c8 * 8) = v;
        }
    }
}

// chain step: Pout_l = Pin_l @ F_j^T.  grid (12,12,5), 64^2 tiles
__global__ __launch_bounds__(256) void k_chain64(
    const u16* __restrict__ Pin, u16* __restrict__ Pout,
    const u16* __restrict__ alignb, const int* __restrict__ lang, int j)
{
    const size_t HH = (size_t)Hn * Hn;
    int l = blockIdx.z;
    int lj = lang[j];
    const u16* Pl = Pin + (size_t)l * HH;
    u16* Po = Pout + (size_t)l * HH;
    int m0 = blockIdx.x * 64, n0 = blockIdx.y * 64;
    if (lj == l) {
        int tid = threadIdx.x;
        #pragma unroll
        for (int it = 0; it < 2; ++it) {
            int s = tid + 256 * it;
            int row = s >> 3, seg = s & 7;
            *reinterpret_cast<s16x8*>(Po + (size_t)(m0 + row) * Hn + n0 + seg * 8) =
                *reinterpret_cast<const s16x8*>(Pl + (size_t)(m0 + row) * Hn + n0 + seg * 8);
        }
    } else {
        const u16* F = alignb + ((size_t)l * NLn + lj) * HH;
        gemm64(Pl, F, Po, Hn, m0, n0);
    }
}

// U_l = NT(opwT, MT_l)  (U[k,a] = sum_b opw[b,k] M_l[b,a])  + opb_eff GEMV.
// grid 735: [0,720) = gemm64 tiles (z = b/144), [720,735) = opbeff blocks.
__global__ __launch_bounds__(256) void k_uop(
    const u16* __restrict__ opwT, const u16* __restrict__ MT5,
    const float* __restrict__ opb,
    u16* __restrict__ U5, float* __restrict__ opbeff)
{
    const size_t HH = (size_t)Hn * Hn;
    int bid = blockIdx.x;
    if (bid < 720) {
        int z = bid / 144, r = bid % 144;
        gemm64(opwT, MT5 + (size_t)z * HH, U5 + (size_t)z * HH, Hn,
               (r % 12) * 64, (r / 12) * 64);
    } else {
        int b2 = bid - 720;
        int n = (b2 % 3) * 256 + threadIdx.x;
        int l = b2 / 3;
        const u16* mt = MT5 + ((size_t)l * Hn + n) * Hn;
        float s = 0.f;
        for (int k = 0; k < Hn; k += 8) {
            s16x8 v = *reinterpret_cast<const s16x8*>(mt + k);
            #pragma unroll
            for (int j = 0; j < 8; ++j) s += opb[k + j] * bf2f((u16)v[j]);
        }
        opbeff[(size_t)l * Hn + n] = s;
    }
}

// W_l = NT(projw, U_l)  + bias2_l[m] = sum_a opbeff[l,a]*projw[m,a] + projb[m].
// grid 735: [0,720) = gemm64 tiles, [720,735) = bias2 blocks.
__global__ __launch_bounds__(256) void k_wb2(
    const u16* __restrict__ pjwb, const u16* __restrict__ U5,
    const float* __restrict__ opbeff, const float* __restrict__ projw,
    const float* __restrict__ projb,
    u16* __restrict__ W5, float* __restrict__ bias2)
{
    const size_t HH = (size_t)Hn * Hn;
    int bid = blockIdx.x;
    if (bid < 720) {
        int z = bid / 144, r = bid % 144;
        gemm64(pjwb, U5 + (size_t)z * HH, W5 + (size_t)z * HH, Hn,
               (r % 12) * 64, (r / 12) * 64);
    } else {
        int b2 = bid - 720;
        int m = (b2 % 3) * 256 + threadIdx.x;
        int l = b2 / 3;
        const float4* w = reinterpret_cast<const float4*>(projw + (size_t)m * Hn);
        const float4* ob = reinterpret_cast<const float4*>(opbeff + (size_t)l * Hn);
        float s = 0.f;
        for (int j = 0; j < Hn / 4; ++j) {
            float4 a = w[j], b = ob[j];
            s += a.x * b.x + a.y * b.y + a.z * b.z + a.w * b.w;
        }
        bias2[(size_t)l * Hn + m] = s + projb[m];
    }
}

// x = NT(ctx, W[lang]) + bias2[lang] + hidden -> f32 out.  grid (48,6)
__global__ __launch_bounds__(256) void k_xfused(
    const u16* __restrict__ ctx, const u16* __restrict__ W5,
    const float* __restrict__ bias2, const int* __restrict__ lang,
    const float* __restrict__ hidden, float* __restrict__ x)
{
    int l = lang[blockIdx.x / 6];
    gemm128(ctx, Hn, W5 + (size_t)l * Hn * Hn, Hn, bias2 + (size_t)l * Hn,
            hidden, nullptr, x, nullptr, Hn, Hn,
            blockIdx.x * 128, blockIdx.y * 128, 1.f);
}

// ---------------- flash attention (V^T input), 512 threads ----------------
// one block per (b, h, 128-query tile); 8 waves x 16 q-rows; online softmax.
// K double-buffered via glds16; V single LDS buffer, reg-staged (T14).
// Q pre-scaled by 1/8 at projection time.  grid (6, NH, B), block 512.
__global__ __launch_bounds__(512) void k_attn(
    const u16* __restrict__ Q, const u16* __restrict__ K,
    const u16* __restrict__ VT, u16* __restrict__ ctx)
{
    __shared__ u16 Ks[2][64 * 64];       // [key][d], seg-xor-swizzled
    __shared__ u16 Vs[64 * 64];          // [d][key], seg-xor-swizzled
    __shared__ u16 Pw[8][16 * 72];       // per-wave P, 16B-aligned stride

    const int bz = blockIdx.z, h = blockIdx.y, q0 = blockIdx.x * 128;
    const int tid = threadIdx.x;
    const int wave = tid >> 6, lane = tid & 63;
    const int lrow = lane & 15, lquad = lane >> 4;
    const int sw = lrow & 7;

    const u16* Qp = Q + ((size_t)(bz * Sn + q0 + wave * 16 + lrow)) * Hn + h * HDn;
    const u16* Kb = K + (size_t)bz * Sn * Hn + h * HDn;
    const u16* Vb = VT + ((size_t)(bz * NHn + h) * 64) * Sn;   // row d, stride Sn

    bf16x8 qa0 = ld8(Qp + lquad * 8);
    bf16x8 qa1 = ld8(Qp + 32 + lquad * 8);

    f32x4 z4 = {0.f, 0.f, 0.f, 0.f};
    float m_r[4], l_l[4];                // l_l: per-LANE partial denominators
    f32x4 oacc[4];
    #pragma unroll
    for (int r = 0; r < 4; ++r) { m_r[r] = -1e30f; l_l[r] = 0.f; }
    #pragma unroll
    for (int jd = 0; jd < 4; ++jd) oacc[jd] = z4;

    // V reg-staging: one 16B seg per thread (512 segs = 64x64 tile)
    const int vd0 = tid >> 3, vp0 = (tid & 7) ^ (vd0 & 7);
    const u16* vg0 = Vb + (size_t)vd0 * Sn + vp0 * 8;
    s16x8 vr0;

    auto vload = [&](int t0) {
        vr0 = *reinterpret_cast<const s16x8*>(vg0 + t0);
    };
    auto vstore = [&]() {
        *reinterpret_cast<s16x8*>(&Vs[tid * 8]) = vr0;
    };
    auto stageK = [&](int t0, int buf) {
        int row = tid >> 3, p = tid & 7;        // 512 16B segs
        glds16(Kb + (size_t)(t0 + row) * Hn + (p ^ (row & 7)) * 8,
               &Ks[buf][tid * 8]);
    };

    auto compute = [&](int buf) {
        // QK^T: this wave's 16 q-rows x 64 keys (Q already carries 1/8)
        f32x4 sc[4];
        __builtin_amdgcn_s_setprio(1);
        #pragma unroll
        for (int j = 0; j < 4; ++j) {
            int base = (j * 16 + lrow) * 64 + ((lquad ^ sw) * 8);
            f32x4 s = __builtin_amdgcn_mfma_f32_16x16x32_bf16(qa0, ld8(&Ks[buf][base]), z4, 0, 0, 0);
            sc[j] = __builtin_amdgcn_mfma_f32_16x16x32_bf16(qa1, ld8(&Ks[buf][base ^ 32]), s, 0, 0, 0);
        }
        __builtin_amdgcn_s_setprio(0);
        float tmax[4];
        #pragma unroll
        for (int r = 0; r < 4; ++r)
            tmax[r] = fmaxf(fmaxf(sc[0][r], sc[1][r]), fmaxf(sc[2][r], sc[3][r]));
        #pragma unroll
        for (int off = 1; off < 16; off <<= 1)
            #pragma unroll
            for (int r = 0; r < 4; ++r)
                tmax[r] = fmaxf(tmax[r], __shfl_xor(tmax[r], off));
        // defer-max: rescale only when the running max actually grows (exact)
        bool grow = (tmax[0] > m_r[0]) | (tmax[1] > m_r[1]) |
                    (tmax[2] > m_r[2]) | (tmax[3] > m_r[3]);
        if (grow) {
            #pragma unroll
            for (int r = 0; r < 4; ++r) {
                float mn = fmaxf(m_r[r], tmax[r]);
                float a = __expf(m_r[r] - mn);
                m_r[r] = mn;
                l_l[r] *= a;
                #pragma unroll
                for (int jd = 0; jd < 4; ++jd) oacc[jd][r] *= a;
            }
        }
        float ps[4] = {0.f, 0.f, 0.f, 0.f};
        #pragma unroll
        for (int j = 0; j < 4; ++j)
            #pragma unroll
            for (int r = 0; r < 4; ++r) {
                float p = __expf(sc[j][r] - m_r[r]);
                ps[r] += p;
                Pw[wave][(lquad * 4 + r) * 72 + j * 16 + lrow] = f2bf(p);
            }
        #pragma unroll
        for (int r = 0; r < 4; ++r) l_l[r] += ps[r];   // per-lane; reduce at end
        // PV: A = P[q][key], B = V^T[d][key]
        bf16x8 pa0 = ld8(&Pw[wave][lrow * 72 + lquad * 8]);
        bf16x8 pa1 = ld8(&Pw[wave][lrow * 72 + 32 + lquad * 8]);
        __builtin_amdgcn_s_setprio(1);
        #pragma unroll
        for (int jd = 0; jd < 4; ++jd) {
            int vbase = (jd * 16 + lrow) * 64 + ((lquad ^ sw) * 8);
            oacc[jd] = __builtin_amdgcn_mfma_f32_16x16x32_bf16(pa0, ld8(&Vs[vbase]), oacc[jd], 0, 0, 0);
            oacc[jd] = __builtin_amdgcn_mfma_f32_16x16x32_bf16(pa1, ld8(&Vs[vbase ^ 32]), oacc[jd], 0, 0, 0);
        }
        __builtin_amdgcn_s_setprio(0);
    };

    // prologue: K(0) -> Ks[0], V(0) -> regs -> Vs
    stageK(0, 0);
    vload(0);
    vstore();
    __syncthreads();
    for (int kt = 0; kt < 12; ++kt) {
        if (kt < 11) {
            vload((kt + 1) * 64);              // latency hidden under compute
            stageK((kt + 1) * 64, (kt + 1) & 1);
        }
        compute(kt & 1);
        if (kt < 11) {
            __syncthreads();                   // all waves done with Vs & K ready
            vstore();                          // Vs <- V(kt+1)
            __syncthreads();
        }
    }

    // final 16-lane reduction of the denominators (once, not per tile)
    #pragma unroll
    for (int off = 1; off < 16; off <<= 1)
        #pragma unroll
        for (int r = 0; r < 4; ++r)
            l_l[r] += __shfl_xor(l_l[r], off);

    float rl[4];
    #pragma unroll
    for (int r = 0; r < 4; ++r) rl[r] = 1.f / l_l[r];
    #pragma unroll
    for (int jd = 0; jd < 4; ++jd)
        #pragma unroll
        for (int r = 0; r < 4; ++r) {
            size_t row = (size_t)bz * Sn + q0 + wave * 16 + lquad * 4 + r;
            ctx[row * Hn + h * HDn + jd * 16 + lrow] = f2bf(oacc[jd][r] * rl[r]);
        }
}

// layernorm in-place on f32 d_out.  grid B*S, block 64
__global__ __launch_bounds__(64) void k_ln(
    float* x, const float* __restrict__ g, const float* __restrict__ beta)
{
    size_t row = blockIdx.x;
    float* xr = x + row * Hn;
    int lane = threadIdx.x;
    float v[12];
    float s = 0.f, ss = 0.f;
    #pragma unroll
    for (int i = 0; i < 12; ++i) {
        v[i] = xr[lane + i * 64];
        s += v[i];
        ss += v[i] * v[i];
    }
    #pragma unroll
    for (int off = 1; off < 64; off <<= 1) {
        s  += __shfl_xor(s, off);
        ss += __shfl_xor(ss, off);
    }
    float mu = s * (1.f / Hn);
    float var = ss * (1.f / Hn) - mu * mu;
    float inv = rsqrtf(var + 1e-5f);
    #pragma unroll
    for (int i = 0; i < 12; ++i) {
        int c = lane + i * 64;
        xr[c] = (v[i] - mu) * inv * g[c] + beta[c];
    }
}

// ---------------- launch ----------------
extern "C" void kernel_launch(void* const* d_in, const int* in_sizes, int n_in,
                              void* d_out, int out_size, void* d_ws, size_t ws_size,
                              hipStream_t stream)
{
    (void)in_sizes; (void)n_in; (void)out_size; (void)ws_size;

    const float* hidden  = (const float*)d_in[0];
    const int*   lang    = (const int*)d_in[1];
    const float* Wq_lang = (const float*)d_in[3];
    const float* bq_lang = (const float*)d_in[4];
    const float* Wk_lang = (const float*)d_in[5];
    const float* bk_lang = (const float*)d_in[6];
    const float* ipw     = (const float*)d_in[7];
    const float* ipb     = (const float*)d_in[8];
    const float* opw     = (const float*)d_in[9];
    const float* opb     = (const float*)d_in[10];
    const float* align   = (const float*)d_in[11];
    const float* projw   = (const float*)d_in[12];
    const float* projb   = (const float*)d_in[13];
    const float* ln_g    = (const float*)d_in[14];
    const float* ln_b    = (const float*)d_in[15];
    float* out = (float*)d_out;

    const size_t HH  = (size_t)Hn * Hn;          // 589824
    const size_t BSH = (size_t)Bn * Sn * Hn;     // 4718592
    const size_t AHH = (size_t)NLn * NLn * HH;   // 14745600

    u16* rA = (u16*)d_ws;        // hb -> ctx
    u16* rB = rA + BSH;          // Q -> U
    u16* rC = rB + BSH;          // K -> MT ping -> W
    u16* rD = rC + BSH;          // V^T -> MT pong (final)
    u16* ipwb = rD + BSH;        // wq|wk|wv bf16 (3*HH)
    u16* pjwb = ipwb + 3 * HH;   // HH
    u16* opwT = pjwb + HH;       // HH
    u16* alignb = opwT + HH;     // 25*HH bf16; pre-attn: weight scratch S[0..20)
    float* beff   = (float*)(alignb + AHH);   // 2*5*768 f32
    float* opbeff = beff + 10 * Hn;           // 5*768 f32
    float* bias2  = opbeff + 5 * Hn;          // 5*768 f32

    u16* S = alignb;             // scratch: WqT[0..5) WkT[5..10) Weffq[10..15) Weffk[15..20)

    // fused prep: conversions + 11 transposes + QK bias folds (one launch)
    k_prep<<<(unsigned)(PREP_NF2B + PREP_NTR + 30), 256, 0, stream>>>(
        hidden, rA, ipw, ipwb, projw, pjwb,
        Wq_lang, Wk_lang, opw, S, opwT,
        ipb, bq_lang, bk_lang, beff);

    // Weffq/Weffk (both in one launch) -> S[10..20)
    k_comb10<<<dim3(6, 6, 10), 256, 0, stream>>>(ipwb, S);

    // fused QKV: Q*(1/8) -> rB, K -> rC, V^T -> rD
    k_gemm_qkv<<<dim3(48, 6, 3), 256, 0, stream>>>(
        rA, S + 10 * HH, S + 15 * HH, ipwb + 2 * HH, beff, ipb, lang, rB, rC, rD);

    // align f32 -> bf16 (scratch S now dead)
    k_f2b1<<<(unsigned)(AHH / 4 / 256), 256, 0, stream>>>(align, alignb, (int)(AHH / 4));

    // attention: ctx -> rA (hb dead).  128-row q-tiles, 512 threads.
    k_attn<<<dim3(6, NHn, Bn), 512, 0, stream>>>(rB, rC, rD, rA);

    // language chain: first step transposing copy (MT0 = F7^T), then 7 GEMM steps
    k_chain_first<<<dim3(12, 12, NLn), 256, 0, stream>>>(alignb, lang, rC);
    u16* Pin = rC;
    u16* Pout = rD;
    for (int j = Bn - 2; j >= 0; --j) {
        k_chain64<<<dim3(12, 12, NLn), 256, 0, stream>>>(Pin, Pout, alignb, lang, j);
        u16* t = Pin; Pin = Pout; Pout = t;
    }
    // 7 steps -> final MT in rD (Pin == rD)

    // U_l = opw^T . M_l  (+ opb_eff GEMV)  -> rB (Q dead)
    k_uop<<<735, 256, 0, stream>>>(opwT, Pin, opb, rB, opbeff);
    // W_l = projw . U_l  (+ bias2 GEMV)    -> rC (chain ping dead)
    k_wb2<<<735, 256, 0, stream>>>(pjwb, rB, opbeff, projw, projb, rC, bias2);

    // x = ctx . W[lang]^T + bias2 + hidden -> d_out (f32)
    k_xfused<<<dim3(48, 6), 256, 0, stream>>>(rA, rC, bias2, lang, hidden, out);
    // layernorm in place
    k_ln<<<(unsigned)(Bn * Sn), 64, 0, stream>>>(out, ln_g, ln_b);
}

// Round 4
// 513.919 us; speedup vs baseline: 1.4127x; 1.0472x over previous
//
#include <hip/hip_runtime.h>

// ---------------- constants ----------------
#define Bn 8
#define Sn 768
#define Hn 768
#define NHn 12
#define HDn 64
#define NLn 5

typedef unsigned short u16;
typedef __bf16 bf16x8 __attribute__((ext_vector_type(8)));
typedef short s16x8 __attribute__((ext_vector_type(8)));
typedef float f32x4 __attribute__((ext_vector_type(4)));
typedef unsigned short u16x4 __attribute__((ext_vector_type(4)));

static __device__ __forceinline__ float bf2f(u16 v) {
    return __uint_as_float(((unsigned)v) << 16);
}
static __device__ __forceinline__ u16 f2bf(float f) {
    unsigned u = __float_as_uint(f);
    unsigned r = u + 0x7fffu + ((u >> 16) & 1u);
    return (u16)(r >> 16);
}
static __device__ __forceinline__ bf16x8 ld8(const u16* p) {
    return *reinterpret_cast<const bf16x8*>(p);
}
static __device__ __forceinline__ void glds16(const u16* g, u16* l) {
    __builtin_amdgcn_global_load_lds(
        (const __attribute__((address_space(1))) void*)g,
        (__attribute__((address_space(3))) void*)l, 16, 0, 0);
}

// ---------------- fused prep: f32->bf16 conversions + transposes + bias folds
#define PREP_NF2B 6912
#define PREP_NTR  1584
__global__ __launch_bounds__(256) void k_prep(
    const float* __restrict__ hidden, u16* __restrict__ hb,
    const float* __restrict__ ipw, u16* __restrict__ ipwb,
    const float* __restrict__ projw, u16* __restrict__ pjwb,
    const float* __restrict__ Wq, const float* __restrict__ Wk,
    const float* __restrict__ opw, u16* __restrict__ S, u16* __restrict__ opwT,
    const float* __restrict__ ipb,
    const float* __restrict__ bq_lang, const float* __restrict__ bk_lang,
    float* __restrict__ beff)
{
    __shared__ float T[64][65];
    const size_t HH = (size_t)Hn * Hn;
    const int bid = blockIdx.x, tid = threadIdx.x;
    if (bid < PREP_NF2B) {
        const int n0 = (int)(Bn * Sn * Hn / 4), n1 = (int)(3 * HH / 4), n2 = (int)(HH / 4);
        int i = bid * 256 + tid;
        const float* s; u16* d; int off;
        if (i < n0)                { s = hidden; d = hb;   off = i; }
        else if (i < n0 + n1)      { s = ipw;    d = ipwb; off = i - n0; }
        else if (i < n0 + n1 + n2) { s = projw;  d = pjwb; off = i - n0 - n1; }
        else return;
        float4 v = reinterpret_cast<const float4*>(s)[off];
        u16x4 o;
        o[0] = f2bf(v.x); o[1] = f2bf(v.y); o[2] = f2bf(v.z); o[3] = f2bf(v.w);
        reinterpret_cast<u16x4*>(d)[off] = o;
    } else if (bid < PREP_NF2B + PREP_NTR) {
        int b2 = bid - PREP_NF2B;
        int z = b2 / 144, r = b2 % 144;
        int bx = r % 12, by = r / 12;
        const float* src;
        u16* dst;
        if (z < 5)       { src = Wq + (size_t)z * HH;       dst = S + (size_t)z * HH; }
        else if (z < 10) { src = Wk + (size_t)(z - 5) * HH; dst = S + (size_t)z * HH; }
        else             { src = opw;                        dst = opwT; }
        int i0 = bx * 64, o0 = by * 64;
        int x = tid & 63, ys = tid >> 6;
        for (int rr = ys; rr < 64; rr += 4)
            T[rr][x] = src[(size_t)(o0 + rr) * Hn + i0 + x];
        __syncthreads();
        for (int rr = ys; rr < 64; rr += 4)
            dst[(size_t)(i0 + rr) * Hn + o0 + x] = f2bf(T[x][rr]);
    } else {
        int b3 = bid - PREP_NF2B - PREP_NTR;       // 0..29
        int ox = b3 % 3, y = b3 / 3;
        int o = ox * 256 + tid;
        int which = y / 5, l = y % 5;
        const float4* w = reinterpret_cast<const float4*>(ipw + (size_t)which * HH + (size_t)o * Hn);
        const float4* bv = reinterpret_cast<const float4*>(((which ? bk_lang : bq_lang) + (size_t)l * Hn));
        float s = 0.f;
        for (int j = 0; j < Hn / 4; ++j) {
            float4 a = w[j], b = bv[j];
            s += a.x * b.x + a.y * b.y + a.z * b.z + a.w * b.w;
        }
        s += ipb[which * Hn + o];
        beff[(size_t)(which * 5 + l) * Hn + o] = s;
    }
}

// single-tensor f32 -> bf16 (align matrices; runs after QKV frees scratch)
__global__ __launch_bounds__(256) void k_f2b1(
    const float* __restrict__ s, u16* __restrict__ d, int n)
{
    int i = blockIdx.x * 256 + threadIdx.x;
    if (i >= n) return;
    float4 v = reinterpret_cast<const float4*>(s)[i];
    u16x4 o;
    o[0] = f2bf(v.x); o[1] = f2bf(v.y); o[2] = f2bf(v.z); o[3] = f2bf(v.w);
    reinterpret_cast<u16x4*>(d)[i] = o;
}

// ---- TM x 128 triple-buffered counted-vmcnt NT GEMM core (256 thr) ----
// C[m,n] = sum_k A[m,k]*B[n,k].  K = 768 (24 steps), 2-deep pipeline:
// per iter: [wait vmcnt(lps); s_barrier; stage(kt+2); compute(kt)].
// lps = loads/stage = TM/64 + 2.  Never drains to 0 until the tail.
template<int TM>
__device__ __forceinline__ void gemm_core(
    const u16* __restrict__ A, int lda,
    const u16* __restrict__ Bw, int ldb,
    const float* __restrict__ bias,
    const float* __restrict__ addres,
    u16* __restrict__ outH, float* __restrict__ outF,
    u16* __restrict__ outVT, int ldc,
    int m0, int n0, float scale)
{
    constexpr int MI = TM / 32;          // acc rows per wave (4 or 8)
    constexpr int AIT = TM / 64;         // A loads per thread (2 or 4)
    __shared__ u16 As[3 * TM * 32];
    __shared__ u16 Bs[3 * 128 * 32];
    const int tid = threadIdx.x;
    const int lane = tid & 63, wave = tid >> 6;
    const int lrow = lane & 15, lquad = lane >> 4;
    const int wm = (wave >> 1) * (TM / 2), wn = (wave & 1) * 64;

    // per-thread staging bases (row = s>>2, seg = s&3; s = tid + 256*it)
    const u16* gA = A + (size_t)(m0 + (tid >> 2)) * lda + (tid & 3) * 8;
    const u16* gB = Bw + (size_t)(n0 + (tid >> 2)) * ldb + (tid & 3) * 8;

    f32x4 z = {0.f, 0.f, 0.f, 0.f};
    f32x4 acc[MI][4];
    #pragma unroll
    for (int i = 0; i < MI; ++i)
        #pragma unroll
        for (int j = 0; j < 4; ++j) acc[i][j] = z;

    auto stage = [&](int bs, int k0) {
        #pragma unroll
        for (int it = 0; it < AIT; ++it)
            glds16(gA + (size_t)(it * 64) * lda + k0, &As[bs * TM * 32 + (tid + 256 * it) * 8]);
        #pragma unroll
        for (int it = 0; it < 2; ++it)
            glds16(gB + (size_t)(it * 64) * ldb + k0, &Bs[bs * 128 * 32 + (tid + 256 * it) * 8]);
    };
    auto compute = [&](int bc) {
        const u16* Ab = &As[bc * TM * 32];
        const u16* Bb = &Bs[bc * 128 * 32];
        bf16x8 af[MI], bf_[4];
        #pragma unroll
        for (int i = 0; i < MI; ++i)
            af[i] = ld8(&Ab[(wm + i * 16 + lrow) * 32 + lquad * 8]);
        #pragma unroll
        for (int j = 0; j < 4; ++j)
            bf_[j] = ld8(&Bb[(wn + j * 16 + lrow) * 32 + lquad * 8]);
        #pragma unroll
        for (int i = 0; i < MI; ++i)
            #pragma unroll
            for (int j = 0; j < 4; ++j)
                acc[i][j] = __builtin_amdgcn_mfma_f32_16x16x32_bf16(af[i], bf_[j], acc[i][j], 0, 0, 0);
    };

    stage(0, 0);
    stage(1, 32);
    int bc = 0, bs = 2;
    for (int kt = 0; kt < 24; ++kt) {
        if (kt < 23) {
            if constexpr (TM == 256) {
                asm volatile("s_waitcnt vmcnt(6)" ::: "memory");
            } else {
                asm volatile("s_waitcnt vmcnt(4)" ::: "memory");
            }
        } else {
            asm volatile("s_waitcnt vmcnt(0)" ::: "memory");
        }
        __builtin_amdgcn_s_barrier();
        if (kt < 22) {
            stage(bs, (kt + 2) * 32);
            bs = (bs == 2) ? 0 : bs + 1;
        }
        compute(bc);
        bc = (bc == 2) ? 0 : bc + 1;
    }

    #pragma unroll
    for (int i = 0; i < MI; ++i) {
        #pragma unroll
        for (int j = 0; j < 4; ++j) {
            int col = n0 + wn + j * 16 + lrow;
            float bv = bias ? bias[col] : 0.f;
            if (outVT) {
                int row0 = m0 + wm + i * 16 + lquad * 4;
                int bb = row0 / Sn, s = row0 % Sn;
                int hh = col >> 6, dd = col & 63;
                u16x4 o;
                #pragma unroll
                for (int r = 0; r < 4; ++r) o[r] = f2bf((acc[i][j][r] + bv) * scale);
                *reinterpret_cast<u16x4*>(
                    outVT + (((size_t)bb * NHn + hh) * 64 + dd) * Sn + s) = o;
            } else {
                #pragma unroll
                for (int r = 0; r < 4; ++r) {
                    int row = m0 + wm + i * 16 + lquad * 4 + r;
                    float v = (acc[i][j][r] + bv) * scale;
                    if (addres) v += addres[(size_t)row * ldc + col];
                    if (outF) outF[(size_t)row * ldc + col] = v;
                    else      outH[(size_t)row * ldc + col] = f2bf(v);
                }
            }
        }
    }
}

// ------- 64x64 triple-buffered counted-vmcnt NT GEMM core (256 thr) -------
__device__ __forceinline__ void gemm64(
    const u16* __restrict__ A, const u16* __restrict__ Bw,
    u16* __restrict__ outH, int m0, int n0)
{
    __shared__ u16 As[3 * 64 * 32];
    __shared__ u16 Bs[3 * 64 * 32];
    const int tid = threadIdx.x;
    const int lane = tid & 63, wave = tid >> 6;
    const int lrow = lane & 15, lquad = lane >> 4;
    const int wm = (wave >> 1) * 32, wn = (wave & 1) * 32;

    const u16* gA = A + (size_t)(m0 + (tid >> 2)) * Hn + (tid & 3) * 8;
    const u16* gB = Bw + (size_t)(n0 + (tid >> 2)) * Hn + (tid & 3) * 8;

    f32x4 z = {0.f, 0.f, 0.f, 0.f};
    f32x4 acc[2][2];
    #pragma unroll
    for (int i = 0; i < 2; ++i)
        #pragma unroll
        for (int j = 0; j < 2; ++j) acc[i][j] = z;

    auto stage = [&](int bs, int k0) {
        glds16(gA + k0, &As[bs * 64 * 32 + tid * 8]);
        glds16(gB + k0, &Bs[bs * 64 * 32 + tid * 8]);
    };
    auto compute = [&](int bc) {
        const u16* Ab = &As[bc * 64 * 32];
        const u16* Bb = &Bs[bc * 64 * 32];
        bf16x8 af[2], bf_[2];
        #pragma unroll
        for (int i = 0; i < 2; ++i)
            af[i] = ld8(&Ab[(wm + i * 16 + lrow) * 32 + lquad * 8]);
        #pragma unroll
        for (int j = 0; j < 2; ++j)
            bf_[j] = ld8(&Bb[(wn + j * 16 + lrow) * 32 + lquad * 8]);
        #pragma unroll
        for (int i = 0; i < 2; ++i)
            #pragma unroll
            for (int j = 0; j < 2; ++j)
                acc[i][j] = __builtin_amdgcn_mfma_f32_16x16x32_bf16(af[i], bf_[j], acc[i][j], 0, 0, 0);
    };

    stage(0, 0);
    stage(1, 32);
    int bc = 0, bs = 2;
    for (int kt = 0; kt < 24; ++kt) {
        if (kt < 23) {
            asm volatile("s_waitcnt vmcnt(2)" ::: "memory");
        } else {
            asm volatile("s_waitcnt vmcnt(0)" ::: "memory");
        }
        __builtin_amdgcn_s_barrier();
        if (kt < 22) {
            stage(bs, (kt + 2) * 32);
            bs = (bs == 2) ? 0 : bs + 1;
        }
        compute(bc);
        bc = (bc == 2) ? 0 : bc + 1;
    }

    #pragma unroll
    for (int i = 0; i < 2; ++i)
        #pragma unroll
        for (int j = 0; j < 2; ++j) {
            int col = n0 + wn + j * 16 + lrow;
            #pragma unroll
            for (int r = 0; r < 4; ++r) {
                int row_ = m0 + wm + i * 16 + lquad * 4 + r;
                outH[(size_t)row_ * Hn + col] = f2bf(acc[i][j][r]);
            }
        }
}

// ---------------- GEMM wrapper kernels ----------------

// fused QKV projection, 256-row tiles.  grid (24, 6, 3): z=0 Q, z=1 K, z=2 V(T).
__global__ __launch_bounds__(256, 2) void k_gemm_qkv(
    const u16* __restrict__ A,
    const u16* __restrict__ Sq, const u16* __restrict__ Sk,
    const u16* __restrict__ Wv,
    const float* __restrict__ beff, const float* __restrict__ ipb,
    const int* __restrict__ lang,
    u16* __restrict__ outQ, u16* __restrict__ outK, u16* __restrict__ outVT)
{
    const size_t HH = (size_t)Hn * Hn;
    int z = blockIdx.z;
    int m0 = blockIdx.x * 256, n0 = blockIdx.y * 128;
    int l = lang[blockIdx.x / 3];
    if (z == 0) {
        gemm_core<256>(A, Hn, Sq + (size_t)l * HH, Hn, beff + (size_t)l * Hn,
                       nullptr, outQ, nullptr, nullptr, Hn, m0, n0, 0.125f);
    } else if (z == 1) {
        gemm_core<256>(A, Hn, Sk + (size_t)l * HH, Hn, beff + (size_t)(5 + l) * Hn,
                       nullptr, outK, nullptr, nullptr, Hn, m0, n0, 1.f);
    } else {
        gemm_core<256>(A, Hn, Wv, Hn, ipb + 2 * Hn,
                       nullptr, nullptr, nullptr, outVT, Hn, m0, n0, 1.f);
    }
}

// fused weight combine: z<5: Weffq_z = NT(wq, WqT_z); z>=5: Weffk.  grid (6,6,10)
__global__ __launch_bounds__(256) void k_comb10(
    const u16* __restrict__ ipwb, u16* __restrict__ S)
{
    const size_t HH = (size_t)Hn * Hn;
    int z = blockIdx.z;
    const u16* Aop = ipwb + (z < 5 ? 0 : HH);
    gemm_core<128>(Aop, Hn, S + (size_t)z * HH, Hn, nullptr, nullptr,
                   S + (size_t)(10 + z) * HH, nullptr, nullptr, Hn,
                   blockIdx.x * 128, blockIdx.y * 128, 1.f);
}

// chain first step: MT0_l = F7^T (transpose of align bf16, or I).  grid (12,12,5)
__global__ __launch_bounds__(256) void k_chain_first(
    const u16* __restrict__ alignb, const int* __restrict__ lang,
    u16* __restrict__ out5)
{
    const size_t HH = (size_t)Hn * Hn;
    int l = blockIdx.z, lj = lang[Bn - 1];
    u16* dst = out5 + (size_t)l * HH;
    int i0 = blockIdx.x * 64, o0 = blockIdx.y * 64;
    const int tid = threadIdx.x;
    if (lj == l) {
        #pragma unroll
        for (int it = 0; it < 2; ++it) {
            int s = tid + 256 * it;
            int ri = s >> 3, c8 = s & 7;
            s16x8 v;
            #pragma unroll
            for (int e = 0; e < 8; ++e)
                v[e] = (short)((i0 + ri == o0 + c8 * 8 + e) ? 0x3F80 : 0);
            *reinterpret_cast<s16x8*>(dst + (size_t)(i0 + ri) * Hn + o0 + c8 * 8) = v;
        }
    } else {
        const u16* src = alignb + ((size_t)l * NLn + lj) * HH;
        __shared__ u16 T[64][72];   // T[i][o] = src[o][i]
        #pragma unroll
        for (int it = 0; it < 2; ++it) {
            int s = tid + 256 * it;
            int r = s >> 3, c8 = s & 7;
            s16x8 v = *reinterpret_cast<const s16x8*>(
                src + (size_t)(o0 + r) * Hn + i0 + c8 * 8);
            #pragma unroll
            for (int e = 0; e < 8; ++e) T[c8 * 8 + e][r] = (u16)v[e];
        }
        __syncthreads();
        #pragma unroll
        for (int it = 0; it < 2; ++it) {
            int s = tid + 256 * it;
            int ri = s >> 3, c8 = s & 7;
            s16x8 v = *reinterpret_cast<const s16x8*>(&T[ri][c8 * 8]);
            *reinterpret_cast<s16x8*>(dst + (size_t)(i0 + ri) * Hn + o0 + c8 * 8) = v;
        }
    }
}

// chain step: Pout_l = Pin_l @ F_j^T.  grid (12,12,5), 64^2 tiles
__global__ __launch_bounds__(256) void k_chain64(
    const u16* __restrict__ Pin, u16* __restrict__ Pout,
    const u16* __restrict__ alignb, const int* __restrict__ lang, int j)
{
    const size_t HH = (size_t)Hn * Hn;
    int l = blockIdx.z;
    int lj = lang[j];
    const u16* Pl = Pin + (size_t)l * HH;
    u16* Po = Pout + (size_t)l * HH;
    int m0 = blockIdx.x * 64, n0 = blockIdx.y * 64;
    if (lj == l) {
        int tid = threadIdx.x;
        #pragma unroll
        for (int it = 0; it < 2; ++it) {
            int s = tid + 256 * it;
            int row = s >> 3, seg = s & 7;
            *reinterpret_cast<s16x8*>(Po + (size_t)(m0 + row) * Hn + n0 + seg * 8) =
                *reinterpret_cast<const s16x8*>(Pl + (size_t)(m0 + row) * Hn + n0 + seg * 8);
        }
    } else {
        const u16* F = alignb + ((size_t)l * NLn + lj) * HH;
        gemm64(Pl, F, Po, m0, n0);
    }
}

// U_l = NT(opwT, MT_l) + opb_eff GEMV.  grid 735.
__global__ __launch_bounds__(256) void k_uop(
    const u16* __restrict__ opwT, const u16* __restrict__ MT5,
    const float* __restrict__ opb,
    u16* __restrict__ U5, float* __restrict__ opbeff)
{
    const size_t HH = (size_t)Hn * Hn;
    int bid = blockIdx.x;
    if (bid < 720) {
        int z = bid / 144, r = bid % 144;
        gemm64(opwT, MT5 + (size_t)z * HH, U5 + (size_t)z * HH,
               (r % 12) * 64, (r / 12) * 64);
    } else {
        int b2 = bid - 720;
        int n = (b2 % 3) * 256 + threadIdx.x;
        int l = b2 / 3;
        const u16* mt = MT5 + ((size_t)l * Hn + n) * Hn;
        float s = 0.f;
        for (int k = 0; k < Hn; k += 8) {
            s16x8 v = *reinterpret_cast<const s16x8*>(mt + k);
            #pragma unroll
            for (int j = 0; j < 8; ++j) s += opb[k + j] * bf2f((u16)v[j]);
        }
        opbeff[(size_t)l * Hn + n] = s;
    }
}

// W_l = NT(projw, U_l) + bias2 GEMV.  grid 735.
__global__ __launch_bounds__(256) void k_wb2(
    const u16* __restrict__ pjwb, const u16* __restrict__ U5,
    const float* __restrict__ opbeff, const float* __restrict__ projw,
    const float* __restrict__ projb,
    u16* __restrict__ W5, float* __restrict__ bias2)
{
    const size_t HH = (size_t)Hn * Hn;
    int bid = blockIdx.x;
    if (bid < 720) {
        int z = bid / 144, r = bid % 144;
        gemm64(pjwb, U5 + (size_t)z * HH, W5 + (size_t)z * HH,
               (r % 12) * 64, (r / 12) * 64);
    } else {
        int b2 = bid - 720;
        int m = (b2 % 3) * 256 + threadIdx.x;
        int l = b2 / 3;
        const float4* w = reinterpret_cast<const float4*>(projw + (size_t)m * Hn);
        const float4* ob = reinterpret_cast<const float4*>(opbeff + (size_t)l * Hn);
        float s = 0.f;
        for (int j = 0; j < Hn / 4; ++j) {
            float4 a = w[j], b = ob[j];
            s += a.x * b.x + a.y * b.y + a.z * b.z + a.w * b.w;
        }
        bias2[(size_t)l * Hn + m] = s + projb[m];
    }
}

// x = NT(ctx, W[lang]) + bias2[lang] + hidden -> f32 out.  grid (48,6)
__global__ __launch_bounds__(256) void k_xfused(
    const u16* __restrict__ ctx, const u16* __restrict__ W5,
    const float* __restrict__ bias2, const int* __restrict__ lang,
    const float* __restrict__ hidden, float* __restrict__ x)
{
    int l = lang[blockIdx.x / 6];
    gemm_core<128>(ctx, Hn, W5 + (size_t)l * Hn * Hn, Hn, bias2 + (size_t)l * Hn,
                   hidden, nullptr, x, nullptr, Hn,
                   blockIdx.x * 128, blockIdx.y * 128, 1.f);
}

// ---------------- flash attention (V^T input), 512 threads ----------------
__global__ __launch_bounds__(512) void k_attn(
    const u16* __restrict__ Q, const u16* __restrict__ K,
    const u16* __restrict__ VT, u16* __restrict__ ctx)
{
    __shared__ u16 Ks[2][64 * 64];       // [key][d], seg-xor-swizzled
    __shared__ u16 Vs[64 * 64];          // [d][key], seg-xor-swizzled
    __shared__ u16 Pw[8][16 * 72];       // per-wave P, 16B-aligned stride

    const int bz = blockIdx.z, h = blockIdx.y, q0 = blockIdx.x * 128;
    const int tid = threadIdx.x;
    const int wave = tid >> 6, lane = tid & 63;
    const int lrow = lane & 15, lquad = lane >> 4;
    const int sw = lrow & 7;

    const u16* Qp = Q + ((size_t)(bz * Sn + q0 + wave * 16 + lrow)) * Hn + h * HDn;
    const u16* Kb = K + (size_t)bz * Sn * Hn + h * HDn;
    const u16* Vb = VT + ((size_t)(bz * NHn + h) * 64) * Sn;   // row d, stride Sn

    bf16x8 qa0 = ld8(Qp + lquad * 8);
    bf16x8 qa1 = ld8(Qp + 32 + lquad * 8);

    f32x4 z4 = {0.f, 0.f, 0.f, 0.f};
    float m_r[4], l_l[4];
    f32x4 oacc[4];
    #pragma unroll
    for (int r = 0; r < 4; ++r) { m_r[r] = -1e30f; l_l[r] = 0.f; }
    #pragma unroll
    for (int jd = 0; jd < 4; ++jd) oacc[jd] = z4;

    const int vd0 = tid >> 3, vp0 = (tid & 7) ^ (vd0 & 7);
    const u16* vg0 = Vb + (size_t)vd0 * Sn + vp0 * 8;
    s16x8 vr0;

    auto vload = [&](int t0) {
        vr0 = *reinterpret_cast<const s16x8*>(vg0 + t0);
    };
    auto vstore = [&]() {
        *reinterpret_cast<s16x8*>(&Vs[tid * 8]) = vr0;
    };
    auto stageK = [&](int t0, int buf) {
        int row = tid >> 3, p = tid & 7;
        glds16(Kb + (size_t)(t0 + row) * Hn + (p ^ (row & 7)) * 8,
               &Ks[buf][tid * 8]);
    };

    auto compute = [&](int buf) {
        f32x4 sc[4];
        __builtin_amdgcn_s_setprio(1);
        #pragma unroll
        for (int j = 0; j < 4; ++j) {
            int base = (j * 16 + lrow) * 64 + ((lquad ^ sw) * 8);
            f32x4 s = __builtin_amdgcn_mfma_f32_16x16x32_bf16(qa0, ld8(&Ks[buf][base]), z4, 0, 0, 0);
            sc[j] = __builtin_amdgcn_mfma_f32_16x16x32_bf16(qa1, ld8(&Ks[buf][base ^ 32]), s, 0, 0, 0);
        }
        __builtin_amdgcn_s_setprio(0);
        float tmax[4];
        #pragma unroll
        for (int r = 0; r < 4; ++r)
            tmax[r] = fmaxf(fmaxf(sc[0][r], sc[1][r]), fmaxf(sc[2][r], sc[3][r]));
        #pragma unroll
        for (int off = 1; off < 16; off <<= 1)
            #pragma unroll
            for (int r = 0; r < 4; ++r)
                tmax[r] = fmaxf(tmax[r], __shfl_xor(tmax[r], off));
        bool grow = (tmax[0] > m_r[0]) | (tmax[1] > m_r[1]) |
                    (tmax[2] > m_r[2]) | (tmax[3] > m_r[3]);
        if (grow) {
            #pragma unroll
            for (int r = 0; r < 4; ++r) {
                float mn = fmaxf(m_r[r], tmax[r]);
                float a = __expf(m_r[r] - mn);
                m_r[r] = mn;
                l_l[r] *= a;
                #pragma unroll
                for (int jd = 0; jd < 4; ++jd) oacc[jd][r] *= a;
            }
        }
        float ps[4] = {0.f, 0.f, 0.f, 0.f};
        #pragma unroll
        for (int j = 0; j < 4; ++j)
            #pragma unroll
            for (int r = 0; r < 4; ++r) {
                float p = __expf(sc[j][r] - m_r[r]);
                ps[r] += p;
                Pw[wave][(lquad * 4 + r) * 72 + j * 16 + lrow] = f2bf(p);
            }
        #pragma unroll
        for (int r = 0; r < 4; ++r) l_l[r] += ps[r];
        bf16x8 pa0 = ld8(&Pw[wave][lrow * 72 + lquad * 8]);
        bf16x8 pa1 = ld8(&Pw[wave][lrow * 72 + 32 + lquad * 8]);
        __builtin_amdgcn_s_setprio(1);
        #pragma unroll
        for (int jd = 0; jd < 4; ++jd) {
            int vbase = (jd * 16 + lrow) * 64 + ((lquad ^ sw) * 8);
            oacc[jd] = __builtin_amdgcn_mfma_f32_16x16x32_bf16(pa0, ld8(&Vs[vbase]), oacc[jd], 0, 0, 0);
            oacc[jd] = __builtin_amdgcn_mfma_f32_16x16x32_bf16(pa1, ld8(&Vs[vbase ^ 32]), oacc[jd], 0, 0, 0);
        }
        __builtin_amdgcn_s_setprio(0);
    };

    stageK(0, 0);
    vload(0);
    vstore();
    __syncthreads();
    for (int kt = 0; kt < 12; ++kt) {
        if (kt < 11) {
            vload((kt + 1) * 64);
            stageK((kt + 1) * 64, (kt + 1) & 1);
        }
        compute(kt & 1);
        if (kt < 11) {
            __syncthreads();
            vstore();
            __syncthreads();
        }
    }

    #pragma unroll
    for (int off = 1; off < 16; off <<= 1)
        #pragma unroll
        for (int r = 0; r < 4; ++r)
            l_l[r] += __shfl_xor(l_l[r], off);

    float rl[4];
    #pragma unroll
    for (int r = 0; r < 4; ++r) rl[r] = 1.f / l_l[r];
    #pragma unroll
    for (int jd = 0; jd < 4; ++jd)
        #pragma unroll
        for (int r = 0; r < 4; ++r) {
            size_t row = (size_t)bz * Sn + q0 + wave * 16 + lquad * 4 + r;
            ctx[row * Hn + h * HDn + jd * 16 + lrow] = f2bf(oacc[jd][r] * rl[r]);
        }
}

// layernorm in-place on f32 d_out.  grid B*S, block 64
__global__ __launch_bounds__(64) void k_ln(
    float* x, const float* __restrict__ g, const float* __restrict__ beta)
{
    size_t row = blockIdx.x;
    float* xr = x + row * Hn;
    int lane = threadIdx.x;
    float v[12];
    float s = 0.f, ss = 0.f;
    #pragma unroll
    for (int i = 0; i < 12; ++i) {
        v[i] = xr[lane + i * 64];
        s += v[i];
        ss += v[i] * v[i];
    }
    #pragma unroll
    for (int off = 1; off < 64; off <<= 1) {
        s  += __shfl_xor(s, off);
        ss += __shfl_xor(ss, off);
    }
    float mu = s * (1.f / Hn);
    float var = ss * (1.f / Hn) - mu * mu;
    float inv = rsqrtf(var + 1e-5f);
    #pragma unroll
    for (int i = 0; i < 12; ++i) {
        int c = lane + i * 64;
        xr[c] = (v[i] - mu) * inv * g[c] + beta[c];
    }
}

// ---------------- launch ----------------
extern "C" void kernel_launch(void* const* d_in, const int* in_sizes, int n_in,
                              void* d_out, int out_size, void* d_ws, size_t ws_size,
                              hipStream_t stream)
{
    (void)in_sizes; (void)n_in; (void)out_size; (void)ws_size;

    const float* hidden  = (const float*)d_in[0];
    const int*   lang    = (const int*)d_in[1];
    const float* Wq_lang = (const float*)d_in[3];
    const float* bq_lang = (const float*)d_in[4];
    const float* Wk_lang = (const float*)d_in[5];
    const float* bk_lang = (const float*)d_in[6];
    const float* ipw     = (const float*)d_in[7];
    const float* ipb     = (const float*)d_in[8];
    const float* opw     = (const float*)d_in[9];
    const float* opb     = (const float*)d_in[10];
    const float* align   = (const float*)d_in[11];
    const float* projw   = (const float*)d_in[12];
    const float* projb   = (const float*)d_in[13];
    const float* ln_g    = (const float*)d_in[14];
    const float* ln_b    = (const float*)d_in[15];
    float* out = (float*)d_out;

    const size_t HH  = (size_t)Hn * Hn;          // 589824
    const size_t BSH = (size_t)Bn * Sn * Hn;     // 4718592
    const size_t AHH = (size_t)NLn * NLn * HH;   // 14745600

    u16* rA = (u16*)d_ws;        // hb -> ctx
    u16* rB = rA + BSH;          // Q -> U
    u16* rC = rB + BSH;          // K -> MT ping -> W
    u16* rD = rC + BSH;          // V^T -> MT pong (final)
    u16* ipwb = rD + BSH;        // wq|wk|wv bf16 (3*HH)
    u16* pjwb = ipwb + 3 * HH;   // HH
    u16* opwT = pjwb + HH;       // HH
    u16* alignb = opwT + HH;     // 25*HH bf16; pre-attn: weight scratch S[0..20)
    float* beff   = (float*)(alignb + AHH);   // 2*5*768 f32
    float* opbeff = beff + 10 * Hn;           // 5*768 f32
    float* bias2  = opbeff + 5 * Hn;          // 5*768 f32

    u16* S = alignb;             // scratch: WqT[0..5) WkT[5..10) Weffq[10..15) Weffk[15..20)

    // fused prep: conversions + 11 transposes + QK bias folds (one launch)
    k_prep<<<(unsigned)(PREP_NF2B + PREP_NTR + 30), 256, 0, stream>>>(
        hidden, rA, ipw, ipwb, projw, pjwb,
        Wq_lang, Wk_lang, opw, S, opwT,
        ipb, bq_lang, bk_lang, beff);

    // Weffq/Weffk (both in one launch) -> S[10..20)
    k_comb10<<<dim3(6, 6, 10), 256, 0, stream>>>(ipwb, S);

    // fused QKV: Q*(1/8) -> rB, K -> rC, V^T -> rD.  256-row tiles.
    k_gemm_qkv<<<dim3(24, 6, 3), 256, 0, stream>>>(
        rA, S + 10 * HH, S + 15 * HH, ipwb + 2 * HH, beff, ipb, lang, rB, rC, rD);

    // align f32 -> bf16 (scratch S now dead)
    k_f2b1<<<(unsigned)(AHH / 4 / 256), 256, 0, stream>>>(align, alignb, (int)(AHH / 4));

    // attention: ctx -> rA (hb dead).  128-row q-tiles, 512 threads.
    k_attn<<<dim3(6, NHn, Bn), 512, 0, stream>>>(rB, rC, rD, rA);

    // language chain: first step transposing copy (MT0 = F7^T), then 7 GEMM steps
    k_chain_first<<<dim3(12, 12, NLn), 256, 0, stream>>>(alignb, lang, rC);
    u16* Pin = rC;
    u16* Pout = rD;
    for (int j = Bn - 2; j >= 0; --j) {
        k_chain64<<<dim3(12, 12, NLn), 256, 0, stream>>>(Pin, Pout, alignb, lang, j);
        u16* t = Pin; Pin = Pout; Pout = t;
    }
    // 7 steps -> final MT in rD (Pin == rD)

    // U_l = opw^T . M_l  (+ opb_eff GEMV)  -> rB (Q dead)
    k_uop<<<735, 256, 0, stream>>>(opwT, Pin, opb, rB, opbeff);
    // W_l = projw . U_l  (+ bias2 GEMV)    -> rC (chain ping dead)
    k_wb2<<<735, 256, 0, stream>>>(pjwb, rB, opbeff, projw, projb, rC, bias2);

    // x = ctx . W[lang]^T + bias2 + hidden -> d_out (f32)
    k_xfused<<<dim3(48, 6), 256, 0, stream>>>(rA, rC, bias2, lang, hidden, out);
    // layernorm in place
    k_ln<<<(unsigned)(Bn * Sn), 64, 0, stream>>>(out, ln_g, ln_b);
}

// Round 5
// 500.179 us; speedup vs baseline: 1.4515x; 1.0275x over previous
//
#include <hip/hip_runtime.h>

// ---------------- constants ----------------
#define Bn 8
#define Sn 768
#define Hn 768
#define NHn 12
#define HDn 64
#define NLn 5

typedef unsigned short u16;
typedef __bf16 bf16x8 __attribute__((ext_vector_type(8)));
typedef short s16x8 __attribute__((ext_vector_type(8)));
typedef float f32x4 __attribute__((ext_vector_type(4)));
typedef unsigned short u16x4 __attribute__((ext_vector_type(4)));

static __device__ __forceinline__ float bf2f(u16 v) {
    return __uint_as_float(((unsigned)v) << 16);
}
static __device__ __forceinline__ u16 f2bf(float f) {
    unsigned u = __float_as_uint(f);
    unsigned r = u + 0x7fffu + ((u >> 16) & 1u);
    return (u16)(r >> 16);
}
static __device__ __forceinline__ bf16x8 ld8(const u16* p) {
    return *reinterpret_cast<const bf16x8*>(p);
}
static __device__ __forceinline__ void glds16(const u16* g, u16* l) {
    __builtin_amdgcn_global_load_lds(
        (const __attribute__((address_space(1))) void*)g,
        (__attribute__((address_space(3))) void*)l, 16, 0, 0);
}

// ---------------- fused prep: f32->bf16 conversions + transposes + bias folds
#define PREP_NF2B 6912
#define PREP_NTR  1584
__global__ __launch_bounds__(256) void k_prep(
    const float* __restrict__ hidden, u16* __restrict__ hb,
    const float* __restrict__ ipw, u16* __restrict__ ipwb,
    const float* __restrict__ projw, u16* __restrict__ pjwb,
    const float* __restrict__ Wq, const float* __restrict__ Wk,
    const float* __restrict__ opw, u16* __restrict__ S, u16* __restrict__ opwT,
    const float* __restrict__ ipb,
    const float* __restrict__ bq_lang, const float* __restrict__ bk_lang,
    float* __restrict__ beff)
{
    __shared__ float T[64][65];
    const size_t HH = (size_t)Hn * Hn;
    const int bid = blockIdx.x, tid = threadIdx.x;
    if (bid < PREP_NF2B) {
        const int n0 = (int)(Bn * Sn * Hn / 4), n1 = (int)(3 * HH / 4), n2 = (int)(HH / 4);
        int i = bid * 256 + tid;
        const float* s; u16* d; int off;
        if (i < n0)                { s = hidden; d = hb;   off = i; }
        else if (i < n0 + n1)      { s = ipw;    d = ipwb; off = i - n0; }
        else if (i < n0 + n1 + n2) { s = projw;  d = pjwb; off = i - n0 - n1; }
        else return;
        float4 v = reinterpret_cast<const float4*>(s)[off];
        u16x4 o;
        o[0] = f2bf(v.x); o[1] = f2bf(v.y); o[2] = f2bf(v.z); o[3] = f2bf(v.w);
        reinterpret_cast<u16x4*>(d)[off] = o;
    } else if (bid < PREP_NF2B + PREP_NTR) {
        int b2 = bid - PREP_NF2B;
        int z = b2 / 144, r = b2 % 144;
        int bx = r % 12, by = r / 12;
        const float* src;
        u16* dst;
        if (z < 5)       { src = Wq + (size_t)z * HH;       dst = S + (size_t)z * HH; }
        else if (z < 10) { src = Wk + (size_t)(z - 5) * HH; dst = S + (size_t)z * HH; }
        else             { src = opw;                        dst = opwT; }
        int i0 = bx * 64, o0 = by * 64;
        int x = tid & 63, ys = tid >> 6;
        for (int rr = ys; rr < 64; rr += 4)
            T[rr][x] = src[(size_t)(o0 + rr) * Hn + i0 + x];
        __syncthreads();
        for (int rr = ys; rr < 64; rr += 4)
            dst[(size_t)(i0 + rr) * Hn + o0 + x] = f2bf(T[x][rr]);
    } else {
        int b3 = bid - PREP_NF2B - PREP_NTR;       // 0..29
        int ox = b3 % 3, y = b3 / 3;
        int o = ox * 256 + tid;
        int which = y / 5, l = y % 5;
        const float4* w = reinterpret_cast<const float4*>(ipw + (size_t)which * HH + (size_t)o * Hn);
        const float4* bv = reinterpret_cast<const float4*>(((which ? bk_lang : bq_lang) + (size_t)l * Hn));
        float s = 0.f;
        for (int j = 0; j < Hn / 4; ++j) {
            float4 a = w[j], b = bv[j];
            s += a.x * b.x + a.y * b.y + a.z * b.z + a.w * b.w;
        }
        s += ipb[which * Hn + o];
        beff[(size_t)(which * 5 + l) * Hn + o] = s;
    }
}

// ---- TM x 128 triple-buffered counted-vmcnt NT GEMM core (256 thr) ----
template<int TM>
__device__ __forceinline__ void gemm_core(
    const u16* __restrict__ A, int lda,
    const u16* __restrict__ Bw, int ldb,
    const float* __restrict__ bias,
    const float* __restrict__ addres,
    u16* __restrict__ outH, float* __restrict__ outF,
    u16* __restrict__ outVT, int ldc,
    int m0, int n0, float scale)
{
    constexpr int MI = TM / 32;          // acc rows per wave (4 or 8)
    constexpr int AIT = TM / 64;         // A loads per thread (2 or 4)
    __shared__ u16 As[3 * TM * 32];
    __shared__ u16 Bs[3 * 128 * 32];
    const int tid = threadIdx.x;
    const int lane = tid & 63, wave = tid >> 6;
    const int lrow = lane & 15, lquad = lane >> 4;
    const int wm = (wave >> 1) * (TM / 2), wn = (wave & 1) * 64;

    const u16* gA = A + (size_t)(m0 + (tid >> 2)) * lda + (tid & 3) * 8;
    const u16* gB = Bw + (size_t)(n0 + (tid >> 2)) * ldb + (tid & 3) * 8;

    f32x4 z = {0.f, 0.f, 0.f, 0.f};
    f32x4 acc[MI][4];
    #pragma unroll
    for (int i = 0; i < MI; ++i)
        #pragma unroll
        for (int j = 0; j < 4; ++j) acc[i][j] = z;

    auto stage = [&](int bs, int k0) {
        #pragma unroll
        for (int it = 0; it < AIT; ++it)
            glds16(gA + (size_t)(it * 64) * lda + k0, &As[bs * TM * 32 + (tid + 256 * it) * 8]);
        #pragma unroll
        for (int it = 0; it < 2; ++it)
            glds16(gB + (size_t)(it * 64) * ldb + k0, &Bs[bs * 128 * 32 + (tid + 256 * it) * 8]);
    };
    auto compute = [&](int bc) {
        const u16* Ab = &As[bc * TM * 32];
        const u16* Bb = &Bs[bc * 128 * 32];
        bf16x8 af[MI], bf_[4];
        #pragma unroll
        for (int i = 0; i < MI; ++i)
            af[i] = ld8(&Ab[(wm + i * 16 + lrow) * 32 + lquad * 8]);
        #pragma unroll
        for (int j = 0; j < 4; ++j)
            bf_[j] = ld8(&Bb[(wn + j * 16 + lrow) * 32 + lquad * 8]);
        #pragma unroll
        for (int i = 0; i < MI; ++i)
            #pragma unroll
            for (int j = 0; j < 4; ++j)
                acc[i][j] = __builtin_amdgcn_mfma_f32_16x16x32_bf16(af[i], bf_[j], acc[i][j], 0, 0, 0);
    };

    stage(0, 0);
    stage(1, 32);
    int bc = 0, bs = 2;
    for (int kt = 0; kt < 24; ++kt) {
        if (kt < 23) {
            if constexpr (TM == 256) {
                asm volatile("s_waitcnt vmcnt(6)" ::: "memory");
            } else {
                asm volatile("s_waitcnt vmcnt(4)" ::: "memory");
            }
        } else {
            asm volatile("s_waitcnt vmcnt(0)" ::: "memory");
        }
        __builtin_amdgcn_s_barrier();
        if (kt < 22) {
            stage(bs, (kt + 2) * 32);
            bs = (bs == 2) ? 0 : bs + 1;
        }
        compute(bc);
        bc = (bc == 2) ? 0 : bc + 1;
    }

    #pragma unroll
    for (int i = 0; i < MI; ++i) {
        #pragma unroll
        for (int j = 0; j < 4; ++j) {
            int col = n0 + wn + j * 16 + lrow;
            float bv = bias ? bias[col] : 0.f;
            if (outVT) {
                int row0 = m0 + wm + i * 16 + lquad * 4;
                int bb = row0 / Sn, s = row0 % Sn;
                int hh = col >> 6, dd = col & 63;
                u16x4 o;
                #pragma unroll
                for (int r = 0; r < 4; ++r) o[r] = f2bf((acc[i][j][r] + bv) * scale);
                *reinterpret_cast<u16x4*>(
                    outVT + (((size_t)bb * NHn + hh) * 64 + dd) * Sn + s) = o;
            } else {
                #pragma unroll
                for (int r = 0; r < 4; ++r) {
                    int row = m0 + wm + i * 16 + lquad * 4 + r;
                    float v = (acc[i][j][r] + bv) * scale;
                    if (addres) v += addres[(size_t)row * ldc + col];
                    if (outF) outF[(size_t)row * ldc + col] = v;
                    else      outH[(size_t)row * ldc + col] = f2bf(v);
                }
            }
        }
    }
}

// ------- 64x64 triple-buffered counted-vmcnt NT GEMM core (256 thr) -------
__device__ __forceinline__ void gemm64(
    const u16* __restrict__ A, const u16* __restrict__ Bw,
    u16* __restrict__ outH, int m0, int n0)
{
    __shared__ u16 As[3 * 64 * 32];
    __shared__ u16 Bs[3 * 64 * 32];
    const int tid = threadIdx.x;
    const int lane = tid & 63, wave = tid >> 6;
    const int lrow = lane & 15, lquad = lane >> 4;
    const int wm = (wave >> 1) * 32, wn = (wave & 1) * 32;

    const u16* gA = A + (size_t)(m0 + (tid >> 2)) * Hn + (tid & 3) * 8;
    const u16* gB = Bw + (size_t)(n0 + (tid >> 2)) * Hn + (tid & 3) * 8;

    f32x4 z = {0.f, 0.f, 0.f, 0.f};
    f32x4 acc[2][2];
    #pragma unroll
    for (int i = 0; i < 2; ++i)
        #pragma unroll
        for (int j = 0; j < 2; ++j) acc[i][j] = z;

    auto stage = [&](int bs, int k0) {
        glds16(gA + k0, &As[bs * 64 * 32 + tid * 8]);
        glds16(gB + k0, &Bs[bs * 64 * 32 + tid * 8]);
    };
    auto compute = [&](int bc) {
        const u16* Ab = &As[bc * 64 * 32];
        const u16* Bb = &Bs[bc * 64 * 32];
        bf16x8 af[2], bf_[2];
        #pragma unroll
        for (int i = 0; i < 2; ++i)
            af[i] = ld8(&Ab[(wm + i * 16 + lrow) * 32 + lquad * 8]);
        #pragma unroll
        for (int j = 0; j < 2; ++j)
            bf_[j] = ld8(&Bb[(wn + j * 16 + lrow) * 32 + lquad * 8]);
        #pragma unroll
        for (int i = 0; i < 2; ++i)
            #pragma unroll
            for (int j = 0; j < 2; ++j)
                acc[i][j] = __builtin_amdgcn_mfma_f32_16x16x32_bf16(af[i], bf_[j], acc[i][j], 0, 0, 0);
    };

    stage(0, 0);
    stage(1, 32);
    int bc = 0, bs = 2;
    for (int kt = 0; kt < 24; ++kt) {
        if (kt < 23) {
            asm volatile("s_waitcnt vmcnt(2)" ::: "memory");
        } else {
            asm volatile("s_waitcnt vmcnt(0)" ::: "memory");
        }
        __builtin_amdgcn_s_barrier();
        if (kt < 22) {
            stage(bs, (kt + 2) * 32);
            bs = (bs == 2) ? 0 : bs + 1;
        }
        compute(bc);
        bc = (bc == 2) ? 0 : bc + 1;
    }

    #pragma unroll
    for (int i = 0; i < 2; ++i)
        #pragma unroll
        for (int j = 0; j < 2; ++j) {
            int col = n0 + wn + j * 16 + lrow;
            #pragma unroll
            for (int r = 0; r < 4; ++r) {
                int row_ = m0 + wm + i * 16 + lquad * 4 + r;
                outH[(size_t)row_ * Hn + col] = f2bf(acc[i][j][r]);
            }
        }
}

// ---------------- GEMM wrapper kernels ----------------

// fused QKV projection, 256-row tiles.  grid (24, 6, 3): z=0 Q, z=1 K, z=2 V(T).
__global__ __launch_bounds__(256, 2) void k_gemm_qkv(
    const u16* __restrict__ A,
    const u16* __restrict__ Sq, const u16* __restrict__ Sk,
    const u16* __restrict__ Wv,
    const float* __restrict__ beff, const float* __restrict__ ipb,
    const int* __restrict__ lang,
    u16* __restrict__ outQ, u16* __restrict__ outK, u16* __restrict__ outVT)
{
    const size_t HH = (size_t)Hn * Hn;
    int z = blockIdx.z;
    int m0 = blockIdx.x * 256, n0 = blockIdx.y * 128;
    int l = lang[blockIdx.x / 3];
    if (z == 0) {
        gemm_core<256>(A, Hn, Sq + (size_t)l * HH, Hn, beff + (size_t)l * Hn,
                       nullptr, outQ, nullptr, nullptr, Hn, m0, n0, 0.125f);
    } else if (z == 1) {
        gemm_core<256>(A, Hn, Sk + (size_t)l * HH, Hn, beff + (size_t)(5 + l) * Hn,
                       nullptr, outK, nullptr, nullptr, Hn, m0, n0, 1.f);
    } else {
        gemm_core<256>(A, Hn, Wv, Hn, ipb + 2 * Hn,
                       nullptr, nullptr, nullptr, outVT, Hn, m0, n0, 1.f);
    }
}

// fused weight combine: z<5: Weffq_z = NT(wq, WqT_z); z>=5: Weffk.  grid (6,6,10)
__global__ __launch_bounds__(256) void k_comb10(
    const u16* __restrict__ ipwb, u16* __restrict__ S)
{
    const size_t HH = (size_t)Hn * Hn;
    int z = blockIdx.z;
    const u16* Aop = ipwb + (z < 5 ? 0 : HH);
    gemm_core<128>(Aop, Hn, S + (size_t)z * HH, Hn, nullptr, nullptr,
                   S + (size_t)(10 + z) * HH, nullptr, nullptr, Hn,
                   blockIdx.x * 128, blockIdx.y * 128, 1.f);
}

// chain first step: MT0_l = F7^T (transpose of align bf16, or I).  grid (12,12,5)
__global__ __launch_bounds__(256) void k_chain_first(
    const u16* __restrict__ alignb, const int* __restrict__ lang,
    u16* __restrict__ out5)
{
    const size_t HH = (size_t)Hn * Hn;
    int l = blockIdx.z, lj = lang[Bn - 1];
    u16* dst = out5 + (size_t)l * HH;
    int i0 = blockIdx.x * 64, o0 = blockIdx.y * 64;
    const int tid = threadIdx.x;
    if (lj == l) {
        #pragma unroll
        for (int it = 0; it < 2; ++it) {
            int s = tid + 256 * it;
            int ri = s >> 3, c8 = s & 7;
            s16x8 v;
            #pragma unroll
            for (int e = 0; e < 8; ++e)
                v[e] = (short)((i0 + ri == o0 + c8 * 8 + e) ? 0x3F80 : 0);
            *reinterpret_cast<s16x8*>(dst + (size_t)(i0 + ri) * Hn + o0 + c8 * 8) = v;
        }
    } else {
        const u16* src = alignb + ((size_t)l * NLn + lj) * HH;
        __shared__ u16 T[64][72];   // T[i][o] = src[o][i]
        #pragma unroll
        for (int it = 0; it < 2; ++it) {
            int s = tid + 256 * it;
            int r = s >> 3, c8 = s & 7;
            s16x8 v = *reinterpret_cast<const s16x8*>(
                src + (size_t)(o0 + r) * Hn + i0 + c8 * 8);
            #pragma unroll
            for (int e = 0; e < 8; ++e) T[c8 * 8 + e][r] = (u16)v[e];
        }
        __syncthreads();
        #pragma unroll
        for (int it = 0; it < 2; ++it) {
            int s = tid + 256 * it;
            int ri = s >> 3, c8 = s & 7;
            s16x8 v = *reinterpret_cast<const s16x8*>(&T[ri][c8 * 8]);
            *reinterpret_cast<s16x8*>(dst + (size_t)(i0 + ri) * Hn + o0 + c8 * 8) = v;
        }
    }
}

// chain step: Pout_l = Pin_l @ F_j^T.  grid (12,12,5), 64^2 tiles
__global__ __launch_bounds__(256) void k_chain64(
    const u16* __restrict__ Pin, u16* __restrict__ Pout,
    const u16* __restrict__ alignb, const int* __restrict__ lang, int j)
{
    const size_t HH = (size_t)Hn * Hn;
    int l = blockIdx.z;
    int lj = lang[j];
    const u16* Pl = Pin + (size_t)l * HH;
    u16* Po = Pout + (size_t)l * HH;
    int m0 = blockIdx.x * 64, n0 = blockIdx.y * 64;
    if (lj == l) {
        int tid = threadIdx.x;
        #pragma unroll
        for (int it = 0; it < 2; ++it) {
            int s = tid + 256 * it;
            int row = s >> 3, seg = s & 7;
            *reinterpret_cast<s16x8*>(Po + (size_t)(m0 + row) * Hn + n0 + seg * 8) =
                *reinterpret_cast<const s16x8*>(Pl + (size_t)(m0 + row) * Hn + n0 + seg * 8);
        }
    } else {
        const u16* F = alignb + ((size_t)l * NLn + lj) * HH;
        gemm64(Pl, F, Po, m0, n0);
    }
}

// U_l = NT(opwT, MT_l) + opb_eff GEMV.  grid 735.
__global__ __launch_bounds__(256) void k_uop(
    const u16* __restrict__ opwT, const u16* __restrict__ MT5,
    const float* __restrict__ opb,
    u16* __restrict__ U5, float* __restrict__ opbeff)
{
    const size_t HH = (size_t)Hn * Hn;
    int bid = blockIdx.x;
    if (bid < 720) {
        int z = bid / 144, r = bid % 144;
        gemm64(opwT, MT5 + (size_t)z * HH, U5 + (size_t)z * HH,
               (r % 12) * 64, (r / 12) * 64);
    } else {
        int b2 = bid - 720;
        int n = (b2 % 3) * 256 + threadIdx.x;
        int l = b2 / 3;
        const u16* mt = MT5 + ((size_t)l * Hn + n) * Hn;
        float s = 0.f;
        for (int k = 0; k < Hn; k += 8) {
            s16x8 v = *reinterpret_cast<const s16x8*>(mt + k);
            #pragma unroll
            for (int j = 0; j < 8; ++j) s += opb[k + j] * bf2f((u16)v[j]);
        }
        opbeff[(size_t)l * Hn + n] = s;
    }
}

// W_l = NT(projw, U_l) + bias2 GEMV.  grid 735.
__global__ __launch_bounds__(256) void k_wb2(
    const u16* __restrict__ pjwb, const u16* __restrict__ U5,
    const float* __restrict__ opbeff, const float* __restrict__ projw,
    const float* __restrict__ projb,
    u16* __restrict__ W5, float* __restrict__ bias2)
{
    const size_t HH = (size_t)Hn * Hn;
    int bid = blockIdx.x;
    if (bid < 720) {
        int z = bid / 144, r = bid % 144;
        gemm64(pjwb, U5 + (size_t)z * HH, W5 + (size_t)z * HH,
               (r % 12) * 64, (r / 12) * 64);
    } else {
        int b2 = bid - 720;
        int m = (b2 % 3) * 256 + threadIdx.x;
        int l = b2 / 3;
        const float4* w = reinterpret_cast<const float4*>(projw + (size_t)m * Hn);
        const float4* ob = reinterpret_cast<const float4*>(opbeff + (size_t)l * Hn);
        float s = 0.f;
        for (int j = 0; j < Hn / 4; ++j) {
            float4 a = w[j], b = ob[j];
            s += a.x * b.x + a.y * b.y + a.z * b.z + a.w * b.w;
        }
        bias2[(size_t)l * Hn + m] = s + projb[m];
    }
}

// x = NT(ctx, W[lang]) + bias2[lang] + hidden -> f32 out.  grid (48,6)
__global__ __launch_bounds__(256) void k_xfused(
    const u16* __restrict__ ctx, const u16* __restrict__ W5,
    const float* __restrict__ bias2, const int* __restrict__ lang,
    const float* __restrict__ hidden, float* __restrict__ x)
{
    int l = lang[blockIdx.x / 6];
    gemm_core<128>(ctx, Hn, W5 + (size_t)l * Hn * Hn, Hn, bias2 + (size_t)l * Hn,
                   hidden, nullptr, x, nullptr, Hn,
                   blockIdx.x * 128, blockIdx.y * 128, 1.f);
}

// ---------------- flash attention + align conversion, 512 threads ----------
// blocks [0,576): attn, one per (b, h, 128-q tile); 8 waves x 16 q-rows.
// K and V both glds16-staged, 3 buffers, counted vmcnt(2), 1 barrier/iter.
// blocks [576, 7776): align f32 -> bf16 conversion (backfills idle BW).
__global__ __launch_bounds__(512) void k_attn_conv(
    const u16* __restrict__ Q, const u16* __restrict__ K,
    const u16* __restrict__ VT, u16* __restrict__ ctx,
    const float* __restrict__ alignf, u16* __restrict__ alignb)
{
    __shared__ u16 Ks[3][64 * 64];       // [key][d], seg-xor-swizzled
    __shared__ u16 Vs[3][64 * 64];       // [d][key], seg-xor-swizzled
    __shared__ u16 Pw[8][16 * 72];       // per-wave P, 16B-aligned stride

    const int bid = blockIdx.x, tid = threadIdx.x;
    if (bid >= 576) {
        int i = (bid - 576) * 512 + tid;         // 7200*512 = 3686400 float4s
        float4 v = reinterpret_cast<const float4*>(alignf)[i];
        u16x4 o;
        o[0] = f2bf(v.x); o[1] = f2bf(v.y); o[2] = f2bf(v.z); o[3] = f2bf(v.w);
        reinterpret_cast<u16x4*>(alignb)[i] = o;
        return;
    }

    const int q0 = (bid % 6) * 128, h = (bid / 6) % NHn, bz = bid / 72;
    const int wave = tid >> 6, lane = tid & 63;
    const int lrow = lane & 15, lquad = lane >> 4;
    const int sw = lrow & 7;

    const u16* Qp = Q + ((size_t)(bz * Sn + q0 + wave * 16 + lrow)) * Hn + h * HDn;
    const u16* Kb = K + (size_t)bz * Sn * Hn + h * HDn;
    const u16* Vb = VT + ((size_t)(bz * NHn + h) * 64) * Sn;   // row d, stride Sn

    bf16x8 qa0 = ld8(Qp + lquad * 8);
    bf16x8 qa1 = ld8(Qp + 32 + lquad * 8);

    f32x4 z4 = {0.f, 0.f, 0.f, 0.f};
    float m_r[4], l_l[4];
    f32x4 oacc[4];
    #pragma unroll
    for (int r = 0; r < 4; ++r) { m_r[r] = -1e30f; l_l[r] = 0.f; }
    #pragma unroll
    for (int jd = 0; jd < 4; ++jd) oacc[jd] = z4;

    // staging addresses: 512 16B segs each for K and V
    const int krow = tid >> 3, kp = (tid & 7) ^ (krow & 7);
    const u16* kg = Kb + (size_t)krow * Hn + kp * 8;
    const u16* vg = Vb + (size_t)krow * Sn + kp * 8;   // d = krow

    auto stage = [&](int bs, int t0) {
        glds16(kg + (size_t)t0 * Hn, &Ks[bs][tid * 8]);
        glds16(vg + t0, &Vs[bs][tid * 8]);
    };

    auto compute = [&](int bc) {
        f32x4 sc[4];
        __builtin_amdgcn_s_setprio(1);
        #pragma unroll
        for (int j = 0; j < 4; ++j) {
            int base = (j * 16 + lrow) * 64 + ((lquad ^ sw) * 8);
            f32x4 s = __builtin_amdgcn_mfma_f32_16x16x32_bf16(qa0, ld8(&Ks[bc][base]), z4, 0, 0, 0);
            sc[j] = __builtin_amdgcn_mfma_f32_16x16x32_bf16(qa1, ld8(&Ks[bc][base ^ 32]), s, 0, 0, 0);
        }
        __builtin_amdgcn_s_setprio(0);
        float tmax[4];
        #pragma unroll
        for (int r = 0; r < 4; ++r)
            tmax[r] = fmaxf(fmaxf(sc[0][r], sc[1][r]), fmaxf(sc[2][r], sc[3][r]));
        #pragma unroll
        for (int off = 1; off < 16; off <<= 1)
            #pragma unroll
            for (int r = 0; r < 4; ++r)
                tmax[r] = fmaxf(tmax[r], __shfl_xor(tmax[r], off));
        bool grow = (tmax[0] > m_r[0]) | (tmax[1] > m_r[1]) |
                    (tmax[2] > m_r[2]) | (tmax[3] > m_r[3]);
        if (grow) {
            #pragma unroll
            for (int r = 0; r < 4; ++r) {
                float mn = fmaxf(m_r[r], tmax[r]);
                float a = __expf(m_r[r] - mn);
                m_r[r] = mn;
                l_l[r] *= a;
                #pragma unroll
                for (int jd = 0; jd < 4; ++jd) oacc[jd][r] *= a;
            }
        }
        float ps[4] = {0.f, 0.f, 0.f, 0.f};
        #pragma unroll
        for (int j = 0; j < 4; ++j)
            #pragma unroll
            for (int r = 0; r < 4; ++r) {
                float p = __expf(sc[j][r] - m_r[r]);
                ps[r] += p;
                Pw[wave][(lquad * 4 + r) * 72 + j * 16 + lrow] = f2bf(p);
            }
        #pragma unroll
        for (int r = 0; r < 4; ++r) l_l[r] += ps[r];
        bf16x8 pa0 = ld8(&Pw[wave][lrow * 72 + lquad * 8]);
        bf16x8 pa1 = ld8(&Pw[wave][lrow * 72 + 32 + lquad * 8]);
        __builtin_amdgcn_s_setprio(1);
        #pragma unroll
        for (int jd = 0; jd < 4; ++jd) {
            int vbase = (jd * 16 + lrow) * 64 + ((lquad ^ sw) * 8);
            oacc[jd] = __builtin_amdgcn_mfma_f32_16x16x32_bf16(pa0, ld8(&Vs[bc][vbase]), oacc[jd], 0, 0, 0);
            oacc[jd] = __builtin_amdgcn_mfma_f32_16x16x32_bf16(pa1, ld8(&Vs[bc][vbase ^ 32]), oacc[jd], 0, 0, 0);
        }
        __builtin_amdgcn_s_setprio(0);
    };

    // 2-deep prologue, then counted-vmcnt loop (1 barrier / K-tile)
    stage(0, 0);
    stage(1, 64);
    int bc = 0, bs = 2;
    for (int kt = 0; kt < 12; ++kt) {
        if (kt < 11) {
            asm volatile("s_waitcnt vmcnt(2)" ::: "memory");
        } else {
            asm volatile("s_waitcnt vmcnt(0)" ::: "memory");
        }
        __builtin_amdgcn_s_barrier();
        if (kt < 10) {
            stage(bs, (kt + 2) * 64);
            bs = (bs == 2) ? 0 : bs + 1;
        }
        compute(bc);
        bc = (bc == 2) ? 0 : bc + 1;
    }

    // final 16-lane reduction of the denominators
    #pragma unroll
    for (int off = 1; off < 16; off <<= 1)
        #pragma unroll
        for (int r = 0; r < 4; ++r)
            l_l[r] += __shfl_xor(l_l[r], off);

    float rl[4];
    #pragma unroll
    for (int r = 0; r < 4; ++r) rl[r] = 1.f / l_l[r];
    #pragma unroll
    for (int jd = 0; jd < 4; ++jd)
        #pragma unroll
        for (int r = 0; r < 4; ++r) {
            size_t row = (size_t)bz * Sn + q0 + wave * 16 + lquad * 4 + r;
            ctx[row * Hn + h * HDn + jd * 16 + lrow] = f2bf(oacc[jd][r] * rl[r]);
        }
}

// layernorm in-place on f32 d_out.  grid B*S, block 64
__global__ __launch_bounds__(64) void k_ln(
    float* x, const float* __restrict__ g, const float* __restrict__ beta)
{
    size_t row = blockIdx.x;
    float* xr = x + row * Hn;
    int lane = threadIdx.x;
    float v[12];
    float s = 0.f, ss = 0.f;
    #pragma unroll
    for (int i = 0; i < 12; ++i) {
        v[i] = xr[lane + i * 64];
        s += v[i];
        ss += v[i] * v[i];
    }
    #pragma unroll
    for (int off = 1; off < 64; off <<= 1) {
        s  += __shfl_xor(s, off);
        ss += __shfl_xor(ss, off);
    }
    float mu = s * (1.f / Hn);
    float var = ss * (1.f / Hn) - mu * mu;
    float inv = rsqrtf(var + 1e-5f);
    #pragma unroll
    for (int i = 0; i < 12; ++i) {
        int c = lane + i * 64;
        xr[c] = (v[i] - mu) * inv * g[c] + beta[c];
    }
}

// ---------------- launch ----------------
extern "C" void kernel_launch(void* const* d_in, const int* in_sizes, int n_in,
                              void* d_out, int out_size, void* d_ws, size_t ws_size,
                              hipStream_t stream)
{
    (void)in_sizes; (void)n_in; (void)out_size; (void)ws_size;

    const float* hidden  = (const float*)d_in[0];
    const int*   lang    = (const int*)d_in[1];
    const float* Wq_lang = (const float*)d_in[3];
    const float* bq_lang = (const float*)d_in[4];
    const float* Wk_lang = (const float*)d_in[5];
    const float* bk_lang = (const float*)d_in[6];
    const float* ipw     = (const float*)d_in[7];
    const float* ipb     = (const float*)d_in[8];
    const float* opw     = (const float*)d_in[9];
    const float* opb     = (const float*)d_in[10];
    const float* align   = (const float*)d_in[11];
    const float* projw   = (const float*)d_in[12];
    const float* projb   = (const float*)d_in[13];
    const float* ln_g    = (const float*)d_in[14];
    const float* ln_b    = (const float*)d_in[15];
    float* out = (float*)d_out;

    const size_t HH  = (size_t)Hn * Hn;          // 589824
    const size_t BSH = (size_t)Bn * Sn * Hn;     // 4718592
    const size_t AHH = (size_t)NLn * NLn * HH;   // 14745600

    u16* rA = (u16*)d_ws;        // hb -> ctx
    u16* rB = rA + BSH;          // Q -> U
    u16* rC = rB + BSH;          // K -> MT ping -> W
    u16* rD = rC + BSH;          // V^T -> MT pong (final)
    u16* ipwb = rD + BSH;        // wq|wk|wv bf16 (3*HH)
    u16* pjwb = ipwb + 3 * HH;   // HH
    u16* opwT = pjwb + HH;       // HH
    u16* alignb = opwT + HH;     // 25*HH bf16; pre-attn: weight scratch S[0..20)
    float* beff   = (float*)(alignb + AHH);   // 2*5*768 f32
    float* opbeff = beff + 10 * Hn;           // 5*768 f32
    float* bias2  = opbeff + 5 * Hn;          // 5*768 f32

    u16* S = alignb;             // scratch: WqT[0..5) WkT[5..10) Weffq[10..15) Weffk[15..20)

    // fused prep: conversions + 11 transposes + QK bias folds (one launch)
    k_prep<<<(unsigned)(PREP_NF2B + PREP_NTR + 30), 256, 0, stream>>>(
        hidden, rA, ipw, ipwb, projw, pjwb,
        Wq_lang, Wk_lang, opw, S, opwT,
        ipb, bq_lang, bk_lang, beff);

    // Weffq/Weffk (both in one launch) -> S[10..20)
    k_comb10<<<dim3(6, 6, 10), 256, 0, stream>>>(ipwb, S);

    // fused QKV: Q*(1/8) -> rB, K -> rC, V^T -> rD.  256-row tiles.
    k_gemm_qkv<<<dim3(24, 6, 3), 256, 0, stream>>>(
        rA, S + 10 * HH, S + 15 * HH, ipwb + 2 * HH, beff, ipb, lang, rB, rC, rD);

    // attention (ctx -> rA) + align f32->bf16 conversion (S scratch now dead)
    k_attn_conv<<<7776, 512, 0, stream>>>(rB, rC, rD, rA, align, alignb);

    // language chain: first step transposing copy (MT0 = F7^T), then 7 GEMM steps
    k_chain_first<<<dim3(12, 12, NLn), 256, 0, stream>>>(alignb, lang, rC);
    u16* Pin = rC;
    u16* Pout = rD;
    for (int j = Bn - 2; j >= 0; --j) {
        k_chain64<<<dim3(12, 12, NLn), 256, 0, stream>>>(Pin, Pout, alignb, lang, j);
        u16* t = Pin; Pin = Pout; Pout = t;
    }
    // 7 steps -> final MT in rD (Pin == rD)

    // U_l = opw^T . M_l  (+ opb_eff GEMV)  -> rB (Q dead)
    k_uop<<<735, 256, 0, stream>>>(opwT, Pin, opb, rB, opbeff);
    // W_l = projw . U_l  (+ bias2 GEMV)    -> rC (chain ping dead)
    k_wb2<<<735, 256, 0, stream>>>(pjwb, rB, opbeff, projw, projb, rC, bias2);

    // x = ctx . W[lang]^T + bias2 + hidden -> d_out (f32)
    k_xfused<<<dim3(48, 6), 256, 0, stream>>>(rA, rC, bias2, lang, hidden, out);
    // layernorm in place
    k_ln<<<(unsigned)(Bn * Sn), 64, 0, stream>>>(out, ln_g, ln_b);
}

// Round 7
// 488.887 us; speedup vs baseline: 1.4850x; 1.0231x over previous
//
#include <hip/hip_runtime.h>

// ---------------- constants ----------------
#define Bn 8
#define Sn 768
#define Hn 768
#define NHn 12
#define HDn 64
#define NLn 5

typedef unsigned short u16;
typedef __bf16 bf16x8 __attribute__((ext_vector_type(8)));
typedef short s16x8 __attribute__((ext_vector_type(8)));
typedef float f32x4 __attribute__((ext_vector_type(4)));
typedef unsigned short u16x4 __attribute__((ext_vector_type(4)));

static __device__ __forceinline__ float bf2f(u16 v) {
    return __uint_as_float(((unsigned)v) << 16);
}
static __device__ __forceinline__ u16 f2bf(float f) {
    unsigned u = __float_as_uint(f);
    unsigned r = u + 0x7fffu + ((u >> 16) & 1u);
    return (u16)(r >> 16);
}
static __device__ __forceinline__ bf16x8 ld8(const u16* p) {
    return *reinterpret_cast<const bf16x8*>(p);
}
static __device__ __forceinline__ void glds16(const u16* g, u16* l) {
    __builtin_amdgcn_global_load_lds(
        (const __attribute__((address_space(1))) void*)g,
        (__attribute__((address_space(3))) void*)l, 16, 0, 0);
}

// ---------------- fused prep: f32->bf16 conversions + transposes + bias folds
#define PREP_NF2B 6912
#define PREP_NTR  1584
__global__ __launch_bounds__(256) void k_prep(
    const float* __restrict__ hidden, u16* __restrict__ hb,
    const float* __restrict__ ipw, u16* __restrict__ ipwb,
    const float* __restrict__ projw, u16* __restrict__ pjwb,
    const float* __restrict__ Wq, const float* __restrict__ Wk,
    const float* __restrict__ opw, u16* __restrict__ S, u16* __restrict__ opwT,
    const float* __restrict__ ipb,
    const float* __restrict__ bq_lang, const float* __restrict__ bk_lang,
    float* __restrict__ beff)
{
    __shared__ float T[64][65];
    const size_t HH = (size_t)Hn * Hn;
    const int bid = blockIdx.x, tid = threadIdx.x;
    if (bid < PREP_NF2B) {
        const int n0 = (int)(Bn * Sn * Hn / 4), n1 = (int)(3 * HH / 4), n2 = (int)(HH / 4);
        int i = bid * 256 + tid;
        const float* s; u16* d; int off;
        if (i < n0)                { s = hidden; d = hb;   off = i; }
        else if (i < n0 + n1)      { s = ipw;    d = ipwb; off = i - n0; }
        else if (i < n0 + n1 + n2) { s = projw;  d = pjwb; off = i - n0 - n1; }
        else return;
        float4 v = reinterpret_cast<const float4*>(s)[off];
        u16x4 o;
        o[0] = f2bf(v.x); o[1] = f2bf(v.y); o[2] = f2bf(v.z); o[3] = f2bf(v.w);
        reinterpret_cast<u16x4*>(d)[off] = o;
    } else if (bid < PREP_NF2B + PREP_NTR) {
        int b2 = bid - PREP_NF2B;
        int z = b2 / 144, r = b2 % 144;
        int bx = r % 12, by = r / 12;
        const float* src;
        u16* dst;
        if (z < 5)       { src = Wq + (size_t)z * HH;       dst = S + (size_t)z * HH; }
        else if (z < 10) { src = Wk + (size_t)(z - 5) * HH; dst = S + (size_t)z * HH; }
        else             { src = opw;                        dst = opwT; }
        int i0 = bx * 64, o0 = by * 64;
        int x = tid & 63, ys = tid >> 6;
        for (int rr = ys; rr < 64; rr += 4)
            T[rr][x] = src[(size_t)(o0 + rr) * Hn + i0 + x];
        __syncthreads();
        for (int rr = ys; rr < 64; rr += 4)
            dst[(size_t)(i0 + rr) * Hn + o0 + x] = f2bf(T[x][rr]);
    } else {
        int b3 = bid - PREP_NF2B - PREP_NTR;       // 0..29
        int ox = b3 % 3, y = b3 / 3;
        int o = ox * 256 + tid;
        int which = y / 5, l = y % 5;
        const float4* w = reinterpret_cast<const float4*>(ipw + (size_t)which * HH + (size_t)o * Hn);
        const float4* bv = reinterpret_cast<const float4*>(((which ? bk_lang : bq_lang) + (size_t)l * Hn));
        float s = 0.f;
        for (int j = 0; j < Hn / 4; ++j) {
            float4 a = w[j], b = bv[j];
            s += a.x * b.x + a.y * b.y + a.z * b.z + a.w * b.w;
        }
        s += ipb[which * Hn + o];
        beff[(size_t)(which * 5 + l) * Hn + o] = s;
    }
}

// ---- TM x 128 triple-buffered counted-vmcnt NT GEMM core (256 thr) ----
template<int TM>
__device__ __forceinline__ void gemm_core(
    const u16* __restrict__ A, int lda,
    const u16* __restrict__ Bw, int ldb,
    const float* __restrict__ bias,
    const float* __restrict__ addres,
    u16* __restrict__ outH, float* __restrict__ outF,
    u16* __restrict__ outVT, int ldc,
    int m0, int n0, float scale)
{
    constexpr int MI = TM / 32;          // acc rows per wave (4 or 8)
    constexpr int AIT = TM / 64;         // A loads per thread (2 or 4)
    __shared__ u16 As[3 * TM * 32];
    __shared__ u16 Bs[3 * 128 * 32];
    const int tid = threadIdx.x;
    const int lane = tid & 63, wave = tid >> 6;
    const int lrow = lane & 15, lquad = lane >> 4;
    const int wm = (wave >> 1) * (TM / 2), wn = (wave & 1) * 64;

    const u16* gA = A + (size_t)(m0 + (tid >> 2)) * lda + (tid & 3) * 8;
    const u16* gB = Bw + (size_t)(n0 + (tid >> 2)) * ldb + (tid & 3) * 8;

    f32x4 z = {0.f, 0.f, 0.f, 0.f};
    f32x4 acc[MI][4];
    #pragma unroll
    for (int i = 0; i < MI; ++i)
        #pragma unroll
        for (int j = 0; j < 4; ++j) acc[i][j] = z;

    auto stage = [&](int bs, int k0) {
        #pragma unroll
        for (int it = 0; it < AIT; ++it)
            glds16(gA + (size_t)(it * 64) * lda + k0, &As[bs * TM * 32 + (tid + 256 * it) * 8]);
        #pragma unroll
        for (int it = 0; it < 2; ++it)
            glds16(gB + (size_t)(it * 64) * ldb + k0, &Bs[bs * 128 * 32 + (tid + 256 * it) * 8]);
    };
    auto compute = [&](int bc) {
        const u16* Ab = &As[bc * TM * 32];
        const u16* Bb = &Bs[bc * 128 * 32];
        bf16x8 af[MI], bf_[4];
        #pragma unroll
        for (int i = 0; i < MI; ++i)
            af[i] = ld8(&Ab[(wm + i * 16 + lrow) * 32 + lquad * 8]);
        #pragma unroll
        for (int j = 0; j < 4; ++j)
            bf_[j] = ld8(&Bb[(wn + j * 16 + lrow) * 32 + lquad * 8]);
        #pragma unroll
        for (int i = 0; i < MI; ++i)
            #pragma unroll
            for (int j = 0; j < 4; ++j)
                acc[i][j] = __builtin_amdgcn_mfma_f32_16x16x32_bf16(af[i], bf_[j], acc[i][j], 0, 0, 0);
    };

    stage(0, 0);
    stage(1, 32);
    int bc = 0, bs = 2;
    for (int kt = 0; kt < 24; ++kt) {
        if (kt < 23) {
            if constexpr (TM == 256) {
                asm volatile("s_waitcnt vmcnt(6)" ::: "memory");
            } else {
                asm volatile("s_waitcnt vmcnt(4)" ::: "memory");
            }
        } else {
            asm volatile("s_waitcnt vmcnt(0)" ::: "memory");
        }
        __builtin_amdgcn_s_barrier();
        if (kt < 22) {
            stage(bs, (kt + 2) * 32);
            bs = (bs == 2) ? 0 : bs + 1;
        }
        compute(bc);
        bc = (bc == 2) ? 0 : bc + 1;
    }

    #pragma unroll
    for (int i = 0; i < MI; ++i) {
        #pragma unroll
        for (int j = 0; j < 4; ++j) {
            int col = n0 + wn + j * 16 + lrow;
            float bv = bias ? bias[col] : 0.f;
            if (outVT) {
                int row0 = m0 + wm + i * 16 + lquad * 4;
                int bb = row0 / Sn, s = row0 % Sn;
                int hh = col >> 6, dd = col & 63;
                u16x4 o;
                #pragma unroll
                for (int r = 0; r < 4; ++r) o[r] = f2bf((acc[i][j][r] + bv) * scale);
                *reinterpret_cast<u16x4*>(
                    outVT + (((size_t)bb * NHn + hh) * 64 + dd) * Sn + s) = o;
            } else {
                #pragma unroll
                for (int r = 0; r < 4; ++r) {
                    int row = m0 + wm + i * 16 + lquad * 4 + r;
                    float v = (acc[i][j][r] + bv) * scale;
                    if (addres) v += addres[(size_t)row * ldc + col];
                    if (outF) outF[(size_t)row * ldc + col] = v;
                    else      outH[(size_t)row * ldc + col] = f2bf(v);
                }
            }
        }
    }
}

// ------- 64x64 triple-buffered counted-vmcnt NT GEMM core (256 thr) -------
__device__ __forceinline__ void gemm64(
    const u16* __restrict__ A, const u16* __restrict__ Bw,
    u16* __restrict__ outH, int m0, int n0)
{
    __shared__ u16 As[3 * 64 * 32];
    __shared__ u16 Bs[3 * 64 * 32];
    const int tid = threadIdx.x;
    const int lane = tid & 63, wave = tid >> 6;
    const int lrow = lane & 15, lquad = lane >> 4;
    const int wm = (wave >> 1) * 32, wn = (wave & 1) * 32;

    const u16* gA = A + (size_t)(m0 + (tid >> 2)) * Hn + (tid & 3) * 8;
    const u16* gB = Bw + (size_t)(n0 + (tid >> 2)) * Hn + (tid & 3) * 8;

    f32x4 z = {0.f, 0.f, 0.f, 0.f};
    f32x4 acc[2][2];
    #pragma unroll
    for (int i = 0; i < 2; ++i)
        #pragma unroll
        for (int j = 0; j < 2; ++j) acc[i][j] = z;

    auto stage = [&](int bs, int k0) {
        glds16(gA + k0, &As[bs * 64 * 32 + tid * 8]);
        glds16(gB + k0, &Bs[bs * 64 * 32 + tid * 8]);
    };
    auto compute = [&](int bc) {
        const u16* Ab = &As[bc * 64 * 32];
        const u16* Bb = &Bs[bc * 64 * 32];
        bf16x8 af[2], bf_[2];
        #pragma unroll
        for (int i = 0; i < 2; ++i)
            af[i] = ld8(&Ab[(wm + i * 16 + lrow) * 32 + lquad * 8]);
        #pragma unroll
        for (int j = 0; j < 2; ++j)
            bf_[j] = ld8(&Bb[(wn + j * 16 + lrow) * 32 + lquad * 8]);
        #pragma unroll
        for (int i = 0; i < 2; ++i)
            #pragma unroll
            for (int j = 0; j < 2; ++j)
                acc[i][j] = __builtin_amdgcn_mfma_f32_16x16x32_bf16(af[i], bf_[j], acc[i][j], 0, 0, 0);
    };

    stage(0, 0);
    stage(1, 32);
    int bc = 0, bs = 2;
    for (int kt = 0; kt < 24; ++kt) {
        if (kt < 23) {
            asm volatile("s_waitcnt vmcnt(2)" ::: "memory");
        } else {
            asm volatile("s_waitcnt vmcnt(0)" ::: "memory");
        }
        __builtin_amdgcn_s_barrier();
        if (kt < 22) {
            stage(bs, (kt + 2) * 32);
            bs = (bs == 2) ? 0 : bs + 1;
        }
        compute(bc);
        bc = (bc == 2) ? 0 : bc + 1;
    }

    #pragma unroll
    for (int i = 0; i < 2; ++i)
        #pragma unroll
        for (int j = 0; j < 2; ++j) {
            int col = n0 + wn + j * 16 + lrow;
            #pragma unroll
            for (int r = 0; r < 4; ++r) {
                int row_ = m0 + wm + i * 16 + lquad * 4 + r;
                outH[(size_t)row_ * Hn + col] = f2bf(acc[i][j][r]);
            }
        }
}

// ---------------- GEMM wrapper kernels ----------------

// fused QKV projection, 256-row tiles.  grid (24, 6, 3): z=0 Q, z=1 K, z=2 V(T).
__global__ __launch_bounds__(256, 2) void k_gemm_qkv(
    const u16* __restrict__ A,
    const u16* __restrict__ Sq, const u16* __restrict__ Sk,
    const u16* __restrict__ Wv,
    const float* __restrict__ beff, const float* __restrict__ ipb,
    const int* __restrict__ lang,
    u16* __restrict__ outQ, u16* __restrict__ outK, u16* __restrict__ outVT)
{
    const size_t HH = (size_t)Hn * Hn;
    int z = blockIdx.z;
    int m0 = blockIdx.x * 256, n0 = blockIdx.y * 128;
    int l = lang[blockIdx.x / 3];
    if (z == 0) {
        gemm_core<256>(A, Hn, Sq + (size_t)l * HH, Hn, beff + (size_t)l * Hn,
                       nullptr, outQ, nullptr, nullptr, Hn, m0, n0, 0.125f);
    } else if (z == 1) {
        gemm_core<256>(A, Hn, Sk + (size_t)l * HH, Hn, beff + (size_t)(5 + l) * Hn,
                       nullptr, outK, nullptr, nullptr, Hn, m0, n0, 1.f);
    } else {
        gemm_core<256>(A, Hn, Wv, Hn, ipb + 2 * Hn,
                       nullptr, nullptr, nullptr, outVT, Hn, m0, n0, 1.f);
    }
}

// fused weight combine: z<5: Weffq_z = NT(wq, WqT_z); z>=5: Weffk.  grid (6,6,10)
__global__ __launch_bounds__(256) void k_comb10(
    const u16* __restrict__ ipwb, u16* __restrict__ S)
{
    const size_t HH = (size_t)Hn * Hn;
    int z = blockIdx.z;
    const u16* Aop = ipwb + (z < 5 ? 0 : HH);
    gemm_core<128>(Aop, Hn, S + (size_t)z * HH, Hn, nullptr, nullptr,
                   S + (size_t)(10 + z) * HH, nullptr, nullptr, Hn,
                   blockIdx.x * 128, blockIdx.y * 128, 1.f);
}

// chain first step: MT0_l = F7^T (transpose of align bf16, or I).  grid (12,12,5)
__global__ __launch_bounds__(256) void k_chain_first(
    const u16* __restrict__ alignb, const int* __restrict__ lang,
    u16* __restrict__ out5)
{
    const size_t HH = (size_t)Hn * Hn;
    int l = blockIdx.z, lj = lang[Bn - 1];
    u16* dst = out5 + (size_t)l * HH;
    int i0 = blockIdx.x * 64, o0 = blockIdx.y * 64;
    const int tid = threadIdx.x;
    if (lj == l) {
        #pragma unroll
        for (int it = 0; it < 2; ++it) {
            int s = tid + 256 * it;
            int ri = s >> 3, c8 = s & 7;
            s16x8 v;
            #pragma unroll
            for (int e = 0; e < 8; ++e)
                v[e] = (short)((i0 + ri == o0 + c8 * 8 + e) ? 0x3F80 : 0);
            *reinterpret_cast<s16x8*>(dst + (size_t)(i0 + ri) * Hn + o0 + c8 * 8) = v;
        }
    } else {
        const u16* src = alignb + ((size_t)l * NLn + lj) * HH;
        __shared__ u16 T[64][72];   // T[i][o] = src[o][i]
        #pragma unroll
        for (int it = 0; it < 2; ++it) {
            int s = tid + 256 * it;
            int r = s >> 3, c8 = s & 7;
            s16x8 v = *reinterpret_cast<const s16x8*>(
                src + (size_t)(o0 + r) * Hn + i0 + c8 * 8);
            #pragma unroll
            for (int e = 0; e < 8; ++e) T[c8 * 8 + e][r] = (u16)v[e];
        }
        __syncthreads();
        #pragma unroll
        for (int it = 0; it < 2; ++it) {
            int s = tid + 256 * it;
            int ri = s >> 3, c8 = s & 7;
            s16x8 v = *reinterpret_cast<const s16x8*>(&T[ri][c8 * 8]);
            *reinterpret_cast<s16x8*>(dst + (size_t)(i0 + ri) * Hn + o0 + c8 * 8) = v;
        }
    }
}

// chain step: Pout_l = Pin_l @ F_j^T.  grid (12,12,5), 64^2 tiles
__global__ __launch_bounds__(256) void k_chain64(
    const u16* __restrict__ Pin, u16* __restrict__ Pout,
    const u16* __restrict__ alignb, const int* __restrict__ lang, int j)
{
    const size_t HH = (size_t)Hn * Hn;
    int l = blockIdx.z;
    int lj = lang[j];
    const u16* Pl = Pin + (size_t)l * HH;
    u16* Po = Pout + (size_t)l * HH;
    int m0 = blockIdx.x * 64, n0 = blockIdx.y * 64;
    if (lj == l) {
        int tid = threadIdx.x;
        #pragma unroll
        for (int it = 0; it < 2; ++it) {
            int s = tid + 256 * it;
            int row = s >> 3, seg = s & 7;
            *reinterpret_cast<s16x8*>(Po + (size_t)(m0 + row) * Hn + n0 + seg * 8) =
                *reinterpret_cast<const s16x8*>(Pl + (size_t)(m0 + row) * Hn + n0 + seg * 8);
        }
    } else {
        const u16* F = alignb + ((size_t)l * NLn + lj) * HH;
        gemm64(Pl, F, Po, m0, n0);
    }
}

// U_l = NT(opwT, MT_l) + opb_eff GEMV.  grid 735.
__global__ __launch_bounds__(256) void k_uop(
    const u16* __restrict__ opwT, const u16* __restrict__ MT5,
    const float* __restrict__ opb,
    u16* __restrict__ U5, float* __restrict__ opbeff)
{
    const size_t HH = (size_t)Hn * Hn;
    int bid = blockIdx.x;
    if (bid < 720) {
        int z = bid / 144, r = bid % 144;
        gemm64(opwT, MT5 + (size_t)z * HH, U5 + (size_t)z * HH,
               (r % 12) * 64, (r / 12) * 64);
    } else {
        int b2 = bid - 720;
        int n = (b2 % 3) * 256 + threadIdx.x;
        int l = b2 / 3;
        const u16* mt = MT5 + ((size_t)l * Hn + n) * Hn;
        float s = 0.f;
        for (int k = 0; k < Hn; k += 8) {
            s16x8 v = *reinterpret_cast<const s16x8*>(mt + k);
            #pragma unroll
            for (int j = 0; j < 8; ++j) s += opb[k + j] * bf2f((u16)v[j]);
        }
        opbeff[(size_t)l * Hn + n] = s;
    }
}

// W_l = NT(projw, U_l) + bias2 GEMV.  grid 735.
__global__ __launch_bounds__(256) void k_wb2(
    const u16* __restrict__ pjwb, const u16* __restrict__ U5,
    const float* __restrict__ opbeff, const float* __restrict__ projw,
    const float* __restrict__ projb,
    u16* __restrict__ W5, float* __restrict__ bias2)
{
    const size_t HH = (size_t)Hn * Hn;
    int bid = blockIdx.x;
    if (bid < 720) {
        int z = bid / 144, r = bid % 144;
        gemm64(pjwb, U5 + (size_t)z * HH, W5 + (size_t)z * HH,
               (r % 12) * 64, (r / 12) * 64);
    } else {
        int b2 = bid - 720;
        int m = (b2 % 3) * 256 + threadIdx.x;
        int l = b2 / 3;
        const float4* w = reinterpret_cast<const float4*>(projw + (size_t)m * Hn);
        const float4* ob = reinterpret_cast<const float4*>(opbeff + (size_t)l * Hn);
        float s = 0.f;
        for (int j = 0; j < Hn / 4; ++j) {
            float4 a = w[j], b = ob[j];
            s += a.x * b.x + a.y * b.y + a.z * b.z + a.w * b.w;
        }
        bias2[(size_t)l * Hn + m] = s + projb[m];
    }
}

// x = NT(ctx, W[lang]) + bias2[lang] + hidden -> f32 out.  grid (48,6)
__global__ __launch_bounds__(256) void k_xfused(
    const u16* __restrict__ ctx, const u16* __restrict__ W5,
    const float* __restrict__ bias2, const int* __restrict__ lang,
    const float* __restrict__ hidden, float* __restrict__ x)
{
    int l = lang[blockIdx.x / 6];
    gemm_core<128>(ctx, Hn, W5 + (size_t)l * Hn * Hn, Hn, bias2 + (size_t)l * Hn,
                   hidden, nullptr, x, nullptr, Hn,
                   blockIdx.x * 128, blockIdx.y * 128, 1.f);
}

// ---------------- flash attention + align conversion, 512 threads ----------
// blocks [0,576): attn, one per (b, h, 128-q tile); 8 waves x 16 q-rows.
// K/V 2-buffer glds16, counted vmcnt(2), 2 barriers/iter.  LDS 50 KB ->
// 3 blocks/CU -> all 576 attn blocks resident (no tail generation).
// blocks [576, 1476): align f32 -> bf16 conversion, 8 float4s per thread.
__global__ __launch_bounds__(512) void k_attn_conv(
    const u16* __restrict__ Q, const u16* __restrict__ K,
    const u16* __restrict__ VT, u16* __restrict__ ctx,
    const float* __restrict__ alignf, u16* __restrict__ alignb)
{
    __shared__ u16 Ks[2][64 * 64];       // [key][d], seg-xor-swizzled
    __shared__ u16 Vs[2][64 * 64];       // [d][key], seg-xor-swizzled
    __shared__ u16 Pw[8][16 * 72];       // per-wave P, 16B-aligned stride

    const int bid = blockIdx.x, tid = threadIdx.x;
    if (bid >= 576) {
        int base = (bid - 576) * 4096 + tid;     // 900*4096 = 3686400 float4s
        #pragma unroll
        for (int it = 0; it < 8; ++it) {
            int i = base + it * 512;
            float4 v = reinterpret_cast<const float4*>(alignf)[i];
            u16x4 o;
            o[0] = f2bf(v.x); o[1] = f2bf(v.y); o[2] = f2bf(v.z); o[3] = f2bf(v.w);
            reinterpret_cast<u16x4*>(alignb)[i] = o;
        }
        return;
    }

    const int q0 = (bid % 6) * 128, h = (bid / 6) % NHn, bz = bid / 72;
    const int wave = tid >> 6, lane = tid & 63;
    const int lrow = lane & 15, lquad = lane >> 4;
    const int sw = lrow & 7;

    const u16* Qp = Q + ((size_t)(bz * Sn + q0 + wave * 16 + lrow)) * Hn + h * HDn;
    const u16* Kb = K + (size_t)bz * Sn * Hn + h * HDn;
    const u16* Vb = VT + ((size_t)(bz * NHn + h) * 64) * Sn;   // row d, stride Sn

    bf16x8 qa0 = ld8(Qp + lquad * 8);
    bf16x8 qa1 = ld8(Qp + 32 + lquad * 8);

    f32x4 z4 = {0.f, 0.f, 0.f, 0.f};
    float m_r[4], l_l[4];
    f32x4 oacc[4];
    #pragma unroll
    for (int r = 0; r < 4; ++r) { m_r[r] = -1e30f; l_l[r] = 0.f; }
    #pragma unroll
    for (int jd = 0; jd < 4; ++jd) oacc[jd] = z4;

    // staging addresses: 512 16B segs each for K and V
    const int krow = tid >> 3, kp = (tid & 7) ^ (krow & 7);
    const u16* kg = Kb + (size_t)krow * Hn + kp * 8;
    const u16* vg = Vb + (size_t)krow * Sn + kp * 8;   // d = krow

    auto stage = [&](int bs, int t0) {
        glds16(kg + (size_t)t0 * Hn, &Ks[bs][tid * 8]);
        glds16(vg + t0, &Vs[bs][tid * 8]);
    };

    auto compute = [&](int bc) {
        f32x4 sc[4];
        __builtin_amdgcn_s_setprio(1);
        #pragma unroll
        for (int j = 0; j < 4; ++j) {
            int base = (j * 16 + lrow) * 64 + ((lquad ^ sw) * 8);
            f32x4 s = __builtin_amdgcn_mfma_f32_16x16x32_bf16(qa0, ld8(&Ks[bc][base]), z4, 0, 0, 0);
            sc[j] = __builtin_amdgcn_mfma_f32_16x16x32_bf16(qa1, ld8(&Ks[bc][base ^ 32]), s, 0, 0, 0);
        }
        __builtin_amdgcn_s_setprio(0);
        float tmax[4];
        #pragma unroll
        for (int r = 0; r < 4; ++r)
            tmax[r] = fmaxf(fmaxf(sc[0][r], sc[1][r]), fmaxf(sc[2][r], sc[3][r]));
        #pragma unroll
        for (int off = 1; off < 16; off <<= 1)
            #pragma unroll
            for (int r = 0; r < 4; ++r)
                tmax[r] = fmaxf(tmax[r], __shfl_xor(tmax[r], off));
        // defer-max (THR=8): rescale only when max grows past threshold.
        // P values then bounded by e^8 ~ 2981 (fine in bf16/f32 accum).
        bool grow = (tmax[0] > m_r[0] + 8.f) | (tmax[1] > m_r[1] + 8.f) |
                    (tmax[2] > m_r[2] + 8.f) | (tmax[3] > m_r[3] + 8.f);
        if (grow) {
            #pragma unroll
            for (int r = 0; r < 4; ++r) {
                float mn = fmaxf(m_r[r], tmax[r]);
                float a = __expf(m_r[r] - mn);
                m_r[r] = mn;
                l_l[r] *= a;
                #pragma unroll
                for (int jd = 0; jd < 4; ++jd) oacc[jd][r] *= a;
            }
        }
        float ps[4] = {0.f, 0.f, 0.f, 0.f};
        #pragma unroll
        for (int j = 0; j < 4; ++j)
            #pragma unroll
            for (int r = 0; r < 4; ++r) {
                float p = __expf(sc[j][r] - m_r[r]);
                ps[r] += p;
                Pw[wave][(lquad * 4 + r) * 72 + j * 16 + lrow] = f2bf(p);
            }
        #pragma unroll
        for (int r = 0; r < 4; ++r) l_l[r] += ps[r];
        bf16x8 pa0 = ld8(&Pw[wave][lrow * 72 + lquad * 8]);
        bf16x8 pa1 = ld8(&Pw[wave][lrow * 72 + 32 + lquad * 8]);
        __builtin_amdgcn_s_setprio(1);
        #pragma unroll
        for (int jd = 0; jd < 4; ++jd) {
            int vbase = (jd * 16 + lrow) * 64 + ((lquad ^ sw) * 8);
            oacc[jd] = __builtin_amdgcn_mfma_f32_16x16x32_bf16(pa0, ld8(&Vs[bc][vbase]), oacc[jd], 0, 0, 0);
            oacc[jd] = __builtin_amdgcn_mfma_f32_16x16x32_bf16(pa1, ld8(&Vs[bc][vbase ^ 32]), oacc[jd], 0, 0, 0);
        }
        __builtin_amdgcn_s_setprio(0);
    };

    // 2-buffer pipeline: wait vmcnt(2) [tile kt ready, kt+1 in flight];
    // barrier; compute(kt); barrier; stage(kt+2) into the buffer compute
    // just finished reading.  Never drains to 0 until the tail.
    stage(0, 0);
    stage(1, 64);
    for (int kt = 0; kt < 12; ++kt) {
        if (kt < 11) {
            asm volatile("s_waitcnt vmcnt(2)" ::: "memory");
        } else {
            asm volatile("s_waitcnt vmcnt(0)" ::: "memory");
        }
        __builtin_amdgcn_s_barrier();
        compute(kt & 1);
        if (kt < 10) {
            __builtin_amdgcn_s_barrier();
            stage(kt & 1, (kt + 2) * 64);
        }
    }

    // final 16-lane reduction of the denominators
    #pragma unroll
    for (int off = 1; off < 16; off <<= 1)
        #pragma unroll
        for (int r = 0; r < 4; ++r)
            l_l[r] += __shfl_xor(l_l[r], off);

    float rl[4];
    #pragma unroll
    for (int r = 0; r < 4; ++r) rl[r] = 1.f / l_l[r];
    #pragma unroll
    for (int jd = 0; jd < 4; ++jd)
        #pragma unroll
        for (int r = 0; r < 4; ++r) {
            size_t row = (size_t)bz * Sn + q0 + wave * 16 + lquad * 4 + r;
            ctx[row * Hn + h * HDn + jd * 16 + lrow] = f2bf(oacc[jd][r] * rl[r]);
        }
}

// layernorm in-place on f32 d_out.  grid B*S, block 64
__global__ __launch_bounds__(64) void k_ln(
    float* x, const float* __restrict__ g, const float* __restrict__ beta)
{
    size_t row = blockIdx.x;
    float* xr = x + row * Hn;
    int lane = threadIdx.x;
    float v[12];
    float s = 0.f, ss = 0.f;
    #pragma unroll
    for (int i = 0; i < 12; ++i) {
        v[i] = xr[lane + i * 64];
        s += v[i];
        ss += v[i] * v[i];
    }
    #pragma unroll
    for (int off = 1; off < 64; off <<= 1) {
        s  += __shfl_xor(s, off);
        ss += __shfl_xor(ss, off);
    }
    float mu = s * (1.f / Hn);
    float var = ss * (1.f / Hn) - mu * mu;
    float inv = rsqrtf(var + 1e-5f);
    #pragma unroll
    for (int i = 0; i < 12; ++i) {
        int c = lane + i * 64;
        xr[c] = (v[i] - mu) * inv * g[c] + beta[c];
    }
}

// ---------------- launch ----------------
extern "C" void kernel_launch(void* const* d_in, const int* in_sizes, int n_in,
                              void* d_out, int out_size, void* d_ws, size_t ws_size,
                              hipStream_t stream)
{
    (void)in_sizes; (void)n_in; (void)out_size; (void)ws_size;

    const float* hidden  = (const float*)d_in[0];
    const int*   lang    = (const int*)d_in[1];
    const float* Wq_lang = (const float*)d_in[3];
    const float* bq_lang = (const float*)d_in[4];
    const float* Wk_lang = (const float*)d_in[5];
    const float* bk_lang = (const float*)d_in[6];
    const float* ipw     = (const float*)d_in[7];
    const float* ipb     = (const float*)d_in[8];
    const float* opw     = (const float*)d_in[9];
    const float* opb     = (const float*)d_in[10];
    const float* align   = (const float*)d_in[11];
    const float* projw   = (const float*)d_in[12];
    const float* projb   = (const float*)d_in[13];
    const float* ln_g    = (const float*)d_in[14];
    const float* ln_b    = (const float*)d_in[15];
    float* out = (float*)d_out;

    const size_t HH  = (size_t)Hn * Hn;          // 589824
    const size_t BSH = (size_t)Bn * Sn * Hn;     // 4718592
    const size_t AHH = (size_t)NLn * NLn * HH;   // 14745600

    u16* rA = (u16*)d_ws;        // hb -> ctx
    u16* rB = rA + BSH;          // Q -> U
    u16* rC = rB + BSH;          // K -> MT ping -> W
    u16* rD = rC + BSH;          // V^T -> MT pong (final)
    u16* ipwb = rD + BSH;        // wq|wk|wv bf16 (3*HH)
    u16* pjwb = ipwb + 3 * HH;   // HH
    u16* opwT = pjwb + HH;       // HH
    u16* alignb = opwT + HH;     // 25*HH bf16; pre-attn: weight scratch S[0..20)
    float* beff   = (float*)(alignb + AHH);   // 2*5*768 f32
    float* opbeff = beff + 10 * Hn;           // 5*768 f32
    float* bias2  = opbeff + 5 * Hn;          // 5*768 f32

    u16* S = alignb;             // scratch: WqT[0..5) WkT[5..10) Weffq[10..15) Weffk[15..20)

    // fused prep: conversions + 11 transposes + QK bias folds (one launch)
    k_prep<<<(unsigned)(PREP_NF2B + PREP_NTR + 30), 256, 0, stream>>>(
        hidden, rA, ipw, ipwb, projw, pjwb,
        Wq_lang, Wk_lang, opw, S, opwT,
        ipb, bq_lang, bk_lang, beff);

    // Weffq/Weffk (both in one launch) -> S[10..20)
    k_comb10<<<dim3(6, 6, 10), 256, 0, stream>>>(ipwb, S);

    // fused QKV: Q*(1/8) -> rB, K -> rC, V^T -> rD.  256-row tiles.
    k_gemm_qkv<<<dim3(24, 6, 3), 256, 0, stream>>>(
        rA, S + 10 * HH, S + 15 * HH, ipwb + 2 * HH, beff, ipb, lang, rB, rC, rD);

    // attention (ctx -> rA) + align f32->bf16 conversion (S scratch now dead)
    k_attn_conv<<<1476, 512, 0, stream>>>(rB, rC, rD, rA, align, alignb);

    // language chain: first step transposing copy (MT0 = F7^T), then 7 GEMM steps
    k_chain_first<<<dim3(12, 12, NLn), 256, 0, stream>>>(alignb, lang, rC);
    u16* Pin = rC;
    u16* Pout = rD;
    for (int j = Bn - 2; j >= 0; --j) {
        k_chain64<<<dim3(12, 12, NLn), 256, 0, stream>>>(Pin, Pout, alignb, lang, j);
        u16* t = Pin; Pin = Pout; Pout = t;
    }
    // 7 steps -> final MT in rD (Pin == rD)

    // U_l = opw^T . M_l  (+ opb_eff GEMV)  -> rB (Q dead)
    k_uop<<<735, 256, 0, stream>>>(opwT, Pin, opb, rB, opbeff);
    // W_l = projw . U_l  (+ bias2 GEMV)    -> rC (chain ping dead)
    k_wb2<<<735, 256, 0, stream>>>(pjwb, rB, opbeff, projw, projb, rC, bias2);

    // x = ctx . W[lang]^T + bias2 + hidden -> d_out (f32)
    k_xfused<<<dim3(48, 6), 256, 0, stream>>>(rA, rC, bias2, lang, hidden, out);
    // layernorm in place
    k_ln<<<(unsigned)(Bn * Sn), 64, 0, stream>>>(out, ln_g, ln_b);
}

// Round 8
// 482.966 us; speedup vs baseline: 1.5032x; 1.0123x over previous
//
#include <hip/hip_runtime.h>

// ---------------- constants ----------------
#define Bn 8
#define Sn 768
#define Hn 768
#define NHn 12
#define HDn 64
#define NLn 5

typedef unsigned short u16;
typedef __bf16 bf16x8 __attribute__((ext_vector_type(8)));
typedef short s16x8 __attribute__((ext_vector_type(8)));
typedef float f32x4 __attribute__((ext_vector_type(4)));
typedef unsigned short u16x4 __attribute__((ext_vector_type(4)));

static __device__ __forceinline__ float bf2f(u16 v) {
    return __uint_as_float(((unsigned)v) << 16);
}
static __device__ __forceinline__ u16 f2bf(float f) {
    unsigned u = __float_as_uint(f);
    unsigned r = u + 0x7fffu + ((u >> 16) & 1u);
    return (u16)(r >> 16);
}
static __device__ __forceinline__ bf16x8 ld8(const u16* p) {
    return *reinterpret_cast<const bf16x8*>(p);
}
static __device__ __forceinline__ void glds16(const u16* g, u16* l) {
    __builtin_amdgcn_global_load_lds(
        (const __attribute__((address_space(1))) void*)g,
        (__attribute__((address_space(3))) void*)l, 16, 0, 0);
}

// ---------------- fused prep: f32->bf16 conversions + transposes + bias folds
#define PREP_NF2B 6912
#define PREP_NTR  1584
__global__ __launch_bounds__(256) void k_prep(
    const float* __restrict__ hidden, u16* __restrict__ hb,
    const float* __restrict__ ipw, u16* __restrict__ ipwb,
    const float* __restrict__ projw, u16* __restrict__ pjwb,
    const float* __restrict__ Wq, const float* __restrict__ Wk,
    const float* __restrict__ opw, u16* __restrict__ S, u16* __restrict__ opwT,
    const float* __restrict__ ipb,
    const float* __restrict__ bq_lang, const float* __restrict__ bk_lang,
    float* __restrict__ beff)
{
    __shared__ float T[64][65];
    const size_t HH = (size_t)Hn * Hn;
    const int bid = blockIdx.x, tid = threadIdx.x;
    if (bid < PREP_NF2B) {
        const int n0 = (int)(Bn * Sn * Hn / 4), n1 = (int)(3 * HH / 4), n2 = (int)(HH / 4);
        int i = bid * 256 + tid;
        const float* s; u16* d; int off;
        if (i < n0)                { s = hidden; d = hb;   off = i; }
        else if (i < n0 + n1)      { s = ipw;    d = ipwb; off = i - n0; }
        else if (i < n0 + n1 + n2) { s = projw;  d = pjwb; off = i - n0 - n1; }
        else return;
        float4 v = reinterpret_cast<const float4*>(s)[off];
        u16x4 o;
        o[0] = f2bf(v.x); o[1] = f2bf(v.y); o[2] = f2bf(v.z); o[3] = f2bf(v.w);
        reinterpret_cast<u16x4*>(d)[off] = o;
    } else if (bid < PREP_NF2B + PREP_NTR) {
        int b2 = bid - PREP_NF2B;
        int z = b2 / 144, r = b2 % 144;
        int bx = r % 12, by = r / 12;
        const float* src;
        u16* dst;
        if (z < 5)       { src = Wq + (size_t)z * HH;       dst = S + (size_t)z * HH; }
        else if (z < 10) { src = Wk + (size_t)(z - 5) * HH; dst = S + (size_t)z * HH; }
        else             { src = opw;                        dst = opwT; }
        int i0 = bx * 64, o0 = by * 64;
        int x = tid & 63, ys = tid >> 6;
        for (int rr = ys; rr < 64; rr += 4)
            T[rr][x] = src[(size_t)(o0 + rr) * Hn + i0 + x];
        __syncthreads();
        for (int rr = ys; rr < 64; rr += 4)
            dst[(size_t)(i0 + rr) * Hn + o0 + x] = f2bf(T[x][rr]);
    } else {
        int b3 = bid - PREP_NF2B - PREP_NTR;       // 0..29
        int ox = b3 % 3, y = b3 / 3;
        int o = ox * 256 + tid;
        int which = y / 5, l = y % 5;
        const float4* w = reinterpret_cast<const float4*>(ipw + (size_t)which * HH + (size_t)o * Hn);
        const float4* bv = reinterpret_cast<const float4*>(((which ? bk_lang : bq_lang) + (size_t)l * Hn));
        float s = 0.f;
        for (int j = 0; j < Hn / 4; ++j) {
            float4 a = w[j], b = bv[j];
            s += a.x * b.x + a.y * b.y + a.z * b.z + a.w * b.w;
        }
        s += ipb[which * Hn + o];
        beff[(size_t)(which * 5 + l) * Hn + o] = s;
    }
}

// ---- TM x 128 triple-buffered counted-vmcnt NT GEMM core (256 thr) ----
template<int TM>
__device__ __forceinline__ void gemm_core(
    const u16* __restrict__ A, int lda,
    const u16* __restrict__ Bw, int ldb,
    const float* __restrict__ bias,
    const float* __restrict__ addres,
    u16* __restrict__ outH, float* __restrict__ outF,
    u16* __restrict__ outVT, int ldc,
    int m0, int n0, float scale)
{
    constexpr int MI = TM / 32;          // acc rows per wave (4 or 8)
    constexpr int AIT = TM / 64;         // A loads per thread (2 or 4)
    __shared__ u16 As[3 * TM * 32];
    __shared__ u16 Bs[3 * 128 * 32];
    const int tid = threadIdx.x;
    const int lane = tid & 63, wave = tid >> 6;
    const int lrow = lane & 15, lquad = lane >> 4;
    const int wm = (wave >> 1) * (TM / 2), wn = (wave & 1) * 64;

    const u16* gA = A + (size_t)(m0 + (tid >> 2)) * lda + (tid & 3) * 8;
    const u16* gB = Bw + (size_t)(n0 + (tid >> 2)) * ldb + (tid & 3) * 8;

    f32x4 z = {0.f, 0.f, 0.f, 0.f};
    f32x4 acc[MI][4];
    #pragma unroll
    for (int i = 0; i < MI; ++i)
        #pragma unroll
        for (int j = 0; j < 4; ++j) acc[i][j] = z;

    auto stage = [&](int bs, int k0) {
        #pragma unroll
        for (int it = 0; it < AIT; ++it)
            glds16(gA + (size_t)(it * 64) * lda + k0, &As[bs * TM * 32 + (tid + 256 * it) * 8]);
        #pragma unroll
        for (int it = 0; it < 2; ++it)
            glds16(gB + (size_t)(it * 64) * ldb + k0, &Bs[bs * 128 * 32 + (tid + 256 * it) * 8]);
    };
    auto compute = [&](int bc) {
        const u16* Ab = &As[bc * TM * 32];
        const u16* Bb = &Bs[bc * 128 * 32];
        bf16x8 af[MI], bf_[4];
        #pragma unroll
        for (int i = 0; i < MI; ++i)
            af[i] = ld8(&Ab[(wm + i * 16 + lrow) * 32 + lquad * 8]);
        #pragma unroll
        for (int j = 0; j < 4; ++j)
            bf_[j] = ld8(&Bb[(wn + j * 16 + lrow) * 32 + lquad * 8]);
        #pragma unroll
        for (int i = 0; i < MI; ++i)
            #pragma unroll
            for (int j = 0; j < 4; ++j)
                acc[i][j] = __builtin_amdgcn_mfma_f32_16x16x32_bf16(af[i], bf_[j], acc[i][j], 0, 0, 0);
    };

    stage(0, 0);
    stage(1, 32);
    int bc = 0, bs = 2;
    for (int kt = 0; kt < 24; ++kt) {
        if (kt < 23) {
            if constexpr (TM == 256) {
                asm volatile("s_waitcnt vmcnt(6)" ::: "memory");
            } else {
                asm volatile("s_waitcnt vmcnt(4)" ::: "memory");
            }
        } else {
            asm volatile("s_waitcnt vmcnt(0)" ::: "memory");
        }
        __builtin_amdgcn_s_barrier();
        if (kt < 22) {
            stage(bs, (kt + 2) * 32);
            bs = (bs == 2) ? 0 : bs + 1;
        }
        compute(bc);
        bc = (bc == 2) ? 0 : bc + 1;
    }

    #pragma unroll
    for (int i = 0; i < MI; ++i) {
        #pragma unroll
        for (int j = 0; j < 4; ++j) {
            int col = n0 + wn + j * 16 + lrow;
            float bv = bias ? bias[col] : 0.f;
            if (outVT) {
                int row0 = m0 + wm + i * 16 + lquad * 4;
                int bb = row0 / Sn, s = row0 % Sn;
                int hh = col >> 6, dd = col & 63;
                u16x4 o;
                #pragma unroll
                for (int r = 0; r < 4; ++r) o[r] = f2bf((acc[i][j][r] + bv) * scale);
                *reinterpret_cast<u16x4*>(
                    outVT + (((size_t)bb * NHn + hh) * 64 + dd) * Sn + s) = o;
            } else {
                #pragma unroll
                for (int r = 0; r < 4; ++r) {
                    int row = m0 + wm + i * 16 + lquad * 4 + r;
                    float v = (acc[i][j][r] + bv) * scale;
                    if (addres) v += addres[(size_t)row * ldc + col];
                    if (outF) outF[(size_t)row * ldc + col] = v;
                    else      outH[(size_t)row * ldc + col] = f2bf(v);
                }
            }
        }
    }
}

// -- 64x64 triple-buffered counted-vmcnt NT GEMM core (256 thr), epilogue opts --
__device__ __forceinline__ void gemm64(
    const u16* __restrict__ A, const u16* __restrict__ Bw,
    const float* __restrict__ bias, const float* __restrict__ addres,
    u16* __restrict__ outH, float* __restrict__ outF,
    int m0, int n0)
{
    __shared__ u16 As[3 * 64 * 32];
    __shared__ u16 Bs[3 * 64 * 32];
    const int tid = threadIdx.x;
    const int lane = tid & 63, wave = tid >> 6;
    const int lrow = lane & 15, lquad = lane >> 4;
    const int wm = (wave >> 1) * 32, wn = (wave & 1) * 32;

    const u16* gA = A + (size_t)(m0 + (tid >> 2)) * Hn + (tid & 3) * 8;
    const u16* gB = Bw + (size_t)(n0 + (tid >> 2)) * Hn + (tid & 3) * 8;

    f32x4 z = {0.f, 0.f, 0.f, 0.f};
    f32x4 acc[2][2];
    #pragma unroll
    for (int i = 0; i < 2; ++i)
        #pragma unroll
        for (int j = 0; j < 2; ++j) acc[i][j] = z;

    auto stage = [&](int bs, int k0) {
        glds16(gA + k0, &As[bs * 64 * 32 + tid * 8]);
        glds16(gB + k0, &Bs[bs * 64 * 32 + tid * 8]);
    };
    auto compute = [&](int bc) {
        const u16* Ab = &As[bc * 64 * 32];
        const u16* Bb = &Bs[bc * 64 * 32];
        bf16x8 af[2], bf_[2];
        #pragma unroll
        for (int i = 0; i < 2; ++i)
            af[i] = ld8(&Ab[(wm + i * 16 + lrow) * 32 + lquad * 8]);
        #pragma unroll
        for (int j = 0; j < 2; ++j)
            bf_[j] = ld8(&Bb[(wn + j * 16 + lrow) * 32 + lquad * 8]);
        #pragma unroll
        for (int i = 0; i < 2; ++i)
            #pragma unroll
            for (int j = 0; j < 2; ++j)
                acc[i][j] = __builtin_amdgcn_mfma_f32_16x16x32_bf16(af[i], bf_[j], acc[i][j], 0, 0, 0);
    };

    stage(0, 0);
    stage(1, 32);
    int bc = 0, bs = 2;
    for (int kt = 0; kt < 24; ++kt) {
        if (kt < 23) {
            asm volatile("s_waitcnt vmcnt(2)" ::: "memory");
        } else {
            asm volatile("s_waitcnt vmcnt(0)" ::: "memory");
        }
        __builtin_amdgcn_s_barrier();
        if (kt < 22) {
            stage(bs, (kt + 2) * 32);
            bs = (bs == 2) ? 0 : bs + 1;
        }
        compute(bc);
        bc = (bc == 2) ? 0 : bc + 1;
    }

    #pragma unroll
    for (int i = 0; i < 2; ++i)
        #pragma unroll
        for (int j = 0; j < 2; ++j) {
            int col = n0 + wn + j * 16 + lrow;
            float bv = bias ? bias[col] : 0.f;
            #pragma unroll
            for (int r = 0; r < 4; ++r) {
                int row_ = m0 + wm + i * 16 + lquad * 4 + r;
                float v = acc[i][j][r] + bv;
                if (addres) v += addres[(size_t)row_ * Hn + col];
                if (outF) outF[(size_t)row_ * Hn + col] = v;
                else      outH[(size_t)row_ * Hn + col] = f2bf(v);
            }
        }
}

// ---------------- GEMM wrapper kernels ----------------

// fused QKV projection, 128^2 tiles (864 blocks, 3 blocks/CU).
// grid (48, 6, 3): z=0 Q, z=1 K, z=2 V(T layout).
__global__ __launch_bounds__(256) void k_gemm_qkv(
    const u16* __restrict__ A,
    const u16* __restrict__ Sq, const u16* __restrict__ Sk,
    const u16* __restrict__ Wv,
    const float* __restrict__ beff, const float* __restrict__ ipb,
    const int* __restrict__ lang,
    u16* __restrict__ outQ, u16* __restrict__ outK, u16* __restrict__ outVT)
{
    const size_t HH = (size_t)Hn * Hn;
    int z = blockIdx.z;
    int m0 = blockIdx.x * 128, n0 = blockIdx.y * 128;
    int l = lang[blockIdx.x / 6];
    if (z == 0) {
        gemm_core<128>(A, Hn, Sq + (size_t)l * HH, Hn, beff + (size_t)l * Hn,
                       nullptr, outQ, nullptr, nullptr, Hn, m0, n0, 0.125f);
    } else if (z == 1) {
        gemm_core<128>(A, Hn, Sk + (size_t)l * HH, Hn, beff + (size_t)(5 + l) * Hn,
                       nullptr, outK, nullptr, nullptr, Hn, m0, n0, 1.f);
    } else {
        gemm_core<128>(A, Hn, Wv, Hn, ipb + 2 * Hn,
                       nullptr, nullptr, nullptr, outVT, Hn, m0, n0, 1.f);
    }
}

// fused weight combine, 64^2 tiles (1440 blocks, 6 blocks/CU).
// z<5: Weffq_z = NT(wq, WqT_z); z>=5: Weffk.  grid (12,12,10)
__global__ __launch_bounds__(256) void k_comb10(
    const u16* __restrict__ ipwb, u16* __restrict__ S)
{
    const size_t HH = (size_t)Hn * Hn;
    int z = blockIdx.z;
    const u16* Aop = ipwb + (z < 5 ? 0 : HH);
    gemm64(Aop, S + (size_t)z * HH, nullptr, nullptr,
           S + (size_t)(10 + z) * HH, nullptr,
           blockIdx.x * 64, blockIdx.y * 64);
}

// chain first step: P0_l = F7^T (transpose of align bf16, or I) -> rC.  grid (12,12,5)
__global__ __launch_bounds__(256) void k_chain_first(
    const u16* __restrict__ alignb, const int* __restrict__ lang,
    u16* __restrict__ out5)
{
    const size_t HH = (size_t)Hn * Hn;
    int l = blockIdx.z, lj = lang[Bn - 1];
    u16* dst = out5 + (size_t)l * HH;
    int i0 = blockIdx.x * 64, o0 = blockIdx.y * 64;
    const int tid = threadIdx.x;
    if (lj == l) {
        #pragma unroll
        for (int it = 0; it < 2; ++it) {
            int s = tid + 256 * it;
            int ri = s >> 3, c8 = s & 7;
            s16x8 v;
            #pragma unroll
            for (int e = 0; e < 8; ++e)
                v[e] = (short)((i0 + ri == o0 + c8 * 8 + e) ? 0x3F80 : 0);
            *reinterpret_cast<s16x8*>(dst + (size_t)(i0 + ri) * Hn + o0 + c8 * 8) = v;
        }
    } else {
        const u16* src = alignb + ((size_t)l * NLn + lj) * HH;
        __shared__ u16 T[64][72];   // T[i][o] = src[o][i]
        #pragma unroll
        for (int it = 0; it < 2; ++it) {
            int s = tid + 256 * it;
            int r = s >> 3, c8 = s & 7;
            s16x8 v = *reinterpret_cast<const s16x8*>(
                src + (size_t)(o0 + r) * Hn + i0 + c8 * 8);
            #pragma unroll
            for (int e = 0; e < 8; ++e) T[c8 * 8 + e][r] = (u16)v[e];
        }
        __syncthreads();
        #pragma unroll
        for (int it = 0; it < 2; ++it) {
            int s = tid + 256 * it;
            int ri = s >> 3, c8 = s & 7;
            s16x8 v = *reinterpret_cast<const s16x8*>(&T[ri][c8 * 8]);
            *reinterpret_cast<s16x8*>(dst + (size_t)(i0 + ri) * Hn + o0 + c8 * 8) = v;
        }
    }
}

// chain step j (6..0): non-identity only; ping-pong tracked by parity of
// non-identity steps already done (computed from lang, no host knowledge).
// identity steps are complete no-ops (no copy).  grid (12,12,5)
__global__ __launch_bounds__(256) void k_chain64(
    u16* __restrict__ rC, u16* __restrict__ rD,
    const u16* __restrict__ alignb, const int* __restrict__ lang, int j)
{
    const size_t HH = (size_t)Hn * Hn;
    int l = blockIdx.z;
    int lj = lang[j];
    if (lj == l) return;                       // identity: nothing to do
    int c = 0;
    for (int jj = j + 1; jj <= 6; ++jj) c += (lang[jj] != l) ? 1 : 0;
    const u16* in = ((c & 1) ? rD : rC) + (size_t)l * HH;
    u16* out = ((c & 1) ? rC : rD) + (size_t)l * HH;
    const u16* F = alignb + ((size_t)l * NLn + lj) * HH;
    gemm64(in, F, nullptr, nullptr, out, nullptr,
           blockIdx.x * 64, blockIdx.y * 64);
}

// U_l = NT(opwT, MT_l) + opb_eff GEMV.  MT_l read from parity buffer.  grid 735.
__global__ __launch_bounds__(256) void k_uop(
    const u16* __restrict__ opwT,
    const u16* __restrict__ rC, const u16* __restrict__ rD,
    const int* __restrict__ lang, const float* __restrict__ opb,
    u16* __restrict__ U5, float* __restrict__ opbeff)
{
    const size_t HH = (size_t)Hn * Hn;
    int bid = blockIdx.x;
    int l = (bid < 720) ? (bid / 144) : ((bid - 720) / 3);
    int pf = 0;
    for (int jj = 0; jj <= 6; ++jj) pf += (lang[jj] != l) ? 1 : 0;
    const u16* MT = ((pf & 1) ? rD : rC) + (size_t)l * HH;
    if (bid < 720) {
        int r = bid % 144;
        gemm64(opwT, MT, nullptr, nullptr, U5 + (size_t)l * HH, nullptr,
               (r % 12) * 64, (r / 12) * 64);
    } else {
        int b2 = bid - 720;
        int n = (b2 % 3) * 256 + threadIdx.x;
        const u16* mt = MT + (size_t)n * Hn;
        float s = 0.f;
        for (int k = 0; k < Hn; k += 8) {
            s16x8 v = *reinterpret_cast<const s16x8*>(mt + k);
            #pragma unroll
            for (int jq = 0; jq < 8; ++jq) s += opb[k + jq] * bf2f((u16)v[jq]);
        }
        opbeff[(size_t)l * Hn + n] = s;
    }
}

// W_l = NT(projw, U_l) + bias2 GEMV.  grid 735.
__global__ __launch_bounds__(256) void k_wb2(
    const u16* __restrict__ pjwb, const u16* __restrict__ U5,
    const float* __restrict__ opbeff, const float* __restrict__ projw,
    const float* __restrict__ projb,
    u16* __restrict__ W5, float* __restrict__ bias2)
{
    const size_t HH = (size_t)Hn * Hn;
    int bid = blockIdx.x;
    if (bid < 720) {
        int z = bid / 144, r = bid % 144;
        gemm64(pjwb, U5 + (size_t)z * HH, nullptr, nullptr,
               W5 + (size_t)z * HH, nullptr,
               (r % 12) * 64, (r / 12) * 64);
    } else {
        int b2 = bid - 720;
        int m = (b2 % 3) * 256 + threadIdx.x;
        int l = b2 / 3;
        const float4* w = reinterpret_cast<const float4*>(projw + (size_t)m * Hn);
        const float4* ob = reinterpret_cast<const float4*>(opbeff + (size_t)l * Hn);
        float s = 0.f;
        for (int jq = 0; jq < Hn / 4; ++jq) {
            float4 a = w[jq], b = ob[jq];
            s += a.x * b.x + a.y * b.y + a.z * b.z + a.w * b.w;
        }
        bias2[(size_t)l * Hn + m] = s + projb[m];
    }
}

// x = NT(ctx, W[lang]) + bias2[lang] + hidden -> f32 out.  64^2 tiles, grid (96,12)
__global__ __launch_bounds__(256) void k_xfused(
    const u16* __restrict__ ctx, const u16* __restrict__ W5,
    const float* __restrict__ bias2, const int* __restrict__ lang,
    const float* __restrict__ hidden, float* __restrict__ x)
{
    int l = lang[blockIdx.x / 12];
    gemm64(ctx, W5 + (size_t)l * Hn * Hn, bias2 + (size_t)l * Hn,
           hidden, nullptr, x,
           blockIdx.x * 64, blockIdx.y * 64);
}

// ---------------- flash attention + align conversion, 512 threads ----------
// blocks [0,576): attn, one per (b, h, 128-q tile); 8 waves x 16 q-rows.
// K/V 2-buffer glds16, counted vmcnt(2), 2 barriers/iter.  LDS 50 KB ->
// 3 blocks/CU -> all 576 attn blocks resident (no tail generation).
// blocks [576, 1476): align f32 -> bf16 conversion, 8 float4s per thread.
__global__ __launch_bounds__(512) void k_attn_conv(
    const u16* __restrict__ Q, const u16* __restrict__ K,
    const u16* __restrict__ VT, u16* __restrict__ ctx,
    const float* __restrict__ alignf, u16* __restrict__ alignb)
{
    __shared__ u16 Ks[2][64 * 64];       // [key][d], seg-xor-swizzled
    __shared__ u16 Vs[2][64 * 64];       // [d][key], seg-xor-swizzled
    __shared__ u16 Pw[8][16 * 72];       // per-wave P, 16B-aligned stride

    const int bid = blockIdx.x, tid = threadIdx.x;
    if (bid >= 576) {
        int base = (bid - 576) * 4096 + tid;     // 900*4096 = 3686400 float4s
        #pragma unroll
        for (int it = 0; it < 8; ++it) {
            int i = base + it * 512;
            float4 v = reinterpret_cast<const float4*>(alignf)[i];
            u16x4 o;
            o[0] = f2bf(v.x); o[1] = f2bf(v.y); o[2] = f2bf(v.z); o[3] = f2bf(v.w);
            reinterpret_cast<u16x4*>(alignb)[i] = o;
        }
        return;
    }

    const int q0 = (bid % 6) * 128, h = (bid / 6) % NHn, bz = bid / 72;
    const int wave = tid >> 6, lane = tid & 63;
    const int lrow = lane & 15, lquad = lane >> 4;
    const int sw = lrow & 7;

    const u16* Qp = Q + ((size_t)(bz * Sn + q0 + wave * 16 + lrow)) * Hn + h * HDn;
    const u16* Kb = K + (size_t)bz * Sn * Hn + h * HDn;
    const u16* Vb = VT + ((size_t)(bz * NHn + h) * 64) * Sn;   // row d, stride Sn

    bf16x8 qa0 = ld8(Qp + lquad * 8);
    bf16x8 qa1 = ld8(Qp + 32 + lquad * 8);

    f32x4 z4 = {0.f, 0.f, 0.f, 0.f};
    float m_r[4], l_l[4];
    f32x4 oacc[4];
    #pragma unroll
    for (int r = 0; r < 4; ++r) { m_r[r] = -1e30f; l_l[r] = 0.f; }
    #pragma unroll
    for (int jd = 0; jd < 4; ++jd) oacc[jd] = z4;

    // staging addresses: 512 16B segs each for K and V
    const int krow = tid >> 3, kp = (tid & 7) ^ (krow & 7);
    const u16* kg = Kb + (size_t)krow * Hn + kp * 8;
    const u16* vg = Vb + (size_t)krow * Sn + kp * 8;   // d = krow

    auto stage = [&](int bs, int t0) {
        glds16(kg + (size_t)t0 * Hn, &Ks[bs][tid * 8]);
        glds16(vg + t0, &Vs[bs][tid * 8]);
    };

    auto compute = [&](int bc) {
        f32x4 sc[4];
        __builtin_amdgcn_s_setprio(1);
        #pragma unroll
        for (int j = 0; j < 4; ++j) {
            int base = (j * 16 + lrow) * 64 + ((lquad ^ sw) * 8);
            f32x4 s = __builtin_amdgcn_mfma_f32_16x16x32_bf16(qa0, ld8(&Ks[bc][base]), z4, 0, 0, 0);
            sc[j] = __builtin_amdgcn_mfma_f32_16x16x32_bf16(qa1, ld8(&Ks[bc][base ^ 32]), s, 0, 0, 0);
        }
        __builtin_amdgcn_s_setprio(0);
        float tmax[4];
        #pragma unroll
        for (int r = 0; r < 4; ++r)
            tmax[r] = fmaxf(fmaxf(sc[0][r], sc[1][r]), fmaxf(sc[2][r], sc[3][r]));
        #pragma unroll
        for (int off = 1; off < 16; off <<= 1)
            #pragma unroll
            for (int r = 0; r < 4; ++r)
                tmax[r] = fmaxf(tmax[r], __shfl_xor(tmax[r], off));
        // defer-max (THR=8): rescale only when max grows past threshold.
        bool grow = (tmax[0] > m_r[0] + 8.f) | (tmax[1] > m_r[1] + 8.f) |
                    (tmax[2] > m_r[2] + 8.f) | (tmax[3] > m_r[3] + 8.f);
        if (grow) {
            #pragma unroll
            for (int r = 0; r < 4; ++r) {
                float mn = fmaxf(m_r[r], tmax[r]);
                float a = __expf(m_r[r] - mn);
                m_r[r] = mn;
                l_l[r] *= a;
                #pragma unroll
                for (int jd = 0; jd < 4; ++jd) oacc[jd][r] *= a;
            }
        }
        float ps[4] = {0.f, 0.f, 0.f, 0.f};
        #pragma unroll
        for (int j = 0; j < 4; ++j)
            #pragma unroll
            for (int r = 0; r < 4; ++r) {
                float p = __expf(sc[j][r] - m_r[r]);
                ps[r] += p;
                Pw[wave][(lquad * 4 + r) * 72 + j * 16 + lrow] = f2bf(p);
            }
        #pragma unroll
        for (int r = 0; r < 4; ++r) l_l[r] += ps[r];
        bf16x8 pa0 = ld8(&Pw[wave][lrow * 72 + lquad * 8]);
        bf16x8 pa1 = ld8(&Pw[wave][lrow * 72 + 32 + lquad * 8]);
        __builtin_amdgcn_s_setprio(1);
        #pragma unroll
        for (int jd = 0; jd < 4; ++jd) {
            int vbase = (jd * 16 + lrow) * 64 + ((lquad ^ sw) * 8);
            oacc[jd] = __builtin_amdgcn_mfma_f32_16x16x32_bf16(pa0, ld8(&Vs[bc][vbase]), oacc[jd], 0, 0, 0);
            oacc[jd] = __builtin_amdgcn_mfma_f32_16x16x32_bf16(pa1, ld8(&Vs[bc][vbase ^ 32]), oacc[jd], 0, 0, 0);
        }
        __builtin_amdgcn_s_setprio(0);
    };

    // 2-buffer pipeline: wait vmcnt(2); barrier; compute(kt); barrier;
    // stage(kt+2) into the buffer compute just finished reading.
    stage(0, 0);
    stage(1, 64);
    for (int kt = 0; kt < 12; ++kt) {
        if (kt < 11) {
            asm volatile("s_waitcnt vmcnt(2)" ::: "memory");
        } else {
            asm volatile("s_waitcnt vmcnt(0)" ::: "memory");
        }
        __builtin_amdgcn_s_barrier();
        compute(kt & 1);
        if (kt < 10) {
            __builtin_amdgcn_s_barrier();
            stage(kt & 1, (kt + 2) * 64);
        }
    }

    // final 16-lane reduction of the denominators
    #pragma unroll
    for (int off = 1; off < 16; off <<= 1)
        #pragma unroll
        for (int r = 0; r < 4; ++r)
            l_l[r] += __shfl_xor(l_l[r], off);

    float rl[4];
    #pragma unroll
    for (int r = 0; r < 4; ++r) rl[r] = 1.f / l_l[r];
    #pragma unroll
    for (int jd = 0; jd < 4; ++jd)
        #pragma unroll
        for (int r = 0; r < 4; ++r) {
            size_t row = (size_t)bz * Sn + q0 + wave * 16 + lquad * 4 + r;
            ctx[row * Hn + h * HDn + jd * 16 + lrow] = f2bf(oacc[jd][r] * rl[r]);
        }
}

// layernorm in-place on f32 d_out.  grid B*S, block 64
__global__ __launch_bounds__(64) void k_ln(
    float* x, const float* __restrict__ g, const float* __restrict__ beta)
{
    size_t row = blockIdx.x;
    float* xr = x + row * Hn;
    int lane = threadIdx.x;
    float v[12];
    float s = 0.f, ss = 0.f;
    #pragma unroll
    for (int i = 0; i < 12; ++i) {
        v[i] = xr[lane + i * 64];
        s += v[i];
        ss += v[i] * v[i];
    }
    #pragma unroll
    for (int off = 1; off < 64; off <<= 1) {
        s  += __shfl_xor(s, off);
        ss += __shfl_xor(ss, off);
    }
    float mu = s * (1.f / Hn);
    float var = ss * (1.f / Hn) - mu * mu;
    float inv = rsqrtf(var + 1e-5f);
    #pragma unroll
    for (int i = 0; i < 12; ++i) {
        int c = lane + i * 64;
        xr[c] = (v[i] - mu) * inv * g[c] + beta[c];
    }
}

// ---------------- launch ----------------
extern "C" void kernel_launch(void* const* d_in, const int* in_sizes, int n_in,
                              void* d_out, int out_size, void* d_ws, size_t ws_size,
                              hipStream_t stream)
{
    (void)in_sizes; (void)n_in; (void)out_size; (void)ws_size;

    const float* hidden  = (const float*)d_in[0];
    const int*   lang    = (const int*)d_in[1];
    const float* Wq_lang = (const float*)d_in[3];
    const float* bq_lang = (const float*)d_in[4];
    const float* Wk_lang = (const float*)d_in[5];
    const float* bk_lang = (const float*)d_in[6];
    const float* ipw     = (const float*)d_in[7];
    const float* ipb     = (const float*)d_in[8];
    const float* opw     = (const float*)d_in[9];
    const float* opb     = (const float*)d_in[10];
    const float* align   = (const float*)d_in[11];
    const float* projw   = (const float*)d_in[12];
    const float* projb   = (const float*)d_in[13];
    const float* ln_g    = (const float*)d_in[14];
    const float* ln_b    = (const float*)d_in[15];
    float* out = (float*)d_out;

    const size_t HH  = (size_t)Hn * Hn;          // 589824
    const size_t BSH = (size_t)Bn * Sn * Hn;     // 4718592
    const size_t AHH = (size_t)NLn * NLn * HH;   // 14745600

    u16* rA = (u16*)d_ws;        // hb -> ctx
    u16* rB = rA + BSH;          // Q -> U
    u16* rC = rB + BSH;          // K -> chain buf0 -> W
    u16* rD = rC + BSH;          // V^T -> chain buf1
    u16* ipwb = rD + BSH;        // wq|wk|wv bf16 (3*HH)
    u16* pjwb = ipwb + 3 * HH;   // HH
    u16* opwT = pjwb + HH;       // HH
    u16* alignb = opwT + HH;     // 25*HH bf16; pre-attn: weight scratch S[0..20)
    float* beff   = (float*)(alignb + AHH);   // 2*5*768 f32
    float* opbeff = beff + 10 * Hn;           // 5*768 f32
    float* bias2  = opbeff + 5 * Hn;          // 5*768 f32

    u16* S = alignb;             // scratch: WqT[0..5) WkT[5..10) Weffq[10..15) Weffk[15..20)

    // fused prep: conversions + 11 transposes + QK bias folds (one launch)
    k_prep<<<(unsigned)(PREP_NF2B + PREP_NTR + 30), 256, 0, stream>>>(
        hidden, rA, ipw, ipwb, projw, pjwb,
        Wq_lang, Wk_lang, opw, S, opwT,
        ipb, bq_lang, bk_lang, beff);

    // Weffq/Weffk (one launch, 64^2 tiles) -> S[10..20)
    k_comb10<<<dim3(12, 12, 10), 256, 0, stream>>>(ipwb, S);

    // fused QKV: Q*(1/8) -> rB, K -> rC, V^T -> rD.  128^2 tiles.
    k_gemm_qkv<<<dim3(48, 6, 3), 256, 0, stream>>>(
        rA, S + 10 * HH, S + 15 * HH, ipwb + 2 * HH, beff, ipb, lang, rB, rC, rD);

    // attention (ctx -> rA) + align f32->bf16 conversion (S scratch now dead)
    k_attn_conv<<<1476, 512, 0, stream>>>(rB, rC, rD, rA, align, alignb);

    // language chain: first step transposing copy (P0 = F7^T or I) -> rC,
    // then 7 parity-tracked steps (identity steps are no-ops).
    k_chain_first<<<dim3(12, 12, NLn), 256, 0, stream>>>(alignb, lang, rC);
    for (int j = Bn - 2; j >= 0; --j)
        k_chain64<<<dim3(12, 12, NLn), 256, 0, stream>>>(rC, rD, alignb, lang, j);

    // U_l = opw^T . M_l  (+ opb_eff GEMV)  -> rB (Q dead); MT via parity
    k_uop<<<735, 256, 0, stream>>>(opwT, rC, rD, lang, opb, rB, opbeff);
    // W_l = projw . U_l  (+ bias2 GEMV)    -> rC
    k_wb2<<<735, 256, 0, stream>>>(pjwb, rB, opbeff, projw, projb, rC, bias2);

    // x = ctx . W[lang]^T + bias2 + hidden -> d_out (f32).  64^2 tiles.
    k_xfused<<<dim3(96, 12), 256, 0, stream>>>(rA, rC, bias2, lang, hidden, out);
    // layernorm in place
    k_ln<<<(unsigned)(Bn * Sn), 64, 0, stream>>>(out, ln_g, ln_b);
}

// Round 10
// 469.792 us; speedup vs baseline: 1.5454x; 1.0280x over previous
//
#include <hip/hip_runtime.h>

// ---------------- constants ----------------
#define Bn 8
#define Sn 768
#define Hn 768
#define NHn 12
#define HDn 64
#define NLn 5

typedef unsigned short u16;
typedef __bf16 bf16x8 __attribute__((ext_vector_type(8)));
typedef short s16x8 __attribute__((ext_vector_type(8)));
typedef float f32x4 __attribute__((ext_vector_type(4)));
typedef unsigned short u16x4 __attribute__((ext_vector_type(4)));

static __device__ __forceinline__ float bf2f(u16 v) {
    return __uint_as_float(((unsigned)v) << 16);
}
static __device__ __forceinline__ u16 f2bf(float f) {
    unsigned u = __float_as_uint(f);
    unsigned r = u + 0x7fffu + ((u >> 16) & 1u);
    return (u16)(r >> 16);
}
static __device__ __forceinline__ bf16x8 ld8(const u16* p) {
    return *reinterpret_cast<const bf16x8*>(p);
}
static __device__ __forceinline__ void glds16(const u16* g, u16* l) {
    __builtin_amdgcn_global_load_lds(
        (const __attribute__((address_space(1))) void*)g,
        (__attribute__((address_space(3))) void*)l, 16, 0, 0);
}

// ---------------- fused prep: f32->bf16 conversions + transposes + bias folds
#define PREP_NF2B 6912
#define PREP_NTR  1584
__global__ __launch_bounds__(256) void k_prep(
    const float* __restrict__ hidden, u16* __restrict__ hb,
    const float* __restrict__ ipw, u16* __restrict__ ipwb,
    const float* __restrict__ projw, u16* __restrict__ pjwb,
    const float* __restrict__ Wq, const float* __restrict__ Wk,
    const float* __restrict__ opw, u16* __restrict__ S, u16* __restrict__ opwT,
    const float* __restrict__ ipb,
    const float* __restrict__ bq_lang, const float* __restrict__ bk_lang,
    float* __restrict__ beff)
{
    __shared__ float T[64][65];
    const size_t HH = (size_t)Hn * Hn;
    const int bid = blockIdx.x, tid = threadIdx.x;
    if (bid < PREP_NF2B) {
        const int n0 = (int)(Bn * Sn * Hn / 4), n1 = (int)(3 * HH / 4), n2 = (int)(HH / 4);
        int i = bid * 256 + tid;
        const float* s; u16* d; int off;
        if (i < n0)                { s = hidden; d = hb;   off = i; }
        else if (i < n0 + n1)      { s = ipw;    d = ipwb; off = i - n0; }
        else if (i < n0 + n1 + n2) { s = projw;  d = pjwb; off = i - n0 - n1; }
        else return;
        float4 v = reinterpret_cast<const float4*>(s)[off];
        u16x4 o;
        o[0] = f2bf(v.x); o[1] = f2bf(v.y); o[2] = f2bf(v.z); o[3] = f2bf(v.w);
        reinterpret_cast<u16x4*>(d)[off] = o;
    } else if (bid < PREP_NF2B + PREP_NTR) {
        int b2 = bid - PREP_NF2B;
        int z = b2 / 144, r = b2 % 144;
        int bx = r % 12, by = r / 12;
        const float* src;
        u16* dst;
        if (z < 5)       { src = Wq + (size_t)z * HH;       dst = S + (size_t)z * HH; }
        else if (z < 10) { src = Wk + (size_t)(z - 5) * HH; dst = S + (size_t)z * HH; }
        else             { src = opw;                        dst = opwT; }
        int i0 = bx * 64, o0 = by * 64;
        int x = tid & 63, ys = tid >> 6;
        for (int rr = ys; rr < 64; rr += 4)
            T[rr][x] = src[(size_t)(o0 + rr) * Hn + i0 + x];
        __syncthreads();
        for (int rr = ys; rr < 64; rr += 4)
            dst[(size_t)(i0 + rr) * Hn + o0 + x] = f2bf(T[x][rr]);
    } else {
        int b3 = bid - PREP_NF2B - PREP_NTR;       // 0..29
        int ox = b3 % 3, y = b3 / 3;
        int o = ox * 256 + tid;
        int which = y / 5, l = y % 5;
        const float4* w = reinterpret_cast<const float4*>(ipw + (size_t)which * HH + (size_t)o * Hn);
        const float4* bv = reinterpret_cast<const float4*>(((which ? bk_lang : bq_lang) + (size_t)l * Hn));
        float s = 0.f;
        for (int j = 0; j < Hn / 4; ++j) {
            float4 a = w[j], b = bv[j];
            s += a.x * b.x + a.y * b.y + a.z * b.z + a.w * b.w;
        }
        s += ipb[which * Hn + o];
        beff[(size_t)(which * 5 + l) * Hn + o] = s;
    }
}

// ---- TM x 128 triple-buffered counted-vmcnt NT GEMM core (256 thr) ----
template<int TM>
__device__ __forceinline__ void gemm_core(
    const u16* __restrict__ A, int lda,
    const u16* __restrict__ Bw, int ldb,
    const float* __restrict__ bias,
    const float* __restrict__ addres,
    u16* __restrict__ outH, float* __restrict__ outF,
    u16* __restrict__ outVT, int ldc,
    int m0, int n0, float scale)
{
    constexpr int MI = TM / 32;
    constexpr int AIT = TM / 64;
    __shared__ u16 As[3 * TM * 32];
    __shared__ u16 Bs[3 * 128 * 32];
    const int tid = threadIdx.x;
    const int lane = tid & 63, wave = tid >> 6;
    const int lrow = lane & 15, lquad = lane >> 4;
    const int wm = (wave >> 1) * (TM / 2), wn = (wave & 1) * 64;

    const u16* gA = A + (size_t)(m0 + (tid >> 2)) * lda + (tid & 3) * 8;
    const u16* gB = Bw + (size_t)(n0 + (tid >> 2)) * ldb + (tid & 3) * 8;

    f32x4 z = {0.f, 0.f, 0.f, 0.f};
    f32x4 acc[MI][4];
    #pragma unroll
    for (int i = 0; i < MI; ++i)
        #pragma unroll
        for (int j = 0; j < 4; ++j) acc[i][j] = z;

    auto stage = [&](int bs, int k0) {
        #pragma unroll
        for (int it = 0; it < AIT; ++it)
            glds16(gA + (size_t)(it * 64) * lda + k0, &As[bs * TM * 32 + (tid + 256 * it) * 8]);
        #pragma unroll
        for (int it = 0; it < 2; ++it)
            glds16(gB + (size_t)(it * 64) * ldb + k0, &Bs[bs * 128 * 32 + (tid + 256 * it) * 8]);
    };
    auto compute = [&](int bc) {
        const u16* Ab = &As[bc * TM * 32];
        const u16* Bb = &Bs[bc * 128 * 32];
        bf16x8 af[MI], bf_[4];
        #pragma unroll
        for (int i = 0; i < MI; ++i)
            af[i] = ld8(&Ab[(wm + i * 16 + lrow) * 32 + lquad * 8]);
        #pragma unroll
        for (int j = 0; j < 4; ++j)
            bf_[j] = ld8(&Bb[(wn + j * 16 + lrow) * 32 + lquad * 8]);
        #pragma unroll
        for (int i = 0; i < MI; ++i)
            #pragma unroll
            for (int j = 0; j < 4; ++j)
                acc[i][j] = __builtin_amdgcn_mfma_f32_16x16x32_bf16(af[i], bf_[j], acc[i][j], 0, 0, 0);
    };

    stage(0, 0);
    stage(1, 32);
    int bc = 0, bs = 2;
    for (int kt = 0; kt < 24; ++kt) {
        if (kt < 23) {
            if constexpr (TM == 256) {
                asm volatile("s_waitcnt vmcnt(6)" ::: "memory");
            } else {
                asm volatile("s_waitcnt vmcnt(4)" ::: "memory");
            }
        } else {
            asm volatile("s_waitcnt vmcnt(0)" ::: "memory");
        }
        __builtin_amdgcn_s_barrier();
        if (kt < 22) {
            stage(bs, (kt + 2) * 32);
            bs = (bs == 2) ? 0 : bs + 1;
        }
        compute(bc);
        bc = (bc == 2) ? 0 : bc + 1;
    }

    #pragma unroll
    for (int i = 0; i < MI; ++i) {
        #pragma unroll
        for (int j = 0; j < 4; ++j) {
            int col = n0 + wn + j * 16 + lrow;
            float bv = bias ? bias[col] : 0.f;
            if (outVT) {
                int row0 = m0 + wm + i * 16 + lquad * 4;
                int bb = row0 / Sn, s = row0 % Sn;
                int hh = col >> 6, dd = col & 63;
                u16x4 o;
                #pragma unroll
                for (int r = 0; r < 4; ++r) o[r] = f2bf((acc[i][j][r] + bv) * scale);
                *reinterpret_cast<u16x4*>(
                    outVT + (((size_t)bb * NHn + hh) * 64 + dd) * Sn + s) = o;
            } else {
                #pragma unroll
                for (int r = 0; r < 4; ++r) {
                    int row = m0 + wm + i * 16 + lquad * 4 + r;
                    float v = (acc[i][j][r] + bv) * scale;
                    if (addres) v += addres[(size_t)row * ldc + col];
                    if (outF) outF[(size_t)row * ldc + col] = v;
                    else      outH[(size_t)row * ldc + col] = f2bf(v);
                }
            }
        }
    }
}

// -- 64x64 triple-buffered counted-vmcnt NT GEMM core (256 thr), LDS passed in --
__device__ __forceinline__ void gemm64(
    u16* As, u16* Bs,
    const u16* __restrict__ A, const u16* __restrict__ Bw,
    const float* __restrict__ bias, const float* __restrict__ addres,
    u16* __restrict__ outH, float* __restrict__ outF,
    int m0, int n0)
{
    const int tid = threadIdx.x;
    const int lane = tid & 63, wave = tid >> 6;
    const int lrow = lane & 15, lquad = lane >> 4;
    const int wm = (wave >> 1) * 32, wn = (wave & 1) * 32;

    const u16* gA = A + (size_t)(m0 + (tid >> 2)) * Hn + (tid & 3) * 8;
    const u16* gB = Bw + (size_t)(n0 + (tid >> 2)) * Hn + (tid & 3) * 8;

    f32x4 z = {0.f, 0.f, 0.f, 0.f};
    f32x4 acc[2][2];
    #pragma unroll
    for (int i = 0; i < 2; ++i)
        #pragma unroll
        for (int j = 0; j < 2; ++j) acc[i][j] = z;

    auto stage = [&](int bs, int k0) {
        glds16(gA + k0, &As[bs * 64 * 32 + tid * 8]);
        glds16(gB + k0, &Bs[bs * 64 * 32 + tid * 8]);
    };
    auto compute = [&](int bc) {
        const u16* Ab = &As[bc * 64 * 32];
        const u16* Bb = &Bs[bc * 64 * 32];
        bf16x8 af[2], bf_[2];
        #pragma unroll
        for (int i = 0; i < 2; ++i)
            af[i] = ld8(&Ab[(wm + i * 16 + lrow) * 32 + lquad * 8]);
        #pragma unroll
        for (int j = 0; j < 2; ++j)
            bf_[j] = ld8(&Bb[(wn + j * 16 + lrow) * 32 + lquad * 8]);
        #pragma unroll
        for (int i = 0; i < 2; ++i)
            #pragma unroll
            for (int j = 0; j < 2; ++j)
                acc[i][j] = __builtin_amdgcn_mfma_f32_16x16x32_bf16(af[i], bf_[j], acc[i][j], 0, 0, 0);
    };

    stage(0, 0);
    stage(1, 32);
    int bc = 0, bs = 2;
    for (int kt = 0; kt < 24; ++kt) {
        if (kt < 23) {
            asm volatile("s_waitcnt vmcnt(2)" ::: "memory");
        } else {
            asm volatile("s_waitcnt vmcnt(0)" ::: "memory");
        }
        __builtin_amdgcn_s_barrier();
        if (kt < 22) {
            stage(bs, (kt + 2) * 32);
            bs = (bs == 2) ? 0 : bs + 1;
        }
        compute(bc);
        bc = (bc == 2) ? 0 : bc + 1;
    }

    #pragma unroll
    for (int i = 0; i < 2; ++i)
        #pragma unroll
        for (int j = 0; j < 2; ++j) {
            int col = n0 + wn + j * 16 + lrow;
            float bv = bias ? bias[col] : 0.f;
            #pragma unroll
            for (int r = 0; r < 4; ++r) {
                int row_ = m0 + wm + i * 16 + lquad * 4 + r;
                float v = acc[i][j][r] + bv;
                if (addres) v += addres[(size_t)row_ * Hn + col];
                if (outF) outF[(size_t)row_ * Hn + col] = v;
                else      outH[(size_t)row_ * Hn + col] = f2bf(v);
            }
        }
}

// ---- 64x64 tile helpers (256 thr): identity write, copy, transposing copy ----
static __device__ __forceinline__ void ident64(u16* dst, int m0, int n0)
{
    const int tid = threadIdx.x;
    #pragma unroll
    for (int it = 0; it < 2; ++it) {
        int s = tid + 256 * it;
        int ri = s >> 3, c8 = s & 7;
        s16x8 v;
        #pragma unroll
        for (int e = 0; e < 8; ++e)
            v[e] = (short)((m0 + ri == n0 + c8 * 8 + e) ? 0x3F80 : 0);
        *reinterpret_cast<s16x8*>(dst + (size_t)(m0 + ri) * Hn + n0 + c8 * 8) = v;
    }
}
static __device__ __forceinline__ void copy64(u16* dst, const u16* src, int m0, int n0)
{
    const int tid = threadIdx.x;
    #pragma unroll
    for (int it = 0; it < 2; ++it) {
        int s = tid + 256 * it;
        int row = s >> 3, seg = s & 7;
        *reinterpret_cast<s16x8*>(dst + (size_t)(m0 + row) * Hn + n0 + seg * 8) =
            *reinterpret_cast<const s16x8*>(src + (size_t)(m0 + row) * Hn + n0 + seg * 8);
    }
}
// dst = src^T: dst tile (m0,n0) <- src tile (n0,m0) transposed.  lds >= 64*72 u16
static __device__ __forceinline__ void tcopy64(u16* dst, const u16* src, int m0, int n0, u16* lds)
{
    u16 (*T)[72] = reinterpret_cast<u16(*)[72]>(lds);
    const int tid = threadIdx.x;
    #pragma unroll
    for (int it = 0; it < 2; ++it) {
        int s = tid + 256 * it;
        int rr = s >> 3, c8 = s & 7;
        s16x8 v = *reinterpret_cast<const s16x8*>(
            src + (size_t)(n0 + rr) * Hn + m0 + c8 * 8);
        #pragma unroll
        for (int e = 0; e < 8; ++e) T[c8 * 8 + e][rr] = (u16)v[e];
    }
    __syncthreads();
    #pragma unroll
    for (int it = 0; it < 2; ++it) {
        int s = tid + 256 * it;
        int ri = s >> 3, c8 = s & 7;
        *reinterpret_cast<s16x8*>(dst + (size_t)(m0 + ri) * Hn + n0 + c8 * 8) =
            *reinterpret_cast<const s16x8*>(&T[ri][c8 * 8]);
    }
}

// ---------------- GEMM wrapper kernels ----------------

// fused QKV projection, 128^2 tiles.  grid (48, 6, 3): z=0 Q, z=1 K, z=2 V(T).
__global__ __launch_bounds__(256) void k_gemm_qkv(
    const u16* __restrict__ A,
    const u16* __restrict__ Sq, const u16* __restrict__ Sk,
    const u16* __restrict__ Wv,
    const float* __restrict__ beff, const float* __restrict__ ipb,
    const int* __restrict__ lang,
    u16* __restrict__ outQ, u16* __restrict__ outK, u16* __restrict__ outVT)
{
    const size_t HH = (size_t)Hn * Hn;
    int z = blockIdx.z;
    int m0 = blockIdx.x * 128, n0 = blockIdx.y * 128;
    int l = lang[blockIdx.x / 6];
    if (z == 0) {
        gemm_core<128>(A, Hn, Sq + (size_t)l * HH, Hn, beff + (size_t)l * Hn,
                       nullptr, outQ, nullptr, nullptr, Hn, m0, n0, 0.125f);
    } else if (z == 1) {
        gemm_core<128>(A, Hn, Sk + (size_t)l * HH, Hn, beff + (size_t)(5 + l) * Hn,
                       nullptr, outK, nullptr, nullptr, Hn, m0, n0, 1.f);
    } else {
        gemm_core<128>(A, Hn, Wv, Hn, ipb + 2 * Hn,
                       nullptr, nullptr, nullptr, outVT, Hn, m0, n0, 1.f);
    }
}

// fused weight combine, 64^2 tiles.  z<5: Weffq_z; z>=5: Weffk.  grid (12,12,10)
__global__ __launch_bounds__(256) void k_comb10(
    const u16* __restrict__ ipwb, u16* __restrict__ S)
{
    __shared__ u16 As[3 * 64 * 32];
    __shared__ u16 Bs[3 * 64 * 32];
    const size_t HH = (size_t)Hn * Hn;
    int z = blockIdx.z;
    const u16* Aop = ipwb + (z < 5 ? 0 : HH);
    gemm64(As, Bs, Aop, S + (size_t)z * HH, nullptr, nullptr,
           S + (size_t)(10 + z) * HH, nullptr,
           blockIdx.x * 64, blockIdx.y * 64);
}

// ---------------- chain tree ----------------
// MT_l = S7^T S6^T S5^T S4^T S3^T S2^T S1^T S0^T,
// S_j = (lang[j]==l) ? I : align[l, lang[j]].
// L1 nodes per l (slot = l*4+node in N1 = rB region):
//   node0 P_a   = S7^T S6^T       (stored straight)
//   node1 P_bT  = (S5^T S4^T)^T  (stored transposed)
//   node2 P_c   = S3^T S2^T       (straight)
//   node3 P_dT  = (S1^T S0^T)^T  (transposed)
// L2: Q_a = P_a P_b (straight), Q_bT = (P_c P_d)^T.  L3: MT = Q_a Q_b.

// L1.  grid (12,12,20): z = l*4 + node
__global__ __launch_bounds__(256) void k_chainL1(
    const u16* __restrict__ alignb, const u16* __restrict__ alignbT,
    const int* __restrict__ lang, u16* __restrict__ N1)
{
    __shared__ u16 As[3 * 64 * 32];
    __shared__ u16 Bs[3 * 64 * 32];
    const size_t HH = (size_t)Hn * Hn;
    int idx = blockIdx.z, l = idx >> 2, node = idx & 3;
    int ja = 7 - node * 2, jb = 6 - node * 2;
    bool tr = node & 1;
    int la = lang[ja], lb = lang[jb];
    bool sa = (la == l), sb = (lb == l);
    u16* dst = N1 + (size_t)idx * HH;
    int m0 = blockIdx.x * 64, n0 = blockIdx.y * 64;
    if (sa && sb) {
        ident64(dst, m0, n0);
    } else if (sa) {   // value = S_jb^T ; straight->alignbT, transposed->alignb
        copy64(dst, (tr ? alignb : alignbT) + ((size_t)l * NLn + lb) * HH, m0, n0);
    } else if (sb) {   // value = S_ja^T
        copy64(dst, (tr ? alignb : alignbT) + ((size_t)l * NLn + la) * HH, m0, n0);
    } else if (!tr) {  // straight: Fa^T * Fb^T = NT(FaT, Fb)
        gemm64(As, Bs, alignbT + ((size_t)l * NLn + la) * HH,
               alignb + ((size_t)l * NLn + lb) * HH,
               nullptr, nullptr, dst, nullptr, m0, n0);
    } else {           // transposed: Fb * Fa = NT(Fb, FaT)
        gemm64(As, Bs, alignb + ((size_t)l * NLn + lb) * HH,
               alignbT + ((size_t)l * NLn + la) * HH,
               nullptr, nullptr, dst, nullptr, m0, n0);
    }
}

// L2.  grid (12,12,10): z = l*2 + q.  Q_a -> Q2[l], Q_bT -> Q2[5+l]
__global__ __launch_bounds__(256) void k_chainL2(
    const u16* __restrict__ N1, const int* __restrict__ lang,
    u16* __restrict__ Q2)
{
    __shared__ u16 As[3 * 64 * 32];
    __shared__ u16 Bs[3 * 64 * 32];
    const size_t HH = (size_t)Hn * Hn;
    int idx = blockIdx.z, l = idx >> 1, q = idx & 1;
    int m0 = blockIdx.x * 64, n0 = blockIdx.y * 64;
    const u16* Pa  = N1 + (size_t)(l * 4 + 0) * HH;
    const u16* PbT = N1 + (size_t)(l * 4 + 1) * HH;
    const u16* Pc  = N1 + (size_t)(l * 4 + 2) * HH;
    const u16* PdT = N1 + (size_t)(l * 4 + 3) * HH;
    if (q == 0) {
        u16* dst = Q2 + (size_t)l * HH;                     // Q_a straight
        bool ia = (lang[7] == l) && (lang[6] == l);
        bool ib = (lang[5] == l) && (lang[4] == l);
        if (ia && ib)      ident64(dst, m0, n0);
        else if (ia)       tcopy64(dst, PbT, m0, n0, As);   // Q_a = P_b = (P_bT)^T
        else if (ib)       copy64(dst, Pa, m0, n0);
        else               gemm64(As, Bs, Pa, PbT, nullptr, nullptr, dst, nullptr, m0, n0);
    } else {
        u16* dst = Q2 + (size_t)(5 + l) * HH;               // Q_bT
        bool ic = (lang[3] == l) && (lang[2] == l);
        bool id = (lang[1] == l) && (lang[0] == l);
        if (ic && id)      ident64(dst, m0, n0);
        else if (ic)       copy64(dst, PdT, m0, n0);        // Q_bT = P_dT
        else if (id)       tcopy64(dst, Pc, m0, n0, As);    // Q_bT = P_c^T
        else               gemm64(As, Bs, PdT, Pc, nullptr, nullptr, dst, nullptr, m0, n0);
    }
}

// L3.  grid (12,12,5): MT_l = Q_a * Q_b = NT(Q_a, Q_bT)
__global__ __launch_bounds__(256) void k_chainL3(
    const u16* __restrict__ Q2, const int* __restrict__ lang,
    u16* __restrict__ MT)
{
    __shared__ u16 As[3 * 64 * 32];
    __shared__ u16 Bs[3 * 64 * 32];
    const size_t HH = (size_t)Hn * Hn;
    int l = blockIdx.z;
    int m0 = blockIdx.x * 64, n0 = blockIdx.y * 64;
    const u16* Qa  = Q2 + (size_t)l * HH;
    const u16* QbT = Q2 + (size_t)(5 + l) * HH;
    u16* dst = MT + (size_t)l * HH;
    bool iA = (lang[7] == l) && (lang[6] == l) && (lang[5] == l) && (lang[4] == l);
    bool iB = (lang[3] == l) && (lang[2] == l) && (lang[1] == l) && (lang[0] == l);
    if (iA && iB)      ident64(dst, m0, n0);
    else if (iA)       tcopy64(dst, QbT, m0, n0, As);       // MT = Q_b
    else if (iB)       copy64(dst, Qa, m0, n0);
    else               gemm64(As, Bs, Qa, QbT, nullptr, nullptr, dst, nullptr, m0, n0);
}

// U_l = NT(opwT, MT_l) + opb_eff GEMV.  grid 735.
__global__ __launch_bounds__(256) void k_uop(
    const u16* __restrict__ opwT, const u16* __restrict__ MT,
    const float* __restrict__ opb,
    u16* __restrict__ U5, float* __restrict__ opbeff)
{
    __shared__ u16 As[3 * 64 * 32];
    __shared__ u16 Bs[3 * 64 * 32];
    const size_t HH = (size_t)Hn * Hn;
    int bid = blockIdx.x;
    if (bid < 720) {
        int z = bid / 144, r = bid % 144;
        gemm64(As, Bs, opwT, MT + (size_t)z * HH, nullptr, nullptr,
               U5 + (size_t)z * HH, nullptr,
               (r % 12) * 64, (r / 12) * 64);
    } else {
        int b2 = bid - 720;
        int n = (b2 % 3) * 256 + threadIdx.x;
        int l = b2 / 3;
        const u16* mt = MT + ((size_t)l * Hn + n) * Hn;
        float s = 0.f;
        for (int k = 0; k < Hn; k += 8) {
            s16x8 v = *reinterpret_cast<const s16x8*>(mt + k);
            #pragma unroll
            for (int jq = 0; jq < 8; ++jq) s += opb[k + jq] * bf2f((u16)v[jq]);
        }
        opbeff[(size_t)l * Hn + n] = s;
    }
}

// W_l = NT(projw, U_l) + bias2 GEMV.  grid 735.
__global__ __launch_bounds__(256) void k_wb2(
    const u16* __restrict__ pjwb, const u16* __restrict__ U5,
    const float* __restrict__ opbeff, const float* __restrict__ projw,
    const float* __restrict__ projb,
    u16* __restrict__ W5, float* __restrict__ bias2)
{
    __shared__ u16 As[3 * 64 * 32];
    __shared__ u16 Bs[3 * 64 * 32];
    const size_t HH = (size_t)Hn * Hn;
    int bid = blockIdx.x;
    if (bid < 720) {
        int z = bid / 144, r = bid % 144;
        gemm64(As, Bs, pjwb, U5 + (size_t)z * HH, nullptr, nullptr,
               W5 + (size_t)z * HH, nullptr,
               (r % 12) * 64, (r / 12) * 64);
    } else {
        int b2 = bid - 720;
        int m = (b2 % 3) * 256 + threadIdx.x;
        int l = b2 / 3;
        const float4* w = reinterpret_cast<const float4*>(projw + (size_t)m * Hn);
        const float4* ob = reinterpret_cast<const float4*>(opbeff + (size_t)l * Hn);
        float s = 0.f;
        for (int jq = 0; jq < Hn / 4; ++jq) {
            float4 a = w[jq], b = ob[jq];
            s += a.x * b.x + a.y * b.y + a.z * b.z + a.w * b.w;
        }
        bias2[(size_t)l * Hn + m] = s + projb[m];
    }
}

// x = NT(ctx, W[lang]) + bias2[lang] + hidden -> f32 out.  64^2 tiles, grid (96,12)
__global__ __launch_bounds__(256) void k_xfused(
    const u16* __restrict__ ctx, const u16* __restrict__ W5,
    const float* __restrict__ bias2, const int* __restrict__ lang,
    const float* __restrict__ hidden, float* __restrict__ x)
{
    __shared__ u16 As[3 * 64 * 32];
    __shared__ u16 Bs[3 * 64 * 32];
    int l = lang[blockIdx.x / 12];
    gemm64(As, Bs, ctx, W5 + (size_t)l * Hn * Hn, bias2 + (size_t)l * Hn,
           hidden, nullptr, x,
           blockIdx.x * 64, blockIdx.y * 64);
}

// ---------------- flash attention + align conversion, 512 threads ----------
// blocks [0,576): attn.  blocks [576, 576+3600): align f32 -> bf16,
// per 64x64 tile writing BOTH straight (alignb) and transposed (alignbT).
__global__ __launch_bounds__(512) void k_attn_conv(
    const u16* __restrict__ Q, const u16* __restrict__ K,
    const u16* __restrict__ VT, u16* __restrict__ ctx,
    const float* __restrict__ alignf, u16* __restrict__ alignb,
    u16* __restrict__ alignbT)
{
    __shared__ u16 Ks[2][64 * 64];       // [key][d], seg-xor-swizzled
    __shared__ u16 Vs[2][64 * 64];       // [d][key], seg-xor-swizzled
    __shared__ u16 Pw[8][16 * 72];       // per-wave P; conv: f32 T[64][65]

    const int bid = blockIdx.x, tid = threadIdx.x;
    const size_t HH = (size_t)Hn * Hn;
    if (bid >= 576) {
        int t = bid - 576;                   // 0..3599
        int mat = t / 144, r = t % 144;
        int i0 = (r % 12) * 64, o0 = (r / 12) * 64;
        const float* src = alignf + (size_t)mat * HH;
        float (*T)[65] = reinterpret_cast<float(*)[65]>(&Pw[0][0]);
        int x = tid & 63, ys = tid >> 6;     // ys 0..7
        for (int rr = ys; rr < 64; rr += 8) {
            float v = src[(size_t)(o0 + rr) * Hn + i0 + x];
            alignb[(size_t)mat * HH + (size_t)(o0 + rr) * Hn + i0 + x] = f2bf(v);
            T[rr][x] = v;
        }
        __syncthreads();
        for (int rr = ys; rr < 64; rr += 8)
            alignbT[(size_t)mat * HH + (size_t)(i0 + rr) * Hn + o0 + x] = f2bf(T[x][rr]);
        return;
    }

    const int q0 = (bid % 6) * 128, h = (bid / 6) % NHn, bz = bid / 72;
    const int wave = tid >> 6, lane = tid & 63;
    const int lrow = lane & 15, lquad = lane >> 4;
    const int sw = lrow & 7;

    const u16* Qp = Q + ((size_t)(bz * Sn + q0 + wave * 16 + lrow)) * Hn + h * HDn;
    const u16* Kb = K + (size_t)bz * Sn * Hn + h * HDn;
    const u16* Vb = VT + ((size_t)(bz * NHn + h) * 64) * Sn;   // row d, stride Sn

    bf16x8 qa0 = ld8(Qp + lquad * 8);
    bf16x8 qa1 = ld8(Qp + 32 + lquad * 8);

    f32x4 z4 = {0.f, 0.f, 0.f, 0.f};
    float m_r[4], l_l[4];
    f32x4 oacc[4];
    #pragma unroll
    for (int r = 0; r < 4; ++r) { m_r[r] = -1e30f; l_l[r] = 0.f; }
    #pragma unroll
    for (int jd = 0; jd < 4; ++jd) oacc[jd] = z4;

    const int krow = tid >> 3, kp = (tid & 7) ^ (krow & 7);
    const u16* kg = Kb + (size_t)krow * Hn + kp * 8;
    const u16* vg = Vb + (size_t)krow * Sn + kp * 8;

    auto stage = [&](int bs, int t0) {
        glds16(kg + (size_t)t0 * Hn, &Ks[bs][tid * 8]);
        glds16(vg + t0, &Vs[bs][tid * 8]);
    };

    auto compute = [&](int bc) {
        f32x4 sc[4];
        __builtin_amdgcn_s_setprio(1);
        #pragma unroll
        for (int j = 0; j < 4; ++j) {
            int base = (j * 16 + lrow) * 64 + ((lquad ^ sw) * 8);
            f32x4 s = __builtin_amdgcn_mfma_f32_16x16x32_bf16(qa0, ld8(&Ks[bc][base]), z4, 0, 0, 0);
            sc[j] = __builtin_amdgcn_mfma_f32_16x16x32_bf16(qa1, ld8(&Ks[bc][base ^ 32]), s, 0, 0, 0);
        }
        __builtin_amdgcn_s_setprio(0);
        float tmax[4];
        #pragma unroll
        for (int r = 0; r < 4; ++r)
            tmax[r] = fmaxf(fmaxf(sc[0][r], sc[1][r]), fmaxf(sc[2][r], sc[3][r]));
        #pragma unroll
        for (int off = 1; off < 16; off <<= 1)
            #pragma unroll
            for (int r = 0; r < 4; ++r)
                tmax[r] = fmaxf(tmax[r], __shfl_xor(tmax[r], off));
        bool grow = (tmax[0] > m_r[0] + 8.f) | (tmax[1] > m_r[1] + 8.f) |
                    (tmax[2] > m_r[2] + 8.f) | (tmax[3] > m_r[3] + 8.f);
        if (grow) {
            #pragma unroll
            for (int r = 0; r < 4; ++r) {
                float mn = fmaxf(m_r[r], tmax[r]);
                float a = __expf(m_r[r] - mn);
                m_r[r] = mn;
                l_l[r] *= a;
                #pragma unroll
                for (int jd = 0; jd < 4; ++jd) oacc[jd][r] *= a;
            }
        }
        float ps[4] = {0.f, 0.f, 0.f, 0.f};
        #pragma unroll
        for (int j = 0; j < 4; ++j)
            #pragma unroll
            for (int r = 0; r < 4; ++r) {
                float p = __expf(sc[j][r] - m_r[r]);
                ps[r] += p;
                Pw[wave][(lquad * 4 + r) * 72 + j * 16 + lrow] = f2bf(p);
            }
        #pragma unroll
        for (int r = 0; r < 4; ++r) l_l[r] += ps[r];
        bf16x8 pa0 = ld8(&Pw[wave][lrow * 72 + lquad * 8]);
        bf16x8 pa1 = ld8(&Pw[wave][lrow * 72 + 32 + lquad * 8]);
        __builtin_amdgcn_s_setprio(1);
        #pragma unroll
        for (int jd = 0; jd < 4; ++jd) {
            int vbase = (jd * 16 + lrow) * 64 + ((lquad ^ sw) * 8);
            oacc[jd] = __builtin_amdgcn_mfma_f32_16x16x32_bf16(pa0, ld8(&Vs[bc][vbase]), oacc[jd], 0, 0, 0);
            oacc[jd] = __builtin_amdgcn_mfma_f32_16x16x32_bf16(pa1, ld8(&Vs[bc][vbase ^ 32]), oacc[jd], 0, 0, 0);
        }
        __builtin_amdgcn_s_setprio(0);
    };

    stage(0, 0);
    stage(1, 64);
    for (int kt = 0; kt < 12; ++kt) {
        if (kt < 11) {
            asm volatile("s_waitcnt vmcnt(2)" ::: "memory");
        } else {
            asm volatile("s_waitcnt vmcnt(0)" ::: "memory");
        }
        __builtin_amdgcn_s_barrier();
        compute(kt & 1);
        if (kt < 10) {
            __builtin_amdgcn_s_barrier();
            stage(kt & 1, (kt + 2) * 64);
        }
    }

    #pragma unroll
    for (int off = 1; off < 16; off <<= 1)
        #pragma unroll
        for (int r = 0; r < 4; ++r)
            l_l[r] += __shfl_xor(l_l[r], off);

    float rl[4];
    #pragma unroll
    for (int r = 0; r < 4; ++r) rl[r] = 1.f / l_l[r];
    #pragma unroll
    for (int jd = 0; jd < 4; ++jd)
        #pragma unroll
        for (int r = 0; r < 4; ++r) {
            size_t row = (size_t)bz * Sn + q0 + wave * 16 + lquad * 4 + r;
            ctx[row * Hn + h * HDn + jd * 16 + lrow] = f2bf(oacc[jd][r] * rl[r]);
        }
}

// layernorm in-place on f32 d_out.  grid B*S, block 64
__global__ __launch_bounds__(64) void k_ln(
    float* x, const float* __restrict__ g, const float* __restrict__ beta)
{
    size_t row = blockIdx.x;
    float* xr = x + row * Hn;
    int lane = threadIdx.x;
    float v[12];
    float s = 0.f, ss = 0.f;
    #pragma unroll
    for (int i = 0; i < 12; ++i) {
        v[i] = xr[lane + i * 64];
        s += v[i];
        ss += v[i] * v[i];
    }
    #pragma unroll
    for (int off = 1; off < 64; off <<= 1) {
        s  += __shfl_xor(s, off);
        ss += __shfl_xor(ss, off);
    }
    float mu = s * (1.f / Hn);
    float var = ss * (1.f / Hn) - mu * mu;
    float inv = rsqrtf(var + 1e-5f);
    #pragma unroll
    for (int i = 0; i < 12; ++i) {
        int c = lane + i * 64;
        xr[c] = (v[i] - mu) * inv * g[c] + beta[c];
    }
}

// ---------------- launch ----------------
extern "C" void kernel_launch(void* const* d_in, const int* in_sizes, int n_in,
                              void* d_out, int out_size, void* d_ws, size_t ws_size,
                              hipStream_t stream)
{
    (void)in_sizes; (void)n_in; (void)out_size; (void)ws_size;

    const float* hidden  = (const float*)d_in[0];
    const int*   lang    = (const int*)d_in[1];
    const float* Wq_lang = (const float*)d_in[3];
    const float* bq_lang = (const float*)d_in[4];
    const float* Wk_lang = (const float*)d_in[5];
    const float* bk_lang = (const float*)d_in[6];
    const float* ipw     = (const float*)d_in[7];
    const float* ipb     = (const float*)d_in[8];
    const float* opw     = (const float*)d_in[9];
    const float* opb     = (const float*)d_in[10];
    const float* align   = (const float*)d_in[11];
    const float* projw   = (const float*)d_in[12];
    const float* projb   = (const float*)d_in[13];
    const float* ln_g    = (const float*)d_in[14];
    const float* ln_b    = (const float*)d_in[15];
    float* out = (float*)d_out;

    const size_t HH  = (size_t)Hn * Hn;          // 589824
    const size_t BSH = (size_t)Bn * Sn * Hn;     // 4718592 = 8*HH
    const size_t AHH = (size_t)NLn * NLn * HH;   // 25*HH

    u16* rA = (u16*)d_ws;        // hb -> ctx
    u16* rB = rA + BSH;          // Q -> N1 slots 0..7
    u16* rC = rB + BSH;          // K -> N1 slots 8..15
    u16* rD = rC + BSH;          // V^T -> N1 slots 16..19
    u16* ipwb = rD + BSH;        // wq|wk|wv bf16 (3*HH)
    u16* pjwb = ipwb + 3 * HH;   // HH
    u16* opwT = pjwb + HH;       // HH
    u16* alignb = opwT + HH;     // 25*HH; pre-attn: weight scratch S[0..20)
                                 // post-L2: MT[0..5) U[5..10) W[10..15)
    u16* alignbT = alignb + AHH; // 25*HH transposed aligns; post-L1: Q2[0..10)
    float* beff   = (float*)(alignbT + AHH);  // 2*5*768 f32
    float* opbeff = beff + 10 * Hn;           // 5*768 f32
    float* bias2  = opbeff + 5 * Hn;          // 5*768 f32

    u16* S = alignb;             // scratch: WqT[0..5) WkT[5..10) Weffq[10..15) Weffk[15..20)
    u16* N1 = rB;                // 20 node matrices (rB..rD contiguous)
    u16* Q2 = alignbT;           // 10 node matrices (alignbT dead after L1)
    u16* MT = alignb;            // 5 (alignb dead after L1)
    u16* U5 = alignb + 5 * HH;   // 5
    u16* W5 = alignb + 10 * HH;  // 5

    // fused prep: conversions + 11 transposes + QK bias folds (one launch)
    k_prep<<<(unsigned)(PREP_NF2B + PREP_NTR + 30), 256, 0, stream>>>(
        hidden, rA, ipw, ipwb, projw, pjwb,
        Wq_lang, Wk_lang, opw, S, opwT,
        ipb, bq_lang, bk_lang, beff);

    // Weffq/Weffk (one launch, 64^2 tiles) -> S[10..20)
    k_comb10<<<dim3(12, 12, 10), 256, 0, stream>>>(ipwb, S);

    // fused QKV: Q*(1/8) -> rB, K -> rC, V^T -> rD.  128^2 tiles.
    k_gemm_qkv<<<dim3(48, 6, 3), 256, 0, stream>>>(
        rA, S + 10 * HH, S + 15 * HH, ipwb + 2 * HH, beff, ipb, lang, rB, rC, rD);

    // attention (ctx -> rA) + align conversion straight+transposed (S dead)
    k_attn_conv<<<576 + 3600, 512, 0, stream>>>(rB, rC, rD, rA, align, alignb, alignbT);

    // chain tree: 3 launches replace 8 sequential chain steps
    k_chainL1<<<dim3(12, 12, 20), 256, 0, stream>>>(alignb, alignbT, lang, N1);
    k_chainL2<<<dim3(12, 12, 10), 256, 0, stream>>>(N1, lang, Q2);
    k_chainL3<<<dim3(12, 12, 5), 256, 0, stream>>>(Q2, lang, MT);

    // U_l = opw^T . M_l  (+ opb_eff GEMV)
    k_uop<<<735, 256, 0, stream>>>(opwT, MT, opb, U5, opbeff);
    // W_l = projw . U_l  (+ bias2 GEMV)
    k_wb2<<<735, 256, 0, stream>>>(pjwb, U5, opbeff, projw, projb, W5, bias2);

    // x = ctx . W[lang]^T + bias2 + hidden -> d_out (f32).  64^2 tiles.
    k_xfused<<<dim3(96, 12), 256, 0, stream>>>(rA, W5, bias2, lang, hidden, out);
    // layernorm in place
    k_ln<<<(unsigned)(Bn * Sn), 64, 0, stream>>>(out, ln_g, ln_b);
}

// Round 11
// 454.872 us; speedup vs baseline: 1.5961x; 1.0328x over previous
//
#include <hip/hip_runtime.h>

// ---------------- constants ----------------
#define Bn 8
#define Sn 768
#define Hn 768
#define NHn 12
#define HDn 64
#define NLn 5

typedef unsigned short u16;
typedef __bf16 bf16x8 __attribute__((ext_vector_type(8)));
typedef short s16x8 __attribute__((ext_vector_type(8)));
typedef float f32x4 __attribute__((ext_vector_type(4)));
typedef unsigned short u16x4 __attribute__((ext_vector_type(4)));

static __device__ __forceinline__ float bf2f(u16 v) {
    return __uint_as_float(((unsigned)v) << 16);
}
static __device__ __forceinline__ u16 f2bf(float f) {
    unsigned u = __float_as_uint(f);
    unsigned r = u + 0x7fffu + ((u >> 16) & 1u);
    return (u16)(r >> 16);
}
static __device__ __forceinline__ bf16x8 ld8(const u16* p) {
    return *reinterpret_cast<const bf16x8*>(p);
}
static __device__ __forceinline__ void glds16(const u16* g, u16* l) {
    __builtin_amdgcn_global_load_lds(
        (const __attribute__((address_space(1))) void*)g,
        (__attribute__((address_space(3))) void*)l, 16, 0, 0);
}

// ---------------- fused prep: f32->bf16 conversions + transposes + bias folds
// transposes: z<5 Wq -> S, z<10 Wk -> S, z==10 opw -> opwT,
//             z in [11,36): align mat (z-11) -> alignbT (transposed bf16)
#define PREP_NF2B 6912
#define PREP_NTR  (36 * 144)
__global__ __launch_bounds__(256) void k_prep(
    const float* __restrict__ hidden, u16* __restrict__ hb,
    const float* __restrict__ ipw, u16* __restrict__ ipwb,
    const float* __restrict__ projw, u16* __restrict__ pjwb,
    const float* __restrict__ Wq, const float* __restrict__ Wk,
    const float* __restrict__ opw, u16* __restrict__ S, u16* __restrict__ opwT,
    const float* __restrict__ alignf, u16* __restrict__ alignbT,
    const float* __restrict__ ipb,
    const float* __restrict__ bq_lang, const float* __restrict__ bk_lang,
    float* __restrict__ beff)
{
    __shared__ float T[64][65];
    const size_t HH = (size_t)Hn * Hn;
    const int bid = blockIdx.x, tid = threadIdx.x;
    if (bid < PREP_NF2B) {
        const int n0 = (int)(Bn * Sn * Hn / 4), n1 = (int)(3 * HH / 4), n2 = (int)(HH / 4);
        int i = bid * 256 + tid;
        const float* s; u16* d; int off;
        if (i < n0)                { s = hidden; d = hb;   off = i; }
        else if (i < n0 + n1)      { s = ipw;    d = ipwb; off = i - n0; }
        else if (i < n0 + n1 + n2) { s = projw;  d = pjwb; off = i - n0 - n1; }
        else return;
        float4 v = reinterpret_cast<const float4*>(s)[off];
        u16x4 o;
        o[0] = f2bf(v.x); o[1] = f2bf(v.y); o[2] = f2bf(v.z); o[3] = f2bf(v.w);
        reinterpret_cast<u16x4*>(d)[off] = o;
    } else if (bid < PREP_NF2B + PREP_NTR) {
        int b2 = bid - PREP_NF2B;
        int z = b2 / 144, r = b2 % 144;
        int bx = r % 12, by = r / 12;
        const float* src;
        u16* dst;
        if (z < 5)       { src = Wq + (size_t)z * HH;        dst = S + (size_t)z * HH; }
        else if (z < 10) { src = Wk + (size_t)(z - 5) * HH;  dst = S + (size_t)z * HH; }
        else if (z == 10){ src = opw;                         dst = opwT; }
        else             { src = alignf + (size_t)(z - 11) * HH;
                           dst = alignbT + (size_t)(z - 11) * HH; }
        int i0 = bx * 64, o0 = by * 64;
        int x = tid & 63, ys = tid >> 6;
        for (int rr = ys; rr < 64; rr += 4)
            T[rr][x] = src[(size_t)(o0 + rr) * Hn + i0 + x];
        __syncthreads();
        for (int rr = ys; rr < 64; rr += 4)
            dst[(size_t)(i0 + rr) * Hn + o0 + x] = f2bf(T[x][rr]);
    } else {
        int b3 = bid - PREP_NF2B - PREP_NTR;       // 0..29
        int ox = b3 % 3, y = b3 / 3;
        int o = ox * 256 + tid;
        int which = y / 5, l = y % 5;
        const float4* w = reinterpret_cast<const float4*>(ipw + (size_t)which * HH + (size_t)o * Hn);
        const float4* bv = reinterpret_cast<const float4*>(((which ? bk_lang : bq_lang) + (size_t)l * Hn));
        float s = 0.f;
        for (int j = 0; j < Hn / 4; ++j) {
            float4 a = w[j], b = bv[j];
            s += a.x * b.x + a.y * b.y + a.z * b.z + a.w * b.w;
        }
        s += ipb[which * Hn + o];
        beff[(size_t)(which * 5 + l) * Hn + o] = s;
    }
}

// ---- TM x 128 triple-buffered counted-vmcnt NT GEMM core (256 thr) ----
template<int TM>
__device__ __forceinline__ void gemm_core(
    const u16* __restrict__ A, int lda,
    const u16* __restrict__ Bw, int ldb,
    const float* __restrict__ bias,
    const float* __restrict__ addres,
    u16* __restrict__ outH, float* __restrict__ outF,
    u16* __restrict__ outVT, int ldc,
    int m0, int n0, float scale)
{
    constexpr int MI = TM / 32;
    constexpr int AIT = TM / 64;
    __shared__ u16 As[3 * TM * 32];
    __shared__ u16 Bs[3 * 128 * 32];
    const int tid = threadIdx.x;
    const int lane = tid & 63, wave = tid >> 6;
    const int lrow = lane & 15, lquad = lane >> 4;
    const int wm = (wave >> 1) * (TM / 2), wn = (wave & 1) * 64;

    const u16* gA = A + (size_t)(m0 + (tid >> 2)) * lda + (tid & 3) * 8;
    const u16* gB = Bw + (size_t)(n0 + (tid >> 2)) * ldb + (tid & 3) * 8;

    f32x4 z = {0.f, 0.f, 0.f, 0.f};
    f32x4 acc[MI][4];
    #pragma unroll
    for (int i = 0; i < MI; ++i)
        #pragma unroll
        for (int j = 0; j < 4; ++j) acc[i][j] = z;

    auto stage = [&](int bs, int k0) {
        #pragma unroll
        for (int it = 0; it < AIT; ++it)
            glds16(gA + (size_t)(it * 64) * lda + k0, &As[bs * TM * 32 + (tid + 256 * it) * 8]);
        #pragma unroll
        for (int it = 0; it < 2; ++it)
            glds16(gB + (size_t)(it * 64) * ldb + k0, &Bs[bs * 128 * 32 + (tid + 256 * it) * 8]);
    };
    auto compute = [&](int bc) {
        const u16* Ab = &As[bc * TM * 32];
        const u16* Bb = &Bs[bc * 128 * 32];
        bf16x8 af[MI], bf_[4];
        #pragma unroll
        for (int i = 0; i < MI; ++i)
            af[i] = ld8(&Ab[(wm + i * 16 + lrow) * 32 + lquad * 8]);
        #pragma unroll
        for (int j = 0; j < 4; ++j)
            bf_[j] = ld8(&Bb[(wn + j * 16 + lrow) * 32 + lquad * 8]);
        #pragma unroll
        for (int i = 0; i < MI; ++i)
            #pragma unroll
            for (int j = 0; j < 4; ++j)
                acc[i][j] = __builtin_amdgcn_mfma_f32_16x16x32_bf16(af[i], bf_[j], acc[i][j], 0, 0, 0);
    };

    stage(0, 0);
    stage(1, 32);
    int bc = 0, bs = 2;
    for (int kt = 0; kt < 24; ++kt) {
        if (kt < 23) {
            if constexpr (TM == 256) {
                asm volatile("s_waitcnt vmcnt(6)" ::: "memory");
            } else {
                asm volatile("s_waitcnt vmcnt(4)" ::: "memory");
            }
        } else {
            asm volatile("s_waitcnt vmcnt(0)" ::: "memory");
        }
        __builtin_amdgcn_s_barrier();
        if (kt < 22) {
            stage(bs, (kt + 2) * 32);
            bs = (bs == 2) ? 0 : bs + 1;
        }
        compute(bc);
        bc = (bc == 2) ? 0 : bc + 1;
    }

    #pragma unroll
    for (int i = 0; i < MI; ++i) {
        #pragma unroll
        for (int j = 0; j < 4; ++j) {
            int col = n0 + wn + j * 16 + lrow;
            float bv = bias ? bias[col] : 0.f;
            if (outVT) {
                int row0 = m0 + wm + i * 16 + lquad * 4;
                int bb = row0 / Sn, s = row0 % Sn;
                int hh = col >> 6, dd = col & 63;
                u16x4 o;
                #pragma unroll
                for (int r = 0; r < 4; ++r) o[r] = f2bf((acc[i][j][r] + bv) * scale);
                *reinterpret_cast<u16x4*>(
                    outVT + (((size_t)bb * NHn + hh) * 64 + dd) * Sn + s) = o;
            } else {
                #pragma unroll
                for (int r = 0; r < 4; ++r) {
                    int row = m0 + wm + i * 16 + lquad * 4 + r;
                    float v = (acc[i][j][r] + bv) * scale;
                    if (addres) v += addres[(size_t)row * ldc + col];
                    if (outF) outF[(size_t)row * ldc + col] = v;
                    else      outH[(size_t)row * ldc + col] = f2bf(v);
                }
            }
        }
    }
}

// -- 64x64 triple-buffered counted-vmcnt NT GEMM core (256 thr), LDS passed in --
__device__ __forceinline__ void gemm64(
    u16* As, u16* Bs,
    const u16* __restrict__ A, const u16* __restrict__ Bw,
    const float* __restrict__ bias, const float* __restrict__ addres,
    u16* __restrict__ outH, float* __restrict__ outF,
    int m0, int n0)
{
    const int tid = threadIdx.x;
    const int lane = tid & 63, wave = tid >> 6;
    const int lrow = lane & 15, lquad = lane >> 4;
    const int wm = (wave >> 1) * 32, wn = (wave & 1) * 32;

    const u16* gA = A + (size_t)(m0 + (tid >> 2)) * Hn + (tid & 3) * 8;
    const u16* gB = Bw + (size_t)(n0 + (tid >> 2)) * Hn + (tid & 3) * 8;

    f32x4 z = {0.f, 0.f, 0.f, 0.f};
    f32x4 acc[2][2];
    #pragma unroll
    for (int i = 0; i < 2; ++i)
        #pragma unroll
        for (int j = 0; j < 2; ++j) acc[i][j] = z;

    auto stage = [&](int bs, int k0) {
        glds16(gA + k0, &As[bs * 64 * 32 + tid * 8]);
        glds16(gB + k0, &Bs[bs * 64 * 32 + tid * 8]);
    };
    auto compute = [&](int bc) {
        const u16* Ab = &As[bc * 64 * 32];
        const u16* Bb = &Bs[bc * 64 * 32];
        bf16x8 af[2], bf_[2];
        #pragma unroll
        for (int i = 0; i < 2; ++i)
            af[i] = ld8(&Ab[(wm + i * 16 + lrow) * 32 + lquad * 8]);
        #pragma unroll
        for (int j = 0; j < 2; ++j)
            bf_[j] = ld8(&Bb[(wn + j * 16 + lrow) * 32 + lquad * 8]);
        #pragma unroll
        for (int i = 0; i < 2; ++i)
            #pragma unroll
            for (int j = 0; j < 2; ++j)
                acc[i][j] = __builtin_amdgcn_mfma_f32_16x16x32_bf16(af[i], bf_[j], acc[i][j], 0, 0, 0);
    };

    stage(0, 0);
    stage(1, 32);
    int bc = 0, bs = 2;
    for (int kt = 0; kt < 24; ++kt) {
        if (kt < 23) {
            asm volatile("s_waitcnt vmcnt(2)" ::: "memory");
        } else {
            asm volatile("s_waitcnt vmcnt(0)" ::: "memory");
        }
        __builtin_amdgcn_s_barrier();
        if (kt < 22) {
            stage(bs, (kt + 2) * 32);
            bs = (bs == 2) ? 0 : bs + 1;
        }
        compute(bc);
        bc = (bc == 2) ? 0 : bc + 1;
    }

    #pragma unroll
    for (int i = 0; i < 2; ++i)
        #pragma unroll
        for (int j = 0; j < 2; ++j) {
            int col = n0 + wn + j * 16 + lrow;
            float bv = bias ? bias[col] : 0.f;
            #pragma unroll
            for (int r = 0; r < 4; ++r) {
                int row_ = m0 + wm + i * 16 + lquad * 4 + r;
                float v = acc[i][j][r] + bv;
                if (addres) v += addres[(size_t)row_ * Hn + col];
                if (outF) outF[(size_t)row_ * Hn + col] = v;
                else      outH[(size_t)row_ * Hn + col] = f2bf(v);
            }
        }
}

// ---- 64x64 tile helpers (256 thr): identity write, copy, transposing copy ----
static __device__ __forceinline__ void ident64(u16* dst, int m0, int n0)
{
    const int tid = threadIdx.x;
    #pragma unroll
    for (int it = 0; it < 2; ++it) {
        int s = tid + 256 * it;
        int ri = s >> 3, c8 = s & 7;
        s16x8 v;
        #pragma unroll
        for (int e = 0; e < 8; ++e)
            v[e] = (short)((m0 + ri == n0 + c8 * 8 + e) ? 0x3F80 : 0);
        *reinterpret_cast<s16x8*>(dst + (size_t)(m0 + ri) * Hn + n0 + c8 * 8) = v;
    }
}
static __device__ __forceinline__ void copy64(u16* dst, const u16* src, int m0, int n0)
{
    const int tid = threadIdx.x;
    #pragma unroll
    for (int it = 0; it < 2; ++it) {
        int s = tid + 256 * it;
        int row = s >> 3, seg = s & 7;
        *reinterpret_cast<s16x8*>(dst + (size_t)(m0 + row) * Hn + n0 + seg * 8) =
            *reinterpret_cast<const s16x8*>(src + (size_t)(m0 + row) * Hn + n0 + seg * 8);
    }
}
// dst = src^T: dst tile (m0,n0) <- src tile (n0,m0) transposed.  lds >= 64*72 u16
static __device__ __forceinline__ void tcopy64(u16* dst, const u16* src, int m0, int n0, u16* lds)
{
    u16 (*T)[72] = reinterpret_cast<u16(*)[72]>(lds);
    const int tid = threadIdx.x;
    #pragma unroll
    for (int it = 0; it < 2; ++it) {
        int s = tid + 256 * it;
        int rr = s >> 3, c8 = s & 7;
        s16x8 v = *reinterpret_cast<const s16x8*>(
            src + (size_t)(n0 + rr) * Hn + m0 + c8 * 8);
        #pragma unroll
        for (int e = 0; e < 8; ++e) T[c8 * 8 + e][rr] = (u16)v[e];
    }
    __syncthreads();
    #pragma unroll
    for (int it = 0; it < 2; ++it) {
        int s = tid + 256 * it;
        int ri = s >> 3, c8 = s & 7;
        *reinterpret_cast<s16x8*>(dst + (size_t)(m0 + ri) * Hn + n0 + c8 * 8) =
            *reinterpret_cast<const s16x8*>(&T[ri][c8 * 8]);
    }
}

// ---------------- GEMM wrapper kernels ----------------

// fused QKV projection, 256-row tiles (432 blocks -> ONE generation at 2/CU).
// grid (24, 6, 3): z=0 Q, z=1 K, z=2 V(T layout).
__global__ __launch_bounds__(256, 2) void k_gemm_qkv(
    const u16* __restrict__ A,
    const u16* __restrict__ Sq, const u16* __restrict__ Sk,
    const u16* __restrict__ Wv,
    const float* __restrict__ beff, const float* __restrict__ ipb,
    const int* __restrict__ lang,
    u16* __restrict__ outQ, u16* __restrict__ outK, u16* __restrict__ outVT)
{
    const size_t HH = (size_t)Hn * Hn;
    int z = blockIdx.z;
    int m0 = blockIdx.x * 256, n0 = blockIdx.y * 128;
    int l = lang[blockIdx.x / 3];
    if (z == 0) {
        gemm_core<256>(A, Hn, Sq + (size_t)l * HH, Hn, beff + (size_t)l * Hn,
                       nullptr, outQ, nullptr, nullptr, Hn, m0, n0, 0.125f);
    } else if (z == 1) {
        gemm_core<256>(A, Hn, Sk + (size_t)l * HH, Hn, beff + (size_t)(5 + l) * Hn,
                       nullptr, outK, nullptr, nullptr, Hn, m0, n0, 1.f);
    } else {
        gemm_core<256>(A, Hn, Wv, Hn, ipb + 2 * Hn,
                       nullptr, nullptr, nullptr, outVT, Hn, m0, n0, 1.f);
    }
}

// fused weight combine, 64^2 tiles.  z<5: Weffq_z; z>=5: Weffk.  grid (12,12,10)
__global__ __launch_bounds__(256) void k_comb10(
    const u16* __restrict__ ipwb, u16* __restrict__ S)
{
    __shared__ u16 As[3 * 64 * 32];
    __shared__ u16 Bs[3 * 64 * 32];
    const size_t HH = (size_t)Hn * Hn;
    int z = blockIdx.z;
    const u16* Aop = ipwb + (z < 5 ? 0 : HH);
    gemm64(As, Bs, Aop, S + (size_t)z * HH, nullptr, nullptr,
           S + (size_t)(10 + z) * HH, nullptr,
           blockIdx.x * 64, blockIdx.y * 64);
}

// ---------------- chain tree ----------------
// MT_l = S7^T S6^T ... S0^T;  S_j = (lang[j]==l) ? I : align[l, lang[j]].
// L1 (z = l*4+node): node0 P_a = S7^T S6^T (straight); node1 P_bT (transposed);
// node2 P_c (straight); node3 P_dT (transposed).  L2: Q_a, Q_bT.  L3: MT.

// L1.  grid (12,12,20)
__global__ __launch_bounds__(256) void k_chainL1(
    const u16* __restrict__ alignb, const u16* __restrict__ alignbT,
    const int* __restrict__ lang, u16* __restrict__ N1)
{
    __shared__ u16 As[3 * 64 * 32];
    __shared__ u16 Bs[3 * 64 * 32];
    const size_t HH = (size_t)Hn * Hn;
    int idx = blockIdx.z, l = idx >> 2, node = idx & 3;
    int ja = 7 - node * 2, jb = 6 - node * 2;
    bool tr = node & 1;
    int la = lang[ja], lb = lang[jb];
    bool sa = (la == l), sb = (lb == l);
    u16* dst = N1 + (size_t)idx * HH;
    int m0 = blockIdx.x * 64, n0 = blockIdx.y * 64;
    if (sa && sb) {
        ident64(dst, m0, n0);
    } else if (sa) {
        copy64(dst, (tr ? alignb : alignbT) + ((size_t)l * NLn + lb) * HH, m0, n0);
    } else if (sb) {
        copy64(dst, (tr ? alignb : alignbT) + ((size_t)l * NLn + la) * HH, m0, n0);
    } else if (!tr) {  // straight: Fa^T * Fb^T = NT(FaT, Fb)
        gemm64(As, Bs, alignbT + ((size_t)l * NLn + la) * HH,
               alignb + ((size_t)l * NLn + lb) * HH,
               nullptr, nullptr, dst, nullptr, m0, n0);
    } else {           // transposed: Fb * Fa = NT(Fb, FaT)
        gemm64(As, Bs, alignb + ((size_t)l * NLn + lb) * HH,
               alignbT + ((size_t)l * NLn + la) * HH,
               nullptr, nullptr, dst, nullptr, m0, n0);
    }
}

// L2.  grid (12,12,10): z = l*2 + q.  Q_a -> Q2[l], Q_bT -> Q2[5+l]
__global__ __launch_bounds__(256) void k_chainL2(
    const u16* __restrict__ N1, const int* __restrict__ lang,
    u16* __restrict__ Q2)
{
    __shared__ u16 As[3 * 64 * 32];
    __shared__ u16 Bs[3 * 64 * 32];
    const size_t HH = (size_t)Hn * Hn;
    int idx = blockIdx.z, l = idx >> 1, q = idx & 1;
    int m0 = blockIdx.x * 64, n0 = blockIdx.y * 64;
    const u16* Pa  = N1 + (size_t)(l * 4 + 0) * HH;
    const u16* PbT = N1 + (size_t)(l * 4 + 1) * HH;
    const u16* Pc  = N1 + (size_t)(l * 4 + 2) * HH;
    const u16* PdT = N1 + (size_t)(l * 4 + 3) * HH;
    if (q == 0) {
        u16* dst = Q2 + (size_t)l * HH;
        bool ia = (lang[7] == l) && (lang[6] == l);
        bool ib = (lang[5] == l) && (lang[4] == l);
        if (ia && ib)      ident64(dst, m0, n0);
        else if (ia)       tcopy64(dst, PbT, m0, n0, As);
        else if (ib)       copy64(dst, Pa, m0, n0);
        else               gemm64(As, Bs, Pa, PbT, nullptr, nullptr, dst, nullptr, m0, n0);
    } else {
        u16* dst = Q2 + (size_t)(5 + l) * HH;
        bool ic = (lang[3] == l) && (lang[2] == l);
        bool id = (lang[1] == l) && (lang[0] == l);
        if (ic && id)      ident64(dst, m0, n0);
        else if (ic)       copy64(dst, PdT, m0, n0);
        else if (id)       tcopy64(dst, Pc, m0, n0, As);
        else               gemm64(As, Bs, PdT, Pc, nullptr, nullptr, dst, nullptr, m0, n0);
    }
}

// L3.  grid (12,12,5): MT_l = Q_a * Q_b = NT(Q_a, Q_bT)
__global__ __launch_bounds__(256) void k_chainL3(
    const u16* __restrict__ Q2, const int* __restrict__ lang,
    u16* __restrict__ MT)
{
    __shared__ u16 As[3 * 64 * 32];
    __shared__ u16 Bs[3 * 64 * 32];
    const size_t HH = (size_t)Hn * Hn;
    int l = blockIdx.z;
    int m0 = blockIdx.x * 64, n0 = blockIdx.y * 64;
    const u16* Qa  = Q2 + (size_t)l * HH;
    const u16* QbT = Q2 + (size_t)(5 + l) * HH;
    u16* dst = MT + (size_t)l * HH;
    bool iA = (lang[7] == l) && (lang[6] == l) && (lang[5] == l) && (lang[4] == l);
    bool iB = (lang[3] == l) && (lang[2] == l) && (lang[1] == l) && (lang[0] == l);
    if (iA && iB)      ident64(dst, m0, n0);
    else if (iA)       tcopy64(dst, QbT, m0, n0, As);
    else if (iB)       copy64(dst, Qa, m0, n0);
    else               gemm64(As, Bs, Qa, QbT, nullptr, nullptr, dst, nullptr, m0, n0);
}

// U_l = NT(opwT, MT_l) + opb_eff GEMV.  grid 735.
__global__ __launch_bounds__(256) void k_uop(
    const u16* __restrict__ opwT, const u16* __restrict__ MT,
    const float* __restrict__ opb,
    u16* __restrict__ U5, float* __restrict__ opbeff)
{
    __shared__ u16 As[3 * 64 * 32];
    __shared__ u16 Bs[3 * 64 * 32];
    const size_t HH = (size_t)Hn * Hn;
    int bid = blockIdx.x;
    if (bid < 720) {
        int z = bid / 144, r = bid % 144;
        gemm64(As, Bs, opwT, MT + (size_t)z * HH, nullptr, nullptr,
               U5 + (size_t)z * HH, nullptr,
               (r % 12) * 64, (r / 12) * 64);
    } else {
        int b2 = bid - 720;
        int n = (b2 % 3) * 256 + threadIdx.x;
        int l = b2 / 3;
        const u16* mt = MT + ((size_t)l * Hn + n) * Hn;
        float s = 0.f;
        for (int k = 0; k < Hn; k += 8) {
            s16x8 v = *reinterpret_cast<const s16x8*>(mt + k);
            #pragma unroll
            for (int jq = 0; jq < 8; ++jq) s += opb[k + jq] * bf2f((u16)v[jq]);
        }
        opbeff[(size_t)l * Hn + n] = s;
    }
}

// W_l = NT(projw, U_l) + bias2 GEMV.  grid 735.
__global__ __launch_bounds__(256) void k_wb2(
    const u16* __restrict__ pjwb, const u16* __restrict__ U5,
    const float* __restrict__ opbeff, const float* __restrict__ projw,
    const float* __restrict__ projb,
    u16* __restrict__ W5, float* __restrict__ bias2)
{
    __shared__ u16 As[3 * 64 * 32];
    __shared__ u16 Bs[3 * 64 * 32];
    const size_t HH = (size_t)Hn * Hn;
    int bid = blockIdx.x;
    if (bid < 720) {
        int z = bid / 144, r = bid % 144;
        gemm64(As, Bs, pjwb, U5 + (size_t)z * HH, nullptr, nullptr,
               W5 + (size_t)z * HH, nullptr,
               (r % 12) * 64, (r / 12) * 64);
    } else {
        int b2 = bid - 720;
        int m = (b2 % 3) * 256 + threadIdx.x;
        int l = b2 / 3;
        const float4* w = reinterpret_cast<const float4*>(projw + (size_t)m * Hn);
        const float4* ob = reinterpret_cast<const float4*>(opbeff + (size_t)l * Hn);
        float s = 0.f;
        for (int jq = 0; jq < Hn / 4; ++jq) {
            float4 a = w[jq], b = ob[jq];
            s += a.x * b.x + a.y * b.y + a.z * b.z + a.w * b.w;
        }
        bias2[(size_t)l * Hn + m] = s + projb[m];
    }
}

// x = NT(ctx, W[lang]) + bias2[lang] + hidden -> f32 out.  64^2 tiles, grid (96,12)
__global__ __launch_bounds__(256) void k_xfused(
    const u16* __restrict__ ctx, const u16* __restrict__ W5,
    const float* __restrict__ bias2, const int* __restrict__ lang,
    const float* __restrict__ hidden, float* __restrict__ x)
{
    __shared__ u16 As[3 * 64 * 32];
    __shared__ u16 Bs[3 * 64 * 32];
    int l = lang[blockIdx.x / 12];
    gemm64(As, Bs, ctx, W5 + (size_t)l * Hn * Hn, bias2 + (size_t)l * Hn,
           hidden, nullptr, x,
           blockIdx.x * 64, blockIdx.y * 64);
}

// ---------------- flash attention + align conversion, 512 threads ----------
// blocks [0,576): attn.  blocks [576, 1476): align f32 -> bf16 (straight only;
// transposed copy handled in k_prep), 8 float4s per thread.
__global__ __launch_bounds__(512) void k_attn_conv(
    const u16* __restrict__ Q, const u16* __restrict__ K,
    const u16* __restrict__ VT, u16* __restrict__ ctx,
    const float* __restrict__ alignf, u16* __restrict__ alignb)
{
    __shared__ u16 Ks[2][64 * 64];       // [key][d], seg-xor-swizzled
    __shared__ u16 Vs[2][64 * 64];       // [d][key], seg-xor-swizzled
    __shared__ u16 Pw[8][16 * 72];       // per-wave P, 16B-aligned stride

    const int bid = blockIdx.x, tid = threadIdx.x;
    if (bid >= 576) {
        int base = (bid - 576) * 4096 + tid;     // 900*4096 = 3686400 float4s
        #pragma unroll
        for (int it = 0; it < 8; ++it) {
            int i = base + it * 512;
            float4 v = reinterpret_cast<const float4*>(alignf)[i];
            u16x4 o;
            o[0] = f2bf(v.x); o[1] = f2bf(v.y); o[2] = f2bf(v.z); o[3] = f2bf(v.w);
            reinterpret_cast<u16x4*>(alignb)[i] = o;
        }
        return;
    }

    const int q0 = (bid % 6) * 128, h = (bid / 6) % NHn, bz = bid / 72;
    const int wave = tid >> 6, lane = tid & 63;
    const int lrow = lane & 15, lquad = lane >> 4;
    const int sw = lrow & 7;

    const u16* Qp = Q + ((size_t)(bz * Sn + q0 + wave * 16 + lrow)) * Hn + h * HDn;
    const u16* Kb = K + (size_t)bz * Sn * Hn + h * HDn;
    const u16* Vb = VT + ((size_t)(bz * NHn + h) * 64) * Sn;   // row d, stride Sn

    bf16x8 qa0 = ld8(Qp + lquad * 8);
    bf16x8 qa1 = ld8(Qp + 32 + lquad * 8);

    f32x4 z4 = {0.f, 0.f, 0.f, 0.f};
    float m_r[4], l_l[4];
    f32x4 oacc[4];
    #pragma unroll
    for (int r = 0; r < 4; ++r) { m_r[r] = -1e30f; l_l[r] = 0.f; }
    #pragma unroll
    for (int jd = 0; jd < 4; ++jd) oacc[jd] = z4;

    const int krow = tid >> 3, kp = (tid & 7) ^ (krow & 7);
    const u16* kg = Kb + (size_t)krow * Hn + kp * 8;
    const u16* vg = Vb + (size_t)krow * Sn + kp * 8;

    auto stage = [&](int bs, int t0) {
        glds16(kg + (size_t)t0 * Hn, &Ks[bs][tid * 8]);
        glds16(vg + t0, &Vs[bs][tid * 8]);
    };

    auto compute = [&](int bc) {
        f32x4 sc[4];
        __builtin_amdgcn_s_setprio(1);
        #pragma unroll
        for (int j = 0; j < 4; ++j) {
            int base = (j * 16 + lrow) * 64 + ((lquad ^ sw) * 8);
            f32x4 s = __builtin_amdgcn_mfma_f32_16x16x32_bf16(qa0, ld8(&Ks[bc][base]), z4, 0, 0, 0);
            sc[j] = __builtin_amdgcn_mfma_f32_16x16x32_bf16(qa1, ld8(&Ks[bc][base ^ 32]), s, 0, 0, 0);
        }
        __builtin_amdgcn_s_setprio(0);
        float tmax[4];
        #pragma unroll
        for (int r = 0; r < 4; ++r)
            tmax[r] = fmaxf(fmaxf(sc[0][r], sc[1][r]), fmaxf(sc[2][r], sc[3][r]));
        #pragma unroll
        for (int off = 1; off < 16; off <<= 1)
            #pragma unroll
            for (int r = 0; r < 4; ++r)
                tmax[r] = fmaxf(tmax[r], __shfl_xor(tmax[r], off));
        bool grow = (tmax[0] > m_r[0] + 8.f) | (tmax[1] > m_r[1] + 8.f) |
                    (tmax[2] > m_r[2] + 8.f) | (tmax[3] > m_r[3] + 8.f);
        if (grow) {
            #pragma unroll
            for (int r = 0; r < 4; ++r) {
                float mn = fmaxf(m_r[r], tmax[r]);
                float a = __expf(m_r[r] - mn);
                m_r[r] = mn;
                l_l[r] *= a;
                #pragma unroll
                for (int jd = 0; jd < 4; ++jd) oacc[jd][r] *= a;
            }
        }
        float ps[4] = {0.f, 0.f, 0.f, 0.f};
        #pragma unroll
        for (int j = 0; j < 4; ++j)
            #pragma unroll
            for (int r = 0; r < 4; ++r) {
                float p = __expf(sc[j][r] - m_r[r]);
                ps[r] += p;
                Pw[wave][(lquad * 4 + r) * 72 + j * 16 + lrow] = f2bf(p);
            }
        #pragma unroll
        for (int r = 0; r < 4; ++r) l_l[r] += ps[r];
        bf16x8 pa0 = ld8(&Pw[wave][lrow * 72 + lquad * 8]);
        bf16x8 pa1 = ld8(&Pw[wave][lrow * 72 + 32 + lquad * 8]);
        __builtin_amdgcn_s_setprio(1);
        #pragma unroll
        for (int jd = 0; jd < 4; ++jd) {
            int vbase = (jd * 16 + lrow) * 64 + ((lquad ^ sw) * 8);
            oacc[jd] = __builtin_amdgcn_mfma_f32_16x16x32_bf16(pa0, ld8(&Vs[bc][vbase]), oacc[jd], 0, 0, 0);
            oacc[jd] = __builtin_amdgcn_mfma_f32_16x16x32_bf16(pa1, ld8(&Vs[bc][vbase ^ 32]), oacc[jd], 0, 0, 0);
        }
        __builtin_amdgcn_s_setprio(0);
    };

    stage(0, 0);
    stage(1, 64);
    for (int kt = 0; kt < 12; ++kt) {
        if (kt < 11) {
            asm volatile("s_waitcnt vmcnt(2)" ::: "memory");
        } else {
            asm volatile("s_waitcnt vmcnt(0)" ::: "memory");
        }
        __builtin_amdgcn_s_barrier();
        compute(kt & 1);
        if (kt < 10) {
            __builtin_amdgcn_s_barrier();
            stage(kt & 1, (kt + 2) * 64);
        }
    }

    #pragma unroll
    for (int off = 1; off < 16; off <<= 1)
        #pragma unroll
        for (int r = 0; r < 4; ++r)
            l_l[r] += __shfl_xor(l_l[r], off);

    float rl[4];
    #pragma unroll
    for (int r = 0; r < 4; ++r) rl[r] = 1.f / l_l[r];
    #pragma unroll
    for (int jd = 0; jd < 4; ++jd)
        #pragma unroll
        for (int r = 0; r < 4; ++r) {
            size_t row = (size_t)bz * Sn + q0 + wave * 16 + lquad * 4 + r;
            ctx[row * Hn + h * HDn + jd * 16 + lrow] = f2bf(oacc[jd][r] * rl[r]);
        }
}

// layernorm in-place on f32 d_out.  grid B*S, block 64
__global__ __launch_bounds__(64) void k_ln(
    float* x, const float* __restrict__ g, const float* __restrict__ beta)
{
    size_t row = blockIdx.x;
    float* xr = x + row * Hn;
    int lane = threadIdx.x;
    float v[12];
    float s = 0.f, ss = 0.f;
    #pragma unroll
    for (int i = 0; i < 12; ++i) {
        v[i] = xr[lane + i * 64];
        s += v[i];
        ss += v[i] * v[i];
    }
    #pragma unroll
    for (int off = 1; off < 64; off <<= 1) {
        s  += __shfl_xor(s, off);
        ss += __shfl_xor(ss, off);
    }
    float mu = s * (1.f / Hn);
    float var = ss * (1.f / Hn) - mu * mu;
    float inv = rsqrtf(var + 1e-5f);
    #pragma unroll
    for (int i = 0; i < 12; ++i) {
        int c = lane + i * 64;
        xr[c] = (v[i] - mu) * inv * g[c] + beta[c];
    }
}

// ---------------- launch ----------------
extern "C" void kernel_launch(void* const* d_in, const int* in_sizes, int n_in,
                              void* d_out, int out_size, void* d_ws, size_t ws_size,
                              hipStream_t stream)
{
    (void)in_sizes; (void)n_in; (void)out_size; (void)ws_size;

    const float* hidden  = (const float*)d_in[0];
    const int*   lang    = (const int*)d_in[1];
    const float* Wq_lang = (const float*)d_in[3];
    const float* bq_lang = (const float*)d_in[4];
    const float* Wk_lang = (const float*)d_in[5];
    const float* bk_lang = (const float*)d_in[6];
    const float* ipw     = (const float*)d_in[7];
    const float* ipb     = (const float*)d_in[8];
    const float* opw     = (const float*)d_in[9];
    const float* opb     = (const float*)d_in[10];
    const float* align   = (const float*)d_in[11];
    const float* projw   = (const float*)d_in[12];
    const float* projb   = (const float*)d_in[13];
    const float* ln_g    = (const float*)d_in[14];
    const float* ln_b    = (const float*)d_in[15];
    float* out = (float*)d_out;

    const size_t HH  = (size_t)Hn * Hn;          // 589824
    const size_t BSH = (size_t)Bn * Sn * Hn;     // 4718592 = 8*HH
    const size_t AHH = (size_t)NLn * NLn * HH;   // 25*HH

    u16* rA = (u16*)d_ws;        // hb -> ctx
    u16* rB = rA + BSH;          // Q -> N1 slots 0..7
    u16* rC = rB + BSH;          // K -> N1 slots 8..15
    u16* rD = rC + BSH;          // V^T -> N1 slots 16..19
    u16* ipwb = rD + BSH;        // wq|wk|wv bf16 (3*HH)
    u16* pjwb = ipwb + 3 * HH;   // HH
    u16* opwT = pjwb + HH;       // HH
    u16* alignb = opwT + HH;     // 25*HH; pre-attn: weight scratch S[0..20)
                                 // post-L2: MT[0..5) U[5..10) W[10..15)
    u16* alignbT = alignb + AHH; // 25*HH transposed aligns (written by k_prep);
                                 // post-L1: Q2[0..10)
    float* beff   = (float*)(alignbT + AHH);  // 2*5*768 f32
    float* opbeff = beff + 10 * Hn;           // 5*768 f32
    float* bias2  = opbeff + 5 * Hn;          // 5*768 f32

    u16* S = alignb;             // scratch: WqT[0..5) WkT[5..10) Weffq[10..15) Weffk[15..20)
    u16* N1 = rB;                // 20 node matrices (rB..rD contiguous)
    u16* Q2 = alignbT;           // 10 node matrices (alignbT dead after L1)
    u16* MT = alignb;            // 5 (alignb dead after L1)
    u16* U5 = alignb + 5 * HH;   // 5
    u16* W5 = alignb + 10 * HH;  // 5

    // fused prep: conversions + 36 transposes (Wq/Wk/opw/align^T) + bias folds
    k_prep<<<(unsigned)(PREP_NF2B + PREP_NTR + 30), 256, 0, stream>>>(
        hidden, rA, ipw, ipwb, projw, pjwb,
        Wq_lang, Wk_lang, opw, S, opwT, align, alignbT,
        ipb, bq_lang, bk_lang, beff);

    // Weffq/Weffk (one launch, 64^2 tiles) -> S[10..20)
    k_comb10<<<dim3(12, 12, 10), 256, 0, stream>>>(ipwb, S);

    // fused QKV: Q*(1/8) -> rB, K -> rC, V^T -> rD.  256-row tiles, 1 generation.
    k_gemm_qkv<<<dim3(24, 6, 3), 256, 0, stream>>>(
        rA, S + 10 * HH, S + 15 * HH, ipwb + 2 * HH, beff, ipb, lang, rB, rC, rD);

    // attention (ctx -> rA) + straight align conversion (S scratch now dead)
    k_attn_conv<<<1476, 512, 0, stream>>>(rB, rC, rD, rA, align, alignb);

    // chain tree: 3 launches replace 8 sequential chain steps
    k_chainL1<<<dim3(12, 12, 20), 256, 0, stream>>>(alignb, alignbT, lang, N1);
    k_chainL2<<<dim3(12, 12, 10), 256, 0, stream>>>(N1, lang, Q2);
    k_chainL3<<<dim3(12, 12, 5), 256, 0, stream>>>(Q2, lang, MT);

    // U_l = opw^T . M_l  (+ opb_eff GEMV)
    k_uop<<<735, 256, 0, stream>>>(opwT, MT, opb, U5, opbeff);
    // W_l = projw . U_l  (+ bias2 GEMV)
    k_wb2<<<735, 256, 0, stream>>>(pjwb, U5, opbeff, projw, projb, W5, bias2);

    // x = ctx . W[lang]^T + bias2 + hidden -> d_out (f32).  64^2 tiles.
    k_xfused<<<dim3(96, 12), 256, 0, stream>>>(rA, W5, bias2, lang, hidden, out);
    // layernorm in place
    k_ln<<<(unsigned)(Bn * Sn), 64, 0, stream>>>(out, ln_g, ln_b);
}

// Round 12
// 451.940 us; speedup vs baseline: 1.6064x; 1.0065x over previous
//
#include <hip/hip_runtime.h>

// ---------------- constants ----------------
#define Bn 8
#define Sn 768
#define Hn 768
#define NHn 12
#define HDn 64
#define NLn 5

typedef unsigned short u16;
typedef __bf16 bf16x8 __attribute__((ext_vector_type(8)));
typedef short s16x8 __attribute__((ext_vector_type(8)));
typedef float f32x4 __attribute__((ext_vector_type(4)));
typedef unsigned short u16x4 __attribute__((ext_vector_type(4)));

static __device__ __forceinline__ float bf2f(u16 v) {
    return __uint_as_float(((unsigned)v) << 16);
}
static __device__ __forceinline__ u16 f2bf(float f) {
    unsigned u = __float_as_uint(f);
    unsigned r = u + 0x7fffu + ((u >> 16) & 1u);
    return (u16)(r >> 16);
}
static __device__ __forceinline__ bf16x8 ld8(const u16* p) {
    return *reinterpret_cast<const bf16x8*>(p);
}
static __device__ __forceinline__ void glds16(const u16* g, u16* l) {
    __builtin_amdgcn_global_load_lds(
        (const __attribute__((address_space(1))) void*)g,
        (__attribute__((address_space(3))) void*)l, 16, 0, 0);
}

// ---------------- fused prep: f32->bf16 conversions + transposes + bias folds
// f2b: 8 f32/thread (2x float4 in, 1x s16x8 out).
// transposes: float4 staged loads + s16x8 transposed stores.
//   z<5 Wq -> S, z<10 Wk -> S, z==10 opw -> opwT,
//   z in [11,36): align mat (z-11) -> alignbT (transposed bf16)
#define PREP_NF2B 3456
#define PREP_NTR  (36 * 144)
__global__ __launch_bounds__(256) void k_prep(
    const float* __restrict__ hidden, u16* __restrict__ hb,
    const float* __restrict__ ipw, u16* __restrict__ ipwb,
    const float* __restrict__ projw, u16* __restrict__ pjwb,
    const float* __restrict__ Wq, const float* __restrict__ Wk,
    const float* __restrict__ opw, u16* __restrict__ S, u16* __restrict__ opwT,
    const float* __restrict__ alignf, u16* __restrict__ alignbT,
    const float* __restrict__ ipb,
    const float* __restrict__ bq_lang, const float* __restrict__ bk_lang,
    float* __restrict__ beff)
{
    __shared__ float T[64][65];
    const size_t HH = (size_t)Hn * Hn;
    const int bid = blockIdx.x, tid = threadIdx.x;
    if (bid < PREP_NF2B) {
        // 8 f32 per thread
        const int n0 = (int)(Bn * Sn * Hn / 8), n1 = (int)(3 * HH / 8), n2 = (int)(HH / 8);
        int i = bid * 256 + tid;
        const float* s; u16* d; int off;
        if (i < n0)                { s = hidden; d = hb;   off = i; }
        else if (i < n0 + n1)      { s = ipw;    d = ipwb; off = i - n0; }
        else if (i < n0 + n1 + n2) { s = projw;  d = pjwb; off = i - n0 - n1; }
        else return;
        float4 a = reinterpret_cast<const float4*>(s)[off * 2];
        float4 b = reinterpret_cast<const float4*>(s)[off * 2 + 1];
        s16x8 o;
        o[0] = (short)f2bf(a.x); o[1] = (short)f2bf(a.y);
        o[2] = (short)f2bf(a.z); o[3] = (short)f2bf(a.w);
        o[4] = (short)f2bf(b.x); o[5] = (short)f2bf(b.y);
        o[6] = (short)f2bf(b.z); o[7] = (short)f2bf(b.w);
        reinterpret_cast<s16x8*>(d)[off] = o;
    } else if (bid < PREP_NF2B + PREP_NTR) {
        int b2 = bid - PREP_NF2B;
        int z = b2 / 144, r = b2 % 144;
        int bx = r % 12, by = r / 12;
        const float* src;
        u16* dst;
        if (z < 5)       { src = Wq + (size_t)z * HH;        dst = S + (size_t)z * HH; }
        else if (z < 10) { src = Wk + (size_t)(z - 5) * HH;  dst = S + (size_t)z * HH; }
        else if (z == 10){ src = opw;                         dst = opwT; }
        else             { src = alignf + (size_t)(z - 11) * HH;
                           dst = alignbT + (size_t)(z - 11) * HH; }
        int i0 = bx * 64, o0 = by * 64;
        // stage 64x64 f32 tile: float4 loads (1024 float4s, 4 iters)
        #pragma unroll
        for (int it = 0; it < 4; ++it) {
            int s = tid + 256 * it;
            int row = s >> 4, seg = s & 15;
            float4 v = *reinterpret_cast<const float4*>(
                src + (size_t)(o0 + row) * Hn + i0 + seg * 4);
            T[row][seg * 4 + 0] = v.x;
            T[row][seg * 4 + 1] = v.y;
            T[row][seg * 4 + 2] = v.z;
            T[row][seg * 4 + 3] = v.w;
        }
        __syncthreads();
        // write transposed: s16x8 stores (512 segs, 2 iters)
        #pragma unroll
        for (int it = 0; it < 2; ++it) {
            int s = tid + 256 * it;
            int ri = s >> 3, c8 = s & 7;
            s16x8 o;
            #pragma unroll
            for (int e = 0; e < 8; ++e)
                o[e] = (short)f2bf(T[c8 * 8 + e][ri]);
            *reinterpret_cast<s16x8*>(dst + (size_t)(i0 + ri) * Hn + o0 + c8 * 8) = o;
        }
    } else {
        int b3 = bid - PREP_NF2B - PREP_NTR;       // 0..29
        int ox = b3 % 3, y = b3 / 3;
        int o = ox * 256 + tid;
        int which = y / 5, l = y % 5;
        const float4* w = reinterpret_cast<const float4*>(ipw + (size_t)which * HH + (size_t)o * Hn);
        const float4* bv = reinterpret_cast<const float4*>(((which ? bk_lang : bq_lang) + (size_t)l * Hn));
        float s = 0.f;
        for (int j = 0; j < Hn / 4; ++j) {
            float4 a = w[j], b = bv[j];
            s += a.x * b.x + a.y * b.y + a.z * b.z + a.w * b.w;
        }
        s += ipb[which * Hn + o];
        beff[(size_t)(which * 5 + l) * Hn + o] = s;
    }
}

// ---- TM x 128 triple-buffered counted-vmcnt NT GEMM core (256 thr) ----
template<int TM>
__device__ __forceinline__ void gemm_core(
    const u16* __restrict__ A, int lda,
    const u16* __restrict__ Bw, int ldb,
    const float* __restrict__ bias,
    const float* __restrict__ addres,
    u16* __restrict__ outH, float* __restrict__ outF,
    u16* __restrict__ outVT, int ldc,
    int m0, int n0, float scale)
{
    constexpr int MI = TM / 32;
    constexpr int AIT = TM / 64;
    __shared__ u16 As[3 * TM * 32];
    __shared__ u16 Bs[3 * 128 * 32];
    const int tid = threadIdx.x;
    const int lane = tid & 63, wave = tid >> 6;
    const int lrow = lane & 15, lquad = lane >> 4;
    const int wm = (wave >> 1) * (TM / 2), wn = (wave & 1) * 64;

    const u16* gA = A + (size_t)(m0 + (tid >> 2)) * lda + (tid & 3) * 8;
    const u16* gB = Bw + (size_t)(n0 + (tid >> 2)) * ldb + (tid & 3) * 8;

    f32x4 z = {0.f, 0.f, 0.f, 0.f};
    f32x4 acc[MI][4];
    #pragma unroll
    for (int i = 0; i < MI; ++i)
        #pragma unroll
        for (int j = 0; j < 4; ++j) acc[i][j] = z;

    auto stage = [&](int bs, int k0) {
        #pragma unroll
        for (int it = 0; it < AIT; ++it)
            glds16(gA + (size_t)(it * 64) * lda + k0, &As[bs * TM * 32 + (tid + 256 * it) * 8]);
        #pragma unroll
        for (int it = 0; it < 2; ++it)
            glds16(gB + (size_t)(it * 64) * ldb + k0, &Bs[bs * 128 * 32 + (tid + 256 * it) * 8]);
    };
    auto compute = [&](int bc) {
        const u16* Ab = &As[bc * TM * 32];
        const u16* Bb = &Bs[bc * 128 * 32];
        bf16x8 af[MI], bf_[4];
        #pragma unroll
        for (int i = 0; i < MI; ++i)
            af[i] = ld8(&Ab[(wm + i * 16 + lrow) * 32 + lquad * 8]);
        #pragma unroll
        for (int j = 0; j < 4; ++j)
            bf_[j] = ld8(&Bb[(wn + j * 16 + lrow) * 32 + lquad * 8]);
        #pragma unroll
        for (int i = 0; i < MI; ++i)
            #pragma unroll
            for (int j = 0; j < 4; ++j)
                acc[i][j] = __builtin_amdgcn_mfma_f32_16x16x32_bf16(af[i], bf_[j], acc[i][j], 0, 0, 0);
    };

    stage(0, 0);
    stage(1, 32);
    int bc = 0, bs = 2;
    for (int kt = 0; kt < 24; ++kt) {
        if (kt < 23) {
            if constexpr (TM == 256) {
                asm volatile("s_waitcnt vmcnt(6)" ::: "memory");
            } else {
                asm volatile("s_waitcnt vmcnt(4)" ::: "memory");
            }
        } else {
            asm volatile("s_waitcnt vmcnt(0)" ::: "memory");
        }
        __builtin_amdgcn_s_barrier();
        if (kt < 22) {
            stage(bs, (kt + 2) * 32);
            bs = (bs == 2) ? 0 : bs + 1;
        }
        compute(bc);
        bc = (bc == 2) ? 0 : bc + 1;
    }

    #pragma unroll
    for (int i = 0; i < MI; ++i) {
        #pragma unroll
        for (int j = 0; j < 4; ++j) {
            int col = n0 + wn + j * 16 + lrow;
            float bv = bias ? bias[col] : 0.f;
            if (outVT) {
                int row0 = m0 + wm + i * 16 + lquad * 4;
                int bb = row0 / Sn, s = row0 % Sn;
                int hh = col >> 6, dd = col & 63;
                u16x4 o;
                #pragma unroll
                for (int r = 0; r < 4; ++r) o[r] = f2bf((acc[i][j][r] + bv) * scale);
                *reinterpret_cast<u16x4*>(
                    outVT + (((size_t)bb * NHn + hh) * 64 + dd) * Sn + s) = o;
            } else {
                #pragma unroll
                for (int r = 0; r < 4; ++r) {
                    int row = m0 + wm + i * 16 + lquad * 4 + r;
                    float v = (acc[i][j][r] + bv) * scale;
                    if (addres) v += addres[(size_t)row * ldc + col];
                    if (outF) outF[(size_t)row * ldc + col] = v;
                    else      outH[(size_t)row * ldc + col] = f2bf(v);
                }
            }
        }
    }
}

// -- 64x64 triple-buffered counted-vmcnt NT GEMM core (256 thr), LDS passed in --
__device__ __forceinline__ void gemm64(
    u16* As, u16* Bs,
    const u16* __restrict__ A, const u16* __restrict__ Bw,
    const float* __restrict__ bias, const float* __restrict__ addres,
    u16* __restrict__ outH, float* __restrict__ outF,
    int m0, int n0)
{
    const int tid = threadIdx.x;
    const int lane = tid & 63, wave = tid >> 6;
    const int lrow = lane & 15, lquad = lane >> 4;
    const int wm = (wave >> 1) * 32, wn = (wave & 1) * 32;

    const u16* gA = A + (size_t)(m0 + (tid >> 2)) * Hn + (tid & 3) * 8;
    const u16* gB = Bw + (size_t)(n0 + (tid >> 2)) * Hn + (tid & 3) * 8;

    f32x4 z = {0.f, 0.f, 0.f, 0.f};
    f32x4 acc[2][2];
    #pragma unroll
    for (int i = 0; i < 2; ++i)
        #pragma unroll
        for (int j = 0; j < 2; ++j) acc[i][j] = z;

    auto stage = [&](int bs, int k0) {
        glds16(gA + k0, &As[bs * 64 * 32 + tid * 8]);
        glds16(gB + k0, &Bs[bs * 64 * 32 + tid * 8]);
    };
    auto compute = [&](int bc) {
        const u16* Ab = &As[bc * 64 * 32];
        const u16* Bb = &Bs[bc * 64 * 32];
        bf16x8 af[2], bf_[2];
        #pragma unroll
        for (int i = 0; i < 2; ++i)
            af[i] = ld8(&Ab[(wm + i * 16 + lrow) * 32 + lquad * 8]);
        #pragma unroll
        for (int j = 0; j < 2; ++j)
            bf_[j] = ld8(&Bb[(wn + j * 16 + lrow) * 32 + lquad * 8]);
        #pragma unroll
        for (int i = 0; i < 2; ++i)
            #pragma unroll
            for (int j = 0; j < 2; ++j)
                acc[i][j] = __builtin_amdgcn_mfma_f32_16x16x32_bf16(af[i], bf_[j], acc[i][j], 0, 0, 0);
    };

    stage(0, 0);
    stage(1, 32);
    int bc = 0, bs = 2;
    for (int kt = 0; kt < 24; ++kt) {
        if (kt < 23) {
            asm volatile("s_waitcnt vmcnt(2)" ::: "memory");
        } else {
            asm volatile("s_waitcnt vmcnt(0)" ::: "memory");
        }
        __builtin_amdgcn_s_barrier();
        if (kt < 22) {
            stage(bs, (kt + 2) * 32);
            bs = (bs == 2) ? 0 : bs + 1;
        }
        compute(bc);
        bc = (bc == 2) ? 0 : bc + 1;
    }

    #pragma unroll
    for (int i = 0; i < 2; ++i)
        #pragma unroll
        for (int j = 0; j < 2; ++j) {
            int col = n0 + wn + j * 16 + lrow;
            float bv = bias ? bias[col] : 0.f;
            #pragma unroll
            for (int r = 0; r < 4; ++r) {
                int row_ = m0 + wm + i * 16 + lquad * 4 + r;
                float v = acc[i][j][r] + bv;
                if (addres) v += addres[(size_t)row_ * Hn + col];
                if (outF) outF[(size_t)row_ * Hn + col] = v;
                else      outH[(size_t)row_ * Hn + col] = f2bf(v);
            }
        }
}

// ---- 64x64 tile helpers (256 thr): identity write, copy, transposing copy ----
static __device__ __forceinline__ void ident64(u16* dst, int m0, int n0)
{
    const int tid = threadIdx.x;
    #pragma unroll
    for (int it = 0; it < 2; ++it) {
        int s = tid + 256 * it;
        int ri = s >> 3, c8 = s & 7;
        s16x8 v;
        #pragma unroll
        for (int e = 0; e < 8; ++e)
            v[e] = (short)((m0 + ri == n0 + c8 * 8 + e) ? 0x3F80 : 0);
        *reinterpret_cast<s16x8*>(dst + (size_t)(m0 + ri) * Hn + n0 + c8 * 8) = v;
    }
}
static __device__ __forceinline__ void copy64(u16* dst, const u16* src, int m0, int n0)
{
    const int tid = threadIdx.x;
    #pragma unroll
    for (int it = 0; it < 2; ++it) {
        int s = tid + 256 * it;
        int row = s >> 3, seg = s & 7;
        *reinterpret_cast<s16x8*>(dst + (size_t)(m0 + row) * Hn + n0 + seg * 8) =
            *reinterpret_cast<const s16x8*>(src + (size_t)(m0 + row) * Hn + n0 + seg * 8);
    }
}
// dst = src^T: dst tile (m0,n0) <- src tile (n0,m0) transposed.  lds >= 64*72 u16
static __device__ __forceinline__ void tcopy64(u16* dst, const u16* src, int m0, int n0, u16* lds)
{
    u16 (*T)[72] = reinterpret_cast<u16(*)[72]>(lds);
    const int tid = threadIdx.x;
    #pragma unroll
    for (int it = 0; it < 2; ++it) {
        int s = tid + 256 * it;
        int rr = s >> 3, c8 = s & 7;
        s16x8 v = *reinterpret_cast<const s16x8*>(
            src + (size_t)(n0 + rr) * Hn + m0 + c8 * 8);
        #pragma unroll
        for (int e = 0; e < 8; ++e) T[c8 * 8 + e][rr] = (u16)v[e];
    }
    __syncthreads();
    #pragma unroll
    for (int it = 0; it < 2; ++it) {
        int s = tid + 256 * it;
        int ri = s >> 3, c8 = s & 7;
        *reinterpret_cast<s16x8*>(dst + (size_t)(m0 + ri) * Hn + n0 + c8 * 8) =
            *reinterpret_cast<const s16x8*>(&T[ri][c8 * 8]);
    }
}

// ---------------- GEMM wrapper kernels ----------------

// fused QKV projection, 256-row tiles (432 blocks -> ONE generation at 2/CU).
// grid (24, 6, 3): z=0 Q, z=1 K, z=2 V(T layout).
__global__ __launch_bounds__(256, 2) void k_gemm_qkv(
    const u16* __restrict__ A,
    const u16* __restrict__ Sq, const u16* __restrict__ Sk,
    const u16* __restrict__ Wv,
    const float* __restrict__ beff, const float* __restrict__ ipb,
    const int* __restrict__ lang,
    u16* __restrict__ outQ, u16* __restrict__ outK, u16* __restrict__ outVT)
{
    const size_t HH = (size_t)Hn * Hn;
    int z = blockIdx.z;
    int m0 = blockIdx.x * 256, n0 = blockIdx.y * 128;
    int l = lang[blockIdx.x / 3];
    if (z == 0) {
        gemm_core<256>(A, Hn, Sq + (size_t)l * HH, Hn, beff + (size_t)l * Hn,
                       nullptr, outQ, nullptr, nullptr, Hn, m0, n0, 0.125f);
    } else if (z == 1) {
        gemm_core<256>(A, Hn, Sk + (size_t)l * HH, Hn, beff + (size_t)(5 + l) * Hn,
                       nullptr, outK, nullptr, nullptr, Hn, m0, n0, 1.f);
    } else {
        gemm_core<256>(A, Hn, Wv, Hn, ipb + 2 * Hn,
                       nullptr, nullptr, nullptr, outVT, Hn, m0, n0, 1.f);
    }
}

// fused weight combine, 64^2 tiles.  z<5: Weffq_z; z>=5: Weffk.  grid (12,12,10)
__global__ __launch_bounds__(256) void k_comb10(
    const u16* __restrict__ ipwb, u16* __restrict__ S)
{
    __shared__ u16 As[3 * 64 * 32];
    __shared__ u16 Bs[3 * 64 * 32];
    const size_t HH = (size_t)Hn * Hn;
    int z = blockIdx.z;
    const u16* Aop = ipwb + (z < 5 ? 0 : HH);
    gemm64(As, Bs, Aop, S + (size_t)z * HH, nullptr, nullptr,
           S + (size_t)(10 + z) * HH, nullptr,
           blockIdx.x * 64, blockIdx.y * 64);
}

// ---------------- chain tree ----------------
// MT_l = S7^T S6^T ... S0^T;  S_j = (lang[j]==l) ? I : align[l, lang[j]].
// L1 (z = l*4+node): node0 P_a = S7^T S6^T (straight); node1 P_bT (transposed);
// node2 P_c (straight); node3 P_dT (transposed).  L2: Q_a, Q_bT.  L3: MT.

// L1.  grid (12,12,20)
__global__ __launch_bounds__(256) void k_chainL1(
    const u16* __restrict__ alignb, const u16* __restrict__ alignbT,
    const int* __restrict__ lang, u16* __restrict__ N1)
{
    __shared__ u16 As[3 * 64 * 32];
    __shared__ u16 Bs[3 * 64 * 32];
    const size_t HH = (size_t)Hn * Hn;
    int idx = blockIdx.z, l = idx >> 2, node = idx & 3;
    int ja = 7 - node * 2, jb = 6 - node * 2;
    bool tr = node & 1;
    int la = lang[ja], lb = lang[jb];
    bool sa = (la == l), sb = (lb == l);
    u16* dst = N1 + (size_t)idx * HH;
    int m0 = blockIdx.x * 64, n0 = blockIdx.y * 64;
    if (sa && sb) {
        ident64(dst, m0, n0);
    } else if (sa) {
        copy64(dst, (tr ? alignb : alignbT) + ((size_t)l * NLn + lb) * HH, m0, n0);
    } else if (sb) {
        copy64(dst, (tr ? alignb : alignbT) + ((size_t)l * NLn + la) * HH, m0, n0);
    } else if (!tr) {  // straight: Fa^T * Fb^T = NT(FaT, Fb)
        gemm64(As, Bs, alignbT + ((size_t)l * NLn + la) * HH,
               alignb + ((size_t)l * NLn + lb) * HH,
               nullptr, nullptr, dst, nullptr, m0, n0);
    } else {           // transposed: Fb * Fa = NT(Fb, FaT)
        gemm64(As, Bs, alignb + ((size_t)l * NLn + lb) * HH,
               alignbT + ((size_t)l * NLn + la) * HH,
               nullptr, nullptr, dst, nullptr, m0, n0);
    }
}

// L2.  grid (12,12,10): z = l*2 + q.  Q_a -> Q2[l], Q_bT -> Q2[5+l]
__global__ __launch_bounds__(256) void k_chainL2(
    const u16* __restrict__ N1, const int* __restrict__ lang,
    u16* __restrict__ Q2)
{
    __shared__ u16 As[3 * 64 * 32];
    __shared__ u16 Bs[3 * 64 * 32];
    const size_t HH = (size_t)Hn * Hn;
    int idx = blockIdx.z, l = idx >> 1, q = idx & 1;
    int m0 = blockIdx.x * 64, n0 = blockIdx.y * 64;
    const u16* Pa  = N1 + (size_t)(l * 4 + 0) * HH;
    const u16* PbT = N1 + (size_t)(l * 4 + 1) * HH;
    const u16* Pc  = N1 + (size_t)(l * 4 + 2) * HH;
    const u16* PdT = N1 + (size_t)(l * 4 + 3) * HH;
    if (q == 0) {
        u16* dst = Q2 + (size_t)l * HH;
        bool ia = (lang[7] == l) && (lang[6] == l);
        bool ib = (lang[5] == l) && (lang[4] == l);
        if (ia && ib)      ident64(dst, m0, n0);
        else if (ia)       tcopy64(dst, PbT, m0, n0, As);
        else if (ib)       copy64(dst, Pa, m0, n0);
        else               gemm64(As, Bs, Pa, PbT, nullptr, nullptr, dst, nullptr, m0, n0);
    } else {
        u16* dst = Q2 + (size_t)(5 + l) * HH;
        bool ic = (lang[3] == l) && (lang[2] == l);
        bool id = (lang[1] == l) && (lang[0] == l);
        if (ic && id)      ident64(dst, m0, n0);
        else if (ic)       copy64(dst, PdT, m0, n0);
        else if (id)       tcopy64(dst, Pc, m0, n0, As);
        else               gemm64(As, Bs, PdT, Pc, nullptr, nullptr, dst, nullptr, m0, n0);
    }
}

// L3.  grid (12,12,5): MT_l = Q_a * Q_b = NT(Q_a, Q_bT)
__global__ __launch_bounds__(256) void k_chainL3(
    const u16* __restrict__ Q2, const int* __restrict__ lang,
    u16* __restrict__ MT)
{
    __shared__ u16 As[3 * 64 * 32];
    __shared__ u16 Bs[3 * 64 * 32];
    const size_t HH = (size_t)Hn * Hn;
    int l = blockIdx.z;
    int m0 = blockIdx.x * 64, n0 = blockIdx.y * 64;
    const u16* Qa  = Q2 + (size_t)l * HH;
    const u16* QbT = Q2 + (size_t)(5 + l) * HH;
    u16* dst = MT + (size_t)l * HH;
    bool iA = (lang[7] == l) && (lang[6] == l) && (lang[5] == l) && (lang[4] == l);
    bool iB = (lang[3] == l) && (lang[2] == l) && (lang[1] == l) && (lang[0] == l);
    if (iA && iB)      ident64(dst, m0, n0);
    else if (iA)       tcopy64(dst, QbT, m0, n0, As);
    else if (iB)       copy64(dst, Qa, m0, n0);
    else               gemm64(As, Bs, Qa, QbT, nullptr, nullptr, dst, nullptr, m0, n0);
}

// U_l = NT(opwT, MT_l) + opb_eff GEMV.  grid 735.
__global__ __launch_bounds__(256) void k_uop(
    const u16* __restrict__ opwT, const u16* __restrict__ MT,
    const float* __restrict__ opb,
    u16* __restrict__ U5, float* __restrict__ opbeff)
{
    __shared__ u16 As[3 * 64 * 32];
    __shared__ u16 Bs[3 * 64 * 32];
    const size_t HH = (size_t)Hn * Hn;
    int bid = blockIdx.x;
    if (bid < 720) {
        int z = bid / 144, r = bid % 144;
        gemm64(As, Bs, opwT, MT + (size_t)z * HH, nullptr, nullptr,
               U5 + (size_t)z * HH, nullptr,
               (r % 12) * 64, (r / 12) * 64);
    } else {
        int b2 = bid - 720;
        int n = (b2 % 3) * 256 + threadIdx.x;
        int l = b2 / 3;
        const u16* mt = MT + ((size_t)l * Hn + n) * Hn;
        float s = 0.f;
        for (int k = 0; k < Hn; k += 8) {
            s16x8 v = *reinterpret_cast<const s16x8*>(mt + k);
            #pragma unroll
            for (int jq = 0; jq < 8; ++jq) s += opb[k + jq] * bf2f((u16)v[jq]);
        }
        opbeff[(size_t)l * Hn + n] = s;
    }
}

// W_l = NT(projw, U_l) + bias2 GEMV.  grid 735.
__global__ __launch_bounds__(256) void k_wb2(
    const u16* __restrict__ pjwb, const u16* __restrict__ U5,
    const float* __restrict__ opbeff, const float* __restrict__ projw,
    const float* __restrict__ projb,
    u16* __restrict__ W5, float* __restrict__ bias2)
{
    __shared__ u16 As[3 * 64 * 32];
    __shared__ u16 Bs[3 * 64 * 32];
    const size_t HH = (size_t)Hn * Hn;
    int bid = blockIdx.x;
    if (bid < 720) {
        int z = bid / 144, r = bid % 144;
        gemm64(As, Bs, pjwb, U5 + (size_t)z * HH, nullptr, nullptr,
               W5 + (size_t)z * HH, nullptr,
               (r % 12) * 64, (r / 12) * 64);
    } else {
        int b2 = bid - 720;
        int m = (b2 % 3) * 256 + threadIdx.x;
        int l = b2 / 3;
        const float4* w = reinterpret_cast<const float4*>(projw + (size_t)m * Hn);
        const float4* ob = reinterpret_cast<const float4*>(opbeff + (size_t)l * Hn);
        float s = 0.f;
        for (int jq = 0; jq < Hn / 4; ++jq) {
            float4 a = w[jq], b = ob[jq];
            s += a.x * b.x + a.y * b.y + a.z * b.z + a.w * b.w;
        }
        bias2[(size_t)l * Hn + m] = s + projb[m];
    }
}

// x = NT(ctx, W[lang]) + bias2[lang] + hidden -> f32 out.  64^2 tiles, grid (96,12)
__global__ __launch_bounds__(256) void k_xfused(
    const u16* __restrict__ ctx, const u16* __restrict__ W5,
    const float* __restrict__ bias2, const int* __restrict__ lang,
    const float* __restrict__ hidden, float* __restrict__ x)
{
    __shared__ u16 As[3 * 64 * 32];
    __shared__ u16 Bs[3 * 64 * 32];
    int l = lang[blockIdx.x / 12];
    gemm64(As, Bs, ctx, W5 + (size_t)l * Hn * Hn, bias2 + (size_t)l * Hn,
           hidden, nullptr, x,
           blockIdx.x * 64, blockIdx.y * 64);
}

// ---------------- flash attention + align conversion, 512 threads ----------
// blocks [0,576): attn.  blocks [576, 1476): align f32 -> bf16 (straight only;
// transposed copy handled in k_prep), 8 float4s per thread.
__global__ __launch_bounds__(512) void k_attn_conv(
    const u16* __restrict__ Q, const u16* __restrict__ K,
    const u16* __restrict__ VT, u16* __restrict__ ctx,
    const float* __restrict__ alignf, u16* __restrict__ alignb)
{
    __shared__ u16 Ks[2][64 * 64];       // [key][d], seg-xor-swizzled
    __shared__ u16 Vs[2][64 * 64];       // [d][key], seg-xor-swizzled
    __shared__ u16 Pw[8][16 * 72];       // per-wave P, 16B-aligned stride

    const int bid = blockIdx.x, tid = threadIdx.x;
    if (bid >= 576) {
        int base = (bid - 576) * 4096 + tid;     // 900*4096 = 3686400 float4s
        #pragma unroll
        for (int it = 0; it < 8; ++it) {
            int i = base + it * 512;
            float4 v = reinterpret_cast<const float4*>(alignf)[i];
            u16x4 o;
            o[0] = f2bf(v.x); o[1] = f2bf(v.y); o[2] = f2bf(v.z); o[3] = f2bf(v.w);
            reinterpret_cast<u16x4*>(alignb)[i] = o;
        }
        return;
    }

    const int q0 = (bid % 6) * 128, h = (bid / 6) % NHn, bz = bid / 72;
    const int wave = tid >> 6, lane = tid & 63;
    const int lrow = lane & 15, lquad = lane >> 4;
    const int sw = lrow & 7;

    const u16* Qp = Q + ((size_t)(bz * Sn + q0 + wave * 16 + lrow)) * Hn + h * HDn;
    const u16* Kb = K + (size_t)bz * Sn * Hn + h * HDn;
    const u16* Vb = VT + ((size_t)(bz * NHn + h) * 64) * Sn;   // row d, stride Sn

    bf16x8 qa0 = ld8(Qp + lquad * 8);
    bf16x8 qa1 = ld8(Qp + 32 + lquad * 8);

    f32x4 z4 = {0.f, 0.f, 0.f, 0.f};
    float m_r[4], l_l[4];
    f32x4 oacc[4];
    #pragma unroll
    for (int r = 0; r < 4; ++r) { m_r[r] = -1e30f; l_l[r] = 0.f; }
    #pragma unroll
    for (int jd = 0; jd < 4; ++jd) oacc[jd] = z4;

    const int krow = tid >> 3, kp = (tid & 7) ^ (krow & 7);
    const u16* kg = Kb + (size_t)krow * Hn + kp * 8;
    const u16* vg = Vb + (size_t)krow * Sn + kp * 8;

    auto stage = [&](int bs, int t0) {
        glds16(kg + (size_t)t0 * Hn, &Ks[bs][tid * 8]);
        glds16(vg + t0, &Vs[bs][tid * 8]);
    };

    auto compute = [&](int bc) {
        f32x4 sc[4];
        __builtin_amdgcn_s_setprio(1);
        #pragma unroll
        for (int j = 0; j < 4; ++j) {
            int base = (j * 16 + lrow) * 64 + ((lquad ^ sw) * 8);
            f32x4 s = __builtin_amdgcn_mfma_f32_16x16x32_bf16(qa0, ld8(&Ks[bc][base]), z4, 0, 0, 0);
            sc[j] = __builtin_amdgcn_mfma_f32_16x16x32_bf16(qa1, ld8(&Ks[bc][base ^ 32]), s, 0, 0, 0);
        }
        __builtin_amdgcn_s_setprio(0);
        float tmax[4];
        #pragma unroll
        for (int r = 0; r < 4; ++r)
            tmax[r] = fmaxf(fmaxf(sc[0][r], sc[1][r]), fmaxf(sc[2][r], sc[3][r]));
        #pragma unroll
        for (int off = 1; off < 16; off <<= 1)
            #pragma unroll
            for (int r = 0; r < 4; ++r)
                tmax[r] = fmaxf(tmax[r], __shfl_xor(tmax[r], off));
        bool grow = (tmax[0] > m_r[0] + 8.f) | (tmax[1] > m_r[1] + 8.f) |
                    (tmax[2] > m_r[2] + 8.f) | (tmax[3] > m_r[3] + 8.f);
        if (grow) {
            #pragma unroll
            for (int r = 0; r < 4; ++r) {
                float mn = fmaxf(m_r[r], tmax[r]);
                float a = __expf(m_r[r] - mn);
                m_r[r] = mn;
                l_l[r] *= a;
                #pragma unroll
                for (int jd = 0; jd < 4; ++jd) oacc[jd][r] *= a;
            }
        }
        float ps[4] = {0.f, 0.f, 0.f, 0.f};
        #pragma unroll
        for (int j = 0; j < 4; ++j)
            #pragma unroll
            for (int r = 0; r < 4; ++r) {
                float p = __expf(sc[j][r] - m_r[r]);
                ps[r] += p;
                Pw[wave][(lquad * 4 + r) * 72 + j * 16 + lrow] = f2bf(p);
            }
        #pragma unroll
        for (int r = 0; r < 4; ++r) l_l[r] += ps[r];
        bf16x8 pa0 = ld8(&Pw[wave][lrow * 72 + lquad * 8]);
        bf16x8 pa1 = ld8(&Pw[wave][lrow * 72 + 32 + lquad * 8]);
        __builtin_amdgcn_s_setprio(1);
        #pragma unroll
        for (int jd = 0; jd < 4; ++jd) {
            int vbase = (jd * 16 + lrow) * 64 + ((lquad ^ sw) * 8);
            oacc[jd] = __builtin_amdgcn_mfma_f32_16x16x32_bf16(pa0, ld8(&Vs[bc][vbase]), oacc[jd], 0, 0, 0);
            oacc[jd] = __builtin_amdgcn_mfma_f32_16x16x32_bf16(pa1, ld8(&Vs[bc][vbase ^ 32]), oacc[jd], 0, 0, 0);
        }
        __builtin_amdgcn_s_setprio(0);
    };

    stage(0, 0);
    stage(1, 64);
    for (int kt = 0; kt < 12; ++kt) {
        if (kt < 11) {
            asm volatile("s_waitcnt vmcnt(2)" ::: "memory");
        } else {
            asm volatile("s_waitcnt vmcnt(0)" ::: "memory");
        }
        __builtin_amdgcn_s_barrier();
        compute(kt & 1);
        if (kt < 10) {
            __builtin_amdgcn_s_barrier();
            stage(kt & 1, (kt + 2) * 64);
        }
    }

    #pragma unroll
    for (int off = 1; off < 16; off <<= 1)
        #pragma unroll
        for (int r = 0; r < 4; ++r)
            l_l[r] += __shfl_xor(l_l[r], off);

    float rl[4];
    #pragma unroll
    for (int r = 0; r < 4; ++r) rl[r] = 1.f / l_l[r];
    #pragma unroll
    for (int jd = 0; jd < 4; ++jd)
        #pragma unroll
        for (int r = 0; r < 4; ++r) {
            size_t row = (size_t)bz * Sn + q0 + wave * 16 + lquad * 4 + r;
            ctx[row * Hn + h * HDn + jd * 16 + lrow] = f2bf(oacc[jd][r] * rl[r]);
        }
}

// layernorm in-place on f32 d_out.  grid B*S, block 64
__global__ __launch_bounds__(64) void k_ln(
    float* x, const float* __restrict__ g, const float* __restrict__ beta)
{
    size_t row = blockIdx.x;
    float* xr = x + row * Hn;
    int lane = threadIdx.x;
    float v[12];
    float s = 0.f, ss = 0.f;
    #pragma unroll
    for (int i = 0; i < 12; ++i) {
        v[i] = xr[lane + i * 64];
        s += v[i];
        ss += v[i] * v[i];
    }
    #pragma unroll
    for (int off = 1; off < 64; off <<= 1) {
        s  += __shfl_xor(s, off);
        ss += __shfl_xor(ss, off);
    }
    float mu = s * (1.f / Hn);
    float var = ss * (1.f / Hn) - mu * mu;
    float inv = rsqrtf(var + 1e-5f);
    #pragma unroll
    for (int i = 0; i < 12; ++i) {
        int c = lane + i * 64;
        xr[c] = (v[i] - mu) * inv * g[c] + beta[c];
    }
}

// ---------------- launch ----------------
extern "C" void kernel_launch(void* const* d_in, const int* in_sizes, int n_in,
                              void* d_out, int out_size, void* d_ws, size_t ws_size,
                              hipStream_t stream)
{
    (void)in_sizes; (void)n_in; (void)out_size; (void)ws_size;

    const float* hidden  = (const float*)d_in[0];
    const int*   lang    = (const int*)d_in[1];
    const float* Wq_lang = (const float*)d_in[3];
    const float* bq_lang = (const float*)d_in[4];
    const float* Wk_lang = (const float*)d_in[5];
    const float* bk_lang = (const float*)d_in[6];
    const float* ipw     = (const float*)d_in[7];
    const float* ipb     = (const float*)d_in[8];
    const float* opw     = (const float*)d_in[9];
    const float* opb     = (const float*)d_in[10];
    const float* align   = (const float*)d_in[11];
    const float* projw   = (const float*)d_in[12];
    const float* projb   = (const float*)d_in[13];
    const float* ln_g    = (const float*)d_in[14];
    const float* ln_b    = (const float*)d_in[15];
    float* out = (float*)d_out;

    const size_t HH  = (size_t)Hn * Hn;          // 589824
    const size_t BSH = (size_t)Bn * Sn * Hn;     // 4718592 = 8*HH
    const size_t AHH = (size_t)NLn * NLn * HH;   // 25*HH

    u16* rA = (u16*)d_ws;        // hb -> ctx
    u16* rB = rA + BSH;          // Q -> N1 slots 0..7
    u16* rC = rB + BSH;          // K -> N1 slots 8..15
    u16* rD = rC + BSH;          // V^T -> N1 slots 16..19
    u16* ipwb = rD + BSH;        // wq|wk|wv bf16 (3*HH)
    u16* pjwb = ipwb + 3 * HH;   // HH
    u16* opwT = pjwb + HH;       // HH
    u16* alignb = opwT + HH;     // 25*HH; pre-attn: weight scratch S[0..20)
                                 // post-L2: MT[0..5) U[5..10) W[10..15)
    u16* alignbT = alignb + AHH; // 25*HH transposed aligns (written by k_prep);
                                 // post-L1: Q2[0..10)
    float* beff   = (float*)(alignbT + AHH);  // 2*5*768 f32
    float* opbeff = beff + 10 * Hn;           // 5*768 f32
    float* bias2  = opbeff + 5 * Hn;          // 5*768 f32

    u16* S = alignb;             // scratch: WqT[0..5) WkT[5..10) Weffq[10..15) Weffk[15..20)
    u16* N1 = rB;                // 20 node matrices (rB..rD contiguous)
    u16* Q2 = alignbT;           // 10 node matrices (alignbT dead after L1)
    u16* MT = alignb;            // 5 (alignb dead after L1)
    u16* U5 = alignb + 5 * HH;   // 5
    u16* W5 = alignb + 10 * HH;  // 5

    // fused prep: conversions + 36 transposes (Wq/Wk/opw/align^T) + bias folds
    k_prep<<<(unsigned)(PREP_NF2B + PREP_NTR + 30), 256, 0, stream>>>(
        hidden, rA, ipw, ipwb, projw, pjwb,
        Wq_lang, Wk_lang, opw, S, opwT, align, alignbT,
        ipb, bq_lang, bk_lang, beff);

    // Weffq/Weffk (one launch, 64^2 tiles) -> S[10..20)
    k_comb10<<<dim3(12, 12, 10), 256, 0, stream>>>(ipwb, S);

    // fused QKV: Q*(1/8) -> rB, K -> rC, V^T -> rD.  256-row tiles, 1 generation.
    k_gemm_qkv<<<dim3(24, 6, 3), 256, 0, stream>>>(
        rA, S + 10 * HH, S + 15 * HH, ipwb + 2 * HH, beff, ipb, lang, rB, rC, rD);

    // attention (ctx -> rA) + straight align conversion (S scratch now dead)
    k_attn_conv<<<1476, 512, 0, stream>>>(rB, rC, rD, rA, align, alignb);

    // chain tree: 3 launches replace 8 sequential chain steps
    k_chainL1<<<dim3(12, 12, 20), 256, 0, stream>>>(alignb, alignbT, lang, N1);
    k_chainL2<<<dim3(12, 12, 10), 256, 0, stream>>>(N1, lang, Q2);
    k_chainL3<<<dim3(12, 12, 5), 256, 0, stream>>>(Q2, lang, MT);

    // U_l = opw^T . M_l  (+ opb_eff GEMV)
    k_uop<<<735, 256, 0, stream>>>(opwT, MT, opb, U5, opbeff);
    // W_l = projw . U_l  (+ bias2 GEMV)
    k_wb2<<<735, 256, 0, stream>>>(pjwb, U5, opbeff, projw, projb, W5, bias2);

    // x = ctx . W[lang]^T + bias2 + hidden -> d_out (f32).  64^2 tiles.
    k_xfused<<<dim3(96, 12), 256, 0, stream>>>(rA, W5, bias2, lang, hidden, out);
    // layernorm in place
    k_ln<<<(unsigned)(Bn * Sn), 64, 0, stream>>>(out, ln_g, ln_b);
}

// Round 13
// 451.384 us; speedup vs baseline: 1.6084x; 1.0012x over previous
//
#include <hip/hip_runtime.h>

// ---------------- constants ----------------
#define Bn 8
#define Sn 768
#define Hn 768
#define NHn 12
#define HDn 64
#define NLn 5

typedef unsigned short u16;
typedef __bf16 bf16x8 __attribute__((ext_vector_type(8)));
typedef short s16x8 __attribute__((ext_vector_type(8)));
typedef float f32x4 __attribute__((ext_vector_type(4)));
typedef unsigned short u16x4 __attribute__((ext_vector_type(4)));

static __device__ __forceinline__ float bf2f(u16 v) {
    return __uint_as_float(((unsigned)v) << 16);
}
static __device__ __forceinline__ u16 f2bf(float f) {
    unsigned u = __float_as_uint(f);
    unsigned r = u + 0x7fffu + ((u >> 16) & 1u);
    return (u16)(r >> 16);
}
static __device__ __forceinline__ bf16x8 ld8(const u16* p) {
    return *reinterpret_cast<const bf16x8*>(p);
}
static __device__ __forceinline__ void glds16(const u16* g, u16* l) {
    __builtin_amdgcn_global_load_lds(
        (const __attribute__((address_space(1))) void*)g,
        (__attribute__((address_space(3))) void*)l, 16, 0, 0);
}

// ---------------- fused prep: weight conversions + transposes ----------------
// f2b: ipw, projw (8 f32/thread).  transposes: Wq/Wk -> S, opw -> opwT,
// align mats -> alignbT.  (hidden f2b + biasqk moved to k_comb_aux.)
#define PREP_NF2B 1152
#define PREP_NTR  (36 * 144)
__global__ __launch_bounds__(256) void k_prep(
    const float* __restrict__ ipw, u16* __restrict__ ipwb,
    const float* __restrict__ projw, u16* __restrict__ pjwb,
    const float* __restrict__ Wq, const float* __restrict__ Wk,
    const float* __restrict__ opw, u16* __restrict__ S, u16* __restrict__ opwT,
    const float* __restrict__ alignf, u16* __restrict__ alignbT)
{
    __shared__ float T[64][65];
    const size_t HH = (size_t)Hn * Hn;
    const int bid = blockIdx.x, tid = threadIdx.x;
    if (bid < PREP_NF2B) {
        const int n1 = (int)(3 * HH / 8), n2 = (int)(HH / 8);
        int i = bid * 256 + tid;
        const float* s; u16* d; int off;
        if (i < n1)           { s = ipw;   d = ipwb; off = i; }
        else if (i < n1 + n2) { s = projw; d = pjwb; off = i - n1; }
        else return;
        float4 a = reinterpret_cast<const float4*>(s)[off * 2];
        float4 b = reinterpret_cast<const float4*>(s)[off * 2 + 1];
        s16x8 o;
        o[0] = (short)f2bf(a.x); o[1] = (short)f2bf(a.y);
        o[2] = (short)f2bf(a.z); o[3] = (short)f2bf(a.w);
        o[4] = (short)f2bf(b.x); o[5] = (short)f2bf(b.y);
        o[6] = (short)f2bf(b.z); o[7] = (short)f2bf(b.w);
        reinterpret_cast<s16x8*>(d)[off] = o;
    } else if (bid < PREP_NF2B + PREP_NTR) {
        int b2 = bid - PREP_NF2B;
        int z = b2 / 144, r = b2 % 144;
        int bx = r % 12, by = r / 12;
        const float* src;
        u16* dst;
        if (z < 5)       { src = Wq + (size_t)z * HH;        dst = S + (size_t)z * HH; }
        else if (z < 10) { src = Wk + (size_t)(z - 5) * HH;  dst = S + (size_t)z * HH; }
        else if (z == 10){ src = opw;                         dst = opwT; }
        else             { src = alignf + (size_t)(z - 11) * HH;
                           dst = alignbT + (size_t)(z - 11) * HH; }
        int i0 = bx * 64, o0 = by * 64;
        // stage 64x64 f32 tile: float4 loads
        #pragma unroll
        for (int it = 0; it < 4; ++it) {
            int s = tid + 256 * it;
            int row = s >> 4, seg = s & 15;
            float4 v = *reinterpret_cast<const float4*>(
                src + (size_t)(o0 + row) * Hn + i0 + seg * 4);
            T[row][seg * 4 + 0] = v.x;
            T[row][seg * 4 + 1] = v.y;
            T[row][seg * 4 + 2] = v.z;
            T[row][seg * 4 + 3] = v.w;
        }
        __syncthreads();
        // write transposed: s16x8 stores
        #pragma unroll
        for (int it = 0; it < 2; ++it) {
            int s = tid + 256 * it;
            int ri = s >> 3, c8 = s & 7;
            s16x8 o;
            #pragma unroll
            for (int e = 0; e < 8; ++e)
                o[e] = (short)f2bf(T[c8 * 8 + e][ri]);
            *reinterpret_cast<s16x8*>(dst + (size_t)(i0 + ri) * Hn + o0 + c8 * 8) = o;
        }
    }
}

// ---- TM x 128 triple-buffered counted-vmcnt NT GEMM core (256 thr) ----
template<int TM>
__device__ __forceinline__ void gemm_core(
    const u16* __restrict__ A, int lda,
    const u16* __restrict__ Bw, int ldb,
    const float* __restrict__ bias,
    const float* __restrict__ addres,
    u16* __restrict__ outH, float* __restrict__ outF,
    u16* __restrict__ outVT, int ldc,
    int m0, int n0, float scale)
{
    constexpr int MI = TM / 32;
    constexpr int AIT = TM / 64;
    __shared__ u16 As[3 * TM * 32];
    __shared__ u16 Bs[3 * 128 * 32];
    const int tid = threadIdx.x;
    const int lane = tid & 63, wave = tid >> 6;
    const int lrow = lane & 15, lquad = lane >> 4;
    const int wm = (wave >> 1) * (TM / 2), wn = (wave & 1) * 64;

    const u16* gA = A + (size_t)(m0 + (tid >> 2)) * lda + (tid & 3) * 8;
    const u16* gB = Bw + (size_t)(n0 + (tid >> 2)) * ldb + (tid & 3) * 8;

    f32x4 z = {0.f, 0.f, 0.f, 0.f};
    f32x4 acc[MI][4];
    #pragma unroll
    for (int i = 0; i < MI; ++i)
        #pragma unroll
        for (int j = 0; j < 4; ++j) acc[i][j] = z;

    auto stage = [&](int bs, int k0) {
        #pragma unroll
        for (int it = 0; it < AIT; ++it)
            glds16(gA + (size_t)(it * 64) * lda + k0, &As[bs * TM * 32 + (tid + 256 * it) * 8]);
        #pragma unroll
        for (int it = 0; it < 2; ++it)
            glds16(gB + (size_t)(it * 64) * ldb + k0, &Bs[bs * 128 * 32 + (tid + 256 * it) * 8]);
    };
    auto compute = [&](int bc) {
        const u16* Ab = &As[bc * TM * 32];
        const u16* Bb = &Bs[bc * 128 * 32];
        bf16x8 af[MI], bf_[4];
        #pragma unroll
        for (int i = 0; i < MI; ++i)
            af[i] = ld8(&Ab[(wm + i * 16 + lrow) * 32 + lquad * 8]);
        #pragma unroll
        for (int j = 0; j < 4; ++j)
            bf_[j] = ld8(&Bb[(wn + j * 16 + lrow) * 32 + lquad * 8]);
        #pragma unroll
        for (int i = 0; i < MI; ++i)
            #pragma unroll
            for (int j = 0; j < 4; ++j)
                acc[i][j] = __builtin_amdgcn_mfma_f32_16x16x32_bf16(af[i], bf_[j], acc[i][j], 0, 0, 0);
    };

    stage(0, 0);
    stage(1, 32);
    int bc = 0, bs = 2;
    for (int kt = 0; kt < 24; ++kt) {
        if (kt < 23) {
            if constexpr (TM == 256) {
                asm volatile("s_waitcnt vmcnt(6)" ::: "memory");
            } else {
                asm volatile("s_waitcnt vmcnt(4)" ::: "memory");
            }
        } else {
            asm volatile("s_waitcnt vmcnt(0)" ::: "memory");
        }
        __builtin_amdgcn_s_barrier();
        if (kt < 22) {
            stage(bs, (kt + 2) * 32);
            bs = (bs == 2) ? 0 : bs + 1;
        }
        compute(bc);
        bc = (bc == 2) ? 0 : bc + 1;
    }

    #pragma unroll
    for (int i = 0; i < MI; ++i) {
        #pragma unroll
        for (int j = 0; j < 4; ++j) {
            int col = n0 + wn + j * 16 + lrow;
            float bv = bias ? bias[col] : 0.f;
            if (outVT) {
                int row0 = m0 + wm + i * 16 + lquad * 4;
                int bb = row0 / Sn, s = row0 % Sn;
                int hh = col >> 6, dd = col & 63;
                u16x4 o;
                #pragma unroll
                for (int r = 0; r < 4; ++r) o[r] = f2bf((acc[i][j][r] + bv) * scale);
                *reinterpret_cast<u16x4*>(
                    outVT + (((size_t)bb * NHn + hh) * 64 + dd) * Sn + s) = o;
            } else {
                #pragma unroll
                for (int r = 0; r < 4; ++r) {
                    int row = m0 + wm + i * 16 + lquad * 4 + r;
                    float v = (acc[i][j][r] + bv) * scale;
                    if (addres) v += addres[(size_t)row * ldc + col];
                    if (outF) outF[(size_t)row * ldc + col] = v;
                    else      outH[(size_t)row * ldc + col] = f2bf(v);
                }
            }
        }
    }
}

// -- 64x64 triple-buffered counted-vmcnt NT GEMM core (256 thr), LDS passed in --
__device__ __forceinline__ void gemm64(
    u16* As, u16* Bs,
    const u16* __restrict__ A, const u16* __restrict__ Bw,
    const float* __restrict__ bias, const float* __restrict__ addres,
    u16* __restrict__ outH, float* __restrict__ outF,
    int m0, int n0)
{
    const int tid = threadIdx.x;
    const int lane = tid & 63, wave = tid >> 6;
    const int lrow = lane & 15, lquad = lane >> 4;
    const int wm = (wave >> 1) * 32, wn = (wave & 1) * 32;

    const u16* gA = A + (size_t)(m0 + (tid >> 2)) * Hn + (tid & 3) * 8;
    const u16* gB = Bw + (size_t)(n0 + (tid >> 2)) * Hn + (tid & 3) * 8;

    f32x4 z = {0.f, 0.f, 0.f, 0.f};
    f32x4 acc[2][2];
    #pragma unroll
    for (int i = 0; i < 2; ++i)
        #pragma unroll
        for (int j = 0; j < 2; ++j) acc[i][j] = z;

    auto stage = [&](int bs, int k0) {
        glds16(gA + k0, &As[bs * 64 * 32 + tid * 8]);
        glds16(gB + k0, &Bs[bs * 64 * 32 + tid * 8]);
    };
    auto compute = [&](int bc) {
        const u16* Ab = &As[bc * 64 * 32];
        const u16* Bb = &Bs[bc * 64 * 32];
        bf16x8 af[2], bf_[2];
        #pragma unroll
        for (int i = 0; i < 2; ++i)
            af[i] = ld8(&Ab[(wm + i * 16 + lrow) * 32 + lquad * 8]);
        #pragma unroll
        for (int j = 0; j < 2; ++j)
            bf_[j] = ld8(&Bb[(wn + j * 16 + lrow) * 32 + lquad * 8]);
        #pragma unroll
        for (int i = 0; i < 2; ++i)
            #pragma unroll
            for (int j = 0; j < 2; ++j)
                acc[i][j] = __builtin_amdgcn_mfma_f32_16x16x32_bf16(af[i], bf_[j], acc[i][j], 0, 0, 0);
    };

    stage(0, 0);
    stage(1, 32);
    int bc = 0, bs = 2;
    for (int kt = 0; kt < 24; ++kt) {
        if (kt < 23) {
            asm volatile("s_waitcnt vmcnt(2)" ::: "memory");
        } else {
            asm volatile("s_waitcnt vmcnt(0)" ::: "memory");
        }
        __builtin_amdgcn_s_barrier();
        if (kt < 22) {
            stage(bs, (kt + 2) * 32);
            bs = (bs == 2) ? 0 : bs + 1;
        }
        compute(bc);
        bc = (bc == 2) ? 0 : bc + 1;
    }

    #pragma unroll
    for (int i = 0; i < 2; ++i)
        #pragma unroll
        for (int j = 0; j < 2; ++j) {
            int col = n0 + wn + j * 16 + lrow;
            float bv = bias ? bias[col] : 0.f;
            #pragma unroll
            for (int r = 0; r < 4; ++r) {
                int row_ = m0 + wm + i * 16 + lquad * 4 + r;
                float v = acc[i][j][r] + bv;
                if (addres) v += addres[(size_t)row_ * Hn + col];
                if (outF) outF[(size_t)row_ * Hn + col] = v;
                else      outH[(size_t)row_ * Hn + col] = f2bf(v);
            }
        }
}

// ---- 64x64 tile helpers (256 thr): identity write, copy, transposing copy ----
static __device__ __forceinline__ void ident64(u16* dst, int m0, int n0)
{
    const int tid = threadIdx.x;
    #pragma unroll
    for (int it = 0; it < 2; ++it) {
        int s = tid + 256 * it;
        int ri = s >> 3, c8 = s & 7;
        s16x8 v;
        #pragma unroll
        for (int e = 0; e < 8; ++e)
            v[e] = (short)((m0 + ri == n0 + c8 * 8 + e) ? 0x3F80 : 0);
        *reinterpret_cast<s16x8*>(dst + (size_t)(m0 + ri) * Hn + n0 + c8 * 8) = v;
    }
}
static __device__ __forceinline__ void copy64(u16* dst, const u16* src, int m0, int n0)
{
    const int tid = threadIdx.x;
    #pragma unroll
    for (int it = 0; it < 2; ++it) {
        int s = tid + 256 * it;
        int row = s >> 3, seg = s & 7;
        *reinterpret_cast<s16x8*>(dst + (size_t)(m0 + row) * Hn + n0 + seg * 8) =
            *reinterpret_cast<const s16x8*>(src + (size_t)(m0 + row) * Hn + n0 + seg * 8);
    }
}
// dst = src^T: dst tile (m0,n0) <- src tile (n0,m0) transposed.  lds >= 64*72 u16
static __device__ __forceinline__ void tcopy64(u16* dst, const u16* src, int m0, int n0, u16* lds)
{
    u16 (*T)[72] = reinterpret_cast<u16(*)[72]>(lds);
    const int tid = threadIdx.x;
    #pragma unroll
    for (int it = 0; it < 2; ++it) {
        int s = tid + 256 * it;
        int rr = s >> 3, c8 = s & 7;
        s16x8 v = *reinterpret_cast<const s16x8*>(
            src + (size_t)(n0 + rr) * Hn + m0 + c8 * 8);
        #pragma unroll
        for (int e = 0; e < 8; ++e) T[c8 * 8 + e][rr] = (u16)v[e];
    }
    __syncthreads();
    #pragma unroll
    for (int it = 0; it < 2; ++it) {
        int s = tid + 256 * it;
        int ri = s >> 3, c8 = s & 7;
        *reinterpret_cast<s16x8*>(dst + (size_t)(m0 + ri) * Hn + n0 + c8 * 8) =
            *reinterpret_cast<const s16x8*>(&T[ri][c8 * 8]);
    }
}

// ---------------- GEMM wrapper kernels ----------------

// comb + aux backfill.  flat grid 3774 blocks:
//   [0,1440): Weffq/Weffk 64^2 tiles (z = bid/144: z<5 Weffq_z, z>=5 Weffk)
//   [1440, 1440+2304): hidden f32 -> bf16 (8 f32/thread)
//   [3744, 3774): combined QK bias GEMVs
__global__ __launch_bounds__(256) void k_comb_aux(
    const u16* __restrict__ ipwb, u16* __restrict__ S,
    const float* __restrict__ hidden, u16* __restrict__ hb,
    const float* __restrict__ ipw, const float* __restrict__ ipb,
    const float* __restrict__ bq_lang, const float* __restrict__ bk_lang,
    float* __restrict__ beff)
{
    __shared__ u16 As[3 * 64 * 32];
    __shared__ u16 Bs[3 * 64 * 32];
    const size_t HH = (size_t)Hn * Hn;
    const int bid = blockIdx.x, tid = threadIdx.x;
    if (bid < 1440) {
        int z = bid / 144, r = bid % 144;
        const u16* Aop = ipwb + (z < 5 ? 0 : HH);
        gemm64(As, Bs, Aop, S + (size_t)z * HH, nullptr, nullptr,
               S + (size_t)(10 + z) * HH, nullptr,
               (r % 12) * 64, (r / 12) * 64);
    } else if (bid < 3744) {
        int i = (bid - 1440) * 256 + tid;          // 589824 threads
        float4 a = reinterpret_cast<const float4*>(hidden)[i * 2];
        float4 b = reinterpret_cast<const float4*>(hidden)[i * 2 + 1];
        s16x8 o;
        o[0] = (short)f2bf(a.x); o[1] = (short)f2bf(a.y);
        o[2] = (short)f2bf(a.z); o[3] = (short)f2bf(a.w);
        o[4] = (short)f2bf(b.x); o[5] = (short)f2bf(b.y);
        o[6] = (short)f2bf(b.z); o[7] = (short)f2bf(b.w);
        reinterpret_cast<s16x8*>(hb)[i] = o;
    } else {
        int b3 = bid - 3744;                       // 0..29
        int ox = b3 % 3, y = b3 / 3;
        int o = ox * 256 + tid;
        int which = y / 5, l = y % 5;
        const float4* w = reinterpret_cast<const float4*>(ipw + (size_t)which * HH + (size_t)o * Hn);
        const float4* bv = reinterpret_cast<const float4*>(((which ? bk_lang : bq_lang) + (size_t)l * Hn));
        float s = 0.f;
        for (int j = 0; j < Hn / 4; ++j) {
            float4 a = w[j], b = bv[j];
            s += a.x * b.x + a.y * b.y + a.z * b.z + a.w * b.w;
        }
        s += ipb[which * Hn + o];
        beff[(size_t)(which * 5 + l) * Hn + o] = s;
    }
}

// fused QKV projection, 256-row tiles (432 blocks -> ONE generation at 2/CU).
// grid (24, 6, 3): z=0 Q, z=1 K, z=2 V(T layout).
__global__ __launch_bounds__(256, 2) void k_gemm_qkv(
    const u16* __restrict__ A,
    const u16* __restrict__ Sq, const u16* __restrict__ Sk,
    const u16* __restrict__ Wv,
    const float* __restrict__ beff, const float* __restrict__ ipb,
    const int* __restrict__ lang,
    u16* __restrict__ outQ, u16* __restrict__ outK, u16* __restrict__ outVT)
{
    const size_t HH = (size_t)Hn * Hn;
    int z = blockIdx.z;
    int m0 = blockIdx.x * 256, n0 = blockIdx.y * 128;
    int l = lang[blockIdx.x / 3];
    if (z == 0) {
        gemm_core<256>(A, Hn, Sq + (size_t)l * HH, Hn, beff + (size_t)l * Hn,
                       nullptr, outQ, nullptr, nullptr, Hn, m0, n0, 0.125f);
    } else if (z == 1) {
        gemm_core<256>(A, Hn, Sk + (size_t)l * HH, Hn, beff + (size_t)(5 + l) * Hn,
                       nullptr, outK, nullptr, nullptr, Hn, m0, n0, 1.f);
    } else {
        gemm_core<256>(A, Hn, Wv, Hn, ipb + 2 * Hn,
                       nullptr, nullptr, nullptr, outVT, Hn, m0, n0, 1.f);
    }
}

// ---------------- chain tree ----------------
// MT_l = S7^T S6^T ... S0^T;  S_j = (lang[j]==l) ? I : align[l, lang[j]].

// L1.  grid (12,12,20)
__global__ __launch_bounds__(256) void k_chainL1(
    const u16* __restrict__ alignb, const u16* __restrict__ alignbT,
    const int* __restrict__ lang, u16* __restrict__ N1)
{
    __shared__ u16 As[3 * 64 * 32];
    __shared__ u16 Bs[3 * 64 * 32];
    const size_t HH = (size_t)Hn * Hn;
    int idx = blockIdx.z, l = idx >> 2, node = idx & 3;
    int ja = 7 - node * 2, jb = 6 - node * 2;
    bool tr = node & 1;
    int la = lang[ja], lb = lang[jb];
    bool sa = (la == l), sb = (lb == l);
    u16* dst = N1 + (size_t)idx * HH;
    int m0 = blockIdx.x * 64, n0 = blockIdx.y * 64;
    if (sa && sb) {
        ident64(dst, m0, n0);
    } else if (sa) {
        copy64(dst, (tr ? alignb : alignbT) + ((size_t)l * NLn + lb) * HH, m0, n0);
    } else if (sb) {
        copy64(dst, (tr ? alignb : alignbT) + ((size_t)l * NLn + la) * HH, m0, n0);
    } else if (!tr) {  // straight: Fa^T * Fb^T = NT(FaT, Fb)
        gemm64(As, Bs, alignbT + ((size_t)l * NLn + la) * HH,
               alignb + ((size_t)l * NLn + lb) * HH,
               nullptr, nullptr, dst, nullptr, m0, n0);
    } else {           // transposed: Fb * Fa = NT(Fb, FaT)
        gemm64(As, Bs, alignb + ((size_t)l * NLn + lb) * HH,
               alignbT + ((size_t)l * NLn + la) * HH,
               nullptr, nullptr, dst, nullptr, m0, n0);
    }
}

// L2.  grid (12,12,10): z = l*2 + q.  Q_a -> Q2[l], Q_bT -> Q2[5+l]
__global__ __launch_bounds__(256) void k_chainL2(
    const u16* __restrict__ N1, const int* __restrict__ lang,
    u16* __restrict__ Q2)
{
    __shared__ u16 As[3 * 64 * 32];
    __shared__ u16 Bs[3 * 64 * 32];
    const size_t HH = (size_t)Hn * Hn;
    int idx = blockIdx.z, l = idx >> 1, q = idx & 1;
    int m0 = blockIdx.x * 64, n0 = blockIdx.y * 64;
    const u16* Pa  = N1 + (size_t)(l * 4 + 0) * HH;
    const u16* PbT = N1 + (size_t)(l * 4 + 1) * HH;
    const u16* Pc  = N1 + (size_t)(l * 4 + 2) * HH;
    const u16* PdT = N1 + (size_t)(l * 4 + 3) * HH;
    if (q == 0) {
        u16* dst = Q2 + (size_t)l * HH;
        bool ia = (lang[7] == l) && (lang[6] == l);
        bool ib = (lang[5] == l) && (lang[4] == l);
        if (ia && ib)      ident64(dst, m0, n0);
        else if (ia)       tcopy64(dst, PbT, m0, n0, As);
        else if (ib)       copy64(dst, Pa, m0, n0);
        else               gemm64(As, Bs, Pa, PbT, nullptr, nullptr, dst, nullptr, m0, n0);
    } else {
        u16* dst = Q2 + (size_t)(5 + l) * HH;
        bool ic = (lang[3] == l) && (lang[2] == l);
        bool id = (lang[1] == l) && (lang[0] == l);
        if (ic && id)      ident64(dst, m0, n0);
        else if (ic)       copy64(dst, PdT, m0, n0);
        else if (id)       tcopy64(dst, Pc, m0, n0, As);
        else               gemm64(As, Bs, PdT, Pc, nullptr, nullptr, dst, nullptr, m0, n0);
    }
}

// L3.  grid (12,12,5): MT_l = Q_a * Q_b = NT(Q_a, Q_bT)
__global__ __launch_bounds__(256) void k_chainL3(
    const u16* __restrict__ Q2, const int* __restrict__ lang,
    u16* __restrict__ MT)
{
    __shared__ u16 As[3 * 64 * 32];
    __shared__ u16 Bs[3 * 64 * 32];
    const size_t HH = (size_t)Hn * Hn;
    int l = blockIdx.z;
    int m0 = blockIdx.x * 64, n0 = blockIdx.y * 64;
    const u16* Qa  = Q2 + (size_t)l * HH;
    const u16* QbT = Q2 + (size_t)(5 + l) * HH;
    u16* dst = MT + (size_t)l * HH;
    bool iA = (lang[7] == l) && (lang[6] == l) && (lang[5] == l) && (lang[4] == l);
    bool iB = (lang[3] == l) && (lang[2] == l) && (lang[1] == l) && (lang[0] == l);
    if (iA && iB)      ident64(dst, m0, n0);
    else if (iA)       tcopy64(dst, QbT, m0, n0, As);
    else if (iB)       copy64(dst, Qa, m0, n0);
    else               gemm64(As, Bs, Qa, QbT, nullptr, nullptr, dst, nullptr, m0, n0);
}

// U_l = NT(opwT, MT_l) + opb_eff GEMV.  grid 735.
__global__ __launch_bounds__(256) void k_uop(
    const u16* __restrict__ opwT, const u16* __restrict__ MT,
    const float* __restrict__ opb,
    u16* __restrict__ U5, float* __restrict__ opbeff)
{
    __shared__ u16 As[3 * 64 * 32];
    __shared__ u16 Bs[3 * 64 * 32];
    const size_t HH = (size_t)Hn * Hn;
    int bid = blockIdx.x;
    if (bid < 720) {
        int z = bid / 144, r = bid % 144;
        gemm64(As, Bs, opwT, MT + (size_t)z * HH, nullptr, nullptr,
               U5 + (size_t)z * HH, nullptr,
               (r % 12) * 64, (r / 12) * 64);
    } else {
        int b2 = bid - 720;
        int n = (b2 % 3) * 256 + threadIdx.x;
        int l = b2 / 3;
        const u16* mt = MT + ((size_t)l * Hn + n) * Hn;
        float s = 0.f;
        for (int k = 0; k < Hn; k += 8) {
            s16x8 v = *reinterpret_cast<const s16x8*>(mt + k);
            #pragma unroll
            for (int jq = 0; jq < 8; ++jq) s += opb[k + jq] * bf2f((u16)v[jq]);
        }
        opbeff[(size_t)l * Hn + n] = s;
    }
}

// W_l = NT(projw, U_l) + bias2 GEMV.  grid 735.
__global__ __launch_bounds__(256) void k_wb2(
    const u16* __restrict__ pjwb, const u16* __restrict__ U5,
    const float* __restrict__ opbeff, const float* __restrict__ projw,
    const float* __restrict__ projb,
    u16* __restrict__ W5, float* __restrict__ bias2)
{
    __shared__ u16 As[3 * 64 * 32];
    __shared__ u16 Bs[3 * 64 * 32];
    const size_t HH = (size_t)Hn * Hn;
    int bid = blockIdx.x;
    if (bid < 720) {
        int z = bid / 144, r = bid % 144;
        gemm64(As, Bs, pjwb, U5 + (size_t)z * HH, nullptr, nullptr,
               W5 + (size_t)z * HH, nullptr,
               (r % 12) * 64, (r / 12) * 64);
    } else {
        int b2 = bid - 720;
        int m = (b2 % 3) * 256 + threadIdx.x;
        int l = b2 / 3;
        const float4* w = reinterpret_cast<const float4*>(projw + (size_t)m * Hn);
        const float4* ob = reinterpret_cast<const float4*>(opbeff + (size_t)l * Hn);
        float s = 0.f;
        for (int jq = 0; jq < Hn / 4; ++jq) {
            float4 a = w[jq], b = ob[jq];
            s += a.x * b.x + a.y * b.y + a.z * b.z + a.w * b.w;
        }
        bias2[(size_t)l * Hn + m] = s + projb[m];
    }
}

// x = NT(ctx, W[lang]) + bias2[lang] + hidden -> f32 out.  64^2 tiles, grid (96,12)
__global__ __launch_bounds__(256) void k_xfused(
    const u16* __restrict__ ctx, const u16* __restrict__ W5,
    const float* __restrict__ bias2, const int* __restrict__ lang,
    const float* __restrict__ hidden, float* __restrict__ x)
{
    __shared__ u16 As[3 * 64 * 32];
    __shared__ u16 Bs[3 * 64 * 32];
    int l = lang[blockIdx.x / 12];
    gemm64(As, Bs, ctx, W5 + (size_t)l * Hn * Hn, bias2 + (size_t)l * Hn,
           hidden, nullptr, x,
           blockIdx.x * 64, blockIdx.y * 64);
}

// ---------------- flash attention + align conversion, 512 threads ----------
// blocks [0,576): attn.  blocks [576, 1476): align f32 -> bf16 (straight only;
// transposed copy handled in k_prep), 8 float4s per thread.
__global__ __launch_bounds__(512) void k_attn_conv(
    const u16* __restrict__ Q, const u16* __restrict__ K,
    const u16* __restrict__ VT, u16* __restrict__ ctx,
    const float* __restrict__ alignf, u16* __restrict__ alignb)
{
    __shared__ u16 Ks[2][64 * 64];       // [key][d], seg-xor-swizzled
    __shared__ u16 Vs[2][64 * 64];       // [d][key], seg-xor-swizzled
    __shared__ u16 Pw[8][16 * 72];       // per-wave P, 16B-aligned stride

    const int bid = blockIdx.x, tid = threadIdx.x;
    if (bid >= 576) {
        int base = (bid - 576) * 4096 + tid;     // 900*4096 = 3686400 float4s
        #pragma unroll
        for (int it = 0; it < 8; ++it) {
            int i = base + it * 512;
            float4 v = reinterpret_cast<const float4*>(alignf)[i];
            u16x4 o;
            o[0] = f2bf(v.x); o[1] = f2bf(v.y); o[2] = f2bf(v.z); o[3] = f2bf(v.w);
            reinterpret_cast<u16x4*>(alignb)[i] = o;
        }
        return;
    }

    const int q0 = (bid % 6) * 128, h = (bid / 6) % NHn, bz = bid / 72;
    const int wave = tid >> 6, lane = tid & 63;
    const int lrow = lane & 15, lquad = lane >> 4;
    const int sw = lrow & 7;

    const u16* Qp = Q + ((size_t)(bz * Sn + q0 + wave * 16 + lrow)) * Hn + h * HDn;
    const u16* Kb = K + (size_t)bz * Sn * Hn + h * HDn;
    const u16* Vb = VT + ((size_t)(bz * NHn + h) * 64) * Sn;   // row d, stride Sn

    bf16x8 qa0 = ld8(Qp + lquad * 8);
    bf16x8 qa1 = ld8(Qp + 32 + lquad * 8);

    f32x4 z4 = {0.f, 0.f, 0.f, 0.f};
    float m_r[4], l_l[4];
    f32x4 oacc[4];
    #pragma unroll
    for (int r = 0; r < 4; ++r) { m_r[r] = -1e30f; l_l[r] = 0.f; }
    #pragma unroll
    for (int jd = 0; jd < 4; ++jd) oacc[jd] = z4;

    const int krow = tid >> 3, kp = (tid & 7) ^ (krow & 7);
    const u16* kg = Kb + (size_t)krow * Hn + kp * 8;
    const u16* vg = Vb + (size_t)krow * Sn + kp * 8;

    auto stage = [&](int bs, int t0) {
        glds16(kg + (size_t)t0 * Hn, &Ks[bs][tid * 8]);
        glds16(vg + t0, &Vs[bs][tid * 8]);
    };

    auto compute = [&](int bc) {
        f32x4 sc[4];
        __builtin_amdgcn_s_setprio(1);
        #pragma unroll
        for (int j = 0; j < 4; ++j) {
            int base = (j * 16 + lrow) * 64 + ((lquad ^ sw) * 8);
            f32x4 s = __builtin_amdgcn_mfma_f32_16x16x32_bf16(qa0, ld8(&Ks[bc][base]), z4, 0, 0, 0);
            sc[j] = __builtin_amdgcn_mfma_f32_16x16x32_bf16(qa1, ld8(&Ks[bc][base ^ 32]), s, 0, 0, 0);
        }
        __builtin_amdgcn_s_setprio(0);
        float tmax[4];
        #pragma unroll
        for (int r = 0; r < 4; ++r)
            tmax[r] = fmaxf(fmaxf(sc[0][r], sc[1][r]), fmaxf(sc[2][r], sc[3][r]));
        #pragma unroll
        for (int off = 1; off < 16; off <<= 1)
            #pragma unroll
            for (int r = 0; r < 4; ++r)
                tmax[r] = fmaxf(tmax[r], __shfl_xor(tmax[r], off));
        bool grow = (tmax[0] > m_r[0] + 8.f) | (tmax[1] > m_r[1] + 8.f) |
                    (tmax[2] > m_r[2] + 8.f) | (tmax[3] > m_r[3] + 8.f);
        if (grow) {
            #pragma unroll
            for (int r = 0; r < 4; ++r) {
                float mn = fmaxf(m_r[r], tmax[r]);
                float a = __expf(m_r[r] - mn);
                m_r[r] = mn;
                l_l[r] *= a;
                #pragma unroll
                for (int jd = 0; jd < 4; ++jd) oacc[jd][r] *= a;
            }
        }
        float ps[4] = {0.f, 0.f, 0.f, 0.f};
        #pragma unroll
        for (int j = 0; j < 4; ++j)
            #pragma unroll
            for (int r = 0; r < 4; ++r) {
                float p = __expf(sc[j][r] - m_r[r]);
                ps[r] += p;
                Pw[wave][(lquad * 4 + r) * 72 + j * 16 + lrow] = f2bf(p);
            }
        #pragma unroll
        for (int r = 0; r < 4; ++r) l_l[r] += ps[r];
        bf16x8 pa0 = ld8(&Pw[wave][lrow * 72 + lquad * 8]);
        bf16x8 pa1 = ld8(&Pw[wave][lrow * 72 + 32 + lquad * 8]);
        __builtin_amdgcn_s_setprio(1);
        #pragma unroll
        for (int jd = 0; jd < 4; ++jd) {
            int vbase = (jd * 16 + lrow) * 64 + ((lquad ^ sw) * 8);
            oacc[jd] = __builtin_amdgcn_mfma_f32_16x16x32_bf16(pa0, ld8(&Vs[bc][vbase]), oacc[jd], 0, 0, 0);
            oacc[jd] = __builtin_amdgcn_mfma_f32_16x16x32_bf16(pa1, ld8(&Vs[bc][vbase ^ 32]), oacc[jd], 0, 0, 0);
        }
        __builtin_amdgcn_s_setprio(0);
    };

    stage(0, 0);
    stage(1, 64);
    for (int kt = 0; kt < 12; ++kt) {
        if (kt < 11) {
            asm volatile("s_waitcnt vmcnt(2)" ::: "memory");
        } else {
            asm volatile("s_waitcnt vmcnt(0)" ::: "memory");
        }
        __builtin_amdgcn_s_barrier();
        compute(kt & 1);
        if (kt < 10) {
            __builtin_amdgcn_s_barrier();
            stage(kt & 1, (kt + 2) * 64);
        }
    }

    #pragma unroll
    for (int off = 1; off < 16; off <<= 1)
        #pragma unroll
        for (int r = 0; r < 4; ++r)
            l_l[r] += __shfl_xor(l_l[r], off);

    float rl[4];
    #pragma unroll
    for (int r = 0; r < 4; ++r) rl[r] = 1.f / l_l[r];
    #pragma unroll
    for (int jd = 0; jd < 4; ++jd)
        #pragma unroll
        for (int r = 0; r < 4; ++r) {
            size_t row = (size_t)bz * Sn + q0 + wave * 16 + lquad * 4 + r;
            ctx[row * Hn + h * HDn + jd * 16 + lrow] = f2bf(oacc[jd][r] * rl[r]);
        }
}

// layernorm in-place on f32 d_out.  grid B*S, block 64
__global__ __launch_bounds__(64) void k_ln(
    float* x, const float* __restrict__ g, const float* __restrict__ beta)
{
    size_t row = blockIdx.x;
    float* xr = x + row * Hn;
    int lane = threadIdx.x;
    float v[12];
    float s = 0.f, ss = 0.f;
    #pragma unroll
    for (int i = 0; i < 12; ++i) {
        v[i] = xr[lane + i * 64];
        s += v[i];
        ss += v[i] * v[i];
    }
    #pragma unroll
    for (int off = 1; off < 64; off <<= 1) {
        s  += __shfl_xor(s, off);
        ss += __shfl_xor(ss, off);
    }
    float mu = s * (1.f / Hn);
    float var = ss * (1.f / Hn) - mu * mu;
    float inv = rsqrtf(var + 1e-5f);
    #pragma unroll
    for (int i = 0; i < 12; ++i) {
        int c = lane + i * 64;
        xr[c] = (v[i] - mu) * inv * g[c] + beta[c];
    }
}

// ---------------- launch ----------------
extern "C" void kernel_launch(void* const* d_in, const int* in_sizes, int n_in,
                              void* d_out, int out_size, void* d_ws, size_t ws_size,
                              hipStream_t stream)
{
    (void)in_sizes; (void)n_in; (void)out_size; (void)ws_size;

    const float* hidden  = (const float*)d_in[0];
    const int*   lang    = (const int*)d_in[1];
    const float* Wq_lang = (const float*)d_in[3];
    const float* bq_lang = (const float*)d_in[4];
    const float* Wk_lang = (const float*)d_in[5];
    const float* bk_lang = (const float*)d_in[6];
    const float* ipw     = (const float*)d_in[7];
    const float* ipb     = (const float*)d_in[8];
    const float* opw     = (const float*)d_in[9];
    const float* opb     = (const float*)d_in[10];
    const float* align   = (const float*)d_in[11];
    const float* projw   = (const float*)d_in[12];
    const float* projb   = (const float*)d_in[13];
    const float* ln_g    = (const float*)d_in[14];
    const float* ln_b    = (const float*)d_in[15];
    float* out = (float*)d_out;

    const size_t HH  = (size_t)Hn * Hn;          // 589824
    const size_t BSH = (size_t)Bn * Sn * Hn;     // 4718592 = 8*HH
    const size_t AHH = (size_t)NLn * NLn * HH;   // 25*HH

    u16* rA = (u16*)d_ws;        // hb -> ctx
    u16* rB = rA + BSH;          // Q -> N1 slots 0..7
    u16* rC = rB + BSH;          // K -> N1 slots 8..15
    u16* rD = rC + BSH;          // V^T -> N1 slots 16..19
    u16* ipwb = rD + BSH;        // wq|wk|wv bf16 (3*HH)
    u16* pjwb = ipwb + 3 * HH;   // HH
    u16* opwT = pjwb + HH;       // HH
    u16* alignb = opwT + HH;     // 25*HH; pre-attn: weight scratch S[0..20)
                                 // post-L2: MT[0..5) U[5..10) W[10..15)
    u16* alignbT = alignb + AHH; // 25*HH transposed aligns (written by k_prep);
                                 // post-L1: Q2[0..10)
    float* beff   = (float*)(alignbT + AHH);  // 2*5*768 f32
    float* opbeff = beff + 10 * Hn;           // 5*768 f32
    float* bias2  = opbeff + 5 * Hn;          // 5*768 f32

    u16* S = alignb;             // scratch: WqT[0..5) WkT[5..10) Weffq[10..15) Weffk[15..20)
    u16* N1 = rB;                // 20 node matrices (rB..rD contiguous)
    u16* Q2 = alignbT;           // 10 node matrices (alignbT dead after L1)
    u16* MT = alignb;            // 5 (alignb dead after L1)
    u16* U5 = alignb + 5 * HH;   // 5
    u16* W5 = alignb + 10 * HH;  // 5

    // prep: weight conversions + 36 transposes (Wq/Wk/opw/align^T)
    k_prep<<<(unsigned)(PREP_NF2B + PREP_NTR), 256, 0, stream>>>(
        ipw, ipwb, projw, pjwb,
        Wq_lang, Wk_lang, opw, S, opwT, align, alignbT);

    // Weffq/Weffk GEMMs + hidden f32->bf16 backfill + QK bias folds (one launch)
    k_comb_aux<<<3774, 256, 0, stream>>>(
        ipwb, S, hidden, rA, ipw, ipb, bq_lang, bk_lang, beff);

    // fused QKV: Q*(1/8) -> rB, K -> rC, V^T -> rD.  256-row tiles, 1 generation.
    k_gemm_qkv<<<dim3(24, 6, 3), 256, 0, stream>>>(
        rA, S + 10 * HH, S + 15 * HH, ipwb + 2 * HH, beff, ipb, lang, rB, rC, rD);

    // attention (ctx -> rA) + straight align conversion (S scratch now dead)
    k_attn_conv<<<1476, 512, 0, stream>>>(rB, rC, rD, rA, align, alignb);

    // chain tree: 3 launches replace 8 sequential chain steps
    k_chainL1<<<dim3(12, 12, 20), 256, 0, stream>>>(alignb, alignbT, lang, N1);
    k_chainL2<<<dim3(12, 12, 10), 256, 0, stream>>>(N1, lang, Q2);
    k_chainL3<<<dim3(12, 12, 5), 256, 0, stream>>>(Q2, lang, MT);

    // U_l = opw^T . M_l  (+ opb_eff GEMV)
    k_uop<<<735, 256, 0, stream>>>(opwT, MT, opb, U5, opbeff);
    // W_l = projw . U_l  (+ bias2 GEMV)
    k_wb2<<<735, 256, 0, stream>>>(pjwb, U5, opbeff, projw, projb, W5, bias2);

    // x = ctx . W[lang]^T + bias2 + hidden -> d_out (f32).  64^2 tiles.
    k_xfused<<<dim3(96, 12), 256, 0, stream>>>(rA, W5, bias2, lang, hidden, out);
    // layernorm in place
    k_ln<<<(unsigned)(Bn * Sn), 64, 0, stream>>>(out, ln_g, ln_b);
}

// Round 14
// 450.325 us; speedup vs baseline: 1.6122x; 1.0024x over previous
//
#include <hip/hip_runtime.h>

// ---------------- constants ----------------
#define Bn 8
#define Sn 768
#define Hn 768
#define NHn 12
#define HDn 64
#define NLn 5

typedef unsigned short u16;
typedef __bf16 bf16x8 __attribute__((ext_vector_type(8)));
typedef short s16x8 __attribute__((ext_vector_type(8)));
typedef float f32x4 __attribute__((ext_vector_type(4)));
typedef unsigned short u16x4 __attribute__((ext_vector_type(4)));

static __device__ __forceinline__ float bf2f(u16 v) {
    return __uint_as_float(((unsigned)v) << 16);
}
static __device__ __forceinline__ u16 f2bf(float f) {
    unsigned u = __float_as_uint(f);
    unsigned r = u + 0x7fffu + ((u >> 16) & 1u);
    return (u16)(r >> 16);
}
static __device__ __forceinline__ bf16x8 ld8(const u16* p) {
    return *reinterpret_cast<const bf16x8*>(p);
}
static __device__ __forceinline__ void glds16(const u16* g, u16* l) {
    __builtin_amdgcn_global_load_lds(
        (const __attribute__((address_space(1))) void*)g,
        (__attribute__((address_space(3))) void*)l, 16, 0, 0);
}

// ---------------- fused prep: weight conversions + transposes ----------------
// f2b: ipw, projw (8 f32/thread).  transposes: Wq/Wk -> S, opw -> opwT.
// (align conversions moved to k_attn_conv; hidden f2b + biasqk in k_comb_aux.)
#define PREP_NF2B 1152
#define PREP_NTR  (11 * 144)
__global__ __launch_bounds__(256) void k_prep(
    const float* __restrict__ ipw, u16* __restrict__ ipwb,
    const float* __restrict__ projw, u16* __restrict__ pjwb,
    const float* __restrict__ Wq, const float* __restrict__ Wk,
    const float* __restrict__ opw, u16* __restrict__ S, u16* __restrict__ opwT)
{
    __shared__ float T[64][65];
    const size_t HH = (size_t)Hn * Hn;
    const int bid = blockIdx.x, tid = threadIdx.x;
    if (bid < PREP_NF2B) {
        const int n1 = (int)(3 * HH / 8), n2 = (int)(HH / 8);
        int i = bid * 256 + tid;
        const float* s; u16* d; int off;
        if (i < n1)           { s = ipw;   d = ipwb; off = i; }
        else if (i < n1 + n2) { s = projw; d = pjwb; off = i - n1; }
        else return;
        float4 a = reinterpret_cast<const float4*>(s)[off * 2];
        float4 b = reinterpret_cast<const float4*>(s)[off * 2 + 1];
        s16x8 o;
        o[0] = (short)f2bf(a.x); o[1] = (short)f2bf(a.y);
        o[2] = (short)f2bf(a.z); o[3] = (short)f2bf(a.w);
        o[4] = (short)f2bf(b.x); o[5] = (short)f2bf(b.y);
        o[6] = (short)f2bf(b.z); o[7] = (short)f2bf(b.w);
        reinterpret_cast<s16x8*>(d)[off] = o;
    } else if (bid < PREP_NF2B + PREP_NTR) {
        int b2 = bid - PREP_NF2B;
        int z = b2 / 144, r = b2 % 144;
        int bx = r % 12, by = r / 12;
        const float* src;
        u16* dst;
        if (z < 5)       { src = Wq + (size_t)z * HH;        dst = S + (size_t)z * HH; }
        else if (z < 10) { src = Wk + (size_t)(z - 5) * HH;  dst = S + (size_t)z * HH; }
        else             { src = opw;                         dst = opwT; }
        int i0 = bx * 64, o0 = by * 64;
        // stage 64x64 f32 tile: float4 loads
        #pragma unroll
        for (int it = 0; it < 4; ++it) {
            int s = tid + 256 * it;
            int row = s >> 4, seg = s & 15;
            float4 v = *reinterpret_cast<const float4*>(
                src + (size_t)(o0 + row) * Hn + i0 + seg * 4);
            T[row][seg * 4 + 0] = v.x;
            T[row][seg * 4 + 1] = v.y;
            T[row][seg * 4 + 2] = v.z;
            T[row][seg * 4 + 3] = v.w;
        }
        __syncthreads();
        // write transposed: s16x8 stores
        #pragma unroll
        for (int it = 0; it < 2; ++it) {
            int s = tid + 256 * it;
            int ri = s >> 3, c8 = s & 7;
            s16x8 o;
            #pragma unroll
            for (int e = 0; e < 8; ++e)
                o[e] = (short)f2bf(T[c8 * 8 + e][ri]);
            *reinterpret_cast<s16x8*>(dst + (size_t)(i0 + ri) * Hn + o0 + c8 * 8) = o;
        }
    }
}

// ---- TM x 128 triple-buffered counted-vmcnt NT GEMM core (256 thr) ----
template<int TM>
__device__ __forceinline__ void gemm_core(
    const u16* __restrict__ A, int lda,
    const u16* __restrict__ Bw, int ldb,
    const float* __restrict__ bias,
    const float* __restrict__ addres,
    u16* __restrict__ outH, float* __restrict__ outF,
    u16* __restrict__ outVT, int ldc,
    int m0, int n0, float scale)
{
    constexpr int MI = TM / 32;
    constexpr int AIT = TM / 64;
    __shared__ u16 As[3 * TM * 32];
    __shared__ u16 Bs[3 * 128 * 32];
    const int tid = threadIdx.x;
    const int lane = tid & 63, wave = tid >> 6;
    const int lrow = lane & 15, lquad = lane >> 4;
    const int wm = (wave >> 1) * (TM / 2), wn = (wave & 1) * 64;

    const u16* gA = A + (size_t)(m0 + (tid >> 2)) * lda + (tid & 3) * 8;
    const u16* gB = Bw + (size_t)(n0 + (tid >> 2)) * ldb + (tid & 3) * 8;

    f32x4 z = {0.f, 0.f, 0.f, 0.f};
    f32x4 acc[MI][4];
    #pragma unroll
    for (int i = 0; i < MI; ++i)
        #pragma unroll
        for (int j = 0; j < 4; ++j) acc[i][j] = z;

    auto stage = [&](int bs, int k0) {
        #pragma unroll
        for (int it = 0; it < AIT; ++it)
            glds16(gA + (size_t)(it * 64) * lda + k0, &As[bs * TM * 32 + (tid + 256 * it) * 8]);
        #pragma unroll
        for (int it = 0; it < 2; ++it)
            glds16(gB + (size_t)(it * 64) * ldb + k0, &Bs[bs * 128 * 32 + (tid + 256 * it) * 8]);
    };
    auto compute = [&](int bc) {
        const u16* Ab = &As[bc * TM * 32];
        const u16* Bb = &Bs[bc * 128 * 32];
        bf16x8 af[MI], bf_[4];
        #pragma unroll
        for (int i = 0; i < MI; ++i)
            af[i] = ld8(&Ab[(wm + i * 16 + lrow) * 32 + lquad * 8]);
        #pragma unroll
        for (int j = 0; j < 4; ++j)
            bf_[j] = ld8(&Bb[(wn + j * 16 + lrow) * 32 + lquad * 8]);
        #pragma unroll
        for (int i = 0; i < MI; ++i)
            #pragma unroll
            for (int j = 0; j < 4; ++j)
                acc[i][j] = __builtin_amdgcn_mfma_f32_16x16x32_bf16(af[i], bf_[j], acc[i][j], 0, 0, 0);
    };

    stage(0, 0);
    stage(1, 32);
    int bc = 0, bs = 2;
    for (int kt = 0; kt < 24; ++kt) {
        if (kt < 23) {
            if constexpr (TM == 256) {
                asm volatile("s_waitcnt vmcnt(6)" ::: "memory");
            } else {
                asm volatile("s_waitcnt vmcnt(4)" ::: "memory");
            }
        } else {
            asm volatile("s_waitcnt vmcnt(0)" ::: "memory");
        }
        __builtin_amdgcn_s_barrier();
        if (kt < 22) {
            stage(bs, (kt + 2) * 32);
            bs = (bs == 2) ? 0 : bs + 1;
        }
        compute(bc);
        bc = (bc == 2) ? 0 : bc + 1;
    }

    #pragma unroll
    for (int i = 0; i < MI; ++i) {
        #pragma unroll
        for (int j = 0; j < 4; ++j) {
            int col = n0 + wn + j * 16 + lrow;
            float bv = bias ? bias[col] : 0.f;
            if (outVT) {
                int row0 = m0 + wm + i * 16 + lquad * 4;
                int bb = row0 / Sn, s = row0 % Sn;
                int hh = col >> 6, dd = col & 63;
                u16x4 o;
                #pragma unroll
                for (int r = 0; r < 4; ++r) o[r] = f2bf((acc[i][j][r] + bv) * scale);
                *reinterpret_cast<u16x4*>(
                    outVT + (((size_t)bb * NHn + hh) * 64 + dd) * Sn + s) = o;
            } else {
                #pragma unroll
                for (int r = 0; r < 4; ++r) {
                    int row = m0 + wm + i * 16 + lquad * 4 + r;
                    float v = (acc[i][j][r] + bv) * scale;
                    if (addres) v += addres[(size_t)row * ldc + col];
                    if (outF) outF[(size_t)row * ldc + col] = v;
                    else      outH[(size_t)row * ldc + col] = f2bf(v);
                }
            }
        }
    }
}

// -- 64x64 triple-buffered counted-vmcnt NT GEMM core (256 thr), LDS passed in --
__device__ __forceinline__ void gemm64(
    u16* As, u16* Bs,
    const u16* __restrict__ A, const u16* __restrict__ Bw,
    const float* __restrict__ bias, const float* __restrict__ addres,
    u16* __restrict__ outH, float* __restrict__ outF,
    int m0, int n0)
{
    const int tid = threadIdx.x;
    const int lane = tid & 63, wave = tid >> 6;
    const int lrow = lane & 15, lquad = lane >> 4;
    const int wm = (wave >> 1) * 32, wn = (wave & 1) * 32;

    const u16* gA = A + (size_t)(m0 + (tid >> 2)) * Hn + (tid & 3) * 8;
    const u16* gB = Bw + (size_t)(n0 + (tid >> 2)) * Hn + (tid & 3) * 8;

    f32x4 z = {0.f, 0.f, 0.f, 0.f};
    f32x4 acc[2][2];
    #pragma unroll
    for (int i = 0; i < 2; ++i)
        #pragma unroll
        for (int j = 0; j < 2; ++j) acc[i][j] = z;

    auto stage = [&](int bs, int k0) {
        glds16(gA + k0, &As[bs * 64 * 32 + tid * 8]);
        glds16(gB + k0, &Bs[bs * 64 * 32 + tid * 8]);
    };
    auto compute = [&](int bc) {
        const u16* Ab = &As[bc * 64 * 32];
        const u16* Bb = &Bs[bc * 64 * 32];
        bf16x8 af[2], bf_[2];
        #pragma unroll
        for (int i = 0; i < 2; ++i)
            af[i] = ld8(&Ab[(wm + i * 16 + lrow) * 32 + lquad * 8]);
        #pragma unroll
        for (int j = 0; j < 2; ++j)
            bf_[j] = ld8(&Bb[(wn + j * 16 + lrow) * 32 + lquad * 8]);
        #pragma unroll
        for (int i = 0; i < 2; ++i)
            #pragma unroll
            for (int j = 0; j < 2; ++j)
                acc[i][j] = __builtin_amdgcn_mfma_f32_16x16x32_bf16(af[i], bf_[j], acc[i][j], 0, 0, 0);
    };

    stage(0, 0);
    stage(1, 32);
    int bc = 0, bs = 2;
    for (int kt = 0; kt < 24; ++kt) {
        if (kt < 23) {
            asm volatile("s_waitcnt vmcnt(2)" ::: "memory");
        } else {
            asm volatile("s_waitcnt vmcnt(0)" ::: "memory");
        }
        __builtin_amdgcn_s_barrier();
        if (kt < 22) {
            stage(bs, (kt + 2) * 32);
            bs = (bs == 2) ? 0 : bs + 1;
        }
        compute(bc);
        bc = (bc == 2) ? 0 : bc + 1;
    }

    #pragma unroll
    for (int i = 0; i < 2; ++i)
        #pragma unroll
        for (int j = 0; j < 2; ++j) {
            int col = n0 + wn + j * 16 + lrow;
            float bv = bias ? bias[col] : 0.f;
            #pragma unroll
            for (int r = 0; r < 4; ++r) {
                int row_ = m0 + wm + i * 16 + lquad * 4 + r;
                float v = acc[i][j][r] + bv;
                if (addres) v += addres[(size_t)row_ * Hn + col];
                if (outF) outF[(size_t)row_ * Hn + col] = v;
                else      outH[(size_t)row_ * Hn + col] = f2bf(v);
            }
        }
}

// ---- 64x64 tile helpers (256 thr): identity write, copy, transposing copy ----
static __device__ __forceinline__ void ident64(u16* dst, int m0, int n0)
{
    const int tid = threadIdx.x;
    #pragma unroll
    for (int it = 0; it < 2; ++it) {
        int s = tid + 256 * it;
        int ri = s >> 3, c8 = s & 7;
        s16x8 v;
        #pragma unroll
        for (int e = 0; e < 8; ++e)
            v[e] = (short)((m0 + ri == n0 + c8 * 8 + e) ? 0x3F80 : 0);
        *reinterpret_cast<s16x8*>(dst + (size_t)(m0 + ri) * Hn + n0 + c8 * 8) = v;
    }
}
static __device__ __forceinline__ void copy64(u16* dst, const u16* src, int m0, int n0)
{
    const int tid = threadIdx.x;
    #pragma unroll
    for (int it = 0; it < 2; ++it) {
        int s = tid + 256 * it;
        int row = s >> 3, seg = s & 7;
        *reinterpret_cast<s16x8*>(dst + (size_t)(m0 + row) * Hn + n0 + seg * 8) =
            *reinterpret_cast<const s16x8*>(src + (size_t)(m0 + row) * Hn + n0 + seg * 8);
    }
}
// dst = src^T: dst tile (m0,n0) <- src tile (n0,m0) transposed.  lds >= 64*72 u16
static __device__ __forceinline__ void tcopy64(u16* dst, const u16* src, int m0, int n0, u16* lds)
{
    u16 (*T)[72] = reinterpret_cast<u16(*)[72]>(lds);
    const int tid = threadIdx.x;
    #pragma unroll
    for (int it = 0; it < 2; ++it) {
        int s = tid + 256 * it;
        int rr = s >> 3, c8 = s & 7;
        s16x8 v = *reinterpret_cast<const s16x8*>(
            src + (size_t)(n0 + rr) * Hn + m0 + c8 * 8);
        #pragma unroll
        for (int e = 0; e < 8; ++e) T[c8 * 8 + e][rr] = (u16)v[e];
    }
    __syncthreads();
    #pragma unroll
    for (int it = 0; it < 2; ++it) {
        int s = tid + 256 * it;
        int ri = s >> 3, c8 = s & 7;
        *reinterpret_cast<s16x8*>(dst + (size_t)(m0 + ri) * Hn + n0 + c8 * 8) =
            *reinterpret_cast<const s16x8*>(&T[ri][c8 * 8]);
    }
}

// ---------------- GEMM wrapper kernels ----------------

// comb + aux backfill.  flat grid 3774 blocks:
//   [0,1440): Weffq/Weffk 64^2 tiles (z = bid/144: z<5 Weffq_z, z>=5 Weffk)
//   [1440, 3744): hidden f32 -> bf16 (8 f32/thread)
//   [3744, 3774): combined QK bias GEMVs
__global__ __launch_bounds__(256) void k_comb_aux(
    const u16* __restrict__ ipwb, u16* __restrict__ S,
    const float* __restrict__ hidden, u16* __restrict__ hb,
    const float* __restrict__ ipw, const float* __restrict__ ipb,
    const float* __restrict__ bq_lang, const float* __restrict__ bk_lang,
    float* __restrict__ beff)
{
    __shared__ u16 As[3 * 64 * 32];
    __shared__ u16 Bs[3 * 64 * 32];
    const size_t HH = (size_t)Hn * Hn;
    const int bid = blockIdx.x, tid = threadIdx.x;
    if (bid < 1440) {
        int z = bid / 144, r = bid % 144;
        const u16* Aop = ipwb + (z < 5 ? 0 : HH);
        gemm64(As, Bs, Aop, S + (size_t)z * HH, nullptr, nullptr,
               S + (size_t)(10 + z) * HH, nullptr,
               (r % 12) * 64, (r / 12) * 64);
    } else if (bid < 3744) {
        int i = (bid - 1440) * 256 + tid;          // 589824 threads
        float4 a = reinterpret_cast<const float4*>(hidden)[i * 2];
        float4 b = reinterpret_cast<const float4*>(hidden)[i * 2 + 1];
        s16x8 o;
        o[0] = (short)f2bf(a.x); o[1] = (short)f2bf(a.y);
        o[2] = (short)f2bf(a.z); o[3] = (short)f2bf(a.w);
        o[4] = (short)f2bf(b.x); o[5] = (short)f2bf(b.y);
        o[6] = (short)f2bf(b.z); o[7] = (short)f2bf(b.w);
        reinterpret_cast<s16x8*>(hb)[i] = o;
    } else {
        int b3 = bid - 3744;                       // 0..29
        int ox = b3 % 3, y = b3 / 3;
        int o = ox * 256 + tid;
        int which = y / 5, l = y % 5;
        const float4* w = reinterpret_cast<const float4*>(ipw + (size_t)which * HH + (size_t)o * Hn);
        const float4* bv = reinterpret_cast<const float4*>(((which ? bk_lang : bq_lang) + (size_t)l * Hn));
        float s = 0.f;
        for (int j = 0; j < Hn / 4; ++j) {
            float4 a = w[j], b = bv[j];
            s += a.x * b.x + a.y * b.y + a.z * b.z + a.w * b.w;
        }
        s += ipb[which * Hn + o];
        beff[(size_t)(which * 5 + l) * Hn + o] = s;
    }
}

// fused QKV projection, 256-row tiles (432 blocks -> ONE generation at 2/CU).
// grid (24, 6, 3): z=0 Q, z=1 K, z=2 V(T layout).
__global__ __launch_bounds__(256, 2) void k_gemm_qkv(
    const u16* __restrict__ A,
    const u16* __restrict__ Sq, const u16* __restrict__ Sk,
    const u16* __restrict__ Wv,
    const float* __restrict__ beff, const float* __restrict__ ipb,
    const int* __restrict__ lang,
    u16* __restrict__ outQ, u16* __restrict__ outK, u16* __restrict__ outVT)
{
    const size_t HH = (size_t)Hn * Hn;
    int z = blockIdx.z;
    int m0 = blockIdx.x * 256, n0 = blockIdx.y * 128;
    int l = lang[blockIdx.x / 3];
    if (z == 0) {
        gemm_core<256>(A, Hn, Sq + (size_t)l * HH, Hn, beff + (size_t)l * Hn,
                       nullptr, outQ, nullptr, nullptr, Hn, m0, n0, 0.125f);
    } else if (z == 1) {
        gemm_core<256>(A, Hn, Sk + (size_t)l * HH, Hn, beff + (size_t)(5 + l) * Hn,
                       nullptr, outK, nullptr, nullptr, Hn, m0, n0, 1.f);
    } else {
        gemm_core<256>(A, Hn, Wv, Hn, ipb + 2 * Hn,
                       nullptr, nullptr, nullptr, outVT, Hn, m0, n0, 1.f);
    }
}

// ---------------- chain tree ----------------
// MT_l = S7^T S6^T ... S0^T;  S_j = (lang[j]==l) ? I : align[l, lang[j]].

// L1.  grid (12,12,20)
__global__ __launch_bounds__(256) void k_chainL1(
    const u16* __restrict__ alignb, const u16* __restrict__ alignbT,
    const int* __restrict__ lang, u16* __restrict__ N1)
{
    __shared__ u16 As[3 * 64 * 32];
    __shared__ u16 Bs[3 * 64 * 32];
    const size_t HH = (size_t)Hn * Hn;
    int idx = blockIdx.z, l = idx >> 2, node = idx & 3;
    int ja = 7 - node * 2, jb = 6 - node * 2;
    bool tr = node & 1;
    int la = lang[ja], lb = lang[jb];
    bool sa = (la == l), sb = (lb == l);
    u16* dst = N1 + (size_t)idx * HH;
    int m0 = blockIdx.x * 64, n0 = blockIdx.y * 64;
    if (sa && sb) {
        ident64(dst, m0, n0);
    } else if (sa) {
        copy64(dst, (tr ? alignb : alignbT) + ((size_t)l * NLn + lb) * HH, m0, n0);
    } else if (sb) {
        copy64(dst, (tr ? alignb : alignbT) + ((size_t)l * NLn + la) * HH, m0, n0);
    } else if (!tr) {  // straight: Fa^T * Fb^T = NT(FaT, Fb)
        gemm64(As, Bs, alignbT + ((size_t)l * NLn + la) * HH,
               alignb + ((size_t)l * NLn + lb) * HH,
               nullptr, nullptr, dst, nullptr, m0, n0);
    } else {           // transposed: Fb * Fa = NT(Fb, FaT)
        gemm64(As, Bs, alignb + ((size_t)l * NLn + lb) * HH,
               alignbT + ((size_t)l * NLn + la) * HH,
               nullptr, nullptr, dst, nullptr, m0, n0);
    }
}

// L2.  grid (12,12,10): z = l*2 + q.  Q_a -> Q2[l], Q_bT -> Q2[5+l]
__global__ __launch_bounds__(256) void k_chainL2(
    const u16* __restrict__ N1, const int* __restrict__ lang,
    u16* __restrict__ Q2)
{
    __shared__ u16 As[3 * 64 * 32];
    __shared__ u16 Bs[3 * 64 * 32];
    const size_t HH = (size_t)Hn * Hn;
    int idx = blockIdx.z, l = idx >> 1, q = idx & 1;
    int m0 = blockIdx.x * 64, n0 = blockIdx.y * 64;
    const u16* Pa  = N1 + (size_t)(l * 4 + 0) * HH;
    const u16* PbT = N1 + (size_t)(l * 4 + 1) * HH;
    const u16* Pc  = N1 + (size_t)(l * 4 + 2) * HH;
    const u16* PdT = N1 + (size_t)(l * 4 + 3) * HH;
    if (q == 0) {
        u16* dst = Q2 + (size_t)l * HH;
        bool ia = (lang[7] == l) && (lang[6] == l);
        bool ib = (lang[5] == l) && (lang[4] == l);
        if (ia && ib)      ident64(dst, m0, n0);
        else if (ia)       tcopy64(dst, PbT, m0, n0, As);
        else if (ib)       copy64(dst, Pa, m0, n0);
        else               gemm64(As, Bs, Pa, PbT, nullptr, nullptr, dst, nullptr, m0, n0);
    } else {
        u16* dst = Q2 + (size_t)(5 + l) * HH;
        bool ic = (lang[3] == l) && (lang[2] == l);
        bool id = (lang[1] == l) && (lang[0] == l);
        if (ic && id)      ident64(dst, m0, n0);
        else if (ic)       copy64(dst, PdT, m0, n0);
        else if (id)       tcopy64(dst, Pc, m0, n0, As);
        else               gemm64(As, Bs, PdT, Pc, nullptr, nullptr, dst, nullptr, m0, n0);
    }
}

// L3.  grid (12,12,5): MT_l = Q_a * Q_b = NT(Q_a, Q_bT)
__global__ __launch_bounds__(256) void k_chainL3(
    const u16* __restrict__ Q2, const int* __restrict__ lang,
    u16* __restrict__ MT)
{
    __shared__ u16 As[3 * 64 * 32];
    __shared__ u16 Bs[3 * 64 * 32];
    const size_t HH = (size_t)Hn * Hn;
    int l = blockIdx.z;
    int m0 = blockIdx.x * 64, n0 = blockIdx.y * 64;
    const u16* Qa  = Q2 + (size_t)l * HH;
    const u16* QbT = Q2 + (size_t)(5 + l) * HH;
    u16* dst = MT + (size_t)l * HH;
    bool iA = (lang[7] == l) && (lang[6] == l) && (lang[5] == l) && (lang[4] == l);
    bool iB = (lang[3] == l) && (lang[2] == l) && (lang[1] == l) && (lang[0] == l);
    if (iA && iB)      ident64(dst, m0, n0);
    else if (iA)       tcopy64(dst, QbT, m0, n0, As);
    else if (iB)       copy64(dst, Qa, m0, n0);
    else               gemm64(As, Bs, Qa, QbT, nullptr, nullptr, dst, nullptr, m0, n0);
}

// U_l = NT(opwT, MT_l) + opb_eff GEMV.  grid 735.
__global__ __launch_bounds__(256) void k_uop(
    const u16* __restrict__ opwT, const u16* __restrict__ MT,
    const float* __restrict__ opb,
    u16* __restrict__ U5, float* __restrict__ opbeff)
{
    __shared__ u16 As[3 * 64 * 32];
    __shared__ u16 Bs[3 * 64 * 32];
    const size_t HH = (size_t)Hn * Hn;
    int bid = blockIdx.x;
    if (bid < 720) {
        int z = bid / 144, r = bid % 144;
        gemm64(As, Bs, opwT, MT + (size_t)z * HH, nullptr, nullptr,
               U5 + (size_t)z * HH, nullptr,
               (r % 12) * 64, (r / 12) * 64);
    } else {
        int b2 = bid - 720;
        int n = (b2 % 3) * 256 + threadIdx.x;
        int l = b2 / 3;
        const u16* mt = MT + ((size_t)l * Hn + n) * Hn;
        float s = 0.f;
        for (int k = 0; k < Hn; k += 8) {
            s16x8 v = *reinterpret_cast<const s16x8*>(mt + k);
            #pragma unroll
            for (int jq = 0; jq < 8; ++jq) s += opb[k + jq] * bf2f((u16)v[jq]);
        }
        opbeff[(size_t)l * Hn + n] = s;
    }
}

// W_l = NT(projw, U_l) + bias2 GEMV.  grid 735.
__global__ __launch_bounds__(256) void k_wb2(
    const u16* __restrict__ pjwb, const u16* __restrict__ U5,
    const float* __restrict__ opbeff, const float* __restrict__ projw,
    const float* __restrict__ projb,
    u16* __restrict__ W5, float* __restrict__ bias2)
{
    __shared__ u16 As[3 * 64 * 32];
    __shared__ u16 Bs[3 * 64 * 32];
    const size_t HH = (size_t)Hn * Hn;
    int bid = blockIdx.x;
    if (bid < 720) {
        int z = bid / 144, r = bid % 144;
        gemm64(As, Bs, pjwb, U5 + (size_t)z * HH, nullptr, nullptr,
               W5 + (size_t)z * HH, nullptr,
               (r % 12) * 64, (r / 12) * 64);
    } else {
        int b2 = bid - 720;
        int m = (b2 % 3) * 256 + threadIdx.x;
        int l = b2 / 3;
        const float4* w = reinterpret_cast<const float4*>(projw + (size_t)m * Hn);
        const float4* ob = reinterpret_cast<const float4*>(opbeff + (size_t)l * Hn);
        float s = 0.f;
        for (int jq = 0; jq < Hn / 4; ++jq) {
            float4 a = w[jq], b = ob[jq];
            s += a.x * b.x + a.y * b.y + a.z * b.z + a.w * b.w;
        }
        bias2[(size_t)l * Hn + m] = s + projb[m];
    }
}

// x = NT(ctx, W[lang]) + bias2[lang] + hidden -> f32 out.  64^2 tiles, grid (96,12)
__global__ __launch_bounds__(256) void k_xfused(
    const u16* __restrict__ ctx, const u16* __restrict__ W5,
    const float* __restrict__ bias2, const int* __restrict__ lang,
    const float* __restrict__ hidden, float* __restrict__ x)
{
    __shared__ u16 As[3 * 64 * 32];
    __shared__ u16 Bs[3 * 64 * 32];
    int l = lang[blockIdx.x / 12];
    gemm64(As, Bs, ctx, W5 + (size_t)l * Hn * Hn, bias2 + (size_t)l * Hn,
           hidden, nullptr, x,
           blockIdx.x * 64, blockIdx.y * 64);
}

// ---------------- flash attention + align conversion, 512 threads ----------
// blocks [0,576): attn.  blocks [576, 4176): align conversion 64x64 tiles —
// stage f32 tile ONCE, write BOTH alignb (straight) and alignbT (transposed).
__global__ __launch_bounds__(512) void k_attn_conv(
    const u16* __restrict__ Q, const u16* __restrict__ K,
    const u16* __restrict__ VT, u16* __restrict__ ctx,
    const float* __restrict__ alignf, u16* __restrict__ alignb,
    u16* __restrict__ alignbT)
{
    __shared__ u16 Ks[2][64 * 64];       // [key][d], seg-xor-swizzled
    __shared__ u16 Vs[2][64 * 64];       // [d][key], seg-xor-swizzled
    __shared__ u16 Pw[8][16 * 72];       // per-wave P; conv: f32 T[64][65]

    const int bid = blockIdx.x, tid = threadIdx.x;
    const size_t HH = (size_t)Hn * Hn;
    if (bid >= 576) {
        int t = bid - 576;                   // 0..3599
        int mat = t / 144, r = t % 144;
        int i0 = (r % 12) * 64, o0 = (r / 12) * 64;
        const float* src = alignf + (size_t)mat * HH;
        u16* dstS = alignb + (size_t)mat * HH;
        u16* dstT = alignbT + (size_t)mat * HH;
        float (*T)[65] = reinterpret_cast<float(*)[65]>(&Pw[0][0]);
        // 512 threads = 64 rows x 8 col-groups; load 8 f32, write straight s16x8
        {
            int row = tid >> 3, c8 = tid & 7;
            const float* p = src + (size_t)(o0 + row) * Hn + i0 + c8 * 8;
            float4 a = *reinterpret_cast<const float4*>(p);
            float4 b = *reinterpret_cast<const float4*>(p + 4);
            s16x8 o;
            o[0] = (short)f2bf(a.x); o[1] = (short)f2bf(a.y);
            o[2] = (short)f2bf(a.z); o[3] = (short)f2bf(a.w);
            o[4] = (short)f2bf(b.x); o[5] = (short)f2bf(b.y);
            o[6] = (short)f2bf(b.z); o[7] = (short)f2bf(b.w);
            *reinterpret_cast<s16x8*>(dstS + (size_t)(o0 + row) * Hn + i0 + c8 * 8) = o;
            T[row][c8 * 8 + 0] = a.x; T[row][c8 * 8 + 1] = a.y;
            T[row][c8 * 8 + 2] = a.z; T[row][c8 * 8 + 3] = a.w;
            T[row][c8 * 8 + 4] = b.x; T[row][c8 * 8 + 5] = b.y;
            T[row][c8 * 8 + 6] = b.z; T[row][c8 * 8 + 7] = b.w;
        }
        __syncthreads();
        // transposed write: s16x8 column-gather
        {
            int ri = tid >> 3, c8 = tid & 7;
            s16x8 o;
            #pragma unroll
            for (int e = 0; e < 8; ++e)
                o[e] = (short)f2bf(T[c8 * 8 + e][ri]);
            *reinterpret_cast<s16x8*>(dstT + (size_t)(i0 + ri) * Hn + o0 + c8 * 8) = o;
        }
        return;
    }

    const int q0 = (bid % 6) * 128, h = (bid / 6) % NHn, bz = bid / 72;
    const int wave = tid >> 6, lane = tid & 63;
    const int lrow = lane & 15, lquad = lane >> 4;
    const int sw = lrow & 7;

    const u16* Qp = Q + ((size_t)(bz * Sn + q0 + wave * 16 + lrow)) * Hn + h * HDn;
    const u16* Kb = K + (size_t)bz * Sn * Hn + h * HDn;
    const u16* Vb = VT + ((size_t)(bz * NHn + h) * 64) * Sn;   // row d, stride Sn

    bf16x8 qa0 = ld8(Qp + lquad * 8);
    bf16x8 qa1 = ld8(Qp + 32 + lquad * 8);

    f32x4 z4 = {0.f, 0.f, 0.f, 0.f};
    float m_r[4], l_l[4];
    f32x4 oacc[4];
    #pragma unroll
    for (int r = 0; r < 4; ++r) { m_r[r] = -1e30f; l_l[r] = 0.f; }
    #pragma unroll
    for (int jd = 0; jd < 4; ++jd) oacc[jd] = z4;

    const int krow = tid >> 3, kp = (tid & 7) ^ (krow & 7);
    const u16* kg = Kb + (size_t)krow * Hn + kp * 8;
    const u16* vg = Vb + (size_t)krow * Sn + kp * 8;

    auto stage = [&](int bs, int t0) {
        glds16(kg + (size_t)t0 * Hn, &Ks[bs][tid * 8]);
        glds16(vg + t0, &Vs[bs][tid * 8]);
    };

    auto compute = [&](int bc) {
        f32x4 sc[4];
        __builtin_amdgcn_s_setprio(1);
        #pragma unroll
        for (int j = 0; j < 4; ++j) {
            int base = (j * 16 + lrow) * 64 + ((lquad ^ sw) * 8);
            f32x4 s = __builtin_amdgcn_mfma_f32_16x16x32_bf16(qa0, ld8(&Ks[bc][base]), z4, 0, 0, 0);
            sc[j] = __builtin_amdgcn_mfma_f32_16x16x32_bf16(qa1, ld8(&Ks[bc][base ^ 32]), s, 0, 0, 0);
        }
        __builtin_amdgcn_s_setprio(0);
        float tmax[4];
        #pragma unroll
        for (int r = 0; r < 4; ++r)
            tmax[r] = fmaxf(fmaxf(sc[0][r], sc[1][r]), fmaxf(sc[2][r], sc[3][r]));
        #pragma unroll
        for (int off = 1; off < 16; off <<= 1)
            #pragma unroll
            for (int r = 0; r < 4; ++r)
                tmax[r] = fmaxf(tmax[r], __shfl_xor(tmax[r], off));
        bool grow = (tmax[0] > m_r[0] + 8.f) | (tmax[1] > m_r[1] + 8.f) |
                    (tmax[2] > m_r[2] + 8.f) | (tmax[3] > m_r[3] + 8.f);
        if (grow) {
            #pragma unroll
            for (int r = 0; r < 4; ++r) {
                float mn = fmaxf(m_r[r], tmax[r]);
                float a = __expf(m_r[r] - mn);
                m_r[r] = mn;
                l_l[r] *= a;
                #pragma unroll
                for (int jd = 0; jd < 4; ++jd) oacc[jd][r] *= a;
            }
        }
        float ps[4] = {0.f, 0.f, 0.f, 0.f};
        #pragma unroll
        for (int j = 0; j < 4; ++j)
            #pragma unroll
            for (int r = 0; r < 4; ++r) {
                float p = __expf(sc[j][r] - m_r[r]);
                ps[r] += p;
                Pw[wave][(lquad * 4 + r) * 72 + j * 16 + lrow] = f2bf(p);
            }
        #pragma unroll
        for (int r = 0; r < 4; ++r) l_l[r] += ps[r];
        bf16x8 pa0 = ld8(&Pw[wave][lrow * 72 + lquad * 8]);
        bf16x8 pa1 = ld8(&Pw[wave][lrow * 72 + 32 + lquad * 8]);
        __builtin_amdgcn_s_setprio(1);
        #pragma unroll
        for (int jd = 0; jd < 4; ++jd) {
            int vbase = (jd * 16 + lrow) * 64 + ((lquad ^ sw) * 8);
            oacc[jd] = __builtin_amdgcn_mfma_f32_16x16x32_bf16(pa0, ld8(&Vs[bc][vbase]), oacc[jd], 0, 0, 0);
            oacc[jd] = __builtin_amdgcn_mfma_f32_16x16x32_bf16(pa1, ld8(&Vs[bc][vbase ^ 32]), oacc[jd], 0, 0, 0);
        }
        __builtin_amdgcn_s_setprio(0);
    };

    stage(0, 0);
    stage(1, 64);
    for (int kt = 0; kt < 12; ++kt) {
        if (kt < 11) {
            asm volatile("s_waitcnt vmcnt(2)" ::: "memory");
        } else {
            asm volatile("s_waitcnt vmcnt(0)" ::: "memory");
        }
        __builtin_amdgcn_s_barrier();
        compute(kt & 1);
        if (kt < 10) {
            __builtin_amdgcn_s_barrier();
            stage(kt & 1, (kt + 2) * 64);
        }
    }

    #pragma unroll
    for (int off = 1; off < 16; off <<= 1)
        #pragma unroll
        for (int r = 0; r < 4; ++r)
            l_l[r] += __shfl_xor(l_l[r], off);

    float rl[4];
    #pragma unroll
    for (int r = 0; r < 4; ++r) rl[r] = 1.f / l_l[r];
    #pragma unroll
    for (int jd = 0; jd < 4; ++jd)
        #pragma unroll
        for (int r = 0; r < 4; ++r) {
            size_t row = (size_t)bz * Sn + q0 + wave * 16 + lquad * 4 + r;
            ctx[row * Hn + h * HDn + jd * 16 + lrow] = f2bf(oacc[jd][r] * rl[r]);
        }
}

// layernorm in-place on f32 d_out.  grid B*S, block 64
__global__ __launch_bounds__(64) void k_ln(
    float* x, const float* __restrict__ g, const float* __restrict__ beta)
{
    size_t row = blockIdx.x;
    float* xr = x + row * Hn;
    int lane = threadIdx.x;
    float v[12];
    float s = 0.f, ss = 0.f;
    #pragma unroll
    for (int i = 0; i < 12; ++i) {
        v[i] = xr[lane + i * 64];
        s += v[i];
        ss += v[i] * v[i];
    }
    #pragma unroll
    for (int off = 1; off < 64; off <<= 1) {
        s  += __shfl_xor(s, off);
        ss += __shfl_xor(ss, off);
    }
    float mu = s * (1.f / Hn);
    float var = ss * (1.f / Hn) - mu * mu;
    float inv = rsqrtf(var + 1e-5f);
    #pragma unroll
    for (int i = 0; i < 12; ++i) {
        int c = lane + i * 64;
        xr[c] = (v[i] - mu) * inv * g[c] + beta[c];
    }
}

// ---------------- launch ----------------
extern "C" void kernel_launch(void* const* d_in, const int* in_sizes, int n_in,
                              void* d_out, int out_size, void* d_ws, size_t ws_size,
                              hipStream_t stream)
{
    (void)in_sizes; (void)n_in; (void)out_size; (void)ws_size;

    const float* hidden  = (const float*)d_in[0];
    const int*   lang    = (const int*)d_in[1];
    const float* Wq_lang = (const float*)d_in[3];
    const float* bq_lang = (const float*)d_in[4];
    const float* Wk_lang = (const float*)d_in[5];
    const float* bk_lang = (const float*)d_in[6];
    const float* ipw     = (const float*)d_in[7];
    const float* ipb     = (const float*)d_in[8];
    const float* opw     = (const float*)d_in[9];
    const float* opb     = (const float*)d_in[10];
    const float* align   = (const float*)d_in[11];
    const float* projw   = (const float*)d_in[12];
    const float* projb   = (const float*)d_in[13];
    const float* ln_g    = (const float*)d_in[14];
    const float* ln_b    = (const float*)d_in[15];
    float* out = (float*)d_out;

    const size_t HH  = (size_t)Hn * Hn;          // 589824
    const size_t BSH = (size_t)Bn * Sn * Hn;     // 4718592 = 8*HH
    const size_t AHH = (size_t)NLn * NLn * HH;   // 25*HH

    u16* rA = (u16*)d_ws;        // hb -> ctx
    u16* rB = rA + BSH;          // Q -> N1 slots 0..7
    u16* rC = rB + BSH;          // K -> N1 slots 8..15
    u16* rD = rC + BSH;          // V^T -> N1 slots 16..19
    u16* ipwb = rD + BSH;        // wq|wk|wv bf16 (3*HH)
    u16* pjwb = ipwb + 3 * HH;   // HH
    u16* opwT = pjwb + HH;       // HH
    u16* alignb = opwT + HH;     // 25*HH; pre-attn: weight scratch S[0..20)
                                 // post-L2: MT[0..5) U[5..10) W[10..15)
    u16* alignbT = alignb + AHH; // 25*HH transposed aligns (written by attn_conv);
                                 // post-L1: Q2[0..10)
    float* beff   = (float*)(alignbT + AHH);  // 2*5*768 f32
    float* opbeff = beff + 10 * Hn;           // 5*768 f32
    float* bias2  = opbeff + 5 * Hn;          // 5*768 f32

    u16* S = alignb;             // scratch: WqT[0..5) WkT[5..10) Weffq[10..15) Weffk[15..20)
    u16* N1 = rB;                // 20 node matrices (rB..rD contiguous)
    u16* Q2 = alignbT;           // 10 node matrices (alignbT dead after L1)
    u16* MT = alignb;            // 5 (alignb dead after L1)
    u16* U5 = alignb + 5 * HH;   // 5
    u16* W5 = alignb + 10 * HH;  // 5

    // prep: weight conversions + 11 transposes (Wq/Wk/opw)
    k_prep<<<(unsigned)(PREP_NF2B + PREP_NTR), 256, 0, stream>>>(
        ipw, ipwb, projw, pjwb, Wq_lang, Wk_lang, opw, S, opwT);

    // Weffq/Weffk GEMMs + hidden f32->bf16 backfill + QK bias folds (one launch)
    k_comb_aux<<<3774, 256, 0, stream>>>(
        ipwb, S, hidden, rA, ipw, ipb, bq_lang, bk_lang, beff);

    // fused QKV: Q*(1/8) -> rB, K -> rC, V^T -> rD.  256-row tiles, 1 generation.
    k_gemm_qkv<<<dim3(24, 6, 3), 256, 0, stream>>>(
        rA, S + 10 * HH, S + 15 * HH, ipwb + 2 * HH, beff, ipb, lang, rB, rC, rD);

    // attention (ctx -> rA) + align f32 staged ONCE -> alignb + alignbT
    // (S scratch dead once qkv completes)
    k_attn_conv<<<4176, 512, 0, stream>>>(rB, rC, rD, rA, align, alignb, alignbT);

    // chain tree: 3 launches replace 8 sequential chain steps
    k_chainL1<<<dim3(12, 12, 20), 256, 0, stream>>>(alignb, alignbT, lang, N1);
    k_chainL2<<<dim3(12, 12, 10), 256, 0, stream>>>(N1, lang, Q2);
    k_chainL3<<<dim3(12, 12, 5), 256, 0, stream>>>(Q2, lang, MT);

    // U_l = opw^T . M_l  (+ opb_eff GEMV)
    k_uop<<<735, 256, 0, stream>>>(opwT, MT, opb, U5, opbeff);
    // W_l = projw . U_l  (+ bias2 GEMV)
    k_wb2<<<735, 256, 0, stream>>>(pjwb, U5, opbeff, projw, projb, W5, bias2);

    // x = ctx . W[lang]^T + bias2 + hidden -> d_out (f32).  64^2 tiles.
    k_xfused<<<dim3(96, 12), 256, 0, stream>>>(rA, W5, bias2, lang, hidden, out);
    // layernorm in place
    k_ln<<<(unsigned)(Bn * Sn), 64, 0, stream>>>(out, ln_g, ln_b);
}

// Round 15
// 440.232 us; speedup vs baseline: 1.6492x; 1.0229x over previous
//
#include <hip/hip_runtime.h>

// ---------------- constants ----------------
#define Bn 8
#define Sn 768
#define Hn 768
#define NHn 12
#define HDn 64
#define NLn 5

typedef unsigned short u16;
typedef __bf16 bf16x8 __attribute__((ext_vector_type(8)));
typedef short s16x8 __attribute__((ext_vector_type(8)));
typedef float f32x4 __attribute__((ext_vector_type(4)));
typedef unsigned short u16x4 __attribute__((ext_vector_type(4)));

static __device__ __forceinline__ float bf2f(u16 v) {
    return __uint_as_float(((unsigned)v) << 16);
}
static __device__ __forceinline__ u16 f2bf(float f) {
    unsigned u = __float_as_uint(f);
    unsigned r = u + 0x7fffu + ((u >> 16) & 1u);
    return (u16)(r >> 16);
}
static __device__ __forceinline__ bf16x8 ld8(const u16* p) {
    return *reinterpret_cast<const bf16x8*>(p);
}
static __device__ __forceinline__ void glds16(const u16* g, u16* l) {
    __builtin_amdgcn_global_load_lds(
        (const __attribute__((address_space(1))) void*)g,
        (__attribute__((address_space(3))) void*)l, 16, 0, 0);
}

// ---------------- fused prep: weight conversions + transposes ----------------
// f2b: ipw, projw (8 f32/thread).  transposes: Wq/Wk -> S, opw -> opwT.
#define PREP_NF2B 1152
#define PREP_NTR  (11 * 144)
__global__ __launch_bounds__(256) void k_prep(
    const float* __restrict__ ipw, u16* __restrict__ ipwb,
    const float* __restrict__ projw, u16* __restrict__ pjwb,
    const float* __restrict__ Wq, const float* __restrict__ Wk,
    const float* __restrict__ opw, u16* __restrict__ S, u16* __restrict__ opwT)
{
    __shared__ float T[64][65];
    const size_t HH = (size_t)Hn * Hn;
    const int bid = blockIdx.x, tid = threadIdx.x;
    if (bid < PREP_NF2B) {
        const int n1 = (int)(3 * HH / 8), n2 = (int)(HH / 8);
        int i = bid * 256 + tid;
        const float* s; u16* d; int off;
        if (i < n1)           { s = ipw;   d = ipwb; off = i; }
        else if (i < n1 + n2) { s = projw; d = pjwb; off = i - n1; }
        else return;
        float4 a = reinterpret_cast<const float4*>(s)[off * 2];
        float4 b = reinterpret_cast<const float4*>(s)[off * 2 + 1];
        s16x8 o;
        o[0] = (short)f2bf(a.x); o[1] = (short)f2bf(a.y);
        o[2] = (short)f2bf(a.z); o[3] = (short)f2bf(a.w);
        o[4] = (short)f2bf(b.x); o[5] = (short)f2bf(b.y);
        o[6] = (short)f2bf(b.z); o[7] = (short)f2bf(b.w);
        reinterpret_cast<s16x8*>(d)[off] = o;
    } else if (bid < PREP_NF2B + PREP_NTR) {
        int b2 = bid - PREP_NF2B;
        int z = b2 / 144, r = b2 % 144;
        int bx = r % 12, by = r / 12;
        const float* src;
        u16* dst;
        if (z < 5)       { src = Wq + (size_t)z * HH;        dst = S + (size_t)z * HH; }
        else if (z < 10) { src = Wk + (size_t)(z - 5) * HH;  dst = S + (size_t)z * HH; }
        else             { src = opw;                         dst = opwT; }
        int i0 = bx * 64, o0 = by * 64;
        #pragma unroll
        for (int it = 0; it < 4; ++it) {
            int s = tid + 256 * it;
            int row = s >> 4, seg = s & 15;
            float4 v = *reinterpret_cast<const float4*>(
                src + (size_t)(o0 + row) * Hn + i0 + seg * 4);
            T[row][seg * 4 + 0] = v.x;
            T[row][seg * 4 + 1] = v.y;
            T[row][seg * 4 + 2] = v.z;
            T[row][seg * 4 + 3] = v.w;
        }
        __syncthreads();
        #pragma unroll
        for (int it = 0; it < 2; ++it) {
            int s = tid + 256 * it;
            int ri = s >> 3, c8 = s & 7;
            s16x8 o;
            #pragma unroll
            for (int e = 0; e < 8; ++e)
                o[e] = (short)f2bf(T[c8 * 8 + e][ri]);
            *reinterpret_cast<s16x8*>(dst + (size_t)(i0 + ri) * Hn + o0 + c8 * 8) = o;
        }
    }
}

// ---- TM x 128 triple-buffered counted-vmcnt NT GEMM core (256 thr) ----
template<int TM>
__device__ __forceinline__ void gemm_core(
    const u16* __restrict__ A, int lda,
    const u16* __restrict__ Bw, int ldb,
    const float* __restrict__ bias,
    const float* __restrict__ addres,
    u16* __restrict__ outH, float* __restrict__ outF,
    u16* __restrict__ outVT, int ldc,
    int m0, int n0, float scale)
{
    constexpr int MI = TM / 32;
    constexpr int AIT = TM / 64;
    __shared__ u16 As[3 * TM * 32];
    __shared__ u16 Bs[3 * 128 * 32];
    const int tid = threadIdx.x;
    const int lane = tid & 63, wave = tid >> 6;
    const int lrow = lane & 15, lquad = lane >> 4;
    const int wm = (wave >> 1) * (TM / 2), wn = (wave & 1) * 64;

    const u16* gA = A + (size_t)(m0 + (tid >> 2)) * lda + (tid & 3) * 8;
    const u16* gB = Bw + (size_t)(n0 + (tid >> 2)) * ldb + (tid & 3) * 8;

    f32x4 z = {0.f, 0.f, 0.f, 0.f};
    f32x4 acc[MI][4];
    #pragma unroll
    for (int i = 0; i < MI; ++i)
        #pragma unroll
        for (int j = 0; j < 4; ++j) acc[i][j] = z;

    auto stage = [&](int bs, int k0) {
        #pragma unroll
        for (int it = 0; it < AIT; ++it)
            glds16(gA + (size_t)(it * 64) * lda + k0, &As[bs * TM * 32 + (tid + 256 * it) * 8]);
        #pragma unroll
        for (int it = 0; it < 2; ++it)
            glds16(gB + (size_t)(it * 64) * ldb + k0, &Bs[bs * 128 * 32 + (tid + 256 * it) * 8]);
    };
    auto compute = [&](int bc) {
        const u16* Ab = &As[bc * TM * 32];
        const u16* Bb = &Bs[bc * 128 * 32];
        bf16x8 af[MI], bf_[4];
        #pragma unroll
        for (int i = 0; i < MI; ++i)
            af[i] = ld8(&Ab[(wm + i * 16 + lrow) * 32 + lquad * 8]);
        #pragma unroll
        for (int j = 0; j < 4; ++j)
            bf_[j] = ld8(&Bb[(wn + j * 16 + lrow) * 32 + lquad * 8]);
        #pragma unroll
        for (int i = 0; i < MI; ++i)
            #pragma unroll
            for (int j = 0; j < 4; ++j)
                acc[i][j] = __builtin_amdgcn_mfma_f32_16x16x32_bf16(af[i], bf_[j], acc[i][j], 0, 0, 0);
    };

    stage(0, 0);
    stage(1, 32);
    int bc = 0, bs = 2;
    for (int kt = 0; kt < 24; ++kt) {
        if (kt < 23) {
            if constexpr (TM == 256) {
                asm volatile("s_waitcnt vmcnt(6)" ::: "memory");
            } else {
                asm volatile("s_waitcnt vmcnt(4)" ::: "memory");
            }
        } else {
            asm volatile("s_waitcnt vmcnt(0)" ::: "memory");
        }
        __builtin_amdgcn_s_barrier();
        if (kt < 22) {
            stage(bs, (kt + 2) * 32);
            bs = (bs == 2) ? 0 : bs + 1;
        }
        compute(bc);
        bc = (bc == 2) ? 0 : bc + 1;
    }

    #pragma unroll
    for (int i = 0; i < MI; ++i) {
        #pragma unroll
        for (int j = 0; j < 4; ++j) {
            int col = n0 + wn + j * 16 + lrow;
            float bv = bias ? bias[col] : 0.f;
            if (outVT) {
                int row0 = m0 + wm + i * 16 + lquad * 4;
                int bb = row0 / Sn, s = row0 % Sn;
                int hh = col >> 6, dd = col & 63;
                u16x4 o;
                #pragma unroll
                for (int r = 0; r < 4; ++r) o[r] = f2bf((acc[i][j][r] + bv) * scale);
                *reinterpret_cast<u16x4*>(
                    outVT + (((size_t)bb * NHn + hh) * 64 + dd) * Sn + s) = o;
            } else {
                #pragma unroll
                for (int r = 0; r < 4; ++r) {
                    int row = m0 + wm + i * 16 + lquad * 4 + r;
                    float v = (acc[i][j][r] + bv) * scale;
                    if (addres) v += addres[(size_t)row * ldc + col];
                    if (outF) outF[(size_t)row * ldc + col] = v;
                    else      outH[(size_t)row * ldc + col] = f2bf(v);
                }
            }
        }
    }
}

// -- 64x64 triple-buffered counted-vmcnt NT GEMM core (256 thr), LDS passed in --
__device__ __forceinline__ void gemm64(
    u16* As, u16* Bs,
    const u16* __restrict__ A, const u16* __restrict__ Bw,
    const float* __restrict__ bias, const float* __restrict__ addres,
    u16* __restrict__ outH, float* __restrict__ outF,
    int m0, int n0)
{
    const int tid = threadIdx.x;
    const int lane = tid & 63, wave = tid >> 6;
    const int lrow = lane & 15, lquad = lane >> 4;
    const int wm = (wave >> 1) * 32, wn = (wave & 1) * 32;

    const u16* gA = A + (size_t)(m0 + (tid >> 2)) * Hn + (tid & 3) * 8;
    const u16* gB = Bw + (size_t)(n0 + (tid >> 2)) * Hn + (tid & 3) * 8;

    f32x4 z = {0.f, 0.f, 0.f, 0.f};
    f32x4 acc[2][2];
    #pragma unroll
    for (int i = 0; i < 2; ++i)
        #pragma unroll
        for (int j = 0; j < 2; ++j) acc[i][j] = z;

    auto stage = [&](int bs, int k0) {
        glds16(gA + k0, &As[bs * 64 * 32 + tid * 8]);
        glds16(gB + k0, &Bs[bs * 64 * 32 + tid * 8]);
    };
    auto compute = [&](int bc) {
        const u16* Ab = &As[bc * 64 * 32];
        const u16* Bb = &Bs[bc * 64 * 32];
        bf16x8 af[2], bf_[2];
        #pragma unroll
        for (int i = 0; i < 2; ++i)
            af[i] = ld8(&Ab[(wm + i * 16 + lrow) * 32 + lquad * 8]);
        #pragma unroll
        for (int j = 0; j < 2; ++j)
            bf_[j] = ld8(&Bb[(wn + j * 16 + lrow) * 32 + lquad * 8]);
        #pragma unroll
        for (int i = 0; i < 2; ++i)
            #pragma unroll
            for (int j = 0; j < 2; ++j)
                acc[i][j] = __builtin_amdgcn_mfma_f32_16x16x32_bf16(af[i], bf_[j], acc[i][j], 0, 0, 0);
    };

    stage(0, 0);
    stage(1, 32);
    int bc = 0, bs = 2;
    for (int kt = 0; kt < 24; ++kt) {
        if (kt < 23) {
            asm volatile("s_waitcnt vmcnt(2)" ::: "memory");
        } else {
            asm volatile("s_waitcnt vmcnt(0)" ::: "memory");
        }
        __builtin_amdgcn_s_barrier();
        if (kt < 22) {
            stage(bs, (kt + 2) * 32);
            bs = (bs == 2) ? 0 : bs + 1;
        }
        compute(bc);
        bc = (bc == 2) ? 0 : bc + 1;
    }

    #pragma unroll
    for (int i = 0; i < 2; ++i)
        #pragma unroll
        for (int j = 0; j < 2; ++j) {
            int col = n0 + wn + j * 16 + lrow;
            float bv = bias ? bias[col] : 0.f;
            #pragma unroll
            for (int r = 0; r < 4; ++r) {
                int row_ = m0 + wm + i * 16 + lquad * 4 + r;
                float v = acc[i][j][r] + bv;
                if (addres) v += addres[(size_t)row_ * Hn + col];
                if (outF) outF[(size_t)row_ * Hn + col] = v;
                else      outH[(size_t)row_ * Hn + col] = f2bf(v);
            }
        }
}

// ---- 64x64 tile helpers (256 thr): identity write, copy, transposing copy ----
static __device__ __forceinline__ void ident64(u16* dst, int m0, int n0)
{
    const int tid = threadIdx.x;
    #pragma unroll
    for (int it = 0; it < 2; ++it) {
        int s = tid + 256 * it;
        int ri = s >> 3, c8 = s & 7;
        s16x8 v;
        #pragma unroll
        for (int e = 0; e < 8; ++e)
            v[e] = (short)((m0 + ri == n0 + c8 * 8 + e) ? 0x3F80 : 0);
        *reinterpret_cast<s16x8*>(dst + (size_t)(m0 + ri) * Hn + n0 + c8 * 8) = v;
    }
}
static __device__ __forceinline__ void copy64(u16* dst, const u16* src, int m0, int n0)
{
    const int tid = threadIdx.x;
    #pragma unroll
    for (int it = 0; it < 2; ++it) {
        int s = tid + 256 * it;
        int row = s >> 3, seg = s & 7;
        *reinterpret_cast<s16x8*>(dst + (size_t)(m0 + row) * Hn + n0 + seg * 8) =
            *reinterpret_cast<const s16x8*>(src + (size_t)(m0 + row) * Hn + n0 + seg * 8);
    }
}
// dst = src^T: dst tile (m0,n0) <- src tile (n0,m0) transposed.  lds >= 64*72 u16
static __device__ __forceinline__ void tcopy64(u16* dst, const u16* src, int m0, int n0, u16* lds)
{
    u16 (*T)[72] = reinterpret_cast<u16(*)[72]>(lds);
    const int tid = threadIdx.x;
    #pragma unroll
    for (int it = 0; it < 2; ++it) {
        int s = tid + 256 * it;
        int rr = s >> 3, c8 = s & 7;
        s16x8 v = *reinterpret_cast<const s16x8*>(
            src + (size_t)(n0 + rr) * Hn + m0 + c8 * 8);
        #pragma unroll
        for (int e = 0; e < 8; ++e) T[c8 * 8 + e][rr] = (u16)v[e];
    }
    __syncthreads();
    #pragma unroll
    for (int it = 0; it < 2; ++it) {
        int s = tid + 256 * it;
        int ri = s >> 3, c8 = s & 7;
        *reinterpret_cast<s16x8*>(dst + (size_t)(m0 + ri) * Hn + n0 + c8 * 8) =
            *reinterpret_cast<const s16x8*>(&T[ri][c8 * 8]);
    }
}

// ---------------- GEMM wrapper kernels ----------------

// comb + aux backfill.  flat grid 3774 blocks.
__global__ __launch_bounds__(256) void k_comb_aux(
    const u16* __restrict__ ipwb, u16* __restrict__ S,
    const float* __restrict__ hidden, u16* __restrict__ hb,
    const float* __restrict__ ipw, const float* __restrict__ ipb,
    const float* __restrict__ bq_lang, const float* __restrict__ bk_lang,
    float* __restrict__ beff)
{
    __shared__ u16 As[3 * 64 * 32];
    __shared__ u16 Bs[3 * 64 * 32];
    const size_t HH = (size_t)Hn * Hn;
    const int bid = blockIdx.x, tid = threadIdx.x;
    if (bid < 1440) {
        int z = bid / 144, r = bid % 144;
        const u16* Aop = ipwb + (z < 5 ? 0 : HH);
        gemm64(As, Bs, Aop, S + (size_t)z * HH, nullptr, nullptr,
               S + (size_t)(10 + z) * HH, nullptr,
               (r % 12) * 64, (r / 12) * 64);
    } else if (bid < 3744) {
        int i = (bid - 1440) * 256 + tid;          // 589824 threads
        float4 a = reinterpret_cast<const float4*>(hidden)[i * 2];
        float4 b = reinterpret_cast<const float4*>(hidden)[i * 2 + 1];
        s16x8 o;
        o[0] = (short)f2bf(a.x); o[1] = (short)f2bf(a.y);
        o[2] = (short)f2bf(a.z); o[3] = (short)f2bf(a.w);
        o[4] = (short)f2bf(b.x); o[5] = (short)f2bf(b.y);
        o[6] = (short)f2bf(b.z); o[7] = (short)f2bf(b.w);
        reinterpret_cast<s16x8*>(hb)[i] = o;
    } else {
        int b3 = bid - 3744;                       // 0..29
        int ox = b3 % 3, y = b3 / 3;
        int o = ox * 256 + tid;
        int which = y / 5, l = y % 5;
        const float4* w = reinterpret_cast<const float4*>(ipw + (size_t)which * HH + (size_t)o * Hn);
        const float4* bv = reinterpret_cast<const float4*>(((which ? bk_lang : bq_lang) + (size_t)l * Hn));
        float s = 0.f;
        for (int j = 0; j < Hn / 4; ++j) {
            float4 a = w[j], b = bv[j];
            s += a.x * b.x + a.y * b.y + a.z * b.z + a.w * b.w;
        }
        s += ipb[which * Hn + o];
        beff[(size_t)(which * 5 + l) * Hn + o] = s;
    }
}

// fused QKV projection, 256-row tiles (432 blocks -> ONE generation at 2/CU).
__global__ __launch_bounds__(256, 2) void k_gemm_qkv(
    const u16* __restrict__ A,
    const u16* __restrict__ Sq, const u16* __restrict__ Sk,
    const u16* __restrict__ Wv,
    const float* __restrict__ beff, const float* __restrict__ ipb,
    const int* __restrict__ lang,
    u16* __restrict__ outQ, u16* __restrict__ outK, u16* __restrict__ outVT)
{
    const size_t HH = (size_t)Hn * Hn;
    int z = blockIdx.z;
    int m0 = blockIdx.x * 256, n0 = blockIdx.y * 128;
    int l = lang[blockIdx.x / 3];
    if (z == 0) {
        gemm_core<256>(A, Hn, Sq + (size_t)l * HH, Hn, beff + (size_t)l * Hn,
                       nullptr, outQ, nullptr, nullptr, Hn, m0, n0, 0.125f);
    } else if (z == 1) {
        gemm_core<256>(A, Hn, Sk + (size_t)l * HH, Hn, beff + (size_t)(5 + l) * Hn,
                       nullptr, outK, nullptr, nullptr, Hn, m0, n0, 1.f);
    } else {
        gemm_core<256>(A, Hn, Wv, Hn, ipb + 2 * Hn,
                       nullptr, nullptr, nullptr, outVT, Hn, m0, n0, 1.f);
    }
}

// ---------------- chain tree ----------------
// MT_l = S7^T S6^T ... S0^T;  S_j = (lang[j]==l) ? I : align[l, lang[j]].

// L1.  grid (12,12,20)
__global__ __launch_bounds__(256) void k_chainL1(
    const u16* __restrict__ alignb, const u16* __restrict__ alignbT,
    const int* __restrict__ lang, u16* __restrict__ N1)
{
    __shared__ u16 As[3 * 64 * 32];
    __shared__ u16 Bs[3 * 64 * 32];
    const size_t HH = (size_t)Hn * Hn;
    int idx = blockIdx.z, l = idx >> 2, node = idx & 3;
    int ja = 7 - node * 2, jb = 6 - node * 2;
    bool tr = node & 1;
    int la = lang[ja], lb = lang[jb];
    bool sa = (la == l), sb = (lb == l);
    u16* dst = N1 + (size_t)idx * HH;
    int m0 = blockIdx.x * 64, n0 = blockIdx.y * 64;
    if (sa && sb) {
        ident64(dst, m0, n0);
    } else if (sa) {
        copy64(dst, (tr ? alignb : alignbT) + ((size_t)l * NLn + lb) * HH, m0, n0);
    } else if (sb) {
        copy64(dst, (tr ? alignb : alignbT) + ((size_t)l * NLn + la) * HH, m0, n0);
    } else if (!tr) {  // straight: Fa^T * Fb^T = NT(FaT, Fb)
        gemm64(As, Bs, alignbT + ((size_t)l * NLn + la) * HH,
               alignb + ((size_t)l * NLn + lb) * HH,
               nullptr, nullptr, dst, nullptr, m0, n0);
    } else {           // transposed: Fb * Fa = NT(Fb, FaT)
        gemm64(As, Bs, alignb + ((size_t)l * NLn + lb) * HH,
               alignbT + ((size_t)l * NLn + la) * HH,
               nullptr, nullptr, dst, nullptr, m0, n0);
    }
}

// L2.  grid (12,12,10): z = l*2 + q.  Q_a -> Q2[l], Q_bT -> Q2[5+l]
__global__ __launch_bounds__(256) void k_chainL2(
    const u16* __restrict__ N1, const int* __restrict__ lang,
    u16* __restrict__ Q2)
{
    __shared__ u16 As[3 * 64 * 32];
    __shared__ u16 Bs[3 * 64 * 32];
    const size_t HH = (size_t)Hn * Hn;
    int idx = blockIdx.z, l = idx >> 1, q = idx & 1;
    int m0 = blockIdx.x * 64, n0 = blockIdx.y * 64;
    const u16* Pa  = N1 + (size_t)(l * 4 + 0) * HH;
    const u16* PbT = N1 + (size_t)(l * 4 + 1) * HH;
    const u16* Pc  = N1 + (size_t)(l * 4 + 2) * HH;
    const u16* PdT = N1 + (size_t)(l * 4 + 3) * HH;
    if (q == 0) {
        u16* dst = Q2 + (size_t)l * HH;
        bool ia = (lang[7] == l) && (lang[6] == l);
        bool ib = (lang[5] == l) && (lang[4] == l);
        if (ia && ib)      ident64(dst, m0, n0);
        else if (ia)       tcopy64(dst, PbT, m0, n0, As);
        else if (ib)       copy64(dst, Pa, m0, n0);
        else               gemm64(As, Bs, Pa, PbT, nullptr, nullptr, dst, nullptr, m0, n0);
    } else {
        u16* dst = Q2 + (size_t)(5 + l) * HH;
        bool ic = (lang[3] == l) && (lang[2] == l);
        bool id = (lang[1] == l) && (lang[0] == l);
        if (ic && id)      ident64(dst, m0, n0);
        else if (ic)       copy64(dst, PdT, m0, n0);
        else if (id)       tcopy64(dst, Pc, m0, n0, As);
        else               gemm64(As, Bs, PdT, Pc, nullptr, nullptr, dst, nullptr, m0, n0);
    }
}

// L3.  grid (12,12,5): MT_l = Q_a * Q_b = NT(Q_a, Q_bT)
__global__ __launch_bounds__(256) void k_chainL3(
    const u16* __restrict__ Q2, const int* __restrict__ lang,
    u16* __restrict__ MT)
{
    __shared__ u16 As[3 * 64 * 32];
    __shared__ u16 Bs[3 * 64 * 32];
    const size_t HH = (size_t)Hn * Hn;
    int l = blockIdx.z;
    int m0 = blockIdx.x * 64, n0 = blockIdx.y * 64;
    const u16* Qa  = Q2 + (size_t)l * HH;
    const u16* QbT = Q2 + (size_t)(5 + l) * HH;
    u16* dst = MT + (size_t)l * HH;
    bool iA = (lang[7] == l) && (lang[6] == l) && (lang[5] == l) && (lang[4] == l);
    bool iB = (lang[3] == l) && (lang[2] == l) && (lang[1] == l) && (lang[0] == l);
    if (iA && iB)      ident64(dst, m0, n0);
    else if (iA)       tcopy64(dst, QbT, m0, n0, As);
    else if (iB)       copy64(dst, Qa, m0, n0);
    else               gemm64(As, Bs, Qa, QbT, nullptr, nullptr, dst, nullptr, m0, n0);
}

// U_l = NT(opwT, MT_l) + opb_eff GEMV.  grid 735.
__global__ __launch_bounds__(256) void k_uop(
    const u16* __restrict__ opwT, const u16* __restrict__ MT,
    const float* __restrict__ opb,
    u16* __restrict__ U5, float* __restrict__ opbeff)
{
    __shared__ u16 As[3 * 64 * 32];
    __shared__ u16 Bs[3 * 64 * 32];
    const size_t HH = (size_t)Hn * Hn;
    int bid = blockIdx.x;
    if (bid < 720) {
        int z = bid / 144, r = bid % 144;
        gemm64(As, Bs, opwT, MT + (size_t)z * HH, nullptr, nullptr,
               U5 + (size_t)z * HH, nullptr,
               (r % 12) * 64, (r / 12) * 64);
    } else {
        int b2 = bid - 720;
        int n = (b2 % 3) * 256 + threadIdx.x;
        int l = b2 / 3;
        const u16* mt = MT + ((size_t)l * Hn + n) * Hn;
        float s = 0.f;
        for (int k = 0; k < Hn; k += 8) {
            s16x8 v = *reinterpret_cast<const s16x8*>(mt + k);
            #pragma unroll
            for (int jq = 0; jq < 8; ++jq) s += opb[k + jq] * bf2f((u16)v[jq]);
        }
        opbeff[(size_t)l * Hn + n] = s;
    }
}

// W_l = NT(projw, U_l) + bias2 GEMV.  grid 735.
__global__ __launch_bounds__(256) void k_wb2(
    const u16* __restrict__ pjwb, const u16* __restrict__ U5,
    const float* __restrict__ opbeff, const float* __restrict__ projw,
    const float* __restrict__ projb,
    u16* __restrict__ W5, float* __restrict__ bias2)
{
    __shared__ u16 As[3 * 64 * 32];
    __shared__ u16 Bs[3 * 64 * 32];
    const size_t HH = (size_t)Hn * Hn;
    int bid = blockIdx.x;
    if (bid < 720) {
        int z = bid / 144, r = bid % 144;
        gemm64(As, Bs, pjwb, U5 + (size_t)z * HH, nullptr, nullptr,
               W5 + (size_t)z * HH, nullptr,
               (r % 12) * 64, (r / 12) * 64);
    } else {
        int b2 = bid - 720;
        int m = (b2 % 3) * 256 + threadIdx.x;
        int l = b2 / 3;
        const float4* w = reinterpret_cast<const float4*>(projw + (size_t)m * Hn);
        const float4* ob = reinterpret_cast<const float4*>(opbeff + (size_t)l * Hn);
        float s = 0.f;
        for (int jq = 0; jq < Hn / 4; ++jq) {
            float4 a = w[jq], b = ob[jq];
            s += a.x * b.x + a.y * b.y + a.z * b.z + a.w * b.w;
        }
        bias2[(size_t)l * Hn + m] = s + projb[m];
    }
}

// x = NT(ctx, W[lang]) + bias2[lang] + hidden -> f32 out.  64^2 tiles, grid (96,12)
__global__ __launch_bounds__(256) void k_xfused(
    const u16* __restrict__ ctx, const u16* __restrict__ W5,
    const float* __restrict__ bias2, const int* __restrict__ lang,
    const float* __restrict__ hidden, float* __restrict__ x)
{
    __shared__ u16 As[3 * 64 * 32];
    __shared__ u16 Bs[3 * 64 * 32];
    int l = lang[blockIdx.x / 12];
    gemm64(As, Bs, ctx, W5 + (size_t)l * Hn * Hn, bias2 + (size_t)l * Hn,
           hidden, nullptr, x,
           blockIdx.x * 64, blockIdx.y * 64);
}

// ---------------- flash attention + align conversion, 512 threads ----------
// blocks [0,576): attn.  blocks [576, 1476): align conversion, 4 tiles per
// block (deep grid-stride) — stage f32 tile ONCE, write alignb + alignbT.
__global__ __launch_bounds__(512) void k_attn_conv(
    const u16* __restrict__ Q, const u16* __restrict__ K,
    const u16* __restrict__ VT, u16* __restrict__ ctx,
    const float* __restrict__ alignf, u16* __restrict__ alignb,
    u16* __restrict__ alignbT)
{
    __shared__ u16 Ks[2][64 * 64];       // [key][d], seg-xor-swizzled
    __shared__ u16 Vs[2][64 * 64];       // [d][key], seg-xor-swizzled
    __shared__ u16 Pw[8][16 * 72];       // per-wave P; conv: f32 T[64][65]

    const int bid = blockIdx.x, tid = threadIdx.x;
    const size_t HH = (size_t)Hn * Hn;
    if (bid >= 576) {
        float (*T)[65] = reinterpret_cast<float(*)[65]>(&Pw[0][0]);
        const int row = tid >> 3, c8 = tid & 7;
        #pragma unroll
        for (int tt = 0; tt < 4; ++tt) {
            int t = (bid - 576) * 4 + tt;        // 0..3599
            int mat = t / 144, r = t % 144;
            int i0 = (r % 12) * 64, o0 = (r / 12) * 64;
            const float* src = alignf + (size_t)mat * HH;
            const float* p = src + (size_t)(o0 + row) * Hn + i0 + c8 * 8;
            float4 a = *reinterpret_cast<const float4*>(p);
            float4 b = *reinterpret_cast<const float4*>(p + 4);
            s16x8 o;
            o[0] = (short)f2bf(a.x); o[1] = (short)f2bf(a.y);
            o[2] = (short)f2bf(a.z); o[3] = (short)f2bf(a.w);
            o[4] = (short)f2bf(b.x); o[5] = (short)f2bf(b.y);
            o[6] = (short)f2bf(b.z); o[7] = (short)f2bf(b.w);
            *reinterpret_cast<s16x8*>(
                alignb + (size_t)mat * HH + (size_t)(o0 + row) * Hn + i0 + c8 * 8) = o;
            T[row][c8 * 8 + 0] = a.x; T[row][c8 * 8 + 1] = a.y;
            T[row][c8 * 8 + 2] = a.z; T[row][c8 * 8 + 3] = a.w;
            T[row][c8 * 8 + 4] = b.x; T[row][c8 * 8 + 5] = b.y;
            T[row][c8 * 8 + 6] = b.z; T[row][c8 * 8 + 7] = b.w;
            __syncthreads();
            s16x8 ot;
            #pragma unroll
            for (int e = 0; e < 8; ++e)
                ot[e] = (short)f2bf(T[c8 * 8 + e][row]);
            *reinterpret_cast<s16x8*>(
                alignbT + (size_t)mat * HH + (size_t)(i0 + row) * Hn + o0 + c8 * 8) = ot;
            __syncthreads();                     // LDS reuse guard
        }
        return;
    }

    const int q0 = (bid % 6) * 128, h = (bid / 6) % NHn, bz = bid / 72;
    const int wave = tid >> 6, lane = tid & 63;
    const int lrow = lane & 15, lquad = lane >> 4;
    const int sw = lrow & 7;

    const u16* Qp = Q + ((size_t)(bz * Sn + q0 + wave * 16 + lrow)) * Hn + h * HDn;
    const u16* Kb = K + (size_t)bz * Sn * Hn + h * HDn;
    const u16* Vb = VT + ((size_t)(bz * NHn + h) * 64) * Sn;   // row d, stride Sn

    bf16x8 qa0 = ld8(Qp + lquad * 8);
    bf16x8 qa1 = ld8(Qp + 32 + lquad * 8);

    f32x4 z4 = {0.f, 0.f, 0.f, 0.f};
    float m_r[4], l_l[4];
    f32x4 oacc[4];
    #pragma unroll
    for (int r = 0; r < 4; ++r) { m_r[r] = -1e30f; l_l[r] = 0.f; }
    #pragma unroll
    for (int jd = 0; jd < 4; ++jd) oacc[jd] = z4;

    const int krow = tid >> 3, kp = (tid & 7) ^ (krow & 7);
    const u16* kg = Kb + (size_t)krow * Hn + kp * 8;
    const u16* vg = Vb + (size_t)krow * Sn + kp * 8;

    auto stage = [&](int bs, int t0) {
        glds16(kg + (size_t)t0 * Hn, &Ks[bs][tid * 8]);
        glds16(vg + t0, &Vs[bs][tid * 8]);
    };

    auto compute = [&](int bc) {
        f32x4 sc[4];
        __builtin_amdgcn_s_setprio(1);
        #pragma unroll
        for (int j = 0; j < 4; ++j) {
            int base = (j * 16 + lrow) * 64 + ((lquad ^ sw) * 8);
            f32x4 s = __builtin_amdgcn_mfma_f32_16x16x32_bf16(qa0, ld8(&Ks[bc][base]), z4, 0, 0, 0);
            sc[j] = __builtin_amdgcn_mfma_f32_16x16x32_bf16(qa1, ld8(&Ks[bc][base ^ 32]), s, 0, 0, 0);
        }
        __builtin_amdgcn_s_setprio(0);
        float tmax[4];
        #pragma unroll
        for (int r = 0; r < 4; ++r)
            tmax[r] = fmaxf(fmaxf(sc[0][r], sc[1][r]), fmaxf(sc[2][r], sc[3][r]));
        #pragma unroll
        for (int off = 1; off < 16; off <<= 1)
            #pragma unroll
            for (int r = 0; r < 4; ++r)
                tmax[r] = fmaxf(tmax[r], __shfl_xor(tmax[r], off));
        bool grow = (tmax[0] > m_r[0] + 8.f) | (tmax[1] > m_r[1] + 8.f) |
                    (tmax[2] > m_r[2] + 8.f) | (tmax[3] > m_r[3] + 8.f);
        if (grow) {
            #pragma unroll
            for (int r = 0; r < 4; ++r) {
                float mn = fmaxf(m_r[r], tmax[r]);
                float a = __expf(m_r[r] - mn);
                m_r[r] = mn;
                l_l[r] *= a;
                #pragma unroll
                for (int jd = 0; jd < 4; ++jd) oacc[jd][r] *= a;
            }
        }
        float ps[4] = {0.f, 0.f, 0.f, 0.f};
        #pragma unroll
        for (int j = 0; j < 4; ++j)
            #pragma unroll
            for (int r = 0; r < 4; ++r) {
                float p = __expf(sc[j][r] - m_r[r]);
                ps[r] += p;
                Pw[wave][(lquad * 4 + r) * 72 + j * 16 + lrow] = f2bf(p);
            }
        #pragma unroll
        for (int r = 0; r < 4; ++r) l_l[r] += ps[r];
        bf16x8 pa0 = ld8(&Pw[wave][lrow * 72 + lquad * 8]);
        bf16x8 pa1 = ld8(&Pw[wave][lrow * 72 + 32 + lquad * 8]);
        __builtin_amdgcn_s_setprio(1);
        #pragma unroll
        for (int jd = 0; jd < 4; ++jd) {
            int vbase = (jd * 16 + lrow) * 64 + ((lquad ^ sw) * 8);
            oacc[jd] = __builtin_amdgcn_mfma_f32_16x16x32_bf16(pa0, ld8(&Vs[bc][vbase]), oacc[jd], 0, 0, 0);
            oacc[jd] = __builtin_amdgcn_mfma_f32_16x16x32_bf16(pa1, ld8(&Vs[bc][vbase ^ 32]), oacc[jd], 0, 0, 0);
        }
        __builtin_amdgcn_s_setprio(0);
    };

    stage(0, 0);
    stage(1, 64);
    for (int kt = 0; kt < 12; ++kt) {
        if (kt < 11) {
            asm volatile("s_waitcnt vmcnt(2)" ::: "memory");
        } else {
            asm volatile("s_waitcnt vmcnt(0)" ::: "memory");
        }
        __builtin_amdgcn_s_barrier();
        compute(kt & 1);
        if (kt < 10) {
            __builtin_amdgcn_s_barrier();
            stage(kt & 1, (kt + 2) * 64);
        }
    }

    #pragma unroll
    for (int off = 1; off < 16; off <<= 1)
        #pragma unroll
        for (int r = 0; r < 4; ++r)
            l_l[r] += __shfl_xor(l_l[r], off);

    float rl[4];
    #pragma unroll
    for (int r = 0; r < 4; ++r) rl[r] = 1.f / l_l[r];
    #pragma unroll
    for (int jd = 0; jd < 4; ++jd)
        #pragma unroll
        for (int r = 0; r < 4; ++r) {
            size_t row = (size_t)bz * Sn + q0 + wave * 16 + lquad * 4 + r;
            ctx[row * Hn + h * HDn + jd * 16 + lrow] = f2bf(oacc[jd][r] * rl[r]);
        }
}

// layernorm in-place on f32 d_out.  256 thr = 4 waves, one row per wave.
// grid B*S/4 = 1536.
__global__ __launch_bounds__(256) void k_ln(
    float* x, const float* __restrict__ g, const float* __restrict__ beta)
{
    int wave = threadIdx.x >> 6, lane = threadIdx.x & 63;
    size_t row = (size_t)blockIdx.x * 4 + wave;
    float* xr = x + row * Hn;
    float v[12];
    float s = 0.f, ss = 0.f;
    #pragma unroll
    for (int i = 0; i < 12; ++i) {
        v[i] = xr[lane + i * 64];
        s += v[i];
        ss += v[i] * v[i];
    }
    #pragma unroll
    for (int off = 1; off < 64; off <<= 1) {
        s  += __shfl_xor(s, off);
        ss += __shfl_xor(ss, off);
    }
    float mu = s * (1.f / Hn);
    float var = ss * (1.f / Hn) - mu * mu;
    float inv = rsqrtf(var + 1e-5f);
    #pragma unroll
    for (int i = 0; i < 12; ++i) {
        int c = lane + i * 64;
        xr[c] = (v[i] - mu) * inv * g[c] + beta[c];
    }
}

// ---------------- launch ----------------
extern "C" void kernel_launch(void* const* d_in, const int* in_sizes, int n_in,
                              void* d_out, int out_size, void* d_ws, size_t ws_size,
                              hipStream_t stream)
{
    (void)in_sizes; (void)n_in; (void)out_size; (void)ws_size;

    const float* hidden  = (const float*)d_in[0];
    const int*   lang    = (const int*)d_in[1];
    const float* Wq_lang = (const float*)d_in[3];
    const float* bq_lang = (const float*)d_in[4];
    const float* Wk_lang = (const float*)d_in[5];
    const float* bk_lang = (const float*)d_in[6];
    const float* ipw     = (const float*)d_in[7];
    const float* ipb     = (const float*)d_in[8];
    const float* opw     = (const float*)d_in[9];
    const float* opb     = (const float*)d_in[10];
    const float* align   = (const float*)d_in[11];
    const float* projw   = (const float*)d_in[12];
    const float* projb   = (const float*)d_in[13];
    const float* ln_g    = (const float*)d_in[14];
    const float* ln_b    = (const float*)d_in[15];
    float* out = (float*)d_out;

    const size_t HH  = (size_t)Hn * Hn;          // 589824
    const size_t BSH = (size_t)Bn * Sn * Hn;     // 4718592 = 8*HH
    const size_t AHH = (size_t)NLn * NLn * HH;   // 25*HH

    u16* rA = (u16*)d_ws;        // hb -> ctx
    u16* rB = rA + BSH;          // Q -> N1 slots 0..7
    u16* rC = rB + BSH;          // K -> N1 slots 8..15
    u16* rD = rC + BSH;          // V^T -> N1 slots 16..19
    u16* ipwb = rD + BSH;        // wq|wk|wv bf16 (3*HH)
    u16* pjwb = ipwb + 3 * HH;   // HH
    u16* opwT = pjwb + HH;       // HH
    u16* alignb = opwT + HH;     // 25*HH; pre-attn: weight scratch S[0..20)
                                 // post-L2: MT[0..5) U[5..10) W[10..15)
    u16* alignbT = alignb + AHH; // 25*HH transposed aligns (written by attn_conv);
                                 // post-L1: Q2[0..10)
    float* beff   = (float*)(alignbT + AHH);  // 2*5*768 f32
    float* opbeff = beff + 10 * Hn;           // 5*768 f32
    float* bias2  = opbeff + 5 * Hn;          // 5*768 f32

    u16* S = alignb;             // scratch: WqT[0..5) WkT[5..10) Weffq[10..15) Weffk[15..20)
    u16* N1 = rB;                // 20 node matrices (rB..rD contiguous)
    u16* Q2 = alignbT;           // 10 node matrices (alignbT dead after L1)
    u16* MT = alignb;            // 5 (alignb dead after L1)
    u16* U5 = alignb + 5 * HH;   // 5
    u16* W5 = alignb + 10 * HH;  // 5

    // prep: weight conversions + 11 transposes (Wq/Wk/opw)
    k_prep<<<(unsigned)(PREP_NF2B + PREP_NTR), 256, 0, stream>>>(
        ipw, ipwb, projw, pjwb, Wq_lang, Wk_lang, opw, S, opwT);

    // Weffq/Weffk GEMMs + hidden f32->bf16 backfill + QK bias folds (one launch)
    k_comb_aux<<<3774, 256, 0, stream>>>(
        ipwb, S, hidden, rA, ipw, ipb, bq_lang, bk_lang, beff);

    // fused QKV: Q*(1/8) -> rB, K -> rC, V^T -> rD.  256-row tiles, 1 generation.
    k_gemm_qkv<<<dim3(24, 6, 3), 256, 0, stream>>>(
        rA, S + 10 * HH, S + 15 * HH, ipwb + 2 * HH, beff, ipb, lang, rB, rC, rD);

    // attention (ctx -> rA) + align f32 staged ONCE -> alignb + alignbT
    // (S scratch dead once qkv completes); conv tail 900 deep blocks x 4 tiles
    k_attn_conv<<<1476, 512, 0, stream>>>(rB, rC, rD, rA, align, alignb, alignbT);

    // chain tree: 3 launches replace 8 sequential chain steps
    k_chainL1<<<dim3(12, 12, 20), 256, 0, stream>>>(alignb, alignbT, lang, N1);
    k_chainL2<<<dim3(12, 12, 10), 256, 0, stream>>>(N1, lang, Q2);
    k_chainL3<<<dim3(12, 12, 5), 256, 0, stream>>>(Q2, lang, MT);

    // U_l = opw^T . M_l  (+ opb_eff GEMV)
    k_uop<<<735, 256, 0, stream>>>(opwT, MT, opb, U5, opbeff);
    // W_l = projw . U_l  (+ bias2 GEMV)
    k_wb2<<<735, 256, 0, stream>>>(pjwb, U5, opbeff, projw, projb, W5, bias2);

    // x = ctx . W[lang]^T + bias2 + hidden -> d_out (f32).  64^2 tiles.
    k_xfused<<<dim3(96, 12), 256, 0, stream>>>(rA, W5, bias2, lang, hidden, out);
    // layernorm in place (4 rows per 256-thr block)
    k_ln<<<(unsigned)(Bn * Sn / 4), 256, 0, stream>>>(out, ln_g, ln_b);
}